// Round 1
// baseline (5467.964 us; speedup 1.0000x reference)
//
#include <hip/hip_runtime.h>
#include <math.h>

// OptionCompareCell: B=64,C=4,LO=64,LQ=128,H=768
// Stage plan (round 0, f32 SIMT baseline):
//  K_dot768   : per-token scalar projections (attW1/attW2/Va/coW1/coW2/saW1/saW2)
//  K_attctx<3>: pairwise trilinear att + softmax(u) + ctx, summed over j -> CS
//  GEMM ep=TANH : OCK = tanh([o1|3o1-CS|o1*CS] @ [Wc_self;Wc_hi;Wc_lo] + bias)
//  K_qpool    : Q = softmax(q@Va)^T q   ;  GEMM ep=STORE: Qg = Q@Wg3 + Wg_b
//  GEMM ep=MERGE: G=sig([o1|OCK]@Wg12 + Qg); merged = G*o1+(1-G)*OCK
//  K_a2 / K_poaa: co-attention -> PLO, PHI  (OA eliminated via M2 = APK^T ACK)
//  GEMM ep=RELU : OPK = relu([merged|PLO|PHI] @ Wp + b)
//  K_attctx<1>: self-att -> OSK
//  GEMM ep=RELU_MAX: out = max_lo relu([OPK|OSK|OPK-OSK|OPK*OSK] @ Wf + b)

#define NEGC (-10000.0f)
constexpr int HD = 768;

constexpr int EP_STORE = 0;
constexpr int EP_TANH = 1;
constexpr int EP_MERGE = 2;
constexpr int EP_RELU = 3;
constexpr int EP_RELU_MAX = 4;

__device__ inline void st8(float* dst, float4 a0, float4 a1) {
  dst[0] = a0.x; dst[1] = a0.y; dst[2] = a0.z; dst[3] = a0.w;
  dst[4] = a1.x; dst[5] = a1.y; dst[6] = a1.z; dst[7] = a1.w;
}

// ---------------- per-token dot with a [768] vector + scalar bias ----------------
__global__ __launch_bounds__(256)
void dot768_kernel(const float* __restrict__ x, const float* __restrict__ w,
                   const float* __restrict__ bias, float* __restrict__ out, int ntok) {
  int tok = blockIdx.x * 4 + (threadIdx.x >> 6);
  int lane = threadIdx.x & 63;
  if (tok >= ntok) return;
  const float* xp = x + (size_t)tok * HD;
  float s = 0.f;
#pragma unroll
  for (int i = 0; i < 3; ++i) {
    int c = (lane + (i << 6)) << 2;
    float4 xv = *(const float4*)(xp + c);
    float4 wv = *(const float4*)(w + c);
    s = fmaf(xv.x, wv.x, s); s = fmaf(xv.y, wv.y, s);
    s = fmaf(xv.z, wv.z, s); s = fmaf(xv.w, wv.w, s);
  }
#pragma unroll
  for (int off = 32; off; off >>= 1) s += __shfl_xor(s, off);
  if (lane == 0) out[tok] = s + bias[0];
}

__global__ void bias_ock_kernel(const float* __restrict__ b1, const float* __restrict__ b2,
                                float* __restrict__ o) {
  int n = blockIdx.x * 256 + threadIdx.x;
  if (n < HD) o[n] = b1[n] + 3.f * b2[n];
}

// --------- trilinear attention + softmax(axis u) + ctx; NJ=3: sum_j -> CS ; NJ=1: OSK ---------
template<int NJ>
__global__ __launch_bounds__(256)
void attctx_kernel(const float* __restrict__ X, const float* __restrict__ s1g,
                   const float* __restrict__ s2g, const int* __restrict__ maskg,
                   const float* __restrict__ w3, float* __restrict__ outg) {
  __shared__ float A[64][65];
  __shared__ float Ut[64][33];
  __shared__ float Vt[64][33];
  __shared__ float red[4][64];
  __shared__ float colinv[64];

  const int t = threadIdx.x;
  const int blk = blockIdx.x;          // bc = b*4+i
  const int b = blk >> 2, i = blk & 3;
  const float* V = X + (size_t)blk * (64 * HD);
  const float* s2 = s2g + blk * 64;
  const int* mv = maskg + blk * 64;
  float* out = outg + (size_t)blk * (64 * HD);
  const int tr = t >> 4, tc = t & 15;
  const int lrow = t >> 2, lcs = (t & 3) << 3;

  float s2v[4];
#pragma unroll
  for (int y = 0; y < 4; ++y) {
    int v = (tc << 2) + y;
    s2v[y] = s2[v] + (1.f - (float)mv[v]) * NEGC;
  }

  for (int jj = 0; jj < NJ; ++jj) {
    const int jidx = (NJ == 1) ? i : (jj + (jj >= i ? 1 : 0));
    const float* U = X + (size_t)((b << 2) + jidx) * (64 * HD);
    const float* s1 = s1g + ((b << 2) + jidx) * 64;
    const int* mu = maskg + ((b << 2) + jidx) * 64;

    float acc[4][4];
#pragma unroll
    for (int x = 0; x < 4; ++x)
#pragma unroll
      for (int y = 0; y < 4; ++y) acc[x][y] = 0.f;

    for (int k0 = 0; k0 < HD; k0 += 32) {
      const float* up = U + (size_t)lrow * HD + k0 + lcs;
      const float* vp = V + (size_t)lrow * HD + k0 + lcs;
      float4 u0 = *(const float4*)up;
      float4 u1 = *(const float4*)(up + 4);
      float4 w0 = *(const float4*)(w3 + k0 + lcs);
      float4 w1 = *(const float4*)(w3 + k0 + lcs + 4);
      float4 v0 = *(const float4*)vp;
      float4 v1 = *(const float4*)(vp + 4);
      u0.x *= w0.x; u0.y *= w0.y; u0.z *= w0.z; u0.w *= w0.w;
      u1.x *= w1.x; u1.y *= w1.y; u1.z *= w1.z; u1.w *= w1.w;
      st8(&Ut[lrow][lcs], u0, u1);
      st8(&Vt[lrow][lcs], v0, v1);
      __syncthreads();
#pragma unroll
      for (int kk = 0; kk < 32; ++kk) {
        float av[4], bv[4];
#pragma unroll
        for (int x = 0; x < 4; ++x) av[x] = Ut[(tr << 2) + x][kk];
#pragma unroll
        for (int y = 0; y < 4; ++y) bv[y] = Vt[(tc << 2) + y][kk];
#pragma unroll
        for (int x = 0; x < 4; ++x)
#pragma unroll
          for (int y = 0; y < 4; ++y) acc[x][y] = fmaf(av[x], bv[y], acc[x][y]);
      }
      __syncthreads();
    }

    {
      float s1v[4];
#pragma unroll
      for (int x = 0; x < 4; ++x) {
        int u = (tr << 2) + x;
        s1v[x] = s1[u] + (1.f - (float)mu[u]) * NEGC;
      }
#pragma unroll
      for (int x = 0; x < 4; ++x)
#pragma unroll
        for (int y = 0; y < 4; ++y)
          A[(tr << 2) + x][(tc << 2) + y] = acc[x][y] + s1v[x] + s2v[y];
    }
    __syncthreads();

    // softmax over u per column v
    {
      const int v = t & 63, part = t >> 6;
      float m = -1e30f;
      for (int u = part * 16; u < part * 16 + 16; ++u) m = fmaxf(m, A[u][v]);
      red[part][v] = m;
      __syncthreads();
      float gm = fmaxf(fmaxf(red[0][v], red[1][v]), fmaxf(red[2][v], red[3][v]));
      float s = 0.f;
      for (int u = part * 16; u < part * 16 + 16; ++u) {
        float e = expf(A[u][v] - gm);
        A[u][v] = e;
        s += e;
      }
      __syncthreads();
      red[part][v] = s;
      __syncthreads();
      if (part == 0) colinv[v] = 1.f / (red[0][v] + red[1][v] + red[2][v] + red[3][v]);
    }
    __syncthreads();

    // ctx[v][d] (+)= colinv[v] * sum_u A[u][v] * U[u][d]
    {
      const int dl = t & 31, vp0 = t >> 5;
      for (int dt = 0; dt < HD; dt += 32) {
        const float* up = U + (size_t)lrow * HD + dt + lcs;
        float4 u0 = *(const float4*)up;
        float4 u1 = *(const float4*)(up + 4);
        st8(&Ut[lrow][lcs], u0, u1);
        __syncthreads();
        float accd[8];
#pragma unroll
        for (int m2 = 0; m2 < 8; ++m2) accd[m2] = 0.f;
        for (int u = 0; u < 64; ++u) {
          float ud = Ut[u][dl];
#pragma unroll
          for (int m2 = 0; m2 < 8; ++m2)
            accd[m2] = fmaf(A[u][vp0 + (m2 << 3)], ud, accd[m2]);
        }
#pragma unroll
        for (int m2 = 0; m2 < 8; ++m2) {
          int v = vp0 + (m2 << 3);
          float val = accd[m2] * colinv[v];
          float* op = out + (size_t)v * HD + dt + dl;
          if (jj == 0) *op = val; else *op += val;
        }
        __syncthreads();
      }
    }
    __syncthreads();
  }
}

// ---------------- question pooling: Q[bc,:] = softmax(qa)^T q ----------------
__global__ __launch_bounds__(256)
void qpool_kernel(const float* __restrict__ q, const float* __restrict__ qa,
                  const int* __restrict__ qm, float* __restrict__ Q) {
  __shared__ float wgt[128];
  __shared__ float wred[4];
  int t = threadIdx.x, bc = blockIdx.x;
  const float* qap = qa + bc * 128;
  const int* qmp = qm + bc * 128;
  float v = -1e30f;
  if (t < 128) v = qap[t] + (1.f - (float)qmp[t]) * NEGC;
  float m = v;
#pragma unroll
  for (int off = 32; off; off >>= 1) m = fmaxf(m, __shfl_xor(m, off));
  if ((t & 63) == 0) wred[t >> 6] = m;
  __syncthreads();
  float gm = fmaxf(fmaxf(wred[0], wred[1]), fmaxf(wred[2], wred[3]));
  float e = (t < 128) ? expf(v - gm) : 0.f;
  float s = e;
#pragma unroll
  for (int off = 32; off; off >>= 1) s += __shfl_xor(s, off);
  __syncthreads();
  if ((t & 63) == 0) wred[t >> 6] = s;
  __syncthreads();
  float tot = wred[0] + wred[1] + wred[2] + wred[3];
  if (t < 128) wgt[t] = e / tot;
  __syncthreads();
  const float* qp = q + (size_t)bc * (128 * HD);
  float* Qp = Q + (size_t)bc * HD;
  for (int d = t; d < HD; d += 256) {
    float acc = 0.f;
    for (int l = 0; l < 128; ++l) acc = fmaf(wgt[l], qp[(size_t)l * HD + d], acc);
    Qp[d] = acc;
  }
}

// ---------------- A2[bc][q][v] = trilinear(q, merged) ----------------
__global__ __launch_bounds__(256)
void a2_kernel(const float* __restrict__ q, const float* __restrict__ merged,
               const float* __restrict__ qco1, const float* __restrict__ ms2,
               const int* __restrict__ qm, const int* __restrict__ om,
               const float* __restrict__ w3, float* __restrict__ A2) {
  __shared__ float Qt[128][33];
  __shared__ float Mt[64][33];
  const int t = threadIdx.x, bc = blockIdx.x;
  const float* qp = q + (size_t)bc * (128 * HD);
  const float* mp = merged + (size_t)bc * (64 * HD);
  const int tr = t >> 4, tc = t & 15;
  float acc[8][4];
#pragma unroll
  for (int x = 0; x < 8; ++x)
#pragma unroll
    for (int y = 0; y < 4; ++y) acc[x][y] = 0.f;
  for (int k0 = 0; k0 < HD; k0 += 32) {
    {
      int row = t >> 1, cs = (t & 1) << 4;
      const float* p = qp + (size_t)row * HD + k0 + cs;
#pragma unroll
      for (int z = 0; z < 4; ++z) {
        float4 a = *(const float4*)(p + (z << 2));
        float4 w = *(const float4*)(w3 + k0 + cs + (z << 2));
        Qt[row][cs + (z << 2) + 0] = a.x * w.x;
        Qt[row][cs + (z << 2) + 1] = a.y * w.y;
        Qt[row][cs + (z << 2) + 2] = a.z * w.z;
        Qt[row][cs + (z << 2) + 3] = a.w * w.w;
      }
    }
    {
      int row = t >> 2, cs = (t & 3) << 3;
      const float* p = mp + (size_t)row * HD + k0 + cs;
      float4 a0 = *(const float4*)p, a1 = *(const float4*)(p + 4);
      st8(&Mt[row][cs], a0, a1);
    }
    __syncthreads();
#pragma unroll
    for (int kk = 0; kk < 32; ++kk) {
      float qv[8], mv[4];
#pragma unroll
      for (int x = 0; x < 8; ++x) qv[x] = Qt[(tr << 3) + x][kk];
#pragma unroll
      for (int y = 0; y < 4; ++y) mv[y] = Mt[(tc << 2) + y][kk];
#pragma unroll
      for (int x = 0; x < 8; ++x)
#pragma unroll
        for (int y = 0; y < 4; ++y) acc[x][y] = fmaf(qv[x], mv[y], acc[x][y]);
    }
    __syncthreads();
  }
  const float* qc = qco1 + bc * 128;
  const float* msp = ms2 + bc * 64;
  const int* qmp = qm + bc * 128;
  const int* omp = om + bc * 64;
  float* outp = A2 + (size_t)bc * (128 * 64);
  float cterm[4];
#pragma unroll
  for (int y = 0; y < 4; ++y) {
    int v = (tc << 2) + y;
    cterm[y] = msp[v] + (1.f - (float)omp[v]) * NEGC;
  }
#pragma unroll
  for (int x = 0; x < 8; ++x) {
    int qrow = (tr << 3) + x;
    float rterm = qc[qrow] + (1.f - (float)qmp[qrow]) * NEGC;
#pragma unroll
    for (int y = 0; y < 4; ++y) {
      int v = (tc << 2) + y;
      outp[qrow * 64 + v] = acc[x][y] + rterm + cterm[y];
    }
  }
}

// ------------- POAA: PLO = APK^T q ; PHI = (APK^T ACK) merged (OA eliminated) -------------
__global__ __launch_bounds__(256)
void poaa_kernel(const float* __restrict__ A2, const float* __restrict__ qin,
                 const float* __restrict__ merged,
                 float* __restrict__ PLO, float* __restrict__ PHI) {
  __shared__ float T[128][65];     // exp(A2 - gmax)  (APK base)
  __shared__ float Tf[128][65];    // T * fr[q]       (= ACK)
  __shared__ float M2s[64][65];
  __shared__ float tile[128][33];
  __shared__ float red[4][64];
  __shared__ float rowm[128], rowfac[128];
  __shared__ float colm[64], colfac[64];
  __shared__ float gmax_s;

  const int t = threadIdx.x, bc = blockIdx.x;
  const float* a2 = A2 + (size_t)bc * (128 * 64);
  {
    int row = t >> 1, cs = (t & 1) << 5;
    const float* p = a2 + row * 64 + cs;
#pragma unroll
    for (int z = 0; z < 8; ++z) {
      float4 v = *(const float4*)(p + (z << 2));
      T[row][cs + (z << 2) + 0] = v.x;
      T[row][cs + (z << 2) + 1] = v.y;
      T[row][cs + (z << 2) + 2] = v.z;
      T[row][cs + (z << 2) + 3] = v.w;
    }
  }
  __syncthreads();
  {  // row stats (ACK): max + sum over v
    int qrow = t >> 1, h = t & 1;
    float m = -1e30f;
    for (int v = h * 32; v < h * 32 + 32; ++v) m = fmaxf(m, T[qrow][v]);
    m = fmaxf(m, __shfl_xor(m, 1));
    float s = 0.f;
    for (int v = h * 32; v < h * 32 + 32; ++v) s += expf(T[qrow][v] - m);
    s += __shfl_xor(s, 1);
    if (h == 0) { rowm[qrow] = m; rowfac[qrow] = s; }
  }
  {  // col stats (APK): max + sum over q
    int v = t & 63, part = t >> 6;
    float m = -1e30f;
    for (int qq = part * 32; qq < part * 32 + 32; ++qq) m = fmaxf(m, T[qq][v]);
    red[part][v] = m;
    __syncthreads();
    float cm = fmaxf(fmaxf(red[0][v], red[1][v]), fmaxf(red[2][v], red[3][v]));
    float s = 0.f;
    for (int qq = part * 32; qq < part * 32 + 32; ++qq) s += expf(T[qq][v] - cm);
    __syncthreads();
    red[part][v] = s;
    __syncthreads();
    if (part == 0) { colm[v] = cm; colfac[v] = red[0][v] + red[1][v] + red[2][v] + red[3][v]; }
  }
  __syncthreads();
  if (t < 64) {
    float m = fmaxf(rowm[t], rowm[t + 64]);
#pragma unroll
    for (int off = 32; off; off >>= 1) m = fmaxf(m, __shfl_xor(m, off));
    if (t == 0) gmax_s = m;
  }
  __syncthreads();
  float gmax = gmax_s;
  if (t < 128) rowfac[t] = expf(fminf(gmax - rowm[t], 60.f)) / rowfac[t];
  if (t < 64) colfac[t] = expf(fminf(gmax - colm[t], 60.f)) / colfac[t];
  __syncthreads();
  {
    int row = t >> 1, cs = (t & 1) << 5;
    float fr = rowfac[row];
    for (int z = 0; z < 32; ++z) {
      float e = expf(T[row][cs + z] - gmax);
      T[row][cs + z] = e;
      Tf[row][cs + z] = e * fr;
    }
  }
  __syncthreads();
  {  // M2[o][v] = go[o] * sum_q T[q][o]*Tf[q][v]
    const int tr = t >> 4, tc = t & 15;
    float acc[4][4];
#pragma unroll
    for (int x = 0; x < 4; ++x)
#pragma unroll
      for (int y = 0; y < 4; ++y) acc[x][y] = 0.f;
    for (int qq = 0; qq < 128; ++qq) {
      float a[4], bb[4];
#pragma unroll
      for (int x = 0; x < 4; ++x) a[x] = T[qq][(tr << 2) + x];
#pragma unroll
      for (int y = 0; y < 4; ++y) bb[y] = Tf[qq][(tc << 2) + y];
#pragma unroll
      for (int x = 0; x < 4; ++x)
#pragma unroll
        for (int y = 0; y < 4; ++y) acc[x][y] = fmaf(a[x], bb[y], acc[x][y]);
    }
#pragma unroll
    for (int x = 0; x < 4; ++x) {
      float gf = colfac[(tr << 2) + x];
#pragma unroll
      for (int y = 0; y < 4; ++y) M2s[(tr << 2) + x][(tc << 2) + y] = gf * acc[x][y];
    }
  }
  __syncthreads();
  const float* qp = qin + (size_t)bc * (128 * HD);
  float* plo = PLO + (size_t)bc * (64 * HD);
  {
    const int dl = t & 31, op0 = t >> 5;
    for (int dt = 0; dt < HD; dt += 32) {
      {
        int row = t >> 1, cs = (t & 1) << 4;
        const float* p = qp + (size_t)row * HD + dt + cs;
#pragma unroll
        for (int z = 0; z < 4; ++z) {
          float4 v = *(const float4*)(p + (z << 2));
          tile[row][cs + (z << 2) + 0] = v.x;
          tile[row][cs + (z << 2) + 1] = v.y;
          tile[row][cs + (z << 2) + 2] = v.z;
          tile[row][cs + (z << 2) + 3] = v.w;
        }
      }
      __syncthreads();
      float acc[8];
#pragma unroll
      for (int m2 = 0; m2 < 8; ++m2) acc[m2] = 0.f;
      for (int qq = 0; qq < 128; ++qq) {
        float qd = tile[qq][dl];
#pragma unroll
        for (int m2 = 0; m2 < 8; ++m2)
          acc[m2] = fmaf(T[qq][op0 + (m2 << 3)], qd, acc[m2]);
      }
#pragma unroll
      for (int m2 = 0; m2 < 8; ++m2) {
        int o = op0 + (m2 << 3);
        plo[(size_t)o * HD + dt + dl] = colfac[o] * acc[m2];
      }
      __syncthreads();
    }
  }
  const float* mp = merged + (size_t)bc * (64 * HD);
  float* phi = PHI + (size_t)bc * (64 * HD);
  {
    const int dl = t & 31, op0 = t >> 5;
    for (int dt = 0; dt < HD; dt += 32) {
      {
        int row = t >> 2, cs = (t & 3) << 3;
        const float* p = mp + (size_t)row * HD + dt + cs;
        float4 a0 = *(const float4*)p, a1 = *(const float4*)(p + 4);
        st8(&tile[row][cs], a0, a1);
      }
      __syncthreads();
      float acc[8];
#pragma unroll
      for (int m2 = 0; m2 < 8; ++m2) acc[m2] = 0.f;
      for (int v = 0; v < 64; ++v) {
        float md = tile[v][dl];
#pragma unroll
        for (int m2 = 0; m2 < 8; ++m2)
          acc[m2] = fmaf(M2s[op0 + (m2 << 3)][v], md, acc[m2]);
      }
#pragma unroll
      for (int m2 = 0; m2 < 8; ++m2)
        phi[(size_t)(op0 + (m2 << 3)) * HD + dt + dl] = acc[m2];
      __syncthreads();
    }
  }
}

// ---------------- generic chunked GEMM: out = epilogue( sum_c f_c(A,B) @ W_c + ... ) ----------------
struct GemmArgs {
  const float* a[4];
  const float* bsrc[4];
  int mode[4];           // 0: a ; 1: 3a-b ; 2: a*b ; 3: a-b
  const float* w[4];     // each [768,768] row-major slice
  int nchunks;
  const float* bias;
  const float* aux0;     // o1   (EP_MERGE)
  const float* aux1;     // OCK  (EP_MERGE)
  const float* aux2;     // Qg   (EP_MERGE, includes Wg_b)
  float* out;
};

template<int EP>
__global__ __launch_bounds__(256)
void gemm_kernel(GemmArgs g) {
  __shared__ float As[64][33];
  __shared__ float Ws[32][65];
  __shared__ float red[16][64];
  const int t = threadIdx.x;
  const int m0 = blockIdx.y << 6, n0 = blockIdx.x << 6;
  const int tr = t >> 4, tc = t & 15;
  float acc[4][4];
#pragma unroll
  for (int x = 0; x < 4; ++x)
#pragma unroll
    for (int y = 0; y < 4; ++y) acc[x][y] = 0.f;
  const int arow = t >> 2, acs = (t & 3) << 3;
  const int wrow = t >> 3, wcs = (t & 7) << 3;
  for (int c = 0; c < g.nchunks; ++c) {
    const int mode = g.mode[c];
    const float* Ap = g.a[c] + (size_t)(m0 + arow) * HD + acs;
    const float* Bp = mode ? (g.bsrc[c] + (size_t)(m0 + arow) * HD + acs) : nullptr;
    const float* Wp = g.w[c] + (size_t)wrow * HD + n0 + wcs;
    for (int k0 = 0; k0 < HD; k0 += 32) {
      float4 a0 = *(const float4*)(Ap + k0);
      float4 a1 = *(const float4*)(Ap + k0 + 4);
      if (mode != 0) {
        float4 b0 = *(const float4*)(Bp + k0);
        float4 b1 = *(const float4*)(Bp + k0 + 4);
        if (mode == 1) {
          a0.x = fmaf(3.f, a0.x, -b0.x); a0.y = fmaf(3.f, a0.y, -b0.y);
          a0.z = fmaf(3.f, a0.z, -b0.z); a0.w = fmaf(3.f, a0.w, -b0.w);
          a1.x = fmaf(3.f, a1.x, -b1.x); a1.y = fmaf(3.f, a1.y, -b1.y);
          a1.z = fmaf(3.f, a1.z, -b1.z); a1.w = fmaf(3.f, a1.w, -b1.w);
        } else if (mode == 2) {
          a0.x *= b0.x; a0.y *= b0.y; a0.z *= b0.z; a0.w *= b0.w;
          a1.x *= b1.x; a1.y *= b1.y; a1.z *= b1.z; a1.w *= b1.w;
        } else {
          a0.x -= b0.x; a0.y -= b0.y; a0.z -= b0.z; a0.w -= b0.w;
          a1.x -= b1.x; a1.y -= b1.y; a1.z -= b1.z; a1.w -= b1.w;
        }
      }
      st8(&As[arow][acs], a0, a1);
      float4 w0 = *(const float4*)(Wp + (size_t)k0 * HD);
      float4 w1 = *(const float4*)(Wp + (size_t)k0 * HD + 4);
      st8(&Ws[wrow][wcs], w0, w1);
      __syncthreads();
#pragma unroll
      for (int kk = 0; kk < 32; ++kk) {
        float av[4], bv[4];
#pragma unroll
        for (int x = 0; x < 4; ++x) av[x] = As[(tr << 2) + x][kk];
#pragma unroll
        for (int y = 0; y < 4; ++y) bv[y] = Ws[kk][(tc << 2) + y];
#pragma unroll
        for (int x = 0; x < 4; ++x)
#pragma unroll
          for (int y = 0; y < 4; ++y) acc[x][y] = fmaf(av[x], bv[y], acc[x][y]);
      }
      __syncthreads();
    }
  }
  if (EP == EP_RELU_MAX) {
#pragma unroll
    for (int y = 0; y < 4; ++y) {
      int n = n0 + (tc << 2) + y;
      float b = g.bias[n];
      float m = 0.f;
#pragma unroll
      for (int x = 0; x < 4; ++x) m = fmaxf(m, fmaxf(acc[x][y] + b, 0.f));
      red[tr][(tc << 2) + y] = m;
    }
    __syncthreads();
    if (t < 64) {
      float m = red[0][t];
#pragma unroll
      for (int p = 1; p < 16; ++p) m = fmaxf(m, red[p][t]);
      g.out[(size_t)blockIdx.y * HD + n0 + t] = m;
    }
  } else {
#pragma unroll
    for (int x = 0; x < 4; ++x) {
      const int r = m0 + (tr << 2) + x;
#pragma unroll
      for (int y = 0; y < 4; ++y) {
        const int n = n0 + (tc << 2) + y;
        const size_t oi = (size_t)r * HD + n;
        float v = acc[x][y];
        if (EP == EP_STORE) {
          g.out[oi] = v + g.bias[n];
        } else if (EP == EP_TANH) {
          g.out[oi] = tanhf(v + g.bias[n]);
        } else if (EP == EP_MERGE) {
          float gg = v + g.aux2[(size_t)(r >> 6) * HD + n];
          float sg = 1.f / (1.f + expf(-gg));
          float o1v = g.aux0[oi];
          float ock = g.aux1[oi];
          g.out[oi] = fmaf(sg, o1v - ock, ock);
        } else {  // EP_RELU
          g.out[oi] = fmaxf(v + g.bias[n], 0.f);
        }
      }
    }
  }
}

extern "C" void kernel_launch(void* const* d_in, const int* in_sizes, int n_in,
                              void* d_out, int out_size, void* d_ws, size_t ws_size,
                              hipStream_t stream) {
  const float* enc_o = (const float*)d_in[0];
  const float* enc_q = (const float*)d_in[1];
  const int* om = (const int*)d_in[2];
  const int* qm = (const int*)d_in[3];
  const float* att_W1_w = (const float*)d_in[4];
  const float* att_W1_b = (const float*)d_in[5];
  const float* att_W2_w = (const float*)d_in[6];
  const float* att_W2_b = (const float*)d_in[7];
  const float* att_W3 = (const float*)d_in[8];
  const float* Wc_self_w = (const float*)d_in[9];
  const float* Wc_self_b = (const float*)d_in[10];
  const float* Wc_w = (const float*)d_in[11];
  const float* Wc_b = (const float*)d_in[12];
  const float* Va_w = (const float*)d_in[13];
  const float* Va_b = (const float*)d_in[14];
  const float* Wg_w = (const float*)d_in[15];
  const float* Wg_b = (const float*)d_in[16];
  const float* co_W1_w = (const float*)d_in[17];
  const float* co_W1_b = (const float*)d_in[18];
  const float* co_W2_w = (const float*)d_in[19];
  const float* co_W2_b = (const float*)d_in[20];
  const float* co_W3 = (const float*)d_in[21];
  const float* Wp_w = (const float*)d_in[22];
  const float* Wp_b = (const float*)d_in[23];
  const float* sa_W1_w = (const float*)d_in[24];
  const float* sa_W1_b = (const float*)d_in[25];
  const float* sa_W2_w = (const float*)d_in[26];
  const float* sa_W2_b = (const float*)d_in[27];
  const float* sa_W3 = (const float*)d_in[28];
  const float* Wf_w = (const float*)d_in[29];
  const float* Wf_b = (const float*)d_in[30];
  float* out = (float*)d_out;

  const int NTOK_O = 16384;   // 64*4*64
  const int NTOK_Q = 32768;   // 64*4*128
  const int M_BIG = 16384;    // BC*LO rows

  float* ws = (float*)d_ws;
  size_t off = 0;
  auto carve = [&](size_t n) { float* p = ws + off; off += n; return p; };
  float* s1o   = carve(16384);
  float* s2o   = carve(16384);
  float* qa    = carve(32768);
  float* qco1  = carve(32768);
  float* ms2   = carve(16384);
  float* sa1   = carve(16384);
  float* sa2   = carve(16384);
  float* biasO = carve(1024);
  float* Qpool = carve(196608);
  float* Qg    = carve(196608);
  float* A2buf = carve(2097152);
  float* r1 = carve(12582912);   // CS -> OPK
  float* r2 = carve(12582912);   // OCK -> PLO
  float* r3 = carve(12582912);   // merged -> OSK
  float* r4 = carve(12582912);   // PHI
  if (ws_size < off * sizeof(float)) return;
  float* CS = r1;   float* OPK = r1;
  float* OCK = r2;  float* PLO = r2;
  float* merged = r3; float* OSK = r3;
  float* PHI = r4;

  // 1. per-token scalars
  dot768_kernel<<<NTOK_O / 4, 256, 0, stream>>>(enc_o, att_W1_w, att_W1_b, s1o, NTOK_O);
  dot768_kernel<<<NTOK_O / 4, 256, 0, stream>>>(enc_o, att_W2_w, att_W2_b, s2o, NTOK_O);
  dot768_kernel<<<NTOK_Q / 4, 256, 0, stream>>>(enc_q, Va_w, Va_b, qa, NTOK_Q);
  dot768_kernel<<<NTOK_Q / 4, 256, 0, stream>>>(enc_q, co_W1_w, co_W1_b, qco1, NTOK_Q);
  bias_ock_kernel<<<3, 256, 0, stream>>>(Wc_self_b, Wc_b, biasO);

  // 2. pairwise option-compare summed context
  attctx_kernel<3><<<256, 256, 0, stream>>>(enc_o, s1o, s2o, om, att_W3, CS);

  // 3. OCK = tanh([o1 | 3o1-CS | o1*CS] @ [Wc_self; Wc_hi; Wc_lo] + bias)
  {
    GemmArgs g{};
    g.a[0] = enc_o; g.bsrc[0] = nullptr; g.mode[0] = 0; g.w[0] = Wc_self_w;
    g.a[1] = enc_o; g.bsrc[1] = CS;      g.mode[1] = 1; g.w[1] = Wc_w;
    g.a[2] = enc_o; g.bsrc[2] = CS;      g.mode[2] = 2; g.w[2] = Wc_w + 768 * 768;
    g.nchunks = 3; g.bias = biasO; g.out = OCK;
    gemm_kernel<EP_TANH><<<dim3(12, M_BIG / 64), 256, 0, stream>>>(g);
  }

  // 4. question pooling + Qg
  qpool_kernel<<<256, 256, 0, stream>>>(enc_q, qa, qm, Qpool);
  {
    GemmArgs g{};
    g.a[0] = Qpool; g.bsrc[0] = nullptr; g.mode[0] = 0; g.w[0] = Wg_w + 1536 * 768;
    g.nchunks = 1; g.bias = Wg_b; g.out = Qg;
    gemm_kernel<EP_STORE><<<dim3(12, 4), 256, 0, stream>>>(g);
  }

  // 5. merged = G*o1 + (1-G)*OCK, G = sigmoid([o1|OCK]@Wg12 + Qg)
  {
    GemmArgs g{};
    g.a[0] = enc_o; g.bsrc[0] = nullptr; g.mode[0] = 0; g.w[0] = Wg_w;
    g.a[1] = OCK;   g.bsrc[1] = nullptr; g.mode[1] = 0; g.w[1] = Wg_w + 768 * 768;
    g.nchunks = 2; g.bias = nullptr;
    g.aux0 = enc_o; g.aux1 = OCK; g.aux2 = Qg; g.out = merged;
    gemm_kernel<EP_MERGE><<<dim3(12, M_BIG / 64), 256, 0, stream>>>(g);
  }

  // 6. co-attention
  dot768_kernel<<<NTOK_O / 4, 256, 0, stream>>>(merged, co_W2_w, co_W2_b, ms2, NTOK_O);
  a2_kernel<<<256, 256, 0, stream>>>(enc_q, merged, qco1, ms2, qm, om, co_W3, A2buf);
  poaa_kernel<<<256, 256, 0, stream>>>(A2buf, enc_q, merged, PLO, PHI);

  // 7. OPK = relu([merged | PLO | PHI] @ Wp + b)
  {
    GemmArgs g{};
    g.a[0] = merged; g.bsrc[0] = nullptr; g.mode[0] = 0; g.w[0] = Wp_w;
    g.a[1] = PLO;    g.bsrc[1] = nullptr; g.mode[1] = 0; g.w[1] = Wp_w + 768 * 768;
    g.a[2] = PHI;    g.bsrc[2] = nullptr; g.mode[2] = 0; g.w[2] = Wp_w + 1536 * 768;
    g.nchunks = 3; g.bias = Wp_b; g.out = OPK;
    gemm_kernel<EP_RELU><<<dim3(12, M_BIG / 64), 256, 0, stream>>>(g);
  }

  // 8. self-attention
  dot768_kernel<<<NTOK_O / 4, 256, 0, stream>>>(OPK, sa_W1_w, sa_W1_b, sa1, NTOK_O);
  dot768_kernel<<<NTOK_O / 4, 256, 0, stream>>>(OPK, sa_W2_w, sa_W2_b, sa2, NTOK_O);
  attctx_kernel<1><<<256, 256, 0, stream>>>(OPK, sa1, sa2, om, sa_W3, OSK);

  // 9. out = max_lo relu([OPK | OSK | OPK-OSK | OPK*OSK] @ Wf + b)
  {
    GemmArgs g{};
    g.a[0] = OPK; g.bsrc[0] = nullptr; g.mode[0] = 0; g.w[0] = Wf_w;
    g.a[1] = OSK; g.bsrc[1] = nullptr; g.mode[1] = 0; g.w[1] = Wf_w + 768 * 768;
    g.a[2] = OPK; g.bsrc[2] = OSK;     g.mode[2] = 3; g.w[2] = Wf_w + 1536 * 768;
    g.a[3] = OPK; g.bsrc[3] = OSK;     g.mode[3] = 2; g.w[3] = Wf_w + 2304 * 768;
    g.nchunks = 4; g.bias = Wf_b; g.out = out;
    gemm_kernel<EP_RELU_MAX><<<dim3(12, M_BIG / 64), 256, 0, stream>>>(g);
  }
}

// Round 2
// 1947.224 us; speedup vs baseline: 2.8081x; 2.8081x over previous
//
#include <hip/hip_runtime.h>
#include <math.h>

// OptionCompareCell: B=64,C=4,LO=64,LQ=128,H=768
// Round 2: 4 big GEMMs -> bf16 MFMA (16x16x32), f32 accumulate.
//  - Wt[N][K] bf16 transposed weights (wconv_kernel, reused buffer)
//  - A staged f32->bf16 in-kernel with fused concat modes
//  - padded LDS (stride 40 bf16) to kill ds_read_b128 bank conflicts
// Everything else (attctx/a2/poaa/qpool/dot768) stays f32 from round 1.

#define NEGC (-10000.0f)
constexpr int HD = 768;

constexpr int EP_STORE = 0;
constexpr int EP_TANH = 1;
constexpr int EP_MERGE = 2;
constexpr int EP_RELU = 3;
constexpr int EP_RELU_MAX = 4;

typedef __attribute__((ext_vector_type(8))) short bf16x8;
typedef __attribute__((ext_vector_type(8))) unsigned short u16x8;
typedef __attribute__((ext_vector_type(4))) float f32x4;

__device__ inline void st8(float* dst, float4 a0, float4 a1) {
  dst[0] = a0.x; dst[1] = a0.y; dst[2] = a0.z; dst[3] = a0.w;
  dst[4] = a1.x; dst[5] = a1.y; dst[6] = a1.z; dst[7] = a1.w;
}

__device__ inline unsigned short f2bf(float x) {
  unsigned int u = __float_as_uint(x);
  u += 0x7fffu + ((u >> 16) & 1u);
  return (unsigned short)(u >> 16);
}

__device__ inline u16x8 pack8(float4 a, float4 b) {
  u16x8 r;
  r[0] = f2bf(a.x); r[1] = f2bf(a.y); r[2] = f2bf(a.z); r[3] = f2bf(a.w);
  r[4] = f2bf(b.x); r[5] = f2bf(b.y); r[6] = f2bf(b.z); r[7] = f2bf(b.w);
  return r;
}

// ---------------- per-token dot with a [768] vector + scalar bias ----------------
__global__ __launch_bounds__(256)
void dot768_kernel(const float* __restrict__ x, const float* __restrict__ w,
                   const float* __restrict__ bias, float* __restrict__ out, int ntok) {
  int tok = blockIdx.x * 4 + (threadIdx.x >> 6);
  int lane = threadIdx.x & 63;
  if (tok >= ntok) return;
  const float* xp = x + (size_t)tok * HD;
  float s = 0.f;
#pragma unroll
  for (int i = 0; i < 3; ++i) {
    int c = (lane + (i << 6)) << 2;
    float4 xv = *(const float4*)(xp + c);
    float4 wv = *(const float4*)(w + c);
    s = fmaf(xv.x, wv.x, s); s = fmaf(xv.y, wv.y, s);
    s = fmaf(xv.z, wv.z, s); s = fmaf(xv.w, wv.w, s);
  }
#pragma unroll
  for (int off = 32; off; off >>= 1) s += __shfl_xor(s, off);
  if (lane == 0) out[tok] = s + bias[0];
}

__global__ void bias_ock_kernel(const float* __restrict__ b1, const float* __restrict__ b2,
                                float* __restrict__ o) {
  int n = blockIdx.x * 256 + threadIdx.x;
  if (n < HD) o[n] = b1[n] + 3.f * b2[n];
}

// --------- trilinear attention + softmax(axis u) + ctx; NJ=3: sum_j -> CS ; NJ=1: OSK ---------
template<int NJ>
__global__ __launch_bounds__(256)
void attctx_kernel(const float* __restrict__ X, const float* __restrict__ s1g,
                   const float* __restrict__ s2g, const int* __restrict__ maskg,
                   const float* __restrict__ w3, float* __restrict__ outg) {
  __shared__ float A[64][65];
  __shared__ float Ut[64][33];
  __shared__ float Vt[64][33];
  __shared__ float red[4][64];
  __shared__ float colinv[64];

  const int t = threadIdx.x;
  const int blk = blockIdx.x;          // bc = b*4+i
  const int b = blk >> 2, i = blk & 3;
  const float* V = X + (size_t)blk * (64 * HD);
  const float* s2 = s2g + blk * 64;
  const int* mv = maskg + blk * 64;
  float* out = outg + (size_t)blk * (64 * HD);
  const int tr = t >> 4, tc = t & 15;
  const int lrow = t >> 2, lcs = (t & 3) << 3;

  float s2v[4];
#pragma unroll
  for (int y = 0; y < 4; ++y) {
    int v = (tc << 2) + y;
    s2v[y] = s2[v] + (1.f - (float)mv[v]) * NEGC;
  }

  for (int jj = 0; jj < NJ; ++jj) {
    const int jidx = (NJ == 1) ? i : (jj + (jj >= i ? 1 : 0));
    const float* U = X + (size_t)((b << 2) + jidx) * (64 * HD);
    const float* s1 = s1g + ((b << 2) + jidx) * 64;
    const int* mu = maskg + ((b << 2) + jidx) * 64;

    float acc[4][4];
#pragma unroll
    for (int x = 0; x < 4; ++x)
#pragma unroll
      for (int y = 0; y < 4; ++y) acc[x][y] = 0.f;

    for (int k0 = 0; k0 < HD; k0 += 32) {
      const float* up = U + (size_t)lrow * HD + k0 + lcs;
      const float* vp = V + (size_t)lrow * HD + k0 + lcs;
      float4 u0 = *(const float4*)up;
      float4 u1 = *(const float4*)(up + 4);
      float4 w0 = *(const float4*)(w3 + k0 + lcs);
      float4 w1 = *(const float4*)(w3 + k0 + lcs + 4);
      float4 v0 = *(const float4*)vp;
      float4 v1 = *(const float4*)(vp + 4);
      u0.x *= w0.x; u0.y *= w0.y; u0.z *= w0.z; u0.w *= w0.w;
      u1.x *= w1.x; u1.y *= w1.y; u1.z *= w1.z; u1.w *= w1.w;
      st8(&Ut[lrow][lcs], u0, u1);
      st8(&Vt[lrow][lcs], v0, v1);
      __syncthreads();
#pragma unroll
      for (int kk = 0; kk < 32; ++kk) {
        float av[4], bv[4];
#pragma unroll
        for (int x = 0; x < 4; ++x) av[x] = Ut[(tr << 2) + x][kk];
#pragma unroll
        for (int y = 0; y < 4; ++y) bv[y] = Vt[(tc << 2) + y][kk];
#pragma unroll
        for (int x = 0; x < 4; ++x)
#pragma unroll
          for (int y = 0; y < 4; ++y) acc[x][y] = fmaf(av[x], bv[y], acc[x][y]);
      }
      __syncthreads();
    }

    {
      float s1v[4];
#pragma unroll
      for (int x = 0; x < 4; ++x) {
        int u = (tr << 2) + x;
        s1v[x] = s1[u] + (1.f - (float)mu[u]) * NEGC;
      }
#pragma unroll
      for (int x = 0; x < 4; ++x)
#pragma unroll
        for (int y = 0; y < 4; ++y)
          A[(tr << 2) + x][(tc << 2) + y] = acc[x][y] + s1v[x] + s2v[y];
    }
    __syncthreads();

    // softmax over u per column v
    {
      const int v = t & 63, part = t >> 6;
      float m = -1e30f;
      for (int u = part * 16; u < part * 16 + 16; ++u) m = fmaxf(m, A[u][v]);
      red[part][v] = m;
      __syncthreads();
      float gm = fmaxf(fmaxf(red[0][v], red[1][v]), fmaxf(red[2][v], red[3][v]));
      float s = 0.f;
      for (int u = part * 16; u < part * 16 + 16; ++u) {
        float e = expf(A[u][v] - gm);
        A[u][v] = e;
        s += e;
      }
      __syncthreads();
      red[part][v] = s;
      __syncthreads();
      if (part == 0) colinv[v] = 1.f / (red[0][v] + red[1][v] + red[2][v] + red[3][v]);
    }
    __syncthreads();

    // ctx[v][d] (+)= colinv[v] * sum_u A[u][v] * U[u][d]
    {
      const int dl = t & 31, vp0 = t >> 5;
      for (int dt = 0; dt < HD; dt += 32) {
        const float* up = U + (size_t)lrow * HD + dt + lcs;
        float4 u0 = *(const float4*)up;
        float4 u1 = *(const float4*)(up + 4);
        st8(&Ut[lrow][lcs], u0, u1);
        __syncthreads();
        float accd[8];
#pragma unroll
        for (int m2 = 0; m2 < 8; ++m2) accd[m2] = 0.f;
        for (int u = 0; u < 64; ++u) {
          float ud = Ut[u][dl];
#pragma unroll
          for (int m2 = 0; m2 < 8; ++m2)
            accd[m2] = fmaf(A[u][vp0 + (m2 << 3)], ud, accd[m2]);
        }
#pragma unroll
        for (int m2 = 0; m2 < 8; ++m2) {
          int v = vp0 + (m2 << 3);
          float val = accd[m2] * colinv[v];
          float* op = out + (size_t)v * HD + dt + dl;
          if (jj == 0) *op = val; else *op += val;
        }
        __syncthreads();
      }
    }
    __syncthreads();
  }
}

// ---------------- question pooling: Q[bc,:] = softmax(qa)^T q ----------------
__global__ __launch_bounds__(256)
void qpool_kernel(const float* __restrict__ q, const float* __restrict__ qa,
                  const int* __restrict__ qm, float* __restrict__ Q) {
  __shared__ float wgt[128];
  __shared__ float wred[4];
  int t = threadIdx.x, bc = blockIdx.x;
  const float* qap = qa + bc * 128;
  const int* qmp = qm + bc * 128;
  float v = -1e30f;
  if (t < 128) v = qap[t] + (1.f - (float)qmp[t]) * NEGC;
  float m = v;
#pragma unroll
  for (int off = 32; off; off >>= 1) m = fmaxf(m, __shfl_xor(m, off));
  if ((t & 63) == 0) wred[t >> 6] = m;
  __syncthreads();
  float gm = fmaxf(fmaxf(wred[0], wred[1]), fmaxf(wred[2], wred[3]));
  float e = (t < 128) ? expf(v - gm) : 0.f;
  float s = e;
#pragma unroll
  for (int off = 32; off; off >>= 1) s += __shfl_xor(s, off);
  __syncthreads();
  if ((t & 63) == 0) wred[t >> 6] = s;
  __syncthreads();
  float tot = wred[0] + wred[1] + wred[2] + wred[3];
  if (t < 128) wgt[t] = e / tot;
  __syncthreads();
  const float* qp = q + (size_t)bc * (128 * HD);
  float* Qp = Q + (size_t)bc * HD;
  for (int d = t; d < HD; d += 256) {
    float acc = 0.f;
    for (int l = 0; l < 128; ++l) acc = fmaf(wgt[l], qp[(size_t)l * HD + d], acc);
    Qp[d] = acc;
  }
}

// ---------------- A2[bc][q][v] = trilinear(q, merged) ----------------
__global__ __launch_bounds__(256)
void a2_kernel(const float* __restrict__ q, const float* __restrict__ merged,
               const float* __restrict__ qco1, const float* __restrict__ ms2,
               const int* __restrict__ qm, const int* __restrict__ om,
               const float* __restrict__ w3, float* __restrict__ A2) {
  __shared__ float Qt[128][33];
  __shared__ float Mt[64][33];
  const int t = threadIdx.x, bc = blockIdx.x;
  const float* qp = q + (size_t)bc * (128 * HD);
  const float* mp = merged + (size_t)bc * (64 * HD);
  const int tr = t >> 4, tc = t & 15;
  float acc[8][4];
#pragma unroll
  for (int x = 0; x < 8; ++x)
#pragma unroll
    for (int y = 0; y < 4; ++y) acc[x][y] = 0.f;
  for (int k0 = 0; k0 < HD; k0 += 32) {
    {
      int row = t >> 1, cs = (t & 1) << 4;
      const float* p = qp + (size_t)row * HD + k0 + cs;
#pragma unroll
      for (int z = 0; z < 4; ++z) {
        float4 a = *(const float4*)(p + (z << 2));
        float4 w = *(const float4*)(w3 + k0 + cs + (z << 2));
        Qt[row][cs + (z << 2) + 0] = a.x * w.x;
        Qt[row][cs + (z << 2) + 1] = a.y * w.y;
        Qt[row][cs + (z << 2) + 2] = a.z * w.z;
        Qt[row][cs + (z << 2) + 3] = a.w * w.w;
      }
    }
    {
      int row = t >> 2, cs = (t & 3) << 3;
      const float* p = mp + (size_t)row * HD + k0 + cs;
      float4 a0 = *(const float4*)p, a1 = *(const float4*)(p + 4);
      st8(&Mt[row][cs], a0, a1);
    }
    __syncthreads();
#pragma unroll
    for (int kk = 0; kk < 32; ++kk) {
      float qv[8], mv[4];
#pragma unroll
      for (int x = 0; x < 8; ++x) qv[x] = Qt[(tr << 3) + x][kk];
#pragma unroll
      for (int y = 0; y < 4; ++y) mv[y] = Mt[(tc << 2) + y][kk];
#pragma unroll
      for (int x = 0; x < 8; ++x)
#pragma unroll
        for (int y = 0; y < 4; ++y) acc[x][y] = fmaf(qv[x], mv[y], acc[x][y]);
    }
    __syncthreads();
  }
  const float* qc = qco1 + bc * 128;
  const float* msp = ms2 + bc * 64;
  const int* qmp = qm + bc * 128;
  const int* omp = om + bc * 64;
  float* outp = A2 + (size_t)bc * (128 * 64);
  float cterm[4];
#pragma unroll
  for (int y = 0; y < 4; ++y) {
    int v = (tc << 2) + y;
    cterm[y] = msp[v] + (1.f - (float)omp[v]) * NEGC;
  }
#pragma unroll
  for (int x = 0; x < 8; ++x) {
    int qrow = (tr << 3) + x;
    float rterm = qc[qrow] + (1.f - (float)qmp[qrow]) * NEGC;
#pragma unroll
    for (int y = 0; y < 4; ++y) {
      int v = (tc << 2) + y;
      outp[qrow * 64 + v] = acc[x][y] + rterm + cterm[y];
    }
  }
}

// ------------- POAA: PLO = APK^T q ; PHI = (APK^T ACK) merged (OA eliminated) -------------
__global__ __launch_bounds__(256)
void poaa_kernel(const float* __restrict__ A2, const float* __restrict__ qin,
                 const float* __restrict__ merged,
                 float* __restrict__ PLO, float* __restrict__ PHI) {
  __shared__ float T[128][65];     // exp(A2 - gmax)  (APK base)
  __shared__ float Tf[128][65];    // T * fr[q]       (= ACK)
  __shared__ float M2s[64][65];
  __shared__ float tile[128][33];
  __shared__ float red[4][64];
  __shared__ float rowm[128], rowfac[128];
  __shared__ float colm[64], colfac[64];
  __shared__ float gmax_s;

  const int t = threadIdx.x, bc = blockIdx.x;
  const float* a2 = A2 + (size_t)bc * (128 * 64);
  {
    int row = t >> 1, cs = (t & 1) << 5;
    const float* p = a2 + row * 64 + cs;
#pragma unroll
    for (int z = 0; z < 8; ++z) {
      float4 v = *(const float4*)(p + (z << 2));
      T[row][cs + (z << 2) + 0] = v.x;
      T[row][cs + (z << 2) + 1] = v.y;
      T[row][cs + (z << 2) + 2] = v.z;
      T[row][cs + (z << 2) + 3] = v.w;
    }
  }
  __syncthreads();
  {  // row stats (ACK): max + sum over v
    int qrow = t >> 1, h = t & 1;
    float m = -1e30f;
    for (int v = h * 32; v < h * 32 + 32; ++v) m = fmaxf(m, T[qrow][v]);
    m = fmaxf(m, __shfl_xor(m, 1));
    float s = 0.f;
    for (int v = h * 32; v < h * 32 + 32; ++v) s += expf(T[qrow][v] - m);
    s += __shfl_xor(s, 1);
    if (h == 0) { rowm[qrow] = m; rowfac[qrow] = s; }
  }
  {  // col stats (APK): max + sum over q
    int v = t & 63, part = t >> 6;
    float m = -1e30f;
    for (int qq = part * 32; qq < part * 32 + 32; ++qq) m = fmaxf(m, T[qq][v]);
    red[part][v] = m;
    __syncthreads();
    float cm = fmaxf(fmaxf(red[0][v], red[1][v]), fmaxf(red[2][v], red[3][v]));
    float s = 0.f;
    for (int qq = part * 32; qq < part * 32 + 32; ++qq) s += expf(T[qq][v] - cm);
    __syncthreads();
    red[part][v] = s;
    __syncthreads();
    if (part == 0) { colm[v] = cm; colfac[v] = red[0][v] + red[1][v] + red[2][v] + red[3][v]; }
  }
  __syncthreads();
  if (t < 64) {
    float m = fmaxf(rowm[t], rowm[t + 64]);
#pragma unroll
    for (int off = 32; off; off >>= 1) m = fmaxf(m, __shfl_xor(m, off));
    if (t == 0) gmax_s = m;
  }
  __syncthreads();
  float gmax = gmax_s;
  if (t < 128) rowfac[t] = expf(fminf(gmax - rowm[t], 60.f)) / rowfac[t];
  if (t < 64) colfac[t] = expf(fminf(gmax - colm[t], 60.f)) / colfac[t];
  __syncthreads();
  {
    int row = t >> 1, cs = (t & 1) << 5;
    float fr = rowfac[row];
    for (int z = 0; z < 32; ++z) {
      float e = expf(T[row][cs + z] - gmax);
      T[row][cs + z] = e;
      Tf[row][cs + z] = e * fr;
    }
  }
  __syncthreads();
  {  // M2[o][v] = go[o] * sum_q T[q][o]*Tf[q][v]
    const int tr = t >> 4, tc = t & 15;
    float acc[4][4];
#pragma unroll
    for (int x = 0; x < 4; ++x)
#pragma unroll
      for (int y = 0; y < 4; ++y) acc[x][y] = 0.f;
    for (int qq = 0; qq < 128; ++qq) {
      float a[4], bb[4];
#pragma unroll
      for (int x = 0; x < 4; ++x) a[x] = T[qq][(tr << 2) + x];
#pragma unroll
      for (int y = 0; y < 4; ++y) bb[y] = Tf[qq][(tc << 2) + y];
#pragma unroll
      for (int x = 0; x < 4; ++x)
#pragma unroll
        for (int y = 0; y < 4; ++y) acc[x][y] = fmaf(a[x], bb[y], acc[x][y]);
    }
#pragma unroll
    for (int x = 0; x < 4; ++x) {
      float gf = colfac[(tr << 2) + x];
#pragma unroll
      for (int y = 0; y < 4; ++y) M2s[(tr << 2) + x][(tc << 2) + y] = gf * acc[x][y];
    }
  }
  __syncthreads();
  const float* qp = qin + (size_t)bc * (128 * HD);
  float* plo = PLO + (size_t)bc * (64 * HD);
  {
    const int dl = t & 31, op0 = t >> 5;
    for (int dt = 0; dt < HD; dt += 32) {
      {
        int row = t >> 1, cs = (t & 1) << 4;
        const float* p = qp + (size_t)row * HD + dt + cs;
#pragma unroll
        for (int z = 0; z < 4; ++z) {
          float4 v = *(const float4*)(p + (z << 2));
          tile[row][cs + (z << 2) + 0] = v.x;
          tile[row][cs + (z << 2) + 1] = v.y;
          tile[row][cs + (z << 2) + 2] = v.z;
          tile[row][cs + (z << 2) + 3] = v.w;
        }
      }
      __syncthreads();
      float acc[8];
#pragma unroll
      for (int m2 = 0; m2 < 8; ++m2) acc[m2] = 0.f;
      for (int qq = 0; qq < 128; ++qq) {
        float qd = tile[qq][dl];
#pragma unroll
        for (int m2 = 0; m2 < 8; ++m2)
          acc[m2] = fmaf(T[qq][op0 + (m2 << 3)], qd, acc[m2]);
      }
#pragma unroll
      for (int m2 = 0; m2 < 8; ++m2) {
        int o = op0 + (m2 << 3);
        plo[(size_t)o * HD + dt + dl] = colfac[o] * acc[m2];
      }
      __syncthreads();
    }
  }
  const float* mp = merged + (size_t)bc * (64 * HD);
  float* phi = PHI + (size_t)bc * (64 * HD);
  {
    const int dl = t & 31, op0 = t >> 5;
    for (int dt = 0; dt < HD; dt += 32) {
      {
        int row = t >> 2, cs = (t & 3) << 3;
        const float* p = mp + (size_t)row * HD + dt + cs;
        float4 a0 = *(const float4*)p, a1 = *(const float4*)(p + 4);
        st8(&tile[row][cs], a0, a1);
      }
      __syncthreads();
      float acc[8];
#pragma unroll
      for (int m2 = 0; m2 < 8; ++m2) acc[m2] = 0.f;
      for (int v = 0; v < 64; ++v) {
        float md = tile[v][dl];
#pragma unroll
        for (int m2 = 0; m2 < 8; ++m2)
          acc[m2] = fmaf(M2s[op0 + (m2 << 3)][v], md, acc[m2]);
      }
#pragma unroll
      for (int m2 = 0; m2 < 8; ++m2)
        phi[(size_t)(op0 + (m2 << 3)) * HD + dt + dl] = acc[m2];
      __syncthreads();
    }
  }
}

// ---------------- small f32 GEMM (kept for Qg only) ----------------
struct GemmArgs {
  const float* a[4];
  const float* bsrc[4];
  int mode[4];
  const float* w[4];
  int nchunks;
  const float* bias;
  const float* aux0;
  const float* aux1;
  const float* aux2;
  float* out;
};

template<int EP>
__global__ __launch_bounds__(256)
void gemm_kernel(GemmArgs g) {
  __shared__ float As[64][33];
  __shared__ float Ws[32][65];
  const int t = threadIdx.x;
  const int m0 = blockIdx.y << 6, n0 = blockIdx.x << 6;
  const int tr = t >> 4, tc = t & 15;
  float acc[4][4];
#pragma unroll
  for (int x = 0; x < 4; ++x)
#pragma unroll
    for (int y = 0; y < 4; ++y) acc[x][y] = 0.f;
  const int arow = t >> 2, acs = (t & 3) << 3;
  const int wrow = t >> 3, wcs = (t & 7) << 3;
  for (int c = 0; c < g.nchunks; ++c) {
    const float* Ap = g.a[c] + (size_t)(m0 + arow) * HD + acs;
    const float* Wp = g.w[c] + (size_t)wrow * HD + n0 + wcs;
    for (int k0 = 0; k0 < HD; k0 += 32) {
      float4 a0 = *(const float4*)(Ap + k0);
      float4 a1 = *(const float4*)(Ap + k0 + 4);
      st8(&As[arow][acs], a0, a1);
      float4 w0 = *(const float4*)(Wp + (size_t)k0 * HD);
      float4 w1 = *(const float4*)(Wp + (size_t)k0 * HD + 4);
      st8(&Ws[wrow][wcs], w0, w1);
      __syncthreads();
#pragma unroll
      for (int kk = 0; kk < 32; ++kk) {
        float av[4], bv[4];
#pragma unroll
        for (int x = 0; x < 4; ++x) av[x] = As[(tr << 2) + x][kk];
#pragma unroll
        for (int y = 0; y < 4; ++y) bv[y] = Ws[kk][(tc << 2) + y];
#pragma unroll
        for (int x = 0; x < 4; ++x)
#pragma unroll
          for (int y = 0; y < 4; ++y) acc[x][y] = fmaf(av[x], bv[y], acc[x][y]);
      }
      __syncthreads();
    }
  }
#pragma unroll
  for (int x = 0; x < 4; ++x) {
    const int r = m0 + (tr << 2) + x;
#pragma unroll
    for (int y = 0; y < 4; ++y) {
      const int n = n0 + (tc << 2) + y;
      g.out[(size_t)r * HD + n] = acc[x][y] + g.bias[n];
    }
  }
}

// ---------------- weight convert+transpose: dst[n][kbase+k] = bf16(src[k][n]) ----------------
struct WcArgs {
  const float* src[4];
  unsigned short* dst;
  int Kw;
};

__global__ __launch_bounds__(256)
void wconv_kernel(WcArgs g) {
  __shared__ float tile[64][65];
  const int slice = blockIdx.y;
  const float* src = g.src[slice];
  const int kbase = slice * HD;
  const int bi = blockIdx.x % 12, bj = blockIdx.x / 12;  // bi: k-tile, bj: n-tile
  const int t = threadIdx.x;
  const int r = t >> 2, cseg = (t & 3) << 4;
  const float* p = src + (size_t)(bi * 64 + r) * HD + bj * 64 + cseg;
#pragma unroll
  for (int j = 0; j < 16; j += 4) {
    float4 v = *(const float4*)(p + j);
    tile[r][cseg + j + 0] = v.x; tile[r][cseg + j + 1] = v.y;
    tile[r][cseg + j + 2] = v.z; tile[r][cseg + j + 3] = v.w;
  }
  __syncthreads();
  unsigned short* q = g.dst + (size_t)(bj * 64 + r) * g.Kw + kbase + bi * 64 + cseg;
  u16x8 lo, hi;
#pragma unroll
  for (int j = 0; j < 8; ++j) lo[j] = f2bf(tile[cseg + j][r]);
#pragma unroll
  for (int j = 0; j < 8; ++j) hi[j] = f2bf(tile[cseg + 8 + j][r]);
  *(u16x8*)q = lo;
  *(u16x8*)(q + 8) = hi;
}

// ---------------- bf16 MFMA GEMM: out = ep( [f(a_c,b_c)]_concat @ Wt^T + ... ) ----------------
// A: M x K built on the fly from f32 sources (mode per 768-chunk), Wt: [768][K] bf16.
// Tile 128x128, BK=32, 4 waves (2x2), each wave 64x64 via 16 fragments of 16x16.
struct MMArgs {
  const float* a[4];
  const float* b2[4];
  int mode[4];           // 0: a ; 1: 3a-b ; 2: a*b ; 3: a-b
  int K;
  const unsigned short* wt;
  const float* bias;
  const float* aux0;     // o1   (EP_MERGE)
  const float* aux1;     // OCK  (EP_MERGE)
  const float* aux2;     // Qg   (EP_MERGE, includes Wg_b)
  float* out;
};

constexpr int LDP = 40;  // padded LDS stride in bf16 elems (80 B)

template<int EP>
__global__ __launch_bounds__(256)
void mfma_gemm_kernel(MMArgs g) {
  __shared__ __align__(16) unsigned short As[128 * LDP];
  __shared__ __align__(16) unsigned short Bs[128 * LDP];
  const int t = threadIdx.x;
  const int lane = t & 63, w = t >> 6;
  const int wr = w >> 1, wc = w & 1;
  const int m0 = blockIdx.y << 7, n0 = blockIdx.x << 7;
  const int l15 = lane & 15, l4 = lane >> 4;
  f32x4 acc[4][4] = {};

  const int srow = t >> 1, shalf = t & 1;
  const int nkt = g.K >> 5;
  for (int kt = 0; kt < nkt; ++kt) {
    const int c = kt / 24;                 // 768/32 = 24 k-tiles per chunk
    const int koff = (kt - c * 24) << 5;
    // ---- stage A: f32 load (+mode) -> bf16 -> LDS ----
    {
      const size_t ro = (size_t)(m0 + srow) * HD + koff + (shalf << 4);
      const float* ap = g.a[c] + ro;
      float4 x0 = *(const float4*)(ap);
      float4 x1 = *(const float4*)(ap + 4);
      float4 x2 = *(const float4*)(ap + 8);
      float4 x3 = *(const float4*)(ap + 12);
      const int mode = g.mode[c];
      if (mode) {
        const float* bp = g.b2[c] + ro;
        float4 y0 = *(const float4*)(bp);
        float4 y1 = *(const float4*)(bp + 4);
        float4 y2 = *(const float4*)(bp + 8);
        float4 y3 = *(const float4*)(bp + 12);
        if (mode == 1) {
          x0.x = fmaf(3.f, x0.x, -y0.x); x0.y = fmaf(3.f, x0.y, -y0.y);
          x0.z = fmaf(3.f, x0.z, -y0.z); x0.w = fmaf(3.f, x0.w, -y0.w);
          x1.x = fmaf(3.f, x1.x, -y1.x); x1.y = fmaf(3.f, x1.y, -y1.y);
          x1.z = fmaf(3.f, x1.z, -y1.z); x1.w = fmaf(3.f, x1.w, -y1.w);
          x2.x = fmaf(3.f, x2.x, -y2.x); x2.y = fmaf(3.f, x2.y, -y2.y);
          x2.z = fmaf(3.f, x2.z, -y2.z); x2.w = fmaf(3.f, x2.w, -y2.w);
          x3.x = fmaf(3.f, x3.x, -y3.x); x3.y = fmaf(3.f, x3.y, -y3.y);
          x3.z = fmaf(3.f, x3.z, -y3.z); x3.w = fmaf(3.f, x3.w, -y3.w);
        } else if (mode == 2) {
          x0.x *= y0.x; x0.y *= y0.y; x0.z *= y0.z; x0.w *= y0.w;
          x1.x *= y1.x; x1.y *= y1.y; x1.z *= y1.z; x1.w *= y1.w;
          x2.x *= y2.x; x2.y *= y2.y; x2.z *= y2.z; x2.w *= y2.w;
          x3.x *= y3.x; x3.y *= y3.y; x3.z *= y3.z; x3.w *= y3.w;
        } else {
          x0.x -= y0.x; x0.y -= y0.y; x0.z -= y0.z; x0.w -= y0.w;
          x1.x -= y1.x; x1.y -= y1.y; x1.z -= y1.z; x1.w -= y1.w;
          x2.x -= y2.x; x2.y -= y2.y; x2.z -= y2.z; x2.w -= y2.w;
          x3.x -= y3.x; x3.y -= y3.y; x3.z -= y3.z; x3.w -= y3.w;
        }
      }
      *(u16x8*)(&As[srow * LDP + (shalf << 4)]) = pack8(x0, x1);
      *(u16x8*)(&As[srow * LDP + (shalf << 4) + 8]) = pack8(x2, x3);
    }
    // ---- stage B: bf16 copy from Wt ----
    {
      const unsigned short* bp = g.wt + (size_t)(n0 + srow) * g.K + (kt << 5) + (shalf << 4);
      u16x8 w0 = *(const u16x8*)bp;
      u16x8 w1 = *(const u16x8*)(bp + 8);
      *(u16x8*)(&Bs[srow * LDP + (shalf << 4)]) = w0;
      *(u16x8*)(&Bs[srow * LDP + (shalf << 4) + 8]) = w1;
    }
    __syncthreads();
    bf16x8 af[4], bfr[4];
#pragma unroll
    for (int mi = 0; mi < 4; ++mi)
      af[mi] = *(const bf16x8*)(&As[(wr * 64 + mi * 16 + l15) * LDP + l4 * 8]);
#pragma unroll
    for (int ni = 0; ni < 4; ++ni)
      bfr[ni] = *(const bf16x8*)(&Bs[(wc * 64 + ni * 16 + l15) * LDP + l4 * 8]);
#pragma unroll
    for (int mi = 0; mi < 4; ++mi)
#pragma unroll
      for (int ni = 0; ni < 4; ++ni)
        acc[mi][ni] = __builtin_amdgcn_mfma_f32_16x16x32_bf16(af[mi], bfr[ni], acc[mi][ni], 0, 0, 0);
    __syncthreads();
  }

  if (EP == EP_RELU_MAX) {
#pragma unroll
    for (int ni = 0; ni < 4; ++ni) {
      const int n = n0 + wc * 64 + ni * 16 + l15;
      const float b = g.bias[n];
      float m = 0.f;
#pragma unroll
      for (int mi = 0; mi < 4; ++mi)
#pragma unroll
        for (int r = 0; r < 4; ++r)
          m = fmaxf(m, acc[mi][ni][r] + b);
      m = fmaxf(m, 0.f);
      m = fmaxf(m, __shfl_xor(m, 16));
      m = fmaxf(m, __shfl_xor(m, 32));
      if (l4 == 0) g.out[(size_t)((m0 >> 6) + wr) * HD + n] = m;
    }
  } else {
#pragma unroll
    for (int mi = 0; mi < 4; ++mi)
#pragma unroll
      for (int r = 0; r < 4; ++r) {
        const int row = m0 + wr * 64 + mi * 16 + l4 * 4 + r;
#pragma unroll
        for (int ni = 0; ni < 4; ++ni) {
          const int n = n0 + wc * 64 + ni * 16 + l15;
          const size_t oi = (size_t)row * HD + n;
          float v = acc[mi][ni][r];
          if (EP == EP_TANH) {
            g.out[oi] = tanhf(v + g.bias[n]);
          } else if (EP == EP_MERGE) {
            float gg = v + g.aux2[(size_t)(row >> 6) * HD + n];
            float sg = 1.f / (1.f + expf(-gg));
            float o1v = g.aux0[oi];
            float ock = g.aux1[oi];
            g.out[oi] = fmaf(sg, o1v - ock, ock);
          } else {  // EP_RELU
            g.out[oi] = fmaxf(v + g.bias[n], 0.f);
          }
        }
      }
  }
}

extern "C" void kernel_launch(void* const* d_in, const int* in_sizes, int n_in,
                              void* d_out, int out_size, void* d_ws, size_t ws_size,
                              hipStream_t stream) {
  const float* enc_o = (const float*)d_in[0];
  const float* enc_q = (const float*)d_in[1];
  const int* om = (const int*)d_in[2];
  const int* qm = (const int*)d_in[3];
  const float* att_W1_w = (const float*)d_in[4];
  const float* att_W1_b = (const float*)d_in[5];
  const float* att_W2_w = (const float*)d_in[6];
  const float* att_W2_b = (const float*)d_in[7];
  const float* att_W3 = (const float*)d_in[8];
  const float* Wc_self_w = (const float*)d_in[9];
  const float* Wc_self_b = (const float*)d_in[10];
  const float* Wc_w = (const float*)d_in[11];
  const float* Wc_b = (const float*)d_in[12];
  const float* Va_w = (const float*)d_in[13];
  const float* Va_b = (const float*)d_in[14];
  const float* Wg_w = (const float*)d_in[15];
  const float* Wg_b = (const float*)d_in[16];
  const float* co_W1_w = (const float*)d_in[17];
  const float* co_W1_b = (const float*)d_in[18];
  const float* co_W2_w = (const float*)d_in[19];
  const float* co_W2_b = (const float*)d_in[20];
  const float* co_W3 = (const float*)d_in[21];
  const float* Wp_w = (const float*)d_in[22];
  const float* Wp_b = (const float*)d_in[23];
  const float* sa_W1_w = (const float*)d_in[24];
  const float* sa_W1_b = (const float*)d_in[25];
  const float* sa_W2_w = (const float*)d_in[26];
  const float* sa_W2_b = (const float*)d_in[27];
  const float* sa_W3 = (const float*)d_in[28];
  const float* Wf_w = (const float*)d_in[29];
  const float* Wf_b = (const float*)d_in[30];
  float* out = (float*)d_out;

  const int NTOK_O = 16384;
  const int NTOK_Q = 32768;
  const int HH = 768 * 768;  // 589824

  float* ws = (float*)d_ws;
  size_t off = 0;
  auto carve = [&](size_t n) { float* p = ws + off; off += n; return p; };
  float* s1o   = carve(16384);
  float* s2o   = carve(16384);
  float* qa    = carve(32768);
  float* qco1  = carve(32768);
  float* ms2   = carve(16384);
  float* sa1   = carve(16384);
  float* sa2   = carve(16384);
  float* biasO = carve(1024);
  float* Qpool = carve(196608);
  float* Qg    = carve(196608);
  float* A2buf = carve(2097152);
  float* r1 = carve(12582912);   // CS -> OPK
  float* r2 = carve(12582912);   // OCK -> PLO
  float* r3 = carve(12582912);   // merged -> OSK
  float* r4 = carve(12582912);   // PHI
  unsigned short* wtb = (unsigned short*)carve(1179648);  // 768*3072 bf16 (4.7 MB)
  if (ws_size < off * sizeof(float)) return;
  float* CS = r1;   float* OPK = r1;
  float* OCK = r2;  float* PLO = r2;
  float* merged = r3; float* OSK = r3;
  float* PHI = r4;

  const dim3 GBIG(6, 128);   // 768/128 n-tiles x 16384/128 m-tiles

  // 1. per-token scalars
  dot768_kernel<<<NTOK_O / 4, 256, 0, stream>>>(enc_o, att_W1_w, att_W1_b, s1o, NTOK_O);
  dot768_kernel<<<NTOK_O / 4, 256, 0, stream>>>(enc_o, att_W2_w, att_W2_b, s2o, NTOK_O);
  dot768_kernel<<<NTOK_Q / 4, 256, 0, stream>>>(enc_q, Va_w, Va_b, qa, NTOK_Q);
  dot768_kernel<<<NTOK_Q / 4, 256, 0, stream>>>(enc_q, co_W1_w, co_W1_b, qco1, NTOK_Q);
  bias_ock_kernel<<<3, 256, 0, stream>>>(Wc_self_b, Wc_b, biasO);

  // 2. pairwise option-compare summed context
  attctx_kernel<3><<<256, 256, 0, stream>>>(enc_o, s1o, s2o, om, att_W3, CS);

  // 3. OCK = tanh([o1 | 3o1-CS | o1*CS] @ [Wc_self; Wc_hi; Wc_lo] + bias)
  {
    WcArgs wa{};
    wa.src[0] = Wc_self_w; wa.src[1] = Wc_w; wa.src[2] = Wc_w + HH;
    wa.dst = wtb; wa.Kw = 2304;
    wconv_kernel<<<dim3(144, 3), 256, 0, stream>>>(wa);
    MMArgs g{};
    g.a[0] = enc_o; g.b2[0] = nullptr; g.mode[0] = 0;
    g.a[1] = enc_o; g.b2[1] = CS;      g.mode[1] = 1;
    g.a[2] = enc_o; g.b2[2] = CS;      g.mode[2] = 2;
    g.K = 2304; g.wt = wtb; g.bias = biasO; g.out = OCK;
    mfma_gemm_kernel<EP_TANH><<<GBIG, 256, 0, stream>>>(g);
  }

  // 4. question pooling + Qg (tiny, f32)
  qpool_kernel<<<256, 256, 0, stream>>>(enc_q, qa, qm, Qpool);
  {
    GemmArgs g{};
    g.a[0] = Qpool; g.mode[0] = 0; g.w[0] = Wg_w + 2 * HH;
    g.nchunks = 1; g.bias = Wg_b; g.out = Qg;
    gemm_kernel<EP_STORE><<<dim3(12, 4), 256, 0, stream>>>(g);
  }

  // 5. merged = G*o1 + (1-G)*OCK, G = sigmoid([o1|OCK]@Wg12 + Qg)
  {
    WcArgs wa{};
    wa.src[0] = Wg_w; wa.src[1] = Wg_w + HH;
    wa.dst = wtb; wa.Kw = 1536;
    wconv_kernel<<<dim3(144, 2), 256, 0, stream>>>(wa);
    MMArgs g{};
    g.a[0] = enc_o; g.mode[0] = 0;
    g.a[1] = OCK;   g.mode[1] = 0;
    g.K = 1536; g.wt = wtb; g.bias = nullptr;
    g.aux0 = enc_o; g.aux1 = OCK; g.aux2 = Qg; g.out = merged;
    mfma_gemm_kernel<EP_MERGE><<<GBIG, 256, 0, stream>>>(g);
  }

  // 6. co-attention
  dot768_kernel<<<NTOK_O / 4, 256, 0, stream>>>(merged, co_W2_w, co_W2_b, ms2, NTOK_O);
  a2_kernel<<<256, 256, 0, stream>>>(enc_q, merged, qco1, ms2, qm, om, co_W3, A2buf);
  poaa_kernel<<<256, 256, 0, stream>>>(A2buf, enc_q, merged, PLO, PHI);

  // 7. OPK = relu([merged | PLO | PHI] @ Wp + b)
  {
    WcArgs wa{};
    wa.src[0] = Wp_w; wa.src[1] = Wp_w + HH; wa.src[2] = Wp_w + 2 * HH;
    wa.dst = wtb; wa.Kw = 2304;
    wconv_kernel<<<dim3(144, 3), 256, 0, stream>>>(wa);
    MMArgs g{};
    g.a[0] = merged; g.mode[0] = 0;
    g.a[1] = PLO;    g.mode[1] = 0;
    g.a[2] = PHI;    g.mode[2] = 0;
    g.K = 2304; g.wt = wtb; g.bias = Wp_b; g.out = OPK;
    mfma_gemm_kernel<EP_RELU><<<GBIG, 256, 0, stream>>>(g);
  }

  // 8. self-attention
  dot768_kernel<<<NTOK_O / 4, 256, 0, stream>>>(OPK, sa_W1_w, sa_W1_b, sa1, NTOK_O);
  dot768_kernel<<<NTOK_O / 4, 256, 0, stream>>>(OPK, sa_W2_w, sa_W2_b, sa2, NTOK_O);
  attctx_kernel<1><<<256, 256, 0, stream>>>(OPK, sa1, sa2, om, sa_W3, OSK);

  // 9. out = max_lo relu([OPK | OSK | OPK-OSK | OPK*OSK] @ Wf + b)
  {
    WcArgs wa{};
    wa.src[0] = Wf_w; wa.src[1] = Wf_w + HH; wa.src[2] = Wf_w + 2 * HH; wa.src[3] = Wf_w + 3 * HH;
    wa.dst = wtb; wa.Kw = 3072;
    wconv_kernel<<<dim3(144, 4), 256, 0, stream>>>(wa);
    MMArgs g{};
    g.a[0] = OPK; g.mode[0] = 0;
    g.a[1] = OSK; g.mode[1] = 0;
    g.a[2] = OPK; g.b2[2] = OSK; g.mode[2] = 3;
    g.a[3] = OPK; g.b2[3] = OSK; g.mode[3] = 2;
    g.K = 3072; g.wt = wtb; g.bias = Wf_b; g.out = out;
    mfma_gemm_kernel<EP_RELU_MAX><<<GBIG, 256, 0, stream>>>(g);
  }
}

// Round 3
// 1401.585 us; speedup vs baseline: 3.9013x; 1.3893x over previous
//
#include <hip/hip_runtime.h>
#include <math.h>

// OptionCompareCell: B=64,C=4,LO=64,LQ=128,H=768
// Round 3: attctx -> MFMA 3-kernel pipeline (bfprep + p1 + p2).
//  p1: per-(b,i,j) block, S = Ubf . (w3*V)bf^T via mfma_16x16x32_bf16, softmax,
//      writes Pt[v][u] bf16 to global (transposed so p2 A-frags are b128 reads).
//  p2: per-(d-quarter, bc) block, ctx = sum_j Pt_j . U_j (contraction over u),
//      U staged in LDS with XOR swizzle ((u>>3)&3)<<5, B-frags via ds_read_u16.
// GEMMs/a2/poaa/qpool/dot768 unchanged from round 2.

#define NEGC (-10000.0f)
constexpr int HD = 768;

constexpr int EP_STORE = 0;
constexpr int EP_TANH = 1;
constexpr int EP_MERGE = 2;
constexpr int EP_RELU = 3;
constexpr int EP_RELU_MAX = 4;

typedef __attribute__((ext_vector_type(8))) short bf16x8;
typedef __attribute__((ext_vector_type(8))) unsigned short u16x8;
typedef __attribute__((ext_vector_type(4))) float f32x4;

__device__ inline void st8(float* dst, float4 a0, float4 a1) {
  dst[0] = a0.x; dst[1] = a0.y; dst[2] = a0.z; dst[3] = a0.w;
  dst[4] = a1.x; dst[5] = a1.y; dst[6] = a1.z; dst[7] = a1.w;
}

__device__ inline unsigned short f2bf(float x) {
  unsigned int u = __float_as_uint(x);
  u += 0x7fffu + ((u >> 16) & 1u);
  return (unsigned short)(u >> 16);
}

__device__ inline u16x8 pack8(float4 a, float4 b) {
  u16x8 r;
  r[0] = f2bf(a.x); r[1] = f2bf(a.y); r[2] = f2bf(a.z); r[3] = f2bf(a.w);
  r[4] = f2bf(b.x); r[5] = f2bf(b.y); r[6] = f2bf(b.z); r[7] = f2bf(b.w);
  return r;
}

// ---------------- per-token dot with a [768] vector + scalar bias ----------------
__global__ __launch_bounds__(256)
void dot768_kernel(const float* __restrict__ x, const float* __restrict__ w,
                   const float* __restrict__ bias, float* __restrict__ out, int ntok) {
  int tok = blockIdx.x * 4 + (threadIdx.x >> 6);
  int lane = threadIdx.x & 63;
  if (tok >= ntok) return;
  const float* xp = x + (size_t)tok * HD;
  float s = 0.f;
#pragma unroll
  for (int i = 0; i < 3; ++i) {
    int c = (lane + (i << 6)) << 2;
    float4 xv = *(const float4*)(xp + c);
    float4 wv = *(const float4*)(w + c);
    s = fmaf(xv.x, wv.x, s); s = fmaf(xv.y, wv.y, s);
    s = fmaf(xv.z, wv.z, s); s = fmaf(xv.w, wv.w, s);
  }
#pragma unroll
  for (int off = 32; off; off >>= 1) s += __shfl_xor(s, off);
  if (lane == 0) out[tok] = s + bias[0];
}

__global__ void bias_ock_kernel(const float* __restrict__ b1, const float* __restrict__ b2,
                                float* __restrict__ o) {
  int n = blockIdx.x * 256 + threadIdx.x;
  if (n < HD) o[n] = b1[n] + 3.f * b2[n];
}

// ---------------- bf16 prep: xbf = bf16(x), xw3 = bf16(x * w3[col]) ----------------
__global__ __launch_bounds__(256)
void bfprep_kernel(const float* __restrict__ x, const float* __restrict__ w3,
                   unsigned short* __restrict__ xbf, unsigned short* __restrict__ xw3) {
  size_t base = ((size_t)blockIdx.x * 256 + threadIdx.x) * 8;
  int col = (int)(base % HD);
  float4 a0 = *(const float4*)(x + base);
  float4 a1 = *(const float4*)(x + base + 4);
  float4 w0 = *(const float4*)(w3 + col);
  float4 w1 = *(const float4*)(w3 + col + 4);
  *(u16x8*)(xbf + base) = pack8(a0, a1);
  float4 s0, s1;
  s0.x = a0.x * w0.x; s0.y = a0.y * w0.y; s0.z = a0.z * w0.z; s0.w = a0.w * w0.w;
  s1.x = a1.x * w1.x; s1.y = a1.y * w1.y; s1.z = a1.z * w1.z; s1.w = a1.w * w1.w;
  *(u16x8*)(xw3 + base) = pack8(s0, s1);
}

// ---------------- P1: S = U . Vw3^T (MFMA), softmax over u, write Pt[v][u] bf16 ----------------
// NJ==3: grid 768 blocks = (b, i, jj). NJ==1: grid 256 blocks = bc (self).
template<int NJ>
__global__ __launch_bounds__(256)
void p1_kernel(const unsigned short* __restrict__ Xbf, const unsigned short* __restrict__ Xw3,
               const float* __restrict__ s1g, const float* __restrict__ s2g,
               const int* __restrict__ maskg, unsigned short* __restrict__ PtG) {
  __shared__ __align__(16) unsigned short Ua[64 * 136];
  __shared__ __align__(16) unsigned short Vb[64 * 136];
  __shared__ float Sbuf[64][66];
  __shared__ float red[4][64];
  const int t = threadIdx.x;
  int ubc, vbc;
  if (NJ == 1) {
    ubc = vbc = blockIdx.x;
  } else {
    const int b = blockIdx.x / 12, pr = blockIdx.x % 12;
    const int i = pr / 3, jj = pr % 3;
    const int j = jj + (jj >= i ? 1 : 0);
    vbc = (b << 2) + i; ubc = (b << 2) + j;
  }
  const unsigned short* U = Xbf + (size_t)ubc * (64 * HD);
  const unsigned short* V = Xw3 + (size_t)vbc * (64 * HD);
  const int w = t >> 6, lane = t & 63, l15 = lane & 15, l4 = lane >> 4;
  const int srow = t >> 2, scol = (t & 3) << 5;
  f32x4 acc[4] = {};
  for (int k0 = 0; k0 < HD; k0 += 128) {
    const unsigned short* up = U + (size_t)srow * HD + k0 + scol;
    const unsigned short* vp = V + (size_t)srow * HD + k0 + scol;
    unsigned short* ua = &Ua[srow * 136 + scol];
    unsigned short* vb = &Vb[srow * 136 + scol];
#pragma unroll
    for (int z = 0; z < 4; ++z) {
      *(u16x8*)(ua + z * 8) = *(const u16x8*)(up + z * 8);
      *(u16x8*)(vb + z * 8) = *(const u16x8*)(vp + z * 8);
    }
    __syncthreads();
#pragma unroll
    for (int ks = 0; ks < 4; ++ks) {
      bf16x8 af = *(const bf16x8*)(&Ua[(w * 16 + l15) * 136 + ks * 32 + l4 * 8]);
#pragma unroll
      for (int n = 0; n < 4; ++n) {
        bf16x8 bf = *(const bf16x8*)(&Vb[(n * 16 + l15) * 136 + ks * 32 + l4 * 8]);
        acc[n] = __builtin_amdgcn_mfma_f32_16x16x32_bf16(af, bf, acc[n], 0, 0, 0);
      }
    }
    __syncthreads();
  }
  // add row/col bias+mask terms; S[u][v] into LDS
  {
    float s1v[4];
#pragma unroll
    for (int r = 0; r < 4; ++r) {
      int u = w * 16 + l4 * 4 + r;
      s1v[r] = s1g[ubc * 64 + u] + (1.f - (float)maskg[ubc * 64 + u]) * NEGC;
    }
#pragma unroll
    for (int n = 0; n < 4; ++n) {
      int v = n * 16 + l15;
      float s2v = s2g[vbc * 64 + v] + (1.f - (float)maskg[vbc * 64 + v]) * NEGC;
#pragma unroll
      for (int r = 0; r < 4; ++r)
        Sbuf[w * 16 + l4 * 4 + r][v] = acc[n][r] + s1v[r] + s2v;
    }
  }
  __syncthreads();
  // softmax over u per column v, then Pt[v][u] bf16 (includes 1/sum)
  {
    const int v = t & 63, part = t >> 6;
    float m = -1e30f;
#pragma unroll
    for (int z = 0; z < 16; ++z) m = fmaxf(m, Sbuf[part * 16 + z][v]);
    red[part][v] = m;
    __syncthreads();
    float gm = fmaxf(fmaxf(red[0][v], red[1][v]), fmaxf(red[2][v], red[3][v]));
    float s = 0.f;
#pragma unroll
    for (int z = 0; z < 16; ++z) {
      float e = expf(Sbuf[part * 16 + z][v] - gm);
      Sbuf[part * 16 + z][v] = e;
      s += e;
    }
    __syncthreads();
    red[part][v] = s;
    __syncthreads();
    float cinv = 1.f / (red[0][v] + red[1][v] + red[2][v] + red[3][v]);
    unsigned short* pt = PtG + (size_t)blockIdx.x * 4096 + v * 64 + part * 16;
#pragma unroll
    for (int z = 0; z < 16; ++z) pt[z] = f2bf(Sbuf[part * 16 + z][v] * cinv);
  }
}

// ---------------- P2: ctx[v][d] = sum_j sum_u Pt_j[v][u] * U_j[u][d] ----------------
// grid dim3(4, 256): dq = d-quarter (192 cols), bc. U2 XOR-swizzled, B-frags via u16 reads.
template<int NJ>
__global__ __launch_bounds__(256)
void p2_kernel(const unsigned short* __restrict__ Xbf, const unsigned short* __restrict__ PtG,
               float* __restrict__ outg) {
  __shared__ __align__(16) unsigned short Pts[NJ][64 * 72];
  __shared__ __align__(16) unsigned short U2[64 * 192];
  const int t = threadIdx.x;
  const int dq = blockIdx.x, bc = blockIdx.y;
  const int d0 = dq * 192;
  const int b = bc >> 2, i = bc & 3;
  const int w = t >> 6, lane = t & 63, l15 = lane & 15, l4 = lane >> 4;
  // stage all Pt_j
  {
    const int v = t >> 2, cs = (t & 3) << 4;
#pragma unroll
    for (int jj = 0; jj < NJ; ++jj) {
      size_t src = (NJ == 1 ? (size_t)bc : (size_t)(b * 12 + i * 3 + jj)) * 4096 + v * 64 + cs;
      *(u16x8*)(&Pts[jj][v * 72 + cs]) = *(const u16x8*)(PtG + src);
      *(u16x8*)(&Pts[jj][v * 72 + cs + 8]) = *(const u16x8*)(PtG + src + 8);
    }
  }
  f32x4 acc[4][3] = {};
  const int su = t >> 2, sc0 = (t & 3) * 48;
  const int sswz = ((su >> 3) & 3) << 5;
  for (int jj = 0; jj < NJ; ++jj) {
    const int ubc = (NJ == 1) ? bc : ((b << 2) + (jj + (jj >= i ? 1 : 0)));
    __syncthreads();  // U2 reuse guard (also covers Pt staging on first iter)
    {
      const unsigned short* up = Xbf + (size_t)ubc * (64 * HD) + (size_t)su * HD + d0 + sc0;
#pragma unroll
      for (int it = 0; it < 6; ++it) {
        u16x8 vdat = *(const u16x8*)(up + it * 8);
        *(u16x8*)((char*)U2 + ((su * 384 + (sc0 + it * 8) * 2) ^ sswz)) = vdat;
      }
    }
    __syncthreads();
    const unsigned short* ptj = &Pts[jj][0];
#pragma unroll
    for (int ks = 0; ks < 2; ++ks) {
      bf16x8 bfr[3];
#pragma unroll
      for (int n = 0; n < 3; ++n) {
        const int col = (w * 3 + n) * 16 + l15;
#pragma unroll
        for (int e = 0; e < 8; ++e) {
          const int uk = ks * 32 + l4 * 8 + e;
          const int byte = (uk * 384 + col * 2) ^ (((uk >> 3) & 3) << 5);
          bfr[n][e] = *(const short*)((const char*)U2 + byte);
        }
      }
#pragma unroll
      for (int m = 0; m < 4; ++m) {
        bf16x8 af = *(const bf16x8*)(ptj + (m * 16 + l15) * 72 + ks * 32 + l4 * 8);
#pragma unroll
        for (int n = 0; n < 3; ++n)
          acc[m][n] = __builtin_amdgcn_mfma_f32_16x16x32_bf16(af, bfr[n], acc[m][n], 0, 0, 0);
      }
    }
  }
  float* op = outg + (size_t)bc * (64 * HD);
#pragma unroll
  for (int m = 0; m < 4; ++m)
#pragma unroll
    for (int n = 0; n < 3; ++n) {
      const int d = d0 + (w * 3 + n) * 16 + l15;
#pragma unroll
      for (int r = 0; r < 4; ++r) {
        const int v = m * 16 + l4 * 4 + r;
        op[(size_t)v * HD + d] = acc[m][n][r];
      }
    }
}

// ---------------- question pooling: Q[bc,:] = softmax(qa)^T q ----------------
__global__ __launch_bounds__(256)
void qpool_kernel(const float* __restrict__ q, const float* __restrict__ qa,
                  const int* __restrict__ qm, float* __restrict__ Q) {
  __shared__ float wgt[128];
  __shared__ float wred[4];
  int t = threadIdx.x, bc = blockIdx.x;
  const float* qap = qa + bc * 128;
  const int* qmp = qm + bc * 128;
  float v = -1e30f;
  if (t < 128) v = qap[t] + (1.f - (float)qmp[t]) * NEGC;
  float m = v;
#pragma unroll
  for (int off = 32; off; off >>= 1) m = fmaxf(m, __shfl_xor(m, off));
  if ((t & 63) == 0) wred[t >> 6] = m;
  __syncthreads();
  float gm = fmaxf(fmaxf(wred[0], wred[1]), fmaxf(wred[2], wred[3]));
  float e = (t < 128) ? expf(v - gm) : 0.f;
  float s = e;
#pragma unroll
  for (int off = 32; off; off >>= 1) s += __shfl_xor(s, off);
  __syncthreads();
  if ((t & 63) == 0) wred[t >> 6] = s;
  __syncthreads();
  float tot = wred[0] + wred[1] + wred[2] + wred[3];
  if (t < 128) wgt[t] = e / tot;
  __syncthreads();
  const float* qp = q + (size_t)bc * (128 * HD);
  float* Qp = Q + (size_t)bc * HD;
  for (int d = t; d < HD; d += 256) {
    float acc = 0.f;
    for (int l = 0; l < 128; ++l) acc = fmaf(wgt[l], qp[(size_t)l * HD + d], acc);
    Qp[d] = acc;
  }
}

// ---------------- A2[bc][q][v] = trilinear(q, merged) ----------------
__global__ __launch_bounds__(256)
void a2_kernel(const float* __restrict__ q, const float* __restrict__ merged,
               const float* __restrict__ qco1, const float* __restrict__ ms2,
               const int* __restrict__ qm, const int* __restrict__ om,
               const float* __restrict__ w3, float* __restrict__ A2) {
  __shared__ float Qt[128][33];
  __shared__ float Mt[64][33];
  const int t = threadIdx.x, bc = blockIdx.x;
  const float* qp = q + (size_t)bc * (128 * HD);
  const float* mp = merged + (size_t)bc * (64 * HD);
  const int tr = t >> 4, tc = t & 15;
  float acc[8][4];
#pragma unroll
  for (int x = 0; x < 8; ++x)
#pragma unroll
    for (int y = 0; y < 4; ++y) acc[x][y] = 0.f;
  for (int k0 = 0; k0 < HD; k0 += 32) {
    {
      int row = t >> 1, cs = (t & 1) << 4;
      const float* p = qp + (size_t)row * HD + k0 + cs;
#pragma unroll
      for (int z = 0; z < 4; ++z) {
        float4 a = *(const float4*)(p + (z << 2));
        float4 w = *(const float4*)(w3 + k0 + cs + (z << 2));
        Qt[row][cs + (z << 2) + 0] = a.x * w.x;
        Qt[row][cs + (z << 2) + 1] = a.y * w.y;
        Qt[row][cs + (z << 2) + 2] = a.z * w.z;
        Qt[row][cs + (z << 2) + 3] = a.w * w.w;
      }
    }
    {
      int row = t >> 2, cs = (t & 3) << 3;
      const float* p = mp + (size_t)row * HD + k0 + cs;
      float4 a0 = *(const float4*)p, a1 = *(const float4*)(p + 4);
      st8(&Mt[row][cs], a0, a1);
    }
    __syncthreads();
#pragma unroll
    for (int kk = 0; kk < 32; ++kk) {
      float qv[8], mv[4];
#pragma unroll
      for (int x = 0; x < 8; ++x) qv[x] = Qt[(tr << 3) + x][kk];
#pragma unroll
      for (int y = 0; y < 4; ++y) mv[y] = Mt[(tc << 2) + y][kk];
#pragma unroll
      for (int x = 0; x < 8; ++x)
#pragma unroll
        for (int y = 0; y < 4; ++y) acc[x][y] = fmaf(qv[x], mv[y], acc[x][y]);
    }
    __syncthreads();
  }
  const float* qc = qco1 + bc * 128;
  const float* msp = ms2 + bc * 64;
  const int* qmp = qm + bc * 128;
  const int* omp = om + bc * 64;
  float* outp = A2 + (size_t)bc * (128 * 64);
  float cterm[4];
#pragma unroll
  for (int y = 0; y < 4; ++y) {
    int v = (tc << 2) + y;
    cterm[y] = msp[v] + (1.f - (float)omp[v]) * NEGC;
  }
#pragma unroll
  for (int x = 0; x < 8; ++x) {
    int qrow = (tr << 3) + x;
    float rterm = qc[qrow] + (1.f - (float)qmp[qrow]) * NEGC;
#pragma unroll
    for (int y = 0; y < 4; ++y) {
      int v = (tc << 2) + y;
      outp[qrow * 64 + v] = acc[x][y] + rterm + cterm[y];
    }
  }
}

// ------------- POAA: PLO = APK^T q ; PHI = (APK^T ACK) merged (OA eliminated) -------------
__global__ __launch_bounds__(256)
void poaa_kernel(const float* __restrict__ A2, const float* __restrict__ qin,
                 const float* __restrict__ merged,
                 float* __restrict__ PLO, float* __restrict__ PHI) {
  __shared__ float T[128][65];
  __shared__ float Tf[128][65];
  __shared__ float M2s[64][65];
  __shared__ float tile[128][33];
  __shared__ float red[4][64];
  __shared__ float rowm[128], rowfac[128];
  __shared__ float colm[64], colfac[64];
  __shared__ float gmax_s;

  const int t = threadIdx.x, bc = blockIdx.x;
  const float* a2 = A2 + (size_t)bc * (128 * 64);
  {
    int row = t >> 1, cs = (t & 1) << 5;
    const float* p = a2 + row * 64 + cs;
#pragma unroll
    for (int z = 0; z < 8; ++z) {
      float4 v = *(const float4*)(p + (z << 2));
      T[row][cs + (z << 2) + 0] = v.x;
      T[row][cs + (z << 2) + 1] = v.y;
      T[row][cs + (z << 2) + 2] = v.z;
      T[row][cs + (z << 2) + 3] = v.w;
    }
  }
  __syncthreads();
  {
    int qrow = t >> 1, h = t & 1;
    float m = -1e30f;
    for (int v = h * 32; v < h * 32 + 32; ++v) m = fmaxf(m, T[qrow][v]);
    m = fmaxf(m, __shfl_xor(m, 1));
    float s = 0.f;
    for (int v = h * 32; v < h * 32 + 32; ++v) s += expf(T[qrow][v] - m);
    s += __shfl_xor(s, 1);
    if (h == 0) { rowm[qrow] = m; rowfac[qrow] = s; }
  }
  {
    int v = t & 63, part = t >> 6;
    float m = -1e30f;
    for (int qq = part * 32; qq < part * 32 + 32; ++qq) m = fmaxf(m, T[qq][v]);
    red[part][v] = m;
    __syncthreads();
    float cm = fmaxf(fmaxf(red[0][v], red[1][v]), fmaxf(red[2][v], red[3][v]));
    float s = 0.f;
    for (int qq = part * 32; qq < part * 32 + 32; ++qq) s += expf(T[qq][v] - cm);
    __syncthreads();
    red[part][v] = s;
    __syncthreads();
    if (part == 0) { colm[v] = cm; colfac[v] = red[0][v] + red[1][v] + red[2][v] + red[3][v]; }
  }
  __syncthreads();
  if (t < 64) {
    float m = fmaxf(rowm[t], rowm[t + 64]);
#pragma unroll
    for (int off = 32; off; off >>= 1) m = fmaxf(m, __shfl_xor(m, off));
    if (t == 0) gmax_s = m;
  }
  __syncthreads();
  float gmax = gmax_s;
  if (t < 128) rowfac[t] = expf(fminf(gmax - rowm[t], 60.f)) / rowfac[t];
  if (t < 64) colfac[t] = expf(fminf(gmax - colm[t], 60.f)) / colfac[t];
  __syncthreads();
  {
    int row = t >> 1, cs = (t & 1) << 5;
    float fr = rowfac[row];
    for (int z = 0; z < 32; ++z) {
      float e = expf(T[row][cs + z] - gmax);
      T[row][cs + z] = e;
      Tf[row][cs + z] = e * fr;
    }
  }
  __syncthreads();
  {
    const int tr = t >> 4, tc = t & 15;
    float acc[4][4];
#pragma unroll
    for (int x = 0; x < 4; ++x)
#pragma unroll
      for (int y = 0; y < 4; ++y) acc[x][y] = 0.f;
    for (int qq = 0; qq < 128; ++qq) {
      float a[4], bb[4];
#pragma unroll
      for (int x = 0; x < 4; ++x) a[x] = T[qq][(tr << 2) + x];
#pragma unroll
      for (int y = 0; y < 4; ++y) bb[y] = Tf[qq][(tc << 2) + y];
#pragma unroll
      for (int x = 0; x < 4; ++x)
#pragma unroll
        for (int y = 0; y < 4; ++y) acc[x][y] = fmaf(a[x], bb[y], acc[x][y]);
    }
#pragma unroll
    for (int x = 0; x < 4; ++x) {
      float gf = colfac[(tr << 2) + x];
#pragma unroll
      for (int y = 0; y < 4; ++y) M2s[(tr << 2) + x][(tc << 2) + y] = gf * acc[x][y];
    }
  }
  __syncthreads();
  const float* qp = qin + (size_t)bc * (128 * HD);
  float* plo = PLO + (size_t)bc * (64 * HD);
  {
    const int dl = t & 31, op0 = t >> 5;
    for (int dt = 0; dt < HD; dt += 32) {
      {
        int row = t >> 1, cs = (t & 1) << 4;
        const float* p = qp + (size_t)row * HD + dt + cs;
#pragma unroll
        for (int z = 0; z < 4; ++z) {
          float4 v = *(const float4*)(p + (z << 2));
          tile[row][cs + (z << 2) + 0] = v.x;
          tile[row][cs + (z << 2) + 1] = v.y;
          tile[row][cs + (z << 2) + 2] = v.z;
          tile[row][cs + (z << 2) + 3] = v.w;
        }
      }
      __syncthreads();
      float acc[8];
#pragma unroll
      for (int m2 = 0; m2 < 8; ++m2) acc[m2] = 0.f;
      for (int qq = 0; qq < 128; ++qq) {
        float qd = tile[qq][dl];
#pragma unroll
        for (int m2 = 0; m2 < 8; ++m2)
          acc[m2] = fmaf(T[qq][op0 + (m2 << 3)], qd, acc[m2]);
      }
#pragma unroll
      for (int m2 = 0; m2 < 8; ++m2) {
        int o = op0 + (m2 << 3);
        plo[(size_t)o * HD + dt + dl] = colfac[o] * acc[m2];
      }
      __syncthreads();
    }
  }
  const float* mp = merged + (size_t)bc * (64 * HD);
  float* phi = PHI + (size_t)bc * (64 * HD);
  {
    const int dl = t & 31, op0 = t >> 5;
    for (int dt = 0; dt < HD; dt += 32) {
      {
        int row = t >> 2, cs = (t & 3) << 3;
        const float* p = mp + (size_t)row * HD + dt + cs;
        float4 a0 = *(const float4*)p, a1 = *(const float4*)(p + 4);
        st8(&tile[row][cs], a0, a1);
      }
      __syncthreads();
      float acc[8];
#pragma unroll
      for (int m2 = 0; m2 < 8; ++m2) acc[m2] = 0.f;
      for (int v = 0; v < 64; ++v) {
        float md = tile[v][dl];
#pragma unroll
        for (int m2 = 0; m2 < 8; ++m2)
          acc[m2] = fmaf(M2s[op0 + (m2 << 3)][v], md, acc[m2]);
      }
#pragma unroll
      for (int m2 = 0; m2 < 8; ++m2)
        phi[(size_t)(op0 + (m2 << 3)) * HD + dt + dl] = acc[m2];
      __syncthreads();
    }
  }
}

// ---------------- small f32 GEMM (Qg only) ----------------
struct GemmArgs {
  const float* a[4];
  const float* bsrc[4];
  int mode[4];
  const float* w[4];
  int nchunks;
  const float* bias;
  const float* aux0;
  const float* aux1;
  const float* aux2;
  float* out;
};

template<int EP>
__global__ __launch_bounds__(256)
void gemm_kernel(GemmArgs g) {
  __shared__ float As[64][33];
  __shared__ float Ws[32][65];
  const int t = threadIdx.x;
  const int m0 = blockIdx.y << 6, n0 = blockIdx.x << 6;
  const int tr = t >> 4, tc = t & 15;
  float acc[4][4];
#pragma unroll
  for (int x = 0; x < 4; ++x)
#pragma unroll
    for (int y = 0; y < 4; ++y) acc[x][y] = 0.f;
  const int arow = t >> 2, acs = (t & 3) << 3;
  const int wrow = t >> 3, wcs = (t & 7) << 3;
  for (int c = 0; c < g.nchunks; ++c) {
    const float* Ap = g.a[c] + (size_t)(m0 + arow) * HD + acs;
    const float* Wp = g.w[c] + (size_t)wrow * HD + n0 + wcs;
    for (int k0 = 0; k0 < HD; k0 += 32) {
      float4 a0 = *(const float4*)(Ap + k0);
      float4 a1 = *(const float4*)(Ap + k0 + 4);
      st8(&As[arow][acs], a0, a1);
      float4 w0 = *(const float4*)(Wp + (size_t)k0 * HD);
      float4 w1 = *(const float4*)(Wp + (size_t)k0 * HD + 4);
      st8(&Ws[wrow][wcs], w0, w1);
      __syncthreads();
#pragma unroll
      for (int kk = 0; kk < 32; ++kk) {
        float av[4], bv[4];
#pragma unroll
        for (int x = 0; x < 4; ++x) av[x] = As[(tr << 2) + x][kk];
#pragma unroll
        for (int y = 0; y < 4; ++y) bv[y] = Ws[kk][(tc << 2) + y];
#pragma unroll
        for (int x = 0; x < 4; ++x)
#pragma unroll
          for (int y = 0; y < 4; ++y) acc[x][y] = fmaf(av[x], bv[y], acc[x][y]);
      }
      __syncthreads();
    }
  }
#pragma unroll
  for (int x = 0; x < 4; ++x) {
    const int r = m0 + (tr << 2) + x;
#pragma unroll
    for (int y = 0; y < 4; ++y) {
      const int n = n0 + (tc << 2) + y;
      g.out[(size_t)r * HD + n] = acc[x][y] + g.bias[n];
    }
  }
}

// ---------------- weight convert+transpose ----------------
struct WcArgs {
  const float* src[4];
  unsigned short* dst;
  int Kw;
};

__global__ __launch_bounds__(256)
void wconv_kernel(WcArgs g) {
  __shared__ float tile[64][65];
  const int slice = blockIdx.y;
  const float* src = g.src[slice];
  const int kbase = slice * HD;
  const int bi = blockIdx.x % 12, bj = blockIdx.x / 12;
  const int t = threadIdx.x;
  const int r = t >> 2, cseg = (t & 3) << 4;
  const float* p = src + (size_t)(bi * 64 + r) * HD + bj * 64 + cseg;
#pragma unroll
  for (int j = 0; j < 16; j += 4) {
    float4 v = *(const float4*)(p + j);
    tile[r][cseg + j + 0] = v.x; tile[r][cseg + j + 1] = v.y;
    tile[r][cseg + j + 2] = v.z; tile[r][cseg + j + 3] = v.w;
  }
  __syncthreads();
  unsigned short* q = g.dst + (size_t)(bj * 64 + r) * g.Kw + kbase + bi * 64 + cseg;
  u16x8 lo, hi;
#pragma unroll
  for (int j = 0; j < 8; ++j) lo[j] = f2bf(tile[cseg + j][r]);
#pragma unroll
  for (int j = 0; j < 8; ++j) hi[j] = f2bf(tile[cseg + 8 + j][r]);
  *(u16x8*)q = lo;
  *(u16x8*)(q + 8) = hi;
}

// ---------------- bf16 MFMA GEMM ----------------
struct MMArgs {
  const float* a[4];
  const float* b2[4];
  int mode[4];           // 0: a ; 1: 3a-b ; 2: a*b ; 3: a-b
  int K;
  const unsigned short* wt;
  const float* bias;
  const float* aux0;
  const float* aux1;
  const float* aux2;
  float* out;
};

constexpr int LDP = 40;

template<int EP>
__global__ __launch_bounds__(256)
void mfma_gemm_kernel(MMArgs g) {
  __shared__ __align__(16) unsigned short As[128 * LDP];
  __shared__ __align__(16) unsigned short Bs[128 * LDP];
  const int t = threadIdx.x;
  const int lane = t & 63, w = t >> 6;
  const int wr = w >> 1, wc = w & 1;
  const int m0 = blockIdx.y << 7, n0 = blockIdx.x << 7;
  const int l15 = lane & 15, l4 = lane >> 4;
  f32x4 acc[4][4] = {};

  const int srow = t >> 1, shalf = t & 1;
  const int nkt = g.K >> 5;
  for (int kt = 0; kt < nkt; ++kt) {
    const int c = kt / 24;
    const int koff = (kt - c * 24) << 5;
    {
      const size_t ro = (size_t)(m0 + srow) * HD + koff + (shalf << 4);
      const float* ap = g.a[c] + ro;
      float4 x0 = *(const float4*)(ap);
      float4 x1 = *(const float4*)(ap + 4);
      float4 x2 = *(const float4*)(ap + 8);
      float4 x3 = *(const float4*)(ap + 12);
      const int mode = g.mode[c];
      if (mode) {
        const float* bp = g.b2[c] + ro;
        float4 y0 = *(const float4*)(bp);
        float4 y1 = *(const float4*)(bp + 4);
        float4 y2 = *(const float4*)(bp + 8);
        float4 y3 = *(const float4*)(bp + 12);
        if (mode == 1) {
          x0.x = fmaf(3.f, x0.x, -y0.x); x0.y = fmaf(3.f, x0.y, -y0.y);
          x0.z = fmaf(3.f, x0.z, -y0.z); x0.w = fmaf(3.f, x0.w, -y0.w);
          x1.x = fmaf(3.f, x1.x, -y1.x); x1.y = fmaf(3.f, x1.y, -y1.y);
          x1.z = fmaf(3.f, x1.z, -y1.z); x1.w = fmaf(3.f, x1.w, -y1.w);
          x2.x = fmaf(3.f, x2.x, -y2.x); x2.y = fmaf(3.f, x2.y, -y2.y);
          x2.z = fmaf(3.f, x2.z, -y2.z); x2.w = fmaf(3.f, x2.w, -y2.w);
          x3.x = fmaf(3.f, x3.x, -y3.x); x3.y = fmaf(3.f, x3.y, -y3.y);
          x3.z = fmaf(3.f, x3.z, -y3.z); x3.w = fmaf(3.f, x3.w, -y3.w);
        } else if (mode == 2) {
          x0.x *= y0.x; x0.y *= y0.y; x0.z *= y0.z; x0.w *= y0.w;
          x1.x *= y1.x; x1.y *= y1.y; x1.z *= y1.z; x1.w *= y1.w;
          x2.x *= y2.x; x2.y *= y2.y; x2.z *= y2.z; x2.w *= y2.w;
          x3.x *= y3.x; x3.y *= y3.y; x3.z *= y3.z; x3.w *= y3.w;
        } else {
          x0.x -= y0.x; x0.y -= y0.y; x0.z -= y0.z; x0.w -= y0.w;
          x1.x -= y1.x; x1.y -= y1.y; x1.z -= y1.z; x1.w -= y1.w;
          x2.x -= y2.x; x2.y -= y2.y; x2.z -= y2.z; x2.w -= y2.w;
          x3.x -= y3.x; x3.y -= y3.y; x3.z -= y3.z; x3.w -= y3.w;
        }
      }
      *(u16x8*)(&As[srow * LDP + (shalf << 4)]) = pack8(x0, x1);
      *(u16x8*)(&As[srow * LDP + (shalf << 4) + 8]) = pack8(x2, x3);
    }
    {
      const unsigned short* bp = g.wt + (size_t)(n0 + srow) * g.K + (kt << 5) + (shalf << 4);
      u16x8 w0 = *(const u16x8*)bp;
      u16x8 w1 = *(const u16x8*)(bp + 8);
      *(u16x8*)(&Bs[srow * LDP + (shalf << 4)]) = w0;
      *(u16x8*)(&Bs[srow * LDP + (shalf << 4) + 8]) = w1;
    }
    __syncthreads();
    bf16x8 af[4], bfr[4];
#pragma unroll
    for (int mi = 0; mi < 4; ++mi)
      af[mi] = *(const bf16x8*)(&As[(wr * 64 + mi * 16 + l15) * LDP + l4 * 8]);
#pragma unroll
    for (int ni = 0; ni < 4; ++ni)
      bfr[ni] = *(const bf16x8*)(&Bs[(wc * 64 + ni * 16 + l15) * LDP + l4 * 8]);
#pragma unroll
    for (int mi = 0; mi < 4; ++mi)
#pragma unroll
      for (int ni = 0; ni < 4; ++ni)
        acc[mi][ni] = __builtin_amdgcn_mfma_f32_16x16x32_bf16(af[mi], bfr[ni], acc[mi][ni], 0, 0, 0);
    __syncthreads();
  }

  if (EP == EP_RELU_MAX) {
#pragma unroll
    for (int ni = 0; ni < 4; ++ni) {
      const int n = n0 + wc * 64 + ni * 16 + l15;
      const float b = g.bias[n];
      float m = 0.f;
#pragma unroll
      for (int mi = 0; mi < 4; ++mi)
#pragma unroll
        for (int r = 0; r < 4; ++r)
          m = fmaxf(m, acc[mi][ni][r] + b);
      m = fmaxf(m, 0.f);
      m = fmaxf(m, __shfl_xor(m, 16));
      m = fmaxf(m, __shfl_xor(m, 32));
      if (l4 == 0) g.out[(size_t)((m0 >> 6) + wr) * HD + n] = m;
    }
  } else {
#pragma unroll
    for (int mi = 0; mi < 4; ++mi)
#pragma unroll
      for (int r = 0; r < 4; ++r) {
        const int row = m0 + wr * 64 + mi * 16 + l4 * 4 + r;
#pragma unroll
        for (int ni = 0; ni < 4; ++ni) {
          const int n = n0 + wc * 64 + ni * 16 + l15;
          const size_t oi = (size_t)row * HD + n;
          float v = acc[mi][ni][r];
          if (EP == EP_TANH) {
            g.out[oi] = tanhf(v + g.bias[n]);
          } else if (EP == EP_MERGE) {
            float gg = v + g.aux2[(size_t)(row >> 6) * HD + n];
            float sg = 1.f / (1.f + expf(-gg));
            float o1v = g.aux0[oi];
            float ock = g.aux1[oi];
            g.out[oi] = fmaf(sg, o1v - ock, ock);
          } else {
            g.out[oi] = fmaxf(v + g.bias[n], 0.f);
          }
        }
      }
  }
}

extern "C" void kernel_launch(void* const* d_in, const int* in_sizes, int n_in,
                              void* d_out, int out_size, void* d_ws, size_t ws_size,
                              hipStream_t stream) {
  const float* enc_o = (const float*)d_in[0];
  const float* enc_q = (const float*)d_in[1];
  const int* om = (const int*)d_in[2];
  const int* qm = (const int*)d_in[3];
  const float* att_W1_w = (const float*)d_in[4];
  const float* att_W1_b = (const float*)d_in[5];
  const float* att_W2_w = (const float*)d_in[6];
  const float* att_W2_b = (const float*)d_in[7];
  const float* att_W3 = (const float*)d_in[8];
  const float* Wc_self_w = (const float*)d_in[9];
  const float* Wc_self_b = (const float*)d_in[10];
  const float* Wc_w = (const float*)d_in[11];
  const float* Wc_b = (const float*)d_in[12];
  const float* Va_w = (const float*)d_in[13];
  const float* Va_b = (const float*)d_in[14];
  const float* Wg_w = (const float*)d_in[15];
  const float* Wg_b = (const float*)d_in[16];
  const float* co_W1_w = (const float*)d_in[17];
  const float* co_W1_b = (const float*)d_in[18];
  const float* co_W2_w = (const float*)d_in[19];
  const float* co_W2_b = (const float*)d_in[20];
  const float* co_W3 = (const float*)d_in[21];
  const float* Wp_w = (const float*)d_in[22];
  const float* Wp_b = (const float*)d_in[23];
  const float* sa_W1_w = (const float*)d_in[24];
  const float* sa_W1_b = (const float*)d_in[25];
  const float* sa_W2_w = (const float*)d_in[26];
  const float* sa_W2_b = (const float*)d_in[27];
  const float* sa_W3 = (const float*)d_in[28];
  const float* Wf_w = (const float*)d_in[29];
  const float* Wf_b = (const float*)d_in[30];
  float* out = (float*)d_out;

  const int NTOK_O = 16384;
  const int NTOK_Q = 32768;
  const int HH = 768 * 768;

  float* ws = (float*)d_ws;
  size_t off = 0;
  auto carve = [&](size_t n) { float* p = ws + off; off += n; return p; };
  float* s1o   = carve(16384);
  float* s2o   = carve(16384);
  float* qa    = carve(32768);
  float* qco1  = carve(32768);
  float* ms2   = carve(16384);
  float* sa1   = carve(16384);
  float* sa2   = carve(16384);
  float* biasO = carve(1024);
  float* Qpool = carve(196608);
  float* Qg    = carve(196608);
  float* A2buf = carve(2097152);
  float* r1 = carve(12582912);   // CS -> OPK
  float* r2 = carve(12582912);   // OCK -> PLO -> opkbf/opkw3
  float* r3 = carve(12582912);   // merged -> OSK
  float* r4 = carve(12582912);   // eobf/eow3 -> PHI
  unsigned short* wtb = (unsigned short*)carve(1179648);
  if (ws_size < off * sizeof(float)) return;
  float* CS = r1;   float* OPK = r1;
  float* OCK = r2;  float* PLO = r2;
  float* merged = r3; float* OSK = r3;
  float* PHI = r4;
  // bf16 aliases (stream-ordered reuse)
  unsigned short* eobf  = (unsigned short*)r4;                  // dead before PHI is written
  unsigned short* eow3  = (unsigned short*)(r4 + 6291456);
  unsigned short* opkbf = (unsigned short*)r2;                  // after PLO is consumed
  unsigned short* opkw3 = (unsigned short*)(r2 + 6291456);
  unsigned short* PtG   = (unsigned short*)A2buf;               // before A2 / after poaa

  const dim3 GBIG(6, 128);
  const int PREP_GRID = NTOK_O * HD / (256 * 8);  // 6144

  // 1. per-token scalars + bf16 prep of enc_o
  dot768_kernel<<<NTOK_O / 4, 256, 0, stream>>>(enc_o, att_W1_w, att_W1_b, s1o, NTOK_O);
  dot768_kernel<<<NTOK_O / 4, 256, 0, stream>>>(enc_o, att_W2_w, att_W2_b, s2o, NTOK_O);
  dot768_kernel<<<NTOK_Q / 4, 256, 0, stream>>>(enc_q, Va_w, Va_b, qa, NTOK_Q);
  dot768_kernel<<<NTOK_Q / 4, 256, 0, stream>>>(enc_q, co_W1_w, co_W1_b, qco1, NTOK_Q);
  bias_ock_kernel<<<3, 256, 0, stream>>>(Wc_self_b, Wc_b, biasO);
  bfprep_kernel<<<PREP_GRID, 256, 0, stream>>>(enc_o, att_W3, eobf, eow3);

  // 2. pairwise option-compare: p1 (768 indep (b,i,j) blocks) + p2 (sum over j) -> CS
  p1_kernel<3><<<768, 256, 0, stream>>>(eobf, eow3, s1o, s2o, om, PtG);
  p2_kernel<3><<<dim3(4, 256), 256, 0, stream>>>(eobf, PtG, CS);

  // 3. OCK = tanh([o1 | 3o1-CS | o1*CS] @ [Wc_self; Wc_hi; Wc_lo] + bias)
  {
    WcArgs wa{};
    wa.src[0] = Wc_self_w; wa.src[1] = Wc_w; wa.src[2] = Wc_w + HH;
    wa.dst = wtb; wa.Kw = 2304;
    wconv_kernel<<<dim3(144, 3), 256, 0, stream>>>(wa);
    MMArgs g{};
    g.a[0] = enc_o; g.b2[0] = nullptr; g.mode[0] = 0;
    g.a[1] = enc_o; g.b2[1] = CS;      g.mode[1] = 1;
    g.a[2] = enc_o; g.b2[2] = CS;      g.mode[2] = 2;
    g.K = 2304; g.wt = wtb; g.bias = biasO; g.out = OCK;
    mfma_gemm_kernel<EP_TANH><<<GBIG, 256, 0, stream>>>(g);
  }

  // 4. question pooling + Qg
  qpool_kernel<<<256, 256, 0, stream>>>(enc_q, qa, qm, Qpool);
  {
    GemmArgs g{};
    g.a[0] = Qpool; g.mode[0] = 0; g.w[0] = Wg_w + 2 * HH;
    g.nchunks = 1; g.bias = Wg_b; g.out = Qg;
    gemm_kernel<EP_STORE><<<dim3(12, 4), 256, 0, stream>>>(g);
  }

  // 5. merged = G*o1 + (1-G)*OCK
  {
    WcArgs wa{};
    wa.src[0] = Wg_w; wa.src[1] = Wg_w + HH;
    wa.dst = wtb; wa.Kw = 1536;
    wconv_kernel<<<dim3(144, 2), 256, 0, stream>>>(wa);
    MMArgs g{};
    g.a[0] = enc_o; g.mode[0] = 0;
    g.a[1] = OCK;   g.mode[1] = 0;
    g.K = 1536; g.wt = wtb; g.bias = nullptr;
    g.aux0 = enc_o; g.aux1 = OCK; g.aux2 = Qg; g.out = merged;
    mfma_gemm_kernel<EP_MERGE><<<GBIG, 256, 0, stream>>>(g);
  }

  // 6. co-attention
  dot768_kernel<<<NTOK_O / 4, 256, 0, stream>>>(merged, co_W2_w, co_W2_b, ms2, NTOK_O);
  a2_kernel<<<256, 256, 0, stream>>>(enc_q, merged, qco1, ms2, qm, om, co_W3, A2buf);
  poaa_kernel<<<256, 256, 0, stream>>>(A2buf, enc_q, merged, PLO, PHI);

  // 7. OPK = relu([merged | PLO | PHI] @ Wp + b)
  {
    WcArgs wa{};
    wa.src[0] = Wp_w; wa.src[1] = Wp_w + HH; wa.src[2] = Wp_w + 2 * HH;
    wa.dst = wtb; wa.Kw = 2304;
    wconv_kernel<<<dim3(144, 3), 256, 0, stream>>>(wa);
    MMArgs g{};
    g.a[0] = merged; g.mode[0] = 0;
    g.a[1] = PLO;    g.mode[1] = 0;
    g.a[2] = PHI;    g.mode[2] = 0;
    g.K = 2304; g.wt = wtb; g.bias = Wp_b; g.out = OPK;
    mfma_gemm_kernel<EP_RELU><<<GBIG, 256, 0, stream>>>(g);
  }

  // 8. self-attention (p1/p2 on OPK)
  dot768_kernel<<<NTOK_O / 4, 256, 0, stream>>>(OPK, sa_W1_w, sa_W1_b, sa1, NTOK_O);
  dot768_kernel<<<NTOK_O / 4, 256, 0, stream>>>(OPK, sa_W2_w, sa_W2_b, sa2, NTOK_O);
  bfprep_kernel<<<PREP_GRID, 256, 0, stream>>>(OPK, sa_W3, opkbf, opkw3);
  p1_kernel<1><<<256, 256, 0, stream>>>(opkbf, opkw3, sa1, sa2, om, PtG);
  p2_kernel<1><<<dim3(4, 256), 256, 0, stream>>>(opkbf, PtG, OSK);

  // 9. out = max_lo relu([OPK | OSK | OPK-OSK | OPK*OSK] @ Wf + b)
  {
    WcArgs wa{};
    wa.src[0] = Wf_w; wa.src[1] = Wf_w + HH; wa.src[2] = Wf_w + 2 * HH; wa.src[3] = Wf_w + 3 * HH;
    wa.dst = wtb; wa.Kw = 3072;
    wconv_kernel<<<dim3(144, 4), 256, 0, stream>>>(wa);
    MMArgs g{};
    g.a[0] = OPK; g.mode[0] = 0;
    g.a[1] = OSK; g.mode[1] = 0;
    g.a[2] = OPK; g.b2[2] = OSK; g.mode[2] = 3;
    g.a[3] = OPK; g.b2[3] = OSK; g.mode[3] = 2;
    g.K = 3072; g.wt = wtb; g.bias = Wf_b; g.out = out;
    mfma_gemm_kernel<EP_RELU_MAX><<<GBIG, 256, 0, stream>>>(g);
  }
}

// Round 4
// 1145.256 us; speedup vs baseline: 4.7744x; 1.2238x over previous
//
#include <hip/hip_runtime.h>
#include <math.h>

// OptionCompareCell: B=64,C=4,LO=64,LQ=128,H=768
// Round 4: a2 + poaa -> MFMA with on-the-fly f32->bf16 staging.
//  a2_mfma : A2 = (q*w3).merged^T per bc (M=128,N=64,K=768), bias+mask epilogue.
//  poaa_mfma: f32 stats -> Tt/Tft bf16 (transposed, in LDS) -> M2 = Tt.Tft^T (MFMA)
//             -> per d-chunk: PLO = Tt.q, PHI = M2.merged with XOR-swizzled
//             gather B-frags (swizzle ((row>>3)&3)<<5 on write and read).
// p1/p2/bfprep/mfma_gemm/wconv/dot768/qpool unchanged from round 3.

#define NEGC (-10000.0f)
constexpr int HD = 768;

constexpr int EP_STORE = 0;
constexpr int EP_TANH = 1;
constexpr int EP_MERGE = 2;
constexpr int EP_RELU = 3;
constexpr int EP_RELU_MAX = 4;

typedef __attribute__((ext_vector_type(8))) short bf16x8;
typedef __attribute__((ext_vector_type(8))) unsigned short u16x8;
typedef __attribute__((ext_vector_type(4))) float f32x4;

__device__ inline void st8(float* dst, float4 a0, float4 a1) {
  dst[0] = a0.x; dst[1] = a0.y; dst[2] = a0.z; dst[3] = a0.w;
  dst[4] = a1.x; dst[5] = a1.y; dst[6] = a1.z; dst[7] = a1.w;
}

__device__ inline unsigned short f2bf(float x) {
  unsigned int u = __float_as_uint(x);
  u += 0x7fffu + ((u >> 16) & 1u);
  return (unsigned short)(u >> 16);
}

__device__ inline u16x8 pack8(float4 a, float4 b) {
  u16x8 r;
  r[0] = f2bf(a.x); r[1] = f2bf(a.y); r[2] = f2bf(a.z); r[3] = f2bf(a.w);
  r[4] = f2bf(b.x); r[5] = f2bf(b.y); r[6] = f2bf(b.z); r[7] = f2bf(b.w);
  return r;
}

// ---------------- per-token dot with a [768] vector + scalar bias ----------------
__global__ __launch_bounds__(256)
void dot768_kernel(const float* __restrict__ x, const float* __restrict__ w,
                   const float* __restrict__ bias, float* __restrict__ out, int ntok) {
  int tok = blockIdx.x * 4 + (threadIdx.x >> 6);
  int lane = threadIdx.x & 63;
  if (tok >= ntok) return;
  const float* xp = x + (size_t)tok * HD;
  float s = 0.f;
#pragma unroll
  for (int i = 0; i < 3; ++i) {
    int c = (lane + (i << 6)) << 2;
    float4 xv = *(const float4*)(xp + c);
    float4 wv = *(const float4*)(w + c);
    s = fmaf(xv.x, wv.x, s); s = fmaf(xv.y, wv.y, s);
    s = fmaf(xv.z, wv.z, s); s = fmaf(xv.w, wv.w, s);
  }
#pragma unroll
  for (int off = 32; off; off >>= 1) s += __shfl_xor(s, off);
  if (lane == 0) out[tok] = s + bias[0];
}

__global__ void bias_ock_kernel(const float* __restrict__ b1, const float* __restrict__ b2,
                                float* __restrict__ o) {
  int n = blockIdx.x * 256 + threadIdx.x;
  if (n < HD) o[n] = b1[n] + 3.f * b2[n];
}

// ---------------- bf16 prep: xbf = bf16(x), xw3 = bf16(x * w3[col]) ----------------
__global__ __launch_bounds__(256)
void bfprep_kernel(const float* __restrict__ x, const float* __restrict__ w3,
                   unsigned short* __restrict__ xbf, unsigned short* __restrict__ xw3) {
  size_t base = ((size_t)blockIdx.x * 256 + threadIdx.x) * 8;
  int col = (int)(base % HD);
  float4 a0 = *(const float4*)(x + base);
  float4 a1 = *(const float4*)(x + base + 4);
  float4 w0 = *(const float4*)(w3 + col);
  float4 w1 = *(const float4*)(w3 + col + 4);
  *(u16x8*)(xbf + base) = pack8(a0, a1);
  float4 s0, s1;
  s0.x = a0.x * w0.x; s0.y = a0.y * w0.y; s0.z = a0.z * w0.z; s0.w = a0.w * w0.w;
  s1.x = a1.x * w1.x; s1.y = a1.y * w1.y; s1.z = a1.z * w1.z; s1.w = a1.w * w1.w;
  *(u16x8*)(xw3 + base) = pack8(s0, s1);
}

// ---------------- P1: S = U . Vw3^T (MFMA), softmax over u, write Pt[v][u] bf16 ----------------
template<int NJ>
__global__ __launch_bounds__(256)
void p1_kernel(const unsigned short* __restrict__ Xbf, const unsigned short* __restrict__ Xw3,
               const float* __restrict__ s1g, const float* __restrict__ s2g,
               const int* __restrict__ maskg, unsigned short* __restrict__ PtG) {
  __shared__ __align__(16) unsigned short Ua[64 * 136];
  __shared__ __align__(16) unsigned short Vb[64 * 136];
  __shared__ float Sbuf[64][66];
  __shared__ float red[4][64];
  const int t = threadIdx.x;
  int ubc, vbc;
  if (NJ == 1) {
    ubc = vbc = blockIdx.x;
  } else {
    const int b = blockIdx.x / 12, pr = blockIdx.x % 12;
    const int i = pr / 3, jj = pr % 3;
    const int j = jj + (jj >= i ? 1 : 0);
    vbc = (b << 2) + i; ubc = (b << 2) + j;
  }
  const unsigned short* U = Xbf + (size_t)ubc * (64 * HD);
  const unsigned short* V = Xw3 + (size_t)vbc * (64 * HD);
  const int w = t >> 6, lane = t & 63, l15 = lane & 15, l4 = lane >> 4;
  const int srow = t >> 2, scol = (t & 3) << 5;
  f32x4 acc[4] = {};
  for (int k0 = 0; k0 < HD; k0 += 128) {
    const unsigned short* up = U + (size_t)srow * HD + k0 + scol;
    const unsigned short* vp = V + (size_t)srow * HD + k0 + scol;
    unsigned short* ua = &Ua[srow * 136 + scol];
    unsigned short* vb = &Vb[srow * 136 + scol];
#pragma unroll
    for (int z = 0; z < 4; ++z) {
      *(u16x8*)(ua + z * 8) = *(const u16x8*)(up + z * 8);
      *(u16x8*)(vb + z * 8) = *(const u16x8*)(vp + z * 8);
    }
    __syncthreads();
#pragma unroll
    for (int ks = 0; ks < 4; ++ks) {
      bf16x8 af = *(const bf16x8*)(&Ua[(w * 16 + l15) * 136 + ks * 32 + l4 * 8]);
#pragma unroll
      for (int n = 0; n < 4; ++n) {
        bf16x8 bf = *(const bf16x8*)(&Vb[(n * 16 + l15) * 136 + ks * 32 + l4 * 8]);
        acc[n] = __builtin_amdgcn_mfma_f32_16x16x32_bf16(af, bf, acc[n], 0, 0, 0);
      }
    }
    __syncthreads();
  }
  {
    float s1v[4];
#pragma unroll
    for (int r = 0; r < 4; ++r) {
      int u = w * 16 + l4 * 4 + r;
      s1v[r] = s1g[ubc * 64 + u] + (1.f - (float)maskg[ubc * 64 + u]) * NEGC;
    }
#pragma unroll
    for (int n = 0; n < 4; ++n) {
      int v = n * 16 + l15;
      float s2v = s2g[vbc * 64 + v] + (1.f - (float)maskg[vbc * 64 + v]) * NEGC;
#pragma unroll
      for (int r = 0; r < 4; ++r)
        Sbuf[w * 16 + l4 * 4 + r][v] = acc[n][r] + s1v[r] + s2v;
    }
  }
  __syncthreads();
  {
    const int v = t & 63, part = t >> 6;
    float m = -1e30f;
#pragma unroll
    for (int z = 0; z < 16; ++z) m = fmaxf(m, Sbuf[part * 16 + z][v]);
    red[part][v] = m;
    __syncthreads();
    float gm = fmaxf(fmaxf(red[0][v], red[1][v]), fmaxf(red[2][v], red[3][v]));
    float s = 0.f;
#pragma unroll
    for (int z = 0; z < 16; ++z) {
      float e = expf(Sbuf[part * 16 + z][v] - gm);
      Sbuf[part * 16 + z][v] = e;
      s += e;
    }
    __syncthreads();
    red[part][v] = s;
    __syncthreads();
    float cinv = 1.f / (red[0][v] + red[1][v] + red[2][v] + red[3][v]);
    unsigned short* pt = PtG + (size_t)blockIdx.x * 4096 + v * 64 + part * 16;
#pragma unroll
    for (int z = 0; z < 16; ++z) pt[z] = f2bf(Sbuf[part * 16 + z][v] * cinv);
  }
}

// ---------------- P2: ctx[v][d] = sum_j sum_u Pt_j[v][u] * U_j[u][d] ----------------
template<int NJ>
__global__ __launch_bounds__(256)
void p2_kernel(const unsigned short* __restrict__ Xbf, const unsigned short* __restrict__ PtG,
               float* __restrict__ outg) {
  __shared__ __align__(16) unsigned short Pts[NJ][64 * 72];
  __shared__ __align__(16) unsigned short U2[64 * 192];
  const int t = threadIdx.x;
  const int dq = blockIdx.x, bc = blockIdx.y;
  const int d0 = dq * 192;
  const int b = bc >> 2, i = bc & 3;
  const int w = t >> 6, lane = t & 63, l15 = lane & 15, l4 = lane >> 4;
  {
    const int v = t >> 2, cs = (t & 3) << 4;
#pragma unroll
    for (int jj = 0; jj < NJ; ++jj) {
      size_t src = (NJ == 1 ? (size_t)bc : (size_t)(b * 12 + i * 3 + jj)) * 4096 + v * 64 + cs;
      *(u16x8*)(&Pts[jj][v * 72 + cs]) = *(const u16x8*)(PtG + src);
      *(u16x8*)(&Pts[jj][v * 72 + cs + 8]) = *(const u16x8*)(PtG + src + 8);
    }
  }
  f32x4 acc[4][3] = {};
  const int su = t >> 2, sc0 = (t & 3) * 48;
  const int sswz = ((su >> 3) & 3) << 5;
  for (int jj = 0; jj < NJ; ++jj) {
    const int ubc = (NJ == 1) ? bc : ((b << 2) + (jj + (jj >= i ? 1 : 0)));
    __syncthreads();
    {
      const unsigned short* up = Xbf + (size_t)ubc * (64 * HD) + (size_t)su * HD + d0 + sc0;
#pragma unroll
      for (int it = 0; it < 6; ++it) {
        u16x8 vdat = *(const u16x8*)(up + it * 8);
        *(u16x8*)((char*)U2 + ((su * 384 + (sc0 + it * 8) * 2) ^ sswz)) = vdat;
      }
    }
    __syncthreads();
    const unsigned short* ptj = &Pts[jj][0];
#pragma unroll
    for (int ks = 0; ks < 2; ++ks) {
      bf16x8 bfr[3];
#pragma unroll
      for (int n = 0; n < 3; ++n) {
        const int col = (w * 3 + n) * 16 + l15;
#pragma unroll
        for (int e = 0; e < 8; ++e) {
          const int uk = ks * 32 + l4 * 8 + e;
          const int byte = (uk * 384 + col * 2) ^ (((uk >> 3) & 3) << 5);
          bfr[n][e] = *(const short*)((const char*)U2 + byte);
        }
      }
#pragma unroll
      for (int m = 0; m < 4; ++m) {
        bf16x8 af = *(const bf16x8*)(ptj + (m * 16 + l15) * 72 + ks * 32 + l4 * 8);
#pragma unroll
        for (int n = 0; n < 3; ++n)
          acc[m][n] = __builtin_amdgcn_mfma_f32_16x16x32_bf16(af, bfr[n], acc[m][n], 0, 0, 0);
      }
    }
  }
  float* op = outg + (size_t)bc * (64 * HD);
#pragma unroll
  for (int m = 0; m < 4; ++m)
#pragma unroll
    for (int n = 0; n < 3; ++n) {
      const int d = d0 + (w * 3 + n) * 16 + l15;
#pragma unroll
      for (int r = 0; r < 4; ++r) {
        const int v = m * 16 + l4 * 4 + r;
        op[(size_t)v * HD + d] = acc[m][n][r];
      }
    }
}

// ---------------- question pooling ----------------
__global__ __launch_bounds__(256)
void qpool_kernel(const float* __restrict__ q, const float* __restrict__ qa,
                  const int* __restrict__ qm, float* __restrict__ Q) {
  __shared__ float wgt[128];
  __shared__ float wred[4];
  int t = threadIdx.x, bc = blockIdx.x;
  const float* qap = qa + bc * 128;
  const int* qmp = qm + bc * 128;
  float v = -1e30f;
  if (t < 128) v = qap[t] + (1.f - (float)qmp[t]) * NEGC;
  float m = v;
#pragma unroll
  for (int off = 32; off; off >>= 1) m = fmaxf(m, __shfl_xor(m, off));
  if ((t & 63) == 0) wred[t >> 6] = m;
  __syncthreads();
  float gm = fmaxf(fmaxf(wred[0], wred[1]), fmaxf(wred[2], wred[3]));
  float e = (t < 128) ? expf(v - gm) : 0.f;
  float s = e;
#pragma unroll
  for (int off = 32; off; off >>= 1) s += __shfl_xor(s, off);
  __syncthreads();
  if ((t & 63) == 0) wred[t >> 6] = s;
  __syncthreads();
  float tot = wred[0] + wred[1] + wred[2] + wred[3];
  if (t < 128) wgt[t] = e / tot;
  __syncthreads();
  const float* qp = q + (size_t)bc * (128 * HD);
  float* Qp = Q + (size_t)bc * HD;
  for (int d = t; d < HD; d += 256) {
    float acc = 0.f;
    for (int l = 0; l < 128; ++l) acc = fmaf(wgt[l], qp[(size_t)l * HD + d], acc);
    Qp[d] = acc;
  }
}

// ---------------- A2 via MFMA: A2[q][v] = (q*w3).merged^T + rterm + cterm ----------------
__global__ __launch_bounds__(256)
void a2_mfma_kernel(const float* __restrict__ qin, const float* __restrict__ merged,
                    const float* __restrict__ qco1, const float* __restrict__ ms2,
                    const int* __restrict__ qm, const int* __restrict__ om,
                    const float* __restrict__ w3, float* __restrict__ A2) {
  __shared__ __align__(16) unsigned short Aq[128 * 72];
  __shared__ __align__(16) unsigned short Bm[64 * 72];
  const int t = threadIdx.x, bc = blockIdx.x;
  const float* qp = qin + (size_t)bc * (128 * HD);
  const float* mp = merged + (size_t)bc * (64 * HD);
  const int w = t >> 6, lane = t & 63, l15 = lane & 15, l4 = lane >> 4;
  const int arow = t >> 1, acs = (t & 1) << 5;
  const int brow = t >> 2, bcs = (t & 3) << 4;
  f32x4 acc[2][4] = {};
  for (int k0 = 0; k0 < HD; k0 += 64) {
    {
      const float* p = qp + (size_t)arow * HD + k0 + acs;
      const float* wp = w3 + k0 + acs;
      unsigned short* dst = &Aq[arow * 72 + acs];
#pragma unroll
      for (int z = 0; z < 4; ++z) {
        float4 a = *(const float4*)(p + z * 8);
        float4 b = *(const float4*)(p + z * 8 + 4);
        float4 wa = *(const float4*)(wp + z * 8);
        float4 wb = *(const float4*)(wp + z * 8 + 4);
        a.x *= wa.x; a.y *= wa.y; a.z *= wa.z; a.w *= wa.w;
        b.x *= wb.x; b.y *= wb.y; b.z *= wb.z; b.w *= wb.w;
        *(u16x8*)(dst + z * 8) = pack8(a, b);
      }
    }
    {
      const float* p = mp + (size_t)brow * HD + k0 + bcs;
      unsigned short* dst = &Bm[brow * 72 + bcs];
#pragma unroll
      for (int z = 0; z < 2; ++z) {
        float4 a = *(const float4*)(p + z * 8);
        float4 b = *(const float4*)(p + z * 8 + 4);
        *(u16x8*)(dst + z * 8) = pack8(a, b);
      }
    }
    __syncthreads();
#pragma unroll
    for (int ks = 0; ks < 2; ++ks) {
      bf16x8 af[2], bf[4];
#pragma unroll
      for (int m = 0; m < 2; ++m)
        af[m] = *(const bf16x8*)(&Aq[(w * 32 + m * 16 + l15) * 72 + ks * 32 + l4 * 8]);
#pragma unroll
      for (int n = 0; n < 4; ++n)
        bf[n] = *(const bf16x8*)(&Bm[(n * 16 + l15) * 72 + ks * 32 + l4 * 8]);
#pragma unroll
      for (int m = 0; m < 2; ++m)
#pragma unroll
        for (int n = 0; n < 4; ++n)
          acc[m][n] = __builtin_amdgcn_mfma_f32_16x16x32_bf16(af[m], bf[n], acc[m][n], 0, 0, 0);
    }
    __syncthreads();
  }
  const float* qc = qco1 + bc * 128;
  const int* qmp = qm + bc * 128;
  const float* msp = ms2 + bc * 64;
  const int* omp = om + bc * 64;
  float* outp = A2 + (size_t)bc * (128 * 64);
#pragma unroll
  for (int n = 0; n < 4; ++n) {
    const int v = n * 16 + l15;
    const float ct = msp[v] + (1.f - (float)omp[v]) * NEGC;
#pragma unroll
    for (int m = 0; m < 2; ++m)
#pragma unroll
      for (int r = 0; r < 4; ++r) {
        const int qrow = w * 32 + m * 16 + l4 * 4 + r;
        const float rt = qc[qrow] + (1.f - (float)qmp[qrow]) * NEGC;
        outp[qrow * 64 + v] = acc[m][n][r] + rt + ct;
      }
  }
}

// ---------------- POAA via MFMA ----------------
// Phase1: f32 stats from raw A2. Phase2: Tt[o][q], Tft[v][q] bf16 in LDS.
// Phase3: M2 = Tt.Tft^T (K=128), colfac folded, bf16 in LDS.
// Phase4/5 per 64-wide d-chunk: PLO = Tt.q, PHI = M2.merged, B staged f32->bf16
// with XOR swizzle ((row>>3)&3)<<5 (write and gather-read use the same involution).
__global__ __launch_bounds__(256)
void poaa_mfma_kernel(const float* __restrict__ A2, const float* __restrict__ qin,
                      const float* __restrict__ merged,
                      float* __restrict__ PLO, float* __restrict__ PHI) {
  __shared__ __align__(16) char smem[77312];
  __shared__ float red[4][64];
  __shared__ float rowm[128], rowfac[128];
  __shared__ float colfac[64];
  __shared__ float gmax_s;
  float* T = (float*)smem;                                   // [128][65] f32
  unsigned short* Tt = (unsigned short*)(smem + 33280);       // [64][136]
  unsigned short* Tft = (unsigned short*)(smem + 50688);      // [64][136]
  unsigned short* M2bf = (unsigned short*)(smem + 68096);     // [64][72]
  unsigned short* Qc = (unsigned short*)smem;                 // [128][72] (after phase2)
  unsigned short* Mc = (unsigned short*)(smem + 18432);       // [64][72]

  const int t = threadIdx.x, bc = blockIdx.x;
  const int w = t >> 6, lane = t & 63, l15 = lane & 15, l4 = lane >> 4;
  const float* a2 = A2 + (size_t)bc * (128 * 64);
  // phase 1a: load A2 -> T
  {
    int row = t >> 1, cs = (t & 1) << 5;
    const float* p = a2 + row * 64 + cs;
#pragma unroll
    for (int z = 0; z < 8; ++z) {
      float4 v = *(const float4*)(p + (z << 2));
      T[row * 65 + cs + (z << 2) + 0] = v.x;
      T[row * 65 + cs + (z << 2) + 1] = v.y;
      T[row * 65 + cs + (z << 2) + 2] = v.z;
      T[row * 65 + cs + (z << 2) + 3] = v.w;
    }
  }
  __syncthreads();
  // phase 1b: row stats (ACK axis) — raw values, T not modified
  {
    int qrow = t >> 1, h = t & 1;
    float m = -1e30f;
    for (int v = h * 32; v < h * 32 + 32; ++v) m = fmaxf(m, T[qrow * 65 + v]);
    m = fmaxf(m, __shfl_xor(m, 1));
    float s = 0.f;
    for (int v = h * 32; v < h * 32 + 32; ++v) s += expf(T[qrow * 65 + v] - m);
    s += __shfl_xor(s, 1);
    if (h == 0) { rowm[qrow] = m; rowfac[qrow] = s; }
  }
  // phase 1c: col stats (APK axis)
  float colm_loc = 0.f;
  {
    int v = t & 63, part = t >> 6;
    float m = -1e30f;
    for (int qq = part * 32; qq < part * 32 + 32; ++qq) m = fmaxf(m, T[qq * 65 + v]);
    red[part][v] = m;
    __syncthreads();
    float cm = fmaxf(fmaxf(red[0][v], red[1][v]), fmaxf(red[2][v], red[3][v]));
    float s = 0.f;
    for (int qq = part * 32; qq < part * 32 + 32; ++qq) s += expf(T[qq * 65 + v] - cm);
    __syncthreads();
    red[part][v] = s;
    __syncthreads();
    if (part == 0) { colm_loc = cm; colfac[v] = red[0][v] + red[1][v] + red[2][v] + red[3][v]; }
  }
  __syncthreads();
  if (t < 64) {
    float m = fmaxf(rowm[t], rowm[t + 64]);
#pragma unroll
    for (int off = 32; off; off >>= 1) m = fmaxf(m, __shfl_xor(m, off));
    if (t == 0) gmax_s = m;
  }
  __syncthreads();
  const float gmax = gmax_s;
  if (t < 128) rowfac[t] = expf(fminf(gmax - rowm[t], 60.f)) / rowfac[t];
  if (t < 64) colfac[t] = expf(fminf(gmax - colm_loc, 60.f)) / colfac[t];
  __syncthreads();
  // phase 2: Tt / Tft bf16 (transposed)
  {
    const int o = t >> 2, qs = (t & 3) << 5;
    for (int z = 0; z < 32; ++z) {
      const int qq = qs + z;
      float e = expf(T[qq * 65 + o] - gmax);
      Tt[o * 136 + qq] = f2bf(e);
      Tft[o * 136 + qq] = f2bf(e * rowfac[qq]);
    }
  }
  __syncthreads();
  // phase 3: M2[o][v] = colfac[o] * sum_q Tt[o][q] Tft[v][q]   (K=128)
  {
    f32x4 m2acc[4] = {};
#pragma unroll
    for (int ks = 0; ks < 4; ++ks) {
      bf16x8 af = *(const bf16x8*)(&Tt[(w * 16 + l15) * 136 + ks * 32 + l4 * 8]);
#pragma unroll
      for (int n = 0; n < 4; ++n) {
        bf16x8 bf = *(const bf16x8*)(&Tft[(n * 16 + l15) * 136 + ks * 32 + l4 * 8]);
        m2acc[n] = __builtin_amdgcn_mfma_f32_16x16x32_bf16(af, bf, m2acc[n], 0, 0, 0);
      }
    }
#pragma unroll
    for (int n = 0; n < 4; ++n)
#pragma unroll
      for (int r = 0; r < 4; ++r) {
        const int o = w * 16 + l4 * 4 + r;
        M2bf[o * 72 + n * 16 + l15] = f2bf(colfac[o] * m2acc[n][r]);
      }
  }
  // phase 4/5: d-chunks of 64
  const int dql = t >> 1, dqs = (t & 1) << 5;  // Qc stage: row q, 32-col seg
  const int dml = t >> 2, dms = (t & 3) << 4;  // Mc stage: row v, 16-col seg
  const int swq = ((dql >> 3) & 3) << 5;
  const int swm = ((dml >> 3) & 3) << 5;
  float* plo = PLO + (size_t)bc * (64 * HD);
  float* phi = PHI + (size_t)bc * (64 * HD);
  const float* qp = qin + (size_t)bc * (128 * HD);
  const float* mp = merged + (size_t)bc * (64 * HD);
  for (int dc = 0; dc < 12; ++dc) {
    const int d0 = dc * 64;
    __syncthreads();   // protect Qc/Mc (and phase-3 M2bf reads on first iter)
    {
      const float* p = qp + (size_t)dql * HD + d0 + dqs;
#pragma unroll
      for (int z = 0; z < 4; ++z) {
        float4 a = *(const float4*)(p + z * 8);
        float4 b = *(const float4*)(p + z * 8 + 4);
        *(u16x8*)((char*)Qc + ((dql * 144 + (dqs + z * 8) * 2) ^ swq)) = pack8(a, b);
      }
    }
    {
      const float* p = mp + (size_t)dml * HD + d0 + dms;
#pragma unroll
      for (int z = 0; z < 2; ++z) {
        float4 a = *(const float4*)(p + z * 8);
        float4 b = *(const float4*)(p + z * 8 + 4);
        *(u16x8*)((char*)Mc + ((dml * 144 + (dms + z * 8) * 2) ^ swm)) = pack8(a, b);
      }
    }
    __syncthreads();
    const int col = w * 16 + l15;
    // PLO: K=128 over q
    f32x4 lacc[4] = {};
#pragma unroll
    for (int ks = 0; ks < 4; ++ks) {
      bf16x8 bf;
#pragma unroll
      for (int e = 0; e < 8; ++e) {
        const int qq = ks * 32 + l4 * 8 + e;
        bf[e] = *(const short*)((const char*)Qc + ((qq * 144 + col * 2) ^ (((qq >> 3) & 3) << 5)));
      }
#pragma unroll
      for (int m = 0; m < 4; ++m) {
        bf16x8 af = *(const bf16x8*)(&Tt[(m * 16 + l15) * 136 + ks * 32 + l4 * 8]);
        lacc[m] = __builtin_amdgcn_mfma_f32_16x16x32_bf16(af, bf, lacc[m], 0, 0, 0);
      }
    }
    // PHI: K=64 over v
    f32x4 pacc[4] = {};
#pragma unroll
    for (int ks = 0; ks < 2; ++ks) {
      bf16x8 bf;
#pragma unroll
      for (int e = 0; e < 8; ++e) {
        const int vv = ks * 32 + l4 * 8 + e;
        bf[e] = *(const short*)((const char*)Mc + ((vv * 144 + col * 2) ^ (((vv >> 3) & 3) << 5)));
      }
#pragma unroll
      for (int m = 0; m < 4; ++m) {
        bf16x8 af = *(const bf16x8*)(&M2bf[(m * 16 + l15) * 72 + ks * 32 + l4 * 8]);
        pacc[m] = __builtin_amdgcn_mfma_f32_16x16x32_bf16(af, bf, pacc[m], 0, 0, 0);
      }
    }
#pragma unroll
    for (int m = 0; m < 4; ++m)
#pragma unroll
      for (int r = 0; r < 4; ++r) {
        const int o = m * 16 + l4 * 4 + r;
        const int d = d0 + w * 16 + l15;
        plo[(size_t)o * HD + d] = colfac[o] * lacc[m][r];
        phi[(size_t)o * HD + d] = pacc[m][r];
      }
  }
}

// ---------------- small f32 GEMM (Qg only) ----------------
struct GemmArgs {
  const float* a[4];
  const float* bsrc[4];
  int mode[4];
  const float* w[4];
  int nchunks;
  const float* bias;
  const float* aux0;
  const float* aux1;
  const float* aux2;
  float* out;
};

template<int EP>
__global__ __launch_bounds__(256)
void gemm_kernel(GemmArgs g) {
  __shared__ float As[64][33];
  __shared__ float Ws[32][65];
  const int t = threadIdx.x;
  const int m0 = blockIdx.y << 6, n0 = blockIdx.x << 6;
  const int tr = t >> 4, tc = t & 15;
  float acc[4][4];
#pragma unroll
  for (int x = 0; x < 4; ++x)
#pragma unroll
    for (int y = 0; y < 4; ++y) acc[x][y] = 0.f;
  const int arow = t >> 2, acs = (t & 3) << 3;
  const int wrow = t >> 3, wcs = (t & 7) << 3;
  for (int c = 0; c < g.nchunks; ++c) {
    const float* Ap = g.a[c] + (size_t)(m0 + arow) * HD + acs;
    const float* Wp = g.w[c] + (size_t)wrow * HD + n0 + wcs;
    for (int k0 = 0; k0 < HD; k0 += 32) {
      float4 a0 = *(const float4*)(Ap + k0);
      float4 a1 = *(const float4*)(Ap + k0 + 4);
      st8(&As[arow][acs], a0, a1);
      float4 w0 = *(const float4*)(Wp + (size_t)k0 * HD);
      float4 w1 = *(const float4*)(Wp + (size_t)k0 * HD + 4);
      st8(&Ws[wrow][wcs], w0, w1);
      __syncthreads();
#pragma unroll
      for (int kk = 0; kk < 32; ++kk) {
        float av[4], bv[4];
#pragma unroll
        for (int x = 0; x < 4; ++x) av[x] = As[(tr << 2) + x][kk];
#pragma unroll
        for (int y = 0; y < 4; ++y) bv[y] = Ws[kk][(tc << 2) + y];
#pragma unroll
        for (int x = 0; x < 4; ++x)
#pragma unroll
          for (int y = 0; y < 4; ++y) acc[x][y] = fmaf(av[x], bv[y], acc[x][y]);
      }
      __syncthreads();
    }
  }
#pragma unroll
  for (int x = 0; x < 4; ++x) {
    const int r = m0 + (tr << 2) + x;
#pragma unroll
    for (int y = 0; y < 4; ++y) {
      const int n = n0 + (tc << 2) + y;
      g.out[(size_t)r * HD + n] = acc[x][y] + g.bias[n];
    }
  }
}

// ---------------- weight convert+transpose ----------------
struct WcArgs {
  const float* src[4];
  unsigned short* dst;
  int Kw;
};

__global__ __launch_bounds__(256)
void wconv_kernel(WcArgs g) {
  __shared__ float tile[64][65];
  const int slice = blockIdx.y;
  const float* src = g.src[slice];
  const int kbase = slice * HD;
  const int bi = blockIdx.x % 12, bj = blockIdx.x / 12;
  const int t = threadIdx.x;
  const int r = t >> 2, cseg = (t & 3) << 4;
  const float* p = src + (size_t)(bi * 64 + r) * HD + bj * 64 + cseg;
#pragma unroll
  for (int j = 0; j < 16; j += 4) {
    float4 v = *(const float4*)(p + j);
    tile[r][cseg + j + 0] = v.x; tile[r][cseg + j + 1] = v.y;
    tile[r][cseg + j + 2] = v.z; tile[r][cseg + j + 3] = v.w;
  }
  __syncthreads();
  unsigned short* q = g.dst + (size_t)(bj * 64 + r) * g.Kw + kbase + bi * 64 + cseg;
  u16x8 lo, hi;
#pragma unroll
  for (int j = 0; j < 8; ++j) lo[j] = f2bf(tile[cseg + j][r]);
#pragma unroll
  for (int j = 0; j < 8; ++j) hi[j] = f2bf(tile[cseg + 8 + j][r]);
  *(u16x8*)q = lo;
  *(u16x8*)(q + 8) = hi;
}

// ---------------- bf16 MFMA GEMM ----------------
struct MMArgs {
  const float* a[4];
  const float* b2[4];
  int mode[4];           // 0: a ; 1: 3a-b ; 2: a*b ; 3: a-b
  int K;
  const unsigned short* wt;
  const float* bias;
  const float* aux0;
  const float* aux1;
  const float* aux2;
  float* out;
};

constexpr int LDP = 40;

template<int EP>
__global__ __launch_bounds__(256)
void mfma_gemm_kernel(MMArgs g) {
  __shared__ __align__(16) unsigned short As[128 * LDP];
  __shared__ __align__(16) unsigned short Bs[128 * LDP];
  const int t = threadIdx.x;
  const int lane = t & 63, w = t >> 6;
  const int wr = w >> 1, wc = w & 1;
  const int m0 = blockIdx.y << 7, n0 = blockIdx.x << 7;
  const int l15 = lane & 15, l4 = lane >> 4;
  f32x4 acc[4][4] = {};

  const int srow = t >> 1, shalf = t & 1;
  const int nkt = g.K >> 5;
  for (int kt = 0; kt < nkt; ++kt) {
    const int c = kt / 24;
    const int koff = (kt - c * 24) << 5;
    {
      const size_t ro = (size_t)(m0 + srow) * HD + koff + (shalf << 4);
      const float* ap = g.a[c] + ro;
      float4 x0 = *(const float4*)(ap);
      float4 x1 = *(const float4*)(ap + 4);
      float4 x2 = *(const float4*)(ap + 8);
      float4 x3 = *(const float4*)(ap + 12);
      const int mode = g.mode[c];
      if (mode) {
        const float* bp = g.b2[c] + ro;
        float4 y0 = *(const float4*)(bp);
        float4 y1 = *(const float4*)(bp + 4);
        float4 y2 = *(const float4*)(bp + 8);
        float4 y3 = *(const float4*)(bp + 12);
        if (mode == 1) {
          x0.x = fmaf(3.f, x0.x, -y0.x); x0.y = fmaf(3.f, x0.y, -y0.y);
          x0.z = fmaf(3.f, x0.z, -y0.z); x0.w = fmaf(3.f, x0.w, -y0.w);
          x1.x = fmaf(3.f, x1.x, -y1.x); x1.y = fmaf(3.f, x1.y, -y1.y);
          x1.z = fmaf(3.f, x1.z, -y1.z); x1.w = fmaf(3.f, x1.w, -y1.w);
          x2.x = fmaf(3.f, x2.x, -y2.x); x2.y = fmaf(3.f, x2.y, -y2.y);
          x2.z = fmaf(3.f, x2.z, -y2.z); x2.w = fmaf(3.f, x2.w, -y2.w);
          x3.x = fmaf(3.f, x3.x, -y3.x); x3.y = fmaf(3.f, x3.y, -y3.y);
          x3.z = fmaf(3.f, x3.z, -y3.z); x3.w = fmaf(3.f, x3.w, -y3.w);
        } else if (mode == 2) {
          x0.x *= y0.x; x0.y *= y0.y; x0.z *= y0.z; x0.w *= y0.w;
          x1.x *= y1.x; x1.y *= y1.y; x1.z *= y1.z; x1.w *= y1.w;
          x2.x *= y2.x; x2.y *= y2.y; x2.z *= y2.z; x2.w *= y2.w;
          x3.x *= y3.x; x3.y *= y3.y; x3.z *= y3.z; x3.w *= y3.w;
        } else {
          x0.x -= y0.x; x0.y -= y0.y; x0.z -= y0.z; x0.w -= y0.w;
          x1.x -= y1.x; x1.y -= y1.y; x1.z -= y1.z; x1.w -= y1.w;
          x2.x -= y2.x; x2.y -= y2.y; x2.z -= y2.z; x2.w -= y2.w;
          x3.x -= y3.x; x3.y -= y3.y; x3.z -= y3.z; x3.w -= y3.w;
        }
      }
      *(u16x8*)(&As[srow * LDP + (shalf << 4)]) = pack8(x0, x1);
      *(u16x8*)(&As[srow * LDP + (shalf << 4) + 8]) = pack8(x2, x3);
    }
    {
      const unsigned short* bp = g.wt + (size_t)(n0 + srow) * g.K + (kt << 5) + (shalf << 4);
      u16x8 w0 = *(const u16x8*)bp;
      u16x8 w1 = *(const u16x8*)(bp + 8);
      *(u16x8*)(&Bs[srow * LDP + (shalf << 4)]) = w0;
      *(u16x8*)(&Bs[srow * LDP + (shalf << 4) + 8]) = w1;
    }
    __syncthreads();
    bf16x8 af[4], bfr[4];
#pragma unroll
    for (int mi = 0; mi < 4; ++mi)
      af[mi] = *(const bf16x8*)(&As[(wr * 64 + mi * 16 + l15) * LDP + l4 * 8]);
#pragma unroll
    for (int ni = 0; ni < 4; ++ni)
      bfr[ni] = *(const bf16x8*)(&Bs[(wc * 64 + ni * 16 + l15) * LDP + l4 * 8]);
#pragma unroll
    for (int mi = 0; mi < 4; ++mi)
#pragma unroll
      for (int ni = 0; ni < 4; ++ni)
        acc[mi][ni] = __builtin_amdgcn_mfma_f32_16x16x32_bf16(af[mi], bfr[ni], acc[mi][ni], 0, 0, 0);
    __syncthreads();
  }

  if (EP == EP_RELU_MAX) {
#pragma unroll
    for (int ni = 0; ni < 4; ++ni) {
      const int n = n0 + wc * 64 + ni * 16 + l15;
      const float b = g.bias[n];
      float m = 0.f;
#pragma unroll
      for (int mi = 0; mi < 4; ++mi)
#pragma unroll
        for (int r = 0; r < 4; ++r)
          m = fmaxf(m, acc[mi][ni][r] + b);
      m = fmaxf(m, 0.f);
      m = fmaxf(m, __shfl_xor(m, 16));
      m = fmaxf(m, __shfl_xor(m, 32));
      if (l4 == 0) g.out[(size_t)((m0 >> 6) + wr) * HD + n] = m;
    }
  } else {
#pragma unroll
    for (int mi = 0; mi < 4; ++mi)
#pragma unroll
      for (int r = 0; r < 4; ++r) {
        const int row = m0 + wr * 64 + mi * 16 + l4 * 4 + r;
#pragma unroll
        for (int ni = 0; ni < 4; ++ni) {
          const int n = n0 + wc * 64 + ni * 16 + l15;
          const size_t oi = (size_t)row * HD + n;
          float v = acc[mi][ni][r];
          if (EP == EP_TANH) {
            g.out[oi] = tanhf(v + g.bias[n]);
          } else if (EP == EP_MERGE) {
            float gg = v + g.aux2[(size_t)(row >> 6) * HD + n];
            float sg = 1.f / (1.f + expf(-gg));
            float o1v = g.aux0[oi];
            float ock = g.aux1[oi];
            g.out[oi] = fmaf(sg, o1v - ock, ock);
          } else {
            g.out[oi] = fmaxf(v + g.bias[n], 0.f);
          }
        }
      }
  }
}

extern "C" void kernel_launch(void* const* d_in, const int* in_sizes, int n_in,
                              void* d_out, int out_size, void* d_ws, size_t ws_size,
                              hipStream_t stream) {
  const float* enc_o = (const float*)d_in[0];
  const float* enc_q = (const float*)d_in[1];
  const int* om = (const int*)d_in[2];
  const int* qm = (const int*)d_in[3];
  const float* att_W1_w = (const float*)d_in[4];
  const float* att_W1_b = (const float*)d_in[5];
  const float* att_W2_w = (const float*)d_in[6];
  const float* att_W2_b = (const float*)d_in[7];
  const float* att_W3 = (const float*)d_in[8];
  const float* Wc_self_w = (const float*)d_in[9];
  const float* Wc_self_b = (const float*)d_in[10];
  const float* Wc_w = (const float*)d_in[11];
  const float* Wc_b = (const float*)d_in[12];
  const float* Va_w = (const float*)d_in[13];
  const float* Va_b = (const float*)d_in[14];
  const float* Wg_w = (const float*)d_in[15];
  const float* Wg_b = (const float*)d_in[16];
  const float* co_W1_w = (const float*)d_in[17];
  const float* co_W1_b = (const float*)d_in[18];
  const float* co_W2_w = (const float*)d_in[19];
  const float* co_W2_b = (const float*)d_in[20];
  const float* co_W3 = (const float*)d_in[21];
  const float* Wp_w = (const float*)d_in[22];
  const float* Wp_b = (const float*)d_in[23];
  const float* sa_W1_w = (const float*)d_in[24];
  const float* sa_W1_b = (const float*)d_in[25];
  const float* sa_W2_w = (const float*)d_in[26];
  const float* sa_W2_b = (const float*)d_in[27];
  const float* sa_W3 = (const float*)d_in[28];
  const float* Wf_w = (const float*)d_in[29];
  const float* Wf_b = (const float*)d_in[30];
  float* out = (float*)d_out;

  const int NTOK_O = 16384;
  const int NTOK_Q = 32768;
  const int HH = 768 * 768;

  float* ws = (float*)d_ws;
  size_t off = 0;
  auto carve = [&](size_t n) { float* p = ws + off; off += n; return p; };
  float* s1o   = carve(16384);
  float* s2o   = carve(16384);
  float* qa    = carve(32768);
  float* qco1  = carve(32768);
  float* ms2   = carve(16384);
  float* sa1   = carve(16384);
  float* sa2   = carve(16384);
  float* biasO = carve(1024);
  float* Qpool = carve(196608);
  float* Qg    = carve(196608);
  float* A2buf = carve(2097152);
  float* r1 = carve(12582912);   // CS -> OPK
  float* r2 = carve(12582912);   // OCK -> PLO -> opkbf/opkw3
  float* r3 = carve(12582912);   // merged -> OSK
  float* r4 = carve(12582912);   // eobf/eow3 -> PHI
  unsigned short* wtb = (unsigned short*)carve(1179648);
  if (ws_size < off * sizeof(float)) return;
  float* CS = r1;   float* OPK = r1;
  float* OCK = r2;  float* PLO = r2;
  float* merged = r3; float* OSK = r3;
  float* PHI = r4;
  unsigned short* eobf  = (unsigned short*)r4;
  unsigned short* eow3  = (unsigned short*)(r4 + 6291456);
  unsigned short* opkbf = (unsigned short*)r2;
  unsigned short* opkw3 = (unsigned short*)(r2 + 6291456);
  unsigned short* PtG   = (unsigned short*)A2buf;

  const dim3 GBIG(6, 128);
  const int PREP_GRID = NTOK_O * HD / (256 * 8);  // 6144

  // 1. per-token scalars + bf16 prep of enc_o
  dot768_kernel<<<NTOK_O / 4, 256, 0, stream>>>(enc_o, att_W1_w, att_W1_b, s1o, NTOK_O);
  dot768_kernel<<<NTOK_O / 4, 256, 0, stream>>>(enc_o, att_W2_w, att_W2_b, s2o, NTOK_O);
  dot768_kernel<<<NTOK_Q / 4, 256, 0, stream>>>(enc_q, Va_w, Va_b, qa, NTOK_Q);
  dot768_kernel<<<NTOK_Q / 4, 256, 0, stream>>>(enc_q, co_W1_w, co_W1_b, qco1, NTOK_Q);
  bias_ock_kernel<<<3, 256, 0, stream>>>(Wc_self_b, Wc_b, biasO);
  bfprep_kernel<<<PREP_GRID, 256, 0, stream>>>(enc_o, att_W3, eobf, eow3);

  // 2. pairwise option-compare: p1 + p2 -> CS
  p1_kernel<3><<<768, 256, 0, stream>>>(eobf, eow3, s1o, s2o, om, PtG);
  p2_kernel<3><<<dim3(4, 256), 256, 0, stream>>>(eobf, PtG, CS);

  // 3. OCK = tanh([o1 | 3o1-CS | o1*CS] @ [Wc_self; Wc_hi; Wc_lo] + bias)
  {
    WcArgs wa{};
    wa.src[0] = Wc_self_w; wa.src[1] = Wc_w; wa.src[2] = Wc_w + HH;
    wa.dst = wtb; wa.Kw = 2304;
    wconv_kernel<<<dim3(144, 3), 256, 0, stream>>>(wa);
    MMArgs g{};
    g.a[0] = enc_o; g.b2[0] = nullptr; g.mode[0] = 0;
    g.a[1] = enc_o; g.b2[1] = CS;      g.mode[1] = 1;
    g.a[2] = enc_o; g.b2[2] = CS;      g.mode[2] = 2;
    g.K = 2304; g.wt = wtb; g.bias = biasO; g.out = OCK;
    mfma_gemm_kernel<EP_TANH><<<GBIG, 256, 0, stream>>>(g);
  }

  // 4. question pooling + Qg
  qpool_kernel<<<256, 256, 0, stream>>>(enc_q, qa, qm, Qpool);
  {
    GemmArgs g{};
    g.a[0] = Qpool; g.mode[0] = 0; g.w[0] = Wg_w + 2 * HH;
    g.nchunks = 1; g.bias = Wg_b; g.out = Qg;
    gemm_kernel<EP_STORE><<<dim3(12, 4), 256, 0, stream>>>(g);
  }

  // 5. merged = G*o1 + (1-G)*OCK
  {
    WcArgs wa{};
    wa.src[0] = Wg_w; wa.src[1] = Wg_w + HH;
    wa.dst = wtb; wa.Kw = 1536;
    wconv_kernel<<<dim3(144, 2), 256, 0, stream>>>(wa);
    MMArgs g{};
    g.a[0] = enc_o; g.mode[0] = 0;
    g.a[1] = OCK;   g.mode[1] = 0;
    g.K = 1536; g.wt = wtb; g.bias = nullptr;
    g.aux0 = enc_o; g.aux1 = OCK; g.aux2 = Qg; g.out = merged;
    mfma_gemm_kernel<EP_MERGE><<<GBIG, 256, 0, stream>>>(g);
  }

  // 6. co-attention: A2 (MFMA) -> poaa (MFMA)
  dot768_kernel<<<NTOK_O / 4, 256, 0, stream>>>(merged, co_W2_w, co_W2_b, ms2, NTOK_O);
  a2_mfma_kernel<<<256, 256, 0, stream>>>(enc_q, merged, qco1, ms2, qm, om, co_W3, A2buf);
  poaa_mfma_kernel<<<256, 256, 0, stream>>>(A2buf, enc_q, merged, PLO, PHI);

  // 7. OPK = relu([merged | PLO | PHI] @ Wp + b)
  {
    WcArgs wa{};
    wa.src[0] = Wp_w; wa.src[1] = Wp_w + HH; wa.src[2] = Wp_w + 2 * HH;
    wa.dst = wtb; wa.Kw = 2304;
    wconv_kernel<<<dim3(144, 3), 256, 0, stream>>>(wa);
    MMArgs g{};
    g.a[0] = merged; g.mode[0] = 0;
    g.a[1] = PLO;    g.mode[1] = 0;
    g.a[2] = PHI;    g.mode[2] = 0;
    g.K = 2304; g.wt = wtb; g.bias = Wp_b; g.out = OPK;
    mfma_gemm_kernel<EP_RELU><<<GBIG, 256, 0, stream>>>(g);
  }

  // 8. self-attention (p1/p2 on OPK)
  dot768_kernel<<<NTOK_O / 4, 256, 0, stream>>>(OPK, sa_W1_w, sa_W1_b, sa1, NTOK_O);
  dot768_kernel<<<NTOK_O / 4, 256, 0, stream>>>(OPK, sa_W2_w, sa_W2_b, sa2, NTOK_O);
  bfprep_kernel<<<PREP_GRID, 256, 0, stream>>>(OPK, sa_W3, opkbf, opkw3);
  p1_kernel<1><<<256, 256, 0, stream>>>(opkbf, opkw3, sa1, sa2, om, PtG);
  p2_kernel<1><<<dim3(4, 256), 256, 0, stream>>>(opkbf, PtG, OSK);

  // 9. out = max_lo relu([OPK | OSK | OPK-OSK | OPK*OSK] @ Wf + b)
  {
    WcArgs wa{};
    wa.src[0] = Wf_w; wa.src[1] = Wf_w + HH; wa.src[2] = Wf_w + 2 * HH; wa.src[3] = Wf_w + 3 * HH;
    wa.dst = wtb; wa.Kw = 3072;
    wconv_kernel<<<dim3(144, 4), 256, 0, stream>>>(wa);
    MMArgs g{};
    g.a[0] = OPK; g.mode[0] = 0;
    g.a[1] = OSK; g.mode[1] = 0;
    g.a[2] = OPK; g.b2[2] = OSK; g.mode[2] = 3;
    g.a[3] = OPK; g.b2[3] = OSK; g.mode[3] = 2;
    g.K = 3072; g.wt = wtb; g.bias = Wf_b; g.out = out;
    mfma_gemm_kernel<EP_RELU_MAX><<<GBIG, 256, 0, stream>>>(g);
  }
}

// Round 5
// 796.855 us; speedup vs baseline: 6.8619x; 1.4372x over previous
//
#include <hip/hip_runtime.h>
#include <math.h>

// OptionCompareCell: B=64,C=4,LO=64,LQ=128,H=768
// Round 5: (1) GEMM grid transposed to m-fast (weight slice stays L2-resident
//          per XCD); (2) all big intermediates stored bf16 (OCK, merged, OPK,
//          OSK, PLO, PHI, CS) -> halves GEMM A-traffic and elementwise passes;
//          (3) fused dot768x2 (two projections per read), p1 self-att reads
//          OPK bf16 directly (one bfprep eliminated).

#define NEGC (-10000.0f)
constexpr int HD = 768;

constexpr int EP_STORE = 0;
constexpr int EP_TANH = 1;
constexpr int EP_MERGE = 2;
constexpr int EP_RELU = 3;
constexpr int EP_RELU_MAX = 4;

typedef __attribute__((ext_vector_type(8))) short bf16x8;
typedef __attribute__((ext_vector_type(8))) unsigned short u16x8;
typedef __attribute__((ext_vector_type(4))) unsigned short u16x4;
typedef __attribute__((ext_vector_type(4))) float f32x4;

__device__ inline void st8(float* dst, float4 a0, float4 a1) {
  dst[0] = a0.x; dst[1] = a0.y; dst[2] = a0.z; dst[3] = a0.w;
  dst[4] = a1.x; dst[5] = a1.y; dst[6] = a1.z; dst[7] = a1.w;
}

__device__ inline unsigned short f2bf(float x) {
  unsigned int u = __float_as_uint(x);
  u += 0x7fffu + ((u >> 16) & 1u);
  return (unsigned short)(u >> 16);
}

__device__ inline float bf2f(unsigned short u) {
  return __uint_as_float(((unsigned int)u) << 16);
}

__device__ inline u16x8 pack8(float4 a, float4 b) {
  u16x8 r;
  r[0] = f2bf(a.x); r[1] = f2bf(a.y); r[2] = f2bf(a.z); r[3] = f2bf(a.w);
  r[4] = f2bf(b.x); r[5] = f2bf(b.y); r[6] = f2bf(b.z); r[7] = f2bf(b.w);
  return r;
}

__device__ inline void cvt8f(u16x8 v, float4& a, float4& b) {
  a.x = bf2f(v[0]); a.y = bf2f(v[1]); a.z = bf2f(v[2]); a.w = bf2f(v[3]);
  b.x = bf2f(v[4]); b.y = bf2f(v[5]); b.z = bf2f(v[6]); b.w = bf2f(v[7]);
}

// ---------------- fused per-token dots ----------------
__global__ __launch_bounds__(256)
void dot768x2_bf16(const unsigned short* __restrict__ x,
                   const float* __restrict__ w1, const float* __restrict__ b1,
                   const float* __restrict__ w2, const float* __restrict__ b2,
                   float* __restrict__ o1, float* __restrict__ o2, int ntok) {
  int tok = blockIdx.x * 4 + (threadIdx.x >> 6);
  int lane = threadIdx.x & 63;
  if (tok >= ntok) return;
  const unsigned short* xp = x + (size_t)tok * HD;
  float s1 = 0.f, s2 = 0.f;
#pragma unroll
  for (int i = 0; i < 3; ++i) {
    int c = (lane + (i << 6)) << 2;
    u16x4 xv = *(const u16x4*)(xp + c);
    float4 wa = *(const float4*)(w1 + c);
    float4 wb = *(const float4*)(w2 + c);
    float x0 = bf2f(xv[0]), x1 = bf2f(xv[1]), x2 = bf2f(xv[2]), x3 = bf2f(xv[3]);
    s1 = fmaf(x0, wa.x, s1); s1 = fmaf(x1, wa.y, s1);
    s1 = fmaf(x2, wa.z, s1); s1 = fmaf(x3, wa.w, s1);
    s2 = fmaf(x0, wb.x, s2); s2 = fmaf(x1, wb.y, s2);
    s2 = fmaf(x2, wb.z, s2); s2 = fmaf(x3, wb.w, s2);
  }
#pragma unroll
  for (int off = 32; off; off >>= 1) {
    s1 += __shfl_xor(s1, off);
    s2 += __shfl_xor(s2, off);
  }
  if (lane == 0) { o1[tok] = s1 + b1[0]; o2[tok] = s2 + b2[0]; }
}

__global__ __launch_bounds__(256)
void dot768x2_f32(const float* __restrict__ x,
                  const float* __restrict__ w1, const float* __restrict__ b1,
                  const float* __restrict__ w2, const float* __restrict__ b2,
                  float* __restrict__ o1, float* __restrict__ o2, int ntok) {
  int tok = blockIdx.x * 4 + (threadIdx.x >> 6);
  int lane = threadIdx.x & 63;
  if (tok >= ntok) return;
  const float* xp = x + (size_t)tok * HD;
  float s1 = 0.f, s2 = 0.f;
#pragma unroll
  for (int i = 0; i < 3; ++i) {
    int c = (lane + (i << 6)) << 2;
    float4 xv = *(const float4*)(xp + c);
    float4 wa = *(const float4*)(w1 + c);
    float4 wb = *(const float4*)(w2 + c);
    s1 = fmaf(xv.x, wa.x, s1); s1 = fmaf(xv.y, wa.y, s1);
    s1 = fmaf(xv.z, wa.z, s1); s1 = fmaf(xv.w, wa.w, s1);
    s2 = fmaf(xv.x, wb.x, s2); s2 = fmaf(xv.y, wb.y, s2);
    s2 = fmaf(xv.z, wb.z, s2); s2 = fmaf(xv.w, wb.w, s2);
  }
#pragma unroll
  for (int off = 32; off; off >>= 1) {
    s1 += __shfl_xor(s1, off);
    s2 += __shfl_xor(s2, off);
  }
  if (lane == 0) { o1[tok] = s1 + b1[0]; o2[tok] = s2 + b2[0]; }
}

__global__ __launch_bounds__(256)
void dot768_bf16(const unsigned short* __restrict__ x,
                 const float* __restrict__ w1, const float* __restrict__ b1,
                 float* __restrict__ o1, int ntok) {
  int tok = blockIdx.x * 4 + (threadIdx.x >> 6);
  int lane = threadIdx.x & 63;
  if (tok >= ntok) return;
  const unsigned short* xp = x + (size_t)tok * HD;
  float s1 = 0.f;
#pragma unroll
  for (int i = 0; i < 3; ++i) {
    int c = (lane + (i << 6)) << 2;
    u16x4 xv = *(const u16x4*)(xp + c);
    float4 wa = *(const float4*)(w1 + c);
    s1 = fmaf(bf2f(xv[0]), wa.x, s1); s1 = fmaf(bf2f(xv[1]), wa.y, s1);
    s1 = fmaf(bf2f(xv[2]), wa.z, s1); s1 = fmaf(bf2f(xv[3]), wa.w, s1);
  }
#pragma unroll
  for (int off = 32; off; off >>= 1) s1 += __shfl_xor(s1, off);
  if (lane == 0) o1[tok] = s1 + b1[0];
}

__global__ void bias_ock_kernel(const float* __restrict__ b1, const float* __restrict__ b2,
                                float* __restrict__ o) {
  int n = blockIdx.x * 256 + threadIdx.x;
  if (n < HD) o[n] = b1[n] + 3.f * b2[n];
}

// ---------------- bf16 prep: xbf = bf16(x), xw3 = bf16(x * w3[col]) ----------------
__global__ __launch_bounds__(256)
void bfprep_kernel(const float* __restrict__ x, const float* __restrict__ w3,
                   unsigned short* __restrict__ xbf, unsigned short* __restrict__ xw3) {
  size_t base = ((size_t)blockIdx.x * 256 + threadIdx.x) * 8;
  int col = (int)(base % HD);
  float4 a0 = *(const float4*)(x + base);
  float4 a1 = *(const float4*)(x + base + 4);
  float4 w0 = *(const float4*)(w3 + col);
  float4 w1 = *(const float4*)(w3 + col + 4);
  *(u16x8*)(xbf + base) = pack8(a0, a1);
  float4 s0, s1;
  s0.x = a0.x * w0.x; s0.y = a0.y * w0.y; s0.z = a0.z * w0.z; s0.w = a0.w * w0.w;
  s1.x = a1.x * w1.x; s1.y = a1.y * w1.y; s1.z = a1.z * w1.z; s1.w = a1.w * w1.w;
  *(u16x8*)(xw3 + base) = pack8(s0, s1);
}

// ---------------- w3-scale on bf16 input ----------------
__global__ __launch_bounds__(256)
void w3scale_bf16(const unsigned short* __restrict__ x, const float* __restrict__ w3,
                  unsigned short* __restrict__ xw3) {
  size_t base = ((size_t)blockIdx.x * 256 + threadIdx.x) * 8;
  int col = (int)(base % HD);
  u16x8 v = *(const u16x8*)(x + base);
  float4 a, b;
  cvt8f(v, a, b);
  float4 w0 = *(const float4*)(w3 + col);
  float4 w1 = *(const float4*)(w3 + col + 4);
  a.x *= w0.x; a.y *= w0.y; a.z *= w0.z; a.w *= w0.w;
  b.x *= w1.x; b.y *= w1.y; b.z *= w1.z; b.w *= w1.w;
  *(u16x8*)(xw3 + base) = pack8(a, b);
}

// ---------------- P1: S = U . Vw3^T (MFMA), softmax over u, write Pt[v][u] bf16 ----------------
template<int NJ>
__global__ __launch_bounds__(256)
void p1_kernel(const unsigned short* __restrict__ Xbf, const unsigned short* __restrict__ Xw3,
               const float* __restrict__ s1g, const float* __restrict__ s2g,
               const int* __restrict__ maskg, unsigned short* __restrict__ PtG) {
  __shared__ __align__(16) unsigned short Ua[64 * 136];
  __shared__ __align__(16) unsigned short Vb[64 * 136];
  __shared__ float Sbuf[64][66];
  __shared__ float red[4][64];
  const int t = threadIdx.x;
  int ubc, vbc;
  if (NJ == 1) {
    ubc = vbc = blockIdx.x;
  } else {
    const int b = blockIdx.x / 12, pr = blockIdx.x % 12;
    const int i = pr / 3, jj = pr % 3;
    const int j = jj + (jj >= i ? 1 : 0);
    vbc = (b << 2) + i; ubc = (b << 2) + j;
  }
  const unsigned short* U = Xbf + (size_t)ubc * (64 * HD);
  const unsigned short* V = Xw3 + (size_t)vbc * (64 * HD);
  const int w = t >> 6, lane = t & 63, l15 = lane & 15, l4 = lane >> 4;
  const int srow = t >> 2, scol = (t & 3) << 5;
  f32x4 acc[4] = {};
  for (int k0 = 0; k0 < HD; k0 += 128) {
    const unsigned short* up = U + (size_t)srow * HD + k0 + scol;
    const unsigned short* vp = V + (size_t)srow * HD + k0 + scol;
    unsigned short* ua = &Ua[srow * 136 + scol];
    unsigned short* vb = &Vb[srow * 136 + scol];
#pragma unroll
    for (int z = 0; z < 4; ++z) {
      *(u16x8*)(ua + z * 8) = *(const u16x8*)(up + z * 8);
      *(u16x8*)(vb + z * 8) = *(const u16x8*)(vp + z * 8);
    }
    __syncthreads();
#pragma unroll
    for (int ks = 0; ks < 4; ++ks) {
      bf16x8 af = *(const bf16x8*)(&Ua[(w * 16 + l15) * 136 + ks * 32 + l4 * 8]);
#pragma unroll
      for (int n = 0; n < 4; ++n) {
        bf16x8 bf = *(const bf16x8*)(&Vb[(n * 16 + l15) * 136 + ks * 32 + l4 * 8]);
        acc[n] = __builtin_amdgcn_mfma_f32_16x16x32_bf16(af, bf, acc[n], 0, 0, 0);
      }
    }
    __syncthreads();
  }
  {
    float s1v[4];
#pragma unroll
    for (int r = 0; r < 4; ++r) {
      int u = w * 16 + l4 * 4 + r;
      s1v[r] = s1g[ubc * 64 + u] + (1.f - (float)maskg[ubc * 64 + u]) * NEGC;
    }
#pragma unroll
    for (int n = 0; n < 4; ++n) {
      int v = n * 16 + l15;
      float s2v = s2g[vbc * 64 + v] + (1.f - (float)maskg[vbc * 64 + v]) * NEGC;
#pragma unroll
      for (int r = 0; r < 4; ++r)
        Sbuf[w * 16 + l4 * 4 + r][v] = acc[n][r] + s1v[r] + s2v;
    }
  }
  __syncthreads();
  {
    const int v = t & 63, part = t >> 6;
    float m = -1e30f;
#pragma unroll
    for (int z = 0; z < 16; ++z) m = fmaxf(m, Sbuf[part * 16 + z][v]);
    red[part][v] = m;
    __syncthreads();
    float gm = fmaxf(fmaxf(red[0][v], red[1][v]), fmaxf(red[2][v], red[3][v]));
    float s = 0.f;
#pragma unroll
    for (int z = 0; z < 16; ++z) {
      float e = expf(Sbuf[part * 16 + z][v] - gm);
      Sbuf[part * 16 + z][v] = e;
      s += e;
    }
    __syncthreads();
    red[part][v] = s;
    __syncthreads();
    float cinv = 1.f / (red[0][v] + red[1][v] + red[2][v] + red[3][v]);
    unsigned short* pt = PtG + (size_t)blockIdx.x * 4096 + v * 64 + part * 16;
#pragma unroll
    for (int z = 0; z < 16; ++z) pt[z] = f2bf(Sbuf[part * 16 + z][v] * cinv);
  }
}

// ---------------- P2: ctx[v][d] = sum_j sum_u Pt_j[v][u] * U_j[u][d] -> bf16 ----------------
template<int NJ>
__global__ __launch_bounds__(256)
void p2_kernel(const unsigned short* __restrict__ Xbf, const unsigned short* __restrict__ PtG,
               unsigned short* __restrict__ outg) {
  __shared__ __align__(16) unsigned short Pts[NJ][64 * 72];
  __shared__ __align__(16) unsigned short U2[64 * 192];
  const int t = threadIdx.x;
  const int dq = blockIdx.x, bc = blockIdx.y;
  const int d0 = dq * 192;
  const int b = bc >> 2, i = bc & 3;
  const int w = t >> 6, lane = t & 63, l15 = lane & 15, l4 = lane >> 4;
  {
    const int v = t >> 2, cs = (t & 3) << 4;
#pragma unroll
    for (int jj = 0; jj < NJ; ++jj) {
      size_t src = (NJ == 1 ? (size_t)bc : (size_t)(b * 12 + i * 3 + jj)) * 4096 + v * 64 + cs;
      *(u16x8*)(&Pts[jj][v * 72 + cs]) = *(const u16x8*)(PtG + src);
      *(u16x8*)(&Pts[jj][v * 72 + cs + 8]) = *(const u16x8*)(PtG + src + 8);
    }
  }
  f32x4 acc[4][3] = {};
  const int su = t >> 2, sc0 = (t & 3) * 48;
  const int sswz = ((su >> 3) & 3) << 5;
  for (int jj = 0; jj < NJ; ++jj) {
    const int ubc = (NJ == 1) ? bc : ((b << 2) + (jj + (jj >= i ? 1 : 0)));
    __syncthreads();
    {
      const unsigned short* up = Xbf + (size_t)ubc * (64 * HD) + (size_t)su * HD + d0 + sc0;
#pragma unroll
      for (int it = 0; it < 6; ++it) {
        u16x8 vdat = *(const u16x8*)(up + it * 8);
        *(u16x8*)((char*)U2 + ((su * 384 + (sc0 + it * 8) * 2) ^ sswz)) = vdat;
      }
    }
    __syncthreads();
    const unsigned short* ptj = &Pts[jj][0];
#pragma unroll
    for (int ks = 0; ks < 2; ++ks) {
      bf16x8 bfr[3];
#pragma unroll
      for (int n = 0; n < 3; ++n) {
        const int col = (w * 3 + n) * 16 + l15;
#pragma unroll
        for (int e = 0; e < 8; ++e) {
          const int uk = ks * 32 + l4 * 8 + e;
          const int byte = (uk * 384 + col * 2) ^ (((uk >> 3) & 3) << 5);
          bfr[n][e] = *(const short*)((const char*)U2 + byte);
        }
      }
#pragma unroll
      for (int m = 0; m < 4; ++m) {
        bf16x8 af = *(const bf16x8*)(ptj + (m * 16 + l15) * 72 + ks * 32 + l4 * 8);
#pragma unroll
        for (int n = 0; n < 3; ++n)
          acc[m][n] = __builtin_amdgcn_mfma_f32_16x16x32_bf16(af, bfr[n], acc[m][n], 0, 0, 0);
      }
    }
  }
  unsigned short* op = outg + (size_t)bc * (64 * HD);
#pragma unroll
  for (int m = 0; m < 4; ++m)
#pragma unroll
    for (int n = 0; n < 3; ++n) {
      const int d = d0 + (w * 3 + n) * 16 + l15;
#pragma unroll
      for (int r = 0; r < 4; ++r) {
        const int v = m * 16 + l4 * 4 + r;
        op[(size_t)v * HD + d] = f2bf(acc[m][n][r]);
      }
    }
}

// ---------------- question pooling ----------------
__global__ __launch_bounds__(256)
void qpool_kernel(const float* __restrict__ q, const float* __restrict__ qa,
                  const int* __restrict__ qm, float* __restrict__ Q) {
  __shared__ float wgt[128];
  __shared__ float wred[4];
  int t = threadIdx.x, bc = blockIdx.x;
  const float* qap = qa + bc * 128;
  const int* qmp = qm + bc * 128;
  float v = -1e30f;
  if (t < 128) v = qap[t] + (1.f - (float)qmp[t]) * NEGC;
  float m = v;
#pragma unroll
  for (int off = 32; off; off >>= 1) m = fmaxf(m, __shfl_xor(m, off));
  if ((t & 63) == 0) wred[t >> 6] = m;
  __syncthreads();
  float gm = fmaxf(fmaxf(wred[0], wred[1]), fmaxf(wred[2], wred[3]));
  float e = (t < 128) ? expf(v - gm) : 0.f;
  float s = e;
#pragma unroll
  for (int off = 32; off; off >>= 1) s += __shfl_xor(s, off);
  __syncthreads();
  if ((t & 63) == 0) wred[t >> 6] = s;
  __syncthreads();
  float tot = wred[0] + wred[1] + wred[2] + wred[3];
  if (t < 128) wgt[t] = e / tot;
  __syncthreads();
  const float* qp = q + (size_t)bc * (128 * HD);
  float* Qp = Q + (size_t)bc * HD;
  for (int d = t; d < HD; d += 256) {
    float acc = 0.f;
    for (int l = 0; l < 128; ++l) acc = fmaf(wgt[l], qp[(size_t)l * HD + d], acc);
    Qp[d] = acc;
  }
}

// ---------------- A2 via MFMA: A2[q][v] = (q*w3).merged^T + rterm + cterm ----------------
__global__ __launch_bounds__(256)
void a2_mfma_kernel(const float* __restrict__ qin, const unsigned short* __restrict__ mergedb,
                    const float* __restrict__ qco1, const float* __restrict__ ms2,
                    const int* __restrict__ qm, const int* __restrict__ om,
                    const float* __restrict__ w3, float* __restrict__ A2) {
  __shared__ __align__(16) unsigned short Aq[128 * 72];
  __shared__ __align__(16) unsigned short Bm[64 * 72];
  const int t = threadIdx.x, bc = blockIdx.x;
  const float* qp = qin + (size_t)bc * (128 * HD);
  const unsigned short* mp = mergedb + (size_t)bc * (64 * HD);
  const int w = t >> 6, lane = t & 63, l15 = lane & 15, l4 = lane >> 4;
  const int arow = t >> 1, acs = (t & 1) << 5;
  const int brow = t >> 2, bcs = (t & 3) << 4;
  f32x4 acc[2][4] = {};
  for (int k0 = 0; k0 < HD; k0 += 64) {
    {
      const float* p = qp + (size_t)arow * HD + k0 + acs;
      const float* wp = w3 + k0 + acs;
      unsigned short* dst = &Aq[arow * 72 + acs];
#pragma unroll
      for (int z = 0; z < 4; ++z) {
        float4 a = *(const float4*)(p + z * 8);
        float4 b = *(const float4*)(p + z * 8 + 4);
        float4 wa = *(const float4*)(wp + z * 8);
        float4 wb = *(const float4*)(wp + z * 8 + 4);
        a.x *= wa.x; a.y *= wa.y; a.z *= wa.z; a.w *= wa.w;
        b.x *= wb.x; b.y *= wb.y; b.z *= wb.z; b.w *= wb.w;
        *(u16x8*)(dst + z * 8) = pack8(a, b);
      }
    }
    {
      const unsigned short* p = mp + (size_t)brow * HD + k0 + bcs;
      unsigned short* dst = &Bm[brow * 72 + bcs];
      *(u16x8*)(dst) = *(const u16x8*)(p);
      *(u16x8*)(dst + 8) = *(const u16x8*)(p + 8);
    }
    __syncthreads();
#pragma unroll
    for (int ks = 0; ks < 2; ++ks) {
      bf16x8 af[2], bf[4];
#pragma unroll
      for (int m = 0; m < 2; ++m)
        af[m] = *(const bf16x8*)(&Aq[(w * 32 + m * 16 + l15) * 72 + ks * 32 + l4 * 8]);
#pragma unroll
      for (int n = 0; n < 4; ++n)
        bf[n] = *(const bf16x8*)(&Bm[(n * 16 + l15) * 72 + ks * 32 + l4 * 8]);
#pragma unroll
      for (int m = 0; m < 2; ++m)
#pragma unroll
        for (int n = 0; n < 4; ++n)
          acc[m][n] = __builtin_amdgcn_mfma_f32_16x16x32_bf16(af[m], bf[n], acc[m][n], 0, 0, 0);
    }
    __syncthreads();
  }
  const float* qc = qco1 + bc * 128;
  const int* qmp = qm + bc * 128;
  const float* msp = ms2 + bc * 64;
  const int* omp = om + bc * 64;
  float* outp = A2 + (size_t)bc * (128 * 64);
#pragma unroll
  for (int n = 0; n < 4; ++n) {
    const int v = n * 16 + l15;
    const float ct = msp[v] + (1.f - (float)omp[v]) * NEGC;
#pragma unroll
    for (int m = 0; m < 2; ++m)
#pragma unroll
      for (int r = 0; r < 4; ++r) {
        const int qrow = w * 32 + m * 16 + l4 * 4 + r;
        const float rt = qc[qrow] + (1.f - (float)qmp[qrow]) * NEGC;
        outp[qrow * 64 + v] = acc[m][n][r] + rt + ct;
      }
  }
}

// ---------------- POAA via MFMA (outputs bf16) ----------------
__global__ __launch_bounds__(256)
void poaa_mfma_kernel(const float* __restrict__ A2, const float* __restrict__ qin,
                      const unsigned short* __restrict__ mergedb,
                      unsigned short* __restrict__ PLO, unsigned short* __restrict__ PHI) {
  __shared__ __align__(16) char smem[77312];
  __shared__ float red[4][64];
  __shared__ float rowm[128], rowfac[128];
  __shared__ float colfac[64];
  __shared__ float gmax_s;
  float* T = (float*)smem;                                   // [128][65] f32
  unsigned short* Tt = (unsigned short*)(smem + 33280);       // [64][136]
  unsigned short* Tft = (unsigned short*)(smem + 50688);      // [64][136]
  unsigned short* M2bf = (unsigned short*)(smem + 68096);     // [64][72]
  unsigned short* Qc = (unsigned short*)smem;                 // [128][72] (after phase2)
  unsigned short* Mc = (unsigned short*)(smem + 18432);       // [64][72]

  const int t = threadIdx.x, bc = blockIdx.x;
  const int w = t >> 6, lane = t & 63, l15 = lane & 15, l4 = lane >> 4;
  const float* a2 = A2 + (size_t)bc * (128 * 64);
  {
    int row = t >> 1, cs = (t & 1) << 5;
    const float* p = a2 + row * 64 + cs;
#pragma unroll
    for (int z = 0; z < 8; ++z) {
      float4 v = *(const float4*)(p + (z << 2));
      T[row * 65 + cs + (z << 2) + 0] = v.x;
      T[row * 65 + cs + (z << 2) + 1] = v.y;
      T[row * 65 + cs + (z << 2) + 2] = v.z;
      T[row * 65 + cs + (z << 2) + 3] = v.w;
    }
  }
  __syncthreads();
  {
    int qrow = t >> 1, h = t & 1;
    float m = -1e30f;
    for (int v = h * 32; v < h * 32 + 32; ++v) m = fmaxf(m, T[qrow * 65 + v]);
    m = fmaxf(m, __shfl_xor(m, 1));
    float s = 0.f;
    for (int v = h * 32; v < h * 32 + 32; ++v) s += expf(T[qrow * 65 + v] - m);
    s += __shfl_xor(s, 1);
    if (h == 0) { rowm[qrow] = m; rowfac[qrow] = s; }
  }
  float colm_loc = 0.f;
  {
    int v = t & 63, part = t >> 6;
    float m = -1e30f;
    for (int qq = part * 32; qq < part * 32 + 32; ++qq) m = fmaxf(m, T[qq * 65 + v]);
    red[part][v] = m;
    __syncthreads();
    float cm = fmaxf(fmaxf(red[0][v], red[1][v]), fmaxf(red[2][v], red[3][v]));
    float s = 0.f;
    for (int qq = part * 32; qq < part * 32 + 32; ++qq) s += expf(T[qq * 65 + v] - cm);
    __syncthreads();
    red[part][v] = s;
    __syncthreads();
    if (part == 0) { colm_loc = cm; colfac[v] = red[0][v] + red[1][v] + red[2][v] + red[3][v]; }
  }
  __syncthreads();
  if (t < 64) {
    float m = fmaxf(rowm[t], rowm[t + 64]);
#pragma unroll
    for (int off = 32; off; off >>= 1) m = fmaxf(m, __shfl_xor(m, off));
    if (t == 0) gmax_s = m;
  }
  __syncthreads();
  const float gmax = gmax_s;
  if (t < 128) rowfac[t] = expf(fminf(gmax - rowm[t], 60.f)) / rowfac[t];
  if (t < 64) colfac[t] = expf(fminf(gmax - colm_loc, 60.f)) / colfac[t];
  __syncthreads();
  {
    const int o = t >> 2, qs = (t & 3) << 5;
    for (int z = 0; z < 32; ++z) {
      const int qq = qs + z;
      float e = expf(T[qq * 65 + o] - gmax);
      Tt[o * 136 + qq] = f2bf(e);
      Tft[o * 136 + qq] = f2bf(e * rowfac[qq]);
    }
  }
  __syncthreads();
  {
    f32x4 m2acc[4] = {};
#pragma unroll
    for (int ks = 0; ks < 4; ++ks) {
      bf16x8 af = *(const bf16x8*)(&Tt[(w * 16 + l15) * 136 + ks * 32 + l4 * 8]);
#pragma unroll
      for (int n = 0; n < 4; ++n) {
        bf16x8 bf = *(const bf16x8*)(&Tft[(n * 16 + l15) * 136 + ks * 32 + l4 * 8]);
        m2acc[n] = __builtin_amdgcn_mfma_f32_16x16x32_bf16(af, bf, m2acc[n], 0, 0, 0);
      }
    }
#pragma unroll
    for (int n = 0; n < 4; ++n)
#pragma unroll
      for (int r = 0; r < 4; ++r) {
        const int o = w * 16 + l4 * 4 + r;
        M2bf[o * 72 + n * 16 + l15] = f2bf(colfac[o] * m2acc[n][r]);
      }
  }
  const int dql = t >> 1, dqs = (t & 1) << 5;
  const int dml = t >> 2, dms = (t & 3) << 4;
  const int swq = ((dql >> 3) & 3) << 5;
  const int swm = ((dml >> 3) & 3) << 5;
  unsigned short* plo = PLO + (size_t)bc * (64 * HD);
  unsigned short* phi = PHI + (size_t)bc * (64 * HD);
  const float* qp = qin + (size_t)bc * (128 * HD);
  const unsigned short* mp = mergedb + (size_t)bc * (64 * HD);
  for (int dc = 0; dc < 12; ++dc) {
    const int d0 = dc * 64;
    __syncthreads();
    {
      const float* p = qp + (size_t)dql * HD + d0 + dqs;
#pragma unroll
      for (int z = 0; z < 4; ++z) {
        float4 a = *(const float4*)(p + z * 8);
        float4 b = *(const float4*)(p + z * 8 + 4);
        *(u16x8*)((char*)Qc + ((dql * 144 + (dqs + z * 8) * 2) ^ swq)) = pack8(a, b);
      }
    }
    {
      const unsigned short* p = mp + (size_t)dml * HD + d0 + dms;
      *(u16x8*)((char*)Mc + ((dml * 144 + dms * 2) ^ swm)) = *(const u16x8*)p;
      *(u16x8*)((char*)Mc + ((dml * 144 + (dms + 8) * 2) ^ swm)) = *(const u16x8*)(p + 8);
    }
    __syncthreads();
    const int col = w * 16 + l15;
    f32x4 lacc[4] = {};
#pragma unroll
    for (int ks = 0; ks < 4; ++ks) {
      bf16x8 bf;
#pragma unroll
      for (int e = 0; e < 8; ++e) {
        const int qq = ks * 32 + l4 * 8 + e;
        bf[e] = *(const short*)((const char*)Qc + ((qq * 144 + col * 2) ^ (((qq >> 3) & 3) << 5)));
      }
#pragma unroll
      for (int m = 0; m < 4; ++m) {
        bf16x8 af = *(const bf16x8*)(&Tt[(m * 16 + l15) * 136 + ks * 32 + l4 * 8]);
        lacc[m] = __builtin_amdgcn_mfma_f32_16x16x32_bf16(af, bf, lacc[m], 0, 0, 0);
      }
    }
    f32x4 pacc[4] = {};
#pragma unroll
    for (int ks = 0; ks < 2; ++ks) {
      bf16x8 bf;
#pragma unroll
      for (int e = 0; e < 8; ++e) {
        const int vv = ks * 32 + l4 * 8 + e;
        bf[e] = *(const short*)((const char*)Mc + ((vv * 144 + col * 2) ^ (((vv >> 3) & 3) << 5)));
      }
#pragma unroll
      for (int m = 0; m < 4; ++m) {
        bf16x8 af = *(const bf16x8*)(&M2bf[(m * 16 + l15) * 72 + ks * 32 + l4 * 8]);
        pacc[m] = __builtin_amdgcn_mfma_f32_16x16x32_bf16(af, bf, pacc[m], 0, 0, 0);
      }
    }
#pragma unroll
    for (int m = 0; m < 4; ++m)
#pragma unroll
      for (int r = 0; r < 4; ++r) {
        const int o = m * 16 + l4 * 4 + r;
        const int d = d0 + w * 16 + l15;
        plo[(size_t)o * HD + d] = f2bf(colfac[o] * lacc[m][r]);
        phi[(size_t)o * HD + d] = f2bf(pacc[m][r]);
      }
  }
}

// ---------------- small f32 GEMM (Qg only) ----------------
struct GemmArgs {
  const float* a[4];
  const float* w[4];
  int nchunks;
  const float* bias;
  float* out;
};

__global__ __launch_bounds__(256)
void gemm_store_kernel(GemmArgs g) {
  __shared__ float As[64][33];
  __shared__ float Ws[32][65];
  const int t = threadIdx.x;
  const int m0 = blockIdx.y << 6, n0 = blockIdx.x << 6;
  const int tr = t >> 4, tc = t & 15;
  float acc[4][4];
#pragma unroll
  for (int x = 0; x < 4; ++x)
#pragma unroll
    for (int y = 0; y < 4; ++y) acc[x][y] = 0.f;
  const int arow = t >> 2, acs = (t & 3) << 3;
  const int wrow = t >> 3, wcs = (t & 7) << 3;
  for (int c = 0; c < g.nchunks; ++c) {
    const float* Ap = g.a[c] + (size_t)(m0 + arow) * HD + acs;
    const float* Wp = g.w[c] + (size_t)wrow * HD + n0 + wcs;
    for (int k0 = 0; k0 < HD; k0 += 32) {
      float4 a0 = *(const float4*)(Ap + k0);
      float4 a1 = *(const float4*)(Ap + k0 + 4);
      st8(&As[arow][acs], a0, a1);
      float4 w0 = *(const float4*)(Wp + (size_t)k0 * HD);
      float4 w1 = *(const float4*)(Wp + (size_t)k0 * HD + 4);
      st8(&Ws[wrow][wcs], w0, w1);
      __syncthreads();
#pragma unroll
      for (int kk = 0; kk < 32; ++kk) {
        float av[4], bv[4];
#pragma unroll
        for (int x = 0; x < 4; ++x) av[x] = As[(tr << 2) + x][kk];
#pragma unroll
        for (int y = 0; y < 4; ++y) bv[y] = Ws[kk][(tc << 2) + y];
#pragma unroll
        for (int x = 0; x < 4; ++x)
#pragma unroll
          for (int y = 0; y < 4; ++y) acc[x][y] = fmaf(av[x], bv[y], acc[x][y]);
      }
      __syncthreads();
    }
  }
#pragma unroll
  for (int x = 0; x < 4; ++x) {
    const int r = m0 + (tr << 2) + x;
#pragma unroll
    for (int y = 0; y < 4; ++y) {
      const int n = n0 + (tc << 2) + y;
      g.out[(size_t)r * HD + n] = acc[x][y] + g.bias[n];
    }
  }
}

// ---------------- weight convert+transpose ----------------
struct WcArgs {
  const float* src[4];
  unsigned short* dst;
  int Kw;
};

__global__ __launch_bounds__(256)
void wconv_kernel(WcArgs g) {
  __shared__ float tile[64][65];
  const int slice = blockIdx.y;
  const float* src = g.src[slice];
  const int kbase = slice * HD;
  const int bi = blockIdx.x % 12, bj = blockIdx.x / 12;
  const int t = threadIdx.x;
  const int r = t >> 2, cseg = (t & 3) << 4;
  const float* p = src + (size_t)(bi * 64 + r) * HD + bj * 64 + cseg;
#pragma unroll
  for (int j = 0; j < 16; j += 4) {
    float4 v = *(const float4*)(p + j);
    tile[r][cseg + j + 0] = v.x; tile[r][cseg + j + 1] = v.y;
    tile[r][cseg + j + 2] = v.z; tile[r][cseg + j + 3] = v.w;
  }
  __syncthreads();
  unsigned short* q = g.dst + (size_t)(bj * 64 + r) * g.Kw + kbase + bi * 64 + cseg;
  u16x8 lo, hi;
#pragma unroll
  for (int j = 0; j < 8; ++j) lo[j] = f2bf(tile[cseg + j][r]);
#pragma unroll
  for (int j = 0; j < 8; ++j) hi[j] = f2bf(tile[cseg + 8 + j][r]);
  *(u16x8*)q = lo;
  *(u16x8*)(q + 8) = hi;
}

// ---------------- bf16 MFMA GEMM (bf16 A-sources, m-fast grid) ----------------
struct MMArgs {
  const unsigned short* a[4];
  const unsigned short* b2[4];
  int mode[4];                  // 0: a ; 1: 3a-b ; 2: a*b ; 3: a-b
  int K;
  const unsigned short* wt;
  const float* bias;
  const unsigned short* aux0;   // o1 bf16  (EP_MERGE)
  const unsigned short* aux1;   // OCK bf16 (EP_MERGE)
  const float* aux2;            // Qg f32   (EP_MERGE)
  float* outf;                  // EP_RELU_MAX
  unsigned short* outb;         // others
};

constexpr int LDP = 40;

__device__ inline void mode_apply(int mode, float4& x, const float4& y) {
  if (mode == 1) {
    x.x = fmaf(3.f, x.x, -y.x); x.y = fmaf(3.f, x.y, -y.y);
    x.z = fmaf(3.f, x.z, -y.z); x.w = fmaf(3.f, x.w, -y.w);
  } else if (mode == 2) {
    x.x *= y.x; x.y *= y.y; x.z *= y.z; x.w *= y.w;
  } else {
    x.x -= y.x; x.y -= y.y; x.z -= y.z; x.w -= y.w;
  }
}

template<int EP>
__global__ __launch_bounds__(256)
void mfma_gemm_kernel(MMArgs g) {
  __shared__ __align__(16) unsigned short As[128 * LDP];
  __shared__ __align__(16) unsigned short Bs[128 * LDP];
  const int t = threadIdx.x;
  const int lane = t & 63, w = t >> 6;
  const int wr = w >> 1, wc = w & 1;
  const int m0 = blockIdx.x << 7, n0 = blockIdx.y << 7;  // m-fast: weight slice L2-resident
  const int l15 = lane & 15, l4 = lane >> 4;
  f32x4 acc[4][4] = {};

  const int srow = t >> 1, shalf = t & 1;
  const int nkt = g.K >> 5;
  for (int kt = 0; kt < nkt; ++kt) {
    const int c = kt / 24;
    const int koff = (kt - c * 24) << 5;
    {
      const size_t ro = (size_t)(m0 + srow) * HD + koff + (shalf << 4);
      const unsigned short* ap = g.a[c] + ro;
      u16x8 xv0 = *(const u16x8*)ap;
      u16x8 xv1 = *(const u16x8*)(ap + 8);
      const int mode = g.mode[c];
      if (mode) {
        const unsigned short* bp = g.b2[c] + ro;
        u16x8 yv0 = *(const u16x8*)bp;
        u16x8 yv1 = *(const u16x8*)(bp + 8);
        float4 xa, xb, xc, xd, ya, yb, yc, yd;
        cvt8f(xv0, xa, xb); cvt8f(xv1, xc, xd);
        cvt8f(yv0, ya, yb); cvt8f(yv1, yc, yd);
        mode_apply(mode, xa, ya); mode_apply(mode, xb, yb);
        mode_apply(mode, xc, yc); mode_apply(mode, xd, yd);
        xv0 = pack8(xa, xb); xv1 = pack8(xc, xd);
      }
      *(u16x8*)(&As[srow * LDP + (shalf << 4)]) = xv0;
      *(u16x8*)(&As[srow * LDP + (shalf << 4) + 8]) = xv1;
    }
    {
      const unsigned short* bp = g.wt + (size_t)(n0 + srow) * g.K + (kt << 5) + (shalf << 4);
      u16x8 w0 = *(const u16x8*)bp;
      u16x8 w1 = *(const u16x8*)(bp + 8);
      *(u16x8*)(&Bs[srow * LDP + (shalf << 4)]) = w0;
      *(u16x8*)(&Bs[srow * LDP + (shalf << 4) + 8]) = w1;
    }
    __syncthreads();
    bf16x8 af[4], bfr[4];
#pragma unroll
    for (int mi = 0; mi < 4; ++mi)
      af[mi] = *(const bf16x8*)(&As[(wr * 64 + mi * 16 + l15) * LDP + l4 * 8]);
#pragma unroll
    for (int ni = 0; ni < 4; ++ni)
      bfr[ni] = *(const bf16x8*)(&Bs[(wc * 64 + ni * 16 + l15) * LDP + l4 * 8]);
#pragma unroll
    for (int mi = 0; mi < 4; ++mi)
#pragma unroll
      for (int ni = 0; ni < 4; ++ni)
        acc[mi][ni] = __builtin_amdgcn_mfma_f32_16x16x32_bf16(af[mi], bfr[ni], acc[mi][ni], 0, 0, 0);
    __syncthreads();
  }

  if (EP == EP_RELU_MAX) {
#pragma unroll
    for (int ni = 0; ni < 4; ++ni) {
      const int n = n0 + wc * 64 + ni * 16 + l15;
      const float b = g.bias[n];
      float m = 0.f;
#pragma unroll
      for (int mi = 0; mi < 4; ++mi)
#pragma unroll
        for (int r = 0; r < 4; ++r)
          m = fmaxf(m, acc[mi][ni][r] + b);
      m = fmaxf(m, 0.f);
      m = fmaxf(m, __shfl_xor(m, 16));
      m = fmaxf(m, __shfl_xor(m, 32));
      if (l4 == 0) g.outf[(size_t)((m0 >> 6) + wr) * HD + n] = m;
    }
  } else {
#pragma unroll
    for (int mi = 0; mi < 4; ++mi)
#pragma unroll
      for (int r = 0; r < 4; ++r) {
        const int row = m0 + wr * 64 + mi * 16 + l4 * 4 + r;
#pragma unroll
        for (int ni = 0; ni < 4; ++ni) {
          const int n = n0 + wc * 64 + ni * 16 + l15;
          const size_t oi = (size_t)row * HD + n;
          float v = acc[mi][ni][r];
          if (EP == EP_TANH) {
            g.outb[oi] = f2bf(tanhf(v + g.bias[n]));
          } else if (EP == EP_MERGE) {
            float gg = v + g.aux2[(size_t)(row >> 6) * HD + n];
            float sg = 1.f / (1.f + expf(-gg));
            float o1v = bf2f(g.aux0[oi]);
            float ock = bf2f(g.aux1[oi]);
            g.outb[oi] = f2bf(fmaf(sg, o1v - ock, ock));
          } else {  // EP_RELU
            g.outb[oi] = f2bf(fmaxf(v + g.bias[n], 0.f));
          }
        }
      }
  }
}

extern "C" void kernel_launch(void* const* d_in, const int* in_sizes, int n_in,
                              void* d_out, int out_size, void* d_ws, size_t ws_size,
                              hipStream_t stream) {
  const float* enc_o = (const float*)d_in[0];
  const float* enc_q = (const float*)d_in[1];
  const int* om = (const int*)d_in[2];
  const int* qm = (const int*)d_in[3];
  const float* att_W1_w = (const float*)d_in[4];
  const float* att_W1_b = (const float*)d_in[5];
  const float* att_W2_w = (const float*)d_in[6];
  const float* att_W2_b = (const float*)d_in[7];
  const float* att_W3 = (const float*)d_in[8];
  const float* Wc_self_w = (const float*)d_in[9];
  const float* Wc_self_b = (const float*)d_in[10];
  const float* Wc_w = (const float*)d_in[11];
  const float* Wc_b = (const float*)d_in[12];
  const float* Va_w = (const float*)d_in[13];
  const float* Va_b = (const float*)d_in[14];
  const float* Wg_w = (const float*)d_in[15];
  const float* Wg_b = (const float*)d_in[16];
  const float* co_W1_w = (const float*)d_in[17];
  const float* co_W1_b = (const float*)d_in[18];
  const float* co_W2_w = (const float*)d_in[19];
  const float* co_W2_b = (const float*)d_in[20];
  const float* co_W3 = (const float*)d_in[21];
  const float* Wp_w = (const float*)d_in[22];
  const float* Wp_b = (const float*)d_in[23];
  const float* sa_W1_w = (const float*)d_in[24];
  const float* sa_W1_b = (const float*)d_in[25];
  const float* sa_W2_w = (const float*)d_in[26];
  const float* sa_W2_b = (const float*)d_in[27];
  const float* sa_W3 = (const float*)d_in[28];
  const float* Wf_w = (const float*)d_in[29];
  const float* Wf_b = (const float*)d_in[30];
  float* out = (float*)d_out;

  const int NTOK_O = 16384;
  const int NTOK_Q = 32768;
  const int HH = 768 * 768;

  float* ws = (float*)d_ws;
  size_t off = 0;
  auto carve = [&](size_t n) { float* p = ws + off; off += n; return p; };
  float* s1o   = carve(16384);
  float* s2o   = carve(16384);
  float* qa    = carve(32768);
  float* qco1  = carve(32768);
  float* ms2   = carve(16384);
  float* sa1   = carve(16384);
  float* sa2   = carve(16384);
  float* biasO = carve(1024);
  float* Qpool = carve(196608);
  float* Qg    = carve(196608);
  float* A2buf = carve(2097152);
  float* r1 = carve(12582912);   // CSb -> OPKb
  float* r2 = carve(12582912);   // OCKb -> PLOb -> opkw3
  float* r3 = carve(12582912);   // mergedb -> OSKb
  float* r4 = carve(12582912);   // eobf/eow3 -> PHIb
  unsigned short* wtb = (unsigned short*)carve(1179648);
  if (ws_size < off * sizeof(float)) return;
  // bf16 aliases (stream-ordered reuse; each bf16 buffer = 12.58M shorts = half a carve)
  unsigned short* CSb   = (unsigned short*)r1;
  unsigned short* OPKb  = (unsigned short*)r1;
  unsigned short* OCKb  = (unsigned short*)r2;
  unsigned short* PLOb  = (unsigned short*)r2;
  unsigned short* opkw3 = (unsigned short*)r2;
  unsigned short* MRGb  = (unsigned short*)r3;
  unsigned short* OSKb  = (unsigned short*)r3;
  unsigned short* eobf  = (unsigned short*)r4;
  unsigned short* eow3  = (unsigned short*)(r4 + 6291456);
  unsigned short* PHIb  = (unsigned short*)r4;
  unsigned short* PtG   = (unsigned short*)A2buf;

  const dim3 GBIG(128, 6);  // m-fast: contemporaneous blocks share the weight n-slice
  const int PREP_GRID = NTOK_O * HD / (256 * 8);  // 6144

  // 1. bf16 prep of enc_o, then fused per-token scalars
  bfprep_kernel<<<PREP_GRID, 256, 0, stream>>>(enc_o, att_W3, eobf, eow3);
  dot768x2_bf16<<<NTOK_O / 4, 256, 0, stream>>>(eobf, att_W1_w, att_W1_b,
                                                att_W2_w, att_W2_b, s1o, s2o, NTOK_O);
  dot768x2_f32<<<NTOK_Q / 4, 256, 0, stream>>>(enc_q, Va_w, Va_b,
                                               co_W1_w, co_W1_b, qa, qco1, NTOK_Q);
  bias_ock_kernel<<<3, 256, 0, stream>>>(Wc_self_b, Wc_b, biasO);

  // 2. pairwise option-compare: p1 + p2 -> CS (bf16)
  p1_kernel<3><<<768, 256, 0, stream>>>(eobf, eow3, s1o, s2o, om, PtG);
  p2_kernel<3><<<dim3(4, 256), 256, 0, stream>>>(eobf, PtG, CSb);

  // 3. OCK = tanh([o1 | 3o1-CS | o1*CS] @ [Wc_self; Wc_hi; Wc_lo] + bias)
  {
    WcArgs wa{};
    wa.src[0] = Wc_self_w; wa.src[1] = Wc_w; wa.src[2] = Wc_w + HH;
    wa.dst = wtb; wa.Kw = 2304;
    wconv_kernel<<<dim3(144, 3), 256, 0, stream>>>(wa);
    MMArgs g{};
    g.a[0] = eobf; g.mode[0] = 0;
    g.a[1] = eobf; g.b2[1] = CSb; g.mode[1] = 1;
    g.a[2] = eobf; g.b2[2] = CSb; g.mode[2] = 2;
    g.K = 2304; g.wt = wtb; g.bias = biasO; g.outb = OCKb;
    mfma_gemm_kernel<EP_TANH><<<GBIG, 256, 0, stream>>>(g);
  }

  // 4. question pooling + Qg (f32)
  qpool_kernel<<<256, 256, 0, stream>>>(enc_q, qa, qm, Qpool);
  {
    GemmArgs g{};
    g.a[0] = Qpool; g.w[0] = Wg_w + 2 * HH;
    g.nchunks = 1; g.bias = Wg_b; g.out = Qg;
    gemm_store_kernel<<<dim3(12, 4), 256, 0, stream>>>(g);
  }

  // 5. merged = G*o1 + (1-G)*OCK  (bf16 out)
  {
    WcArgs wa{};
    wa.src[0] = Wg_w; wa.src[1] = Wg_w + HH;
    wa.dst = wtb; wa.Kw = 1536;
    wconv_kernel<<<dim3(144, 2), 256, 0, stream>>>(wa);
    MMArgs g{};
    g.a[0] = eobf; g.mode[0] = 0;
    g.a[1] = OCKb; g.mode[1] = 0;
    g.K = 1536; g.wt = wtb; g.bias = nullptr;
    g.aux0 = eobf; g.aux1 = OCKb; g.aux2 = Qg; g.outb = MRGb;
    mfma_gemm_kernel<EP_MERGE><<<GBIG, 256, 0, stream>>>(g);
  }

  // 6. co-attention: ms2 -> A2 (MFMA) -> poaa (MFMA, bf16 outs)
  dot768_bf16<<<NTOK_O / 4, 256, 0, stream>>>(MRGb, co_W2_w, co_W2_b, ms2, NTOK_O);
  a2_mfma_kernel<<<256, 256, 0, stream>>>(enc_q, MRGb, qco1, ms2, qm, om, co_W3, A2buf);
  poaa_mfma_kernel<<<256, 256, 0, stream>>>(A2buf, enc_q, MRGb, PLOb, PHIb);

  // 7. OPK = relu([merged | PLO | PHI] @ Wp + b)  (bf16 out)
  {
    WcArgs wa{};
    wa.src[0] = Wp_w; wa.src[1] = Wp_w + HH; wa.src[2] = Wp_w + 2 * HH;
    wa.dst = wtb; wa.Kw = 2304;
    wconv_kernel<<<dim3(144, 3), 256, 0, stream>>>(wa);
    MMArgs g{};
    g.a[0] = MRGb; g.mode[0] = 0;
    g.a[1] = PLOb; g.mode[1] = 0;
    g.a[2] = PHIb; g.mode[2] = 0;
    g.K = 2304; g.wt = wtb; g.bias = Wp_b; g.outb = OPKb;
    mfma_gemm_kernel<EP_RELU><<<GBIG, 256, 0, stream>>>(g);
  }

  // 8. self-attention (p1/p2 on OPK bf16; OPK itself is the bf16 operand)
  dot768x2_bf16<<<NTOK_O / 4, 256, 0, stream>>>(OPKb, sa_W1_w, sa_W1_b,
                                                sa_W2_w, sa_W2_b, sa1, sa2, NTOK_O);
  w3scale_bf16<<<PREP_GRID, 256, 0, stream>>>(OPKb, sa_W3, opkw3);
  p1_kernel<1><<<256, 256, 0, stream>>>(OPKb, opkw3, sa1, sa2, om, PtG);
  p2_kernel<1><<<dim3(4, 256), 256, 0, stream>>>(OPKb, PtG, OSKb);

  // 9. out = max_lo relu([OPK | OSK | OPK-OSK | OPK*OSK] @ Wf + b)  (f32 out)
  {
    WcArgs wa{};
    wa.src[0] = Wf_w; wa.src[1] = Wf_w + HH; wa.src[2] = Wf_w + 2 * HH; wa.src[3] = Wf_w + 3 * HH;
    wa.dst = wtb; wa.Kw = 3072;
    wconv_kernel<<<dim3(144, 4), 256, 0, stream>>>(wa);
    MMArgs g{};
    g.a[0] = OPKb; g.mode[0] = 0;
    g.a[1] = OSKb; g.mode[1] = 0;
    g.a[2] = OPKb; g.b2[2] = OSKb; g.mode[2] = 3;
    g.a[3] = OPKb; g.b2[3] = OSKb; g.mode[3] = 2;
    g.K = 3072; g.wt = wtb; g.bias = Wf_b; g.outf = out;
    mfma_gemm_kernel<EP_RELU_MAX><<<GBIG, 256, 0, stream>>>(g);
  }
}

// Round 6
// 752.487 us; speedup vs baseline: 7.2665x; 1.0590x over previous
//
#include <hip/hip_runtime.h>
#include <math.h>

// OptionCompareCell: B=64,C=4,LO=64,LQ=128,H=768
// Round 6: mfma_gemm -> m97 structure: global_load_lds width-16 staging for
//          A and B (linear [128][32] LDS, no reg round-trip); virtual-concat
//          modes pre-materialized as bf16 buffers (modeprep) so every chunk
//          is a plain gather. Everything else unchanged from round 5.

#define NEGC (-10000.0f)
constexpr int HD = 768;

constexpr int EP_TANH = 1;
constexpr int EP_MERGE = 2;
constexpr int EP_RELU = 3;
constexpr int EP_RELU_MAX = 4;

typedef __attribute__((ext_vector_type(8))) short bf16x8;
typedef __attribute__((ext_vector_type(8))) unsigned short u16x8;
typedef __attribute__((ext_vector_type(4))) unsigned short u16x4;
typedef __attribute__((ext_vector_type(4))) float f32x4;

__device__ inline void st8(float* dst, float4 a0, float4 a1) {
  dst[0] = a0.x; dst[1] = a0.y; dst[2] = a0.z; dst[3] = a0.w;
  dst[4] = a1.x; dst[5] = a1.y; dst[6] = a1.z; dst[7] = a1.w;
}

__device__ inline unsigned short f2bf(float x) {
  unsigned int u = __float_as_uint(x);
  u += 0x7fffu + ((u >> 16) & 1u);
  return (unsigned short)(u >> 16);
}

__device__ inline float bf2f(unsigned short u) {
  return __uint_as_float(((unsigned int)u) << 16);
}

__device__ inline u16x8 pack8(float4 a, float4 b) {
  u16x8 r;
  r[0] = f2bf(a.x); r[1] = f2bf(a.y); r[2] = f2bf(a.z); r[3] = f2bf(a.w);
  r[4] = f2bf(b.x); r[5] = f2bf(b.y); r[6] = f2bf(b.z); r[7] = f2bf(b.w);
  return r;
}

__device__ inline void cvt8f(u16x8 v, float4& a, float4& b) {
  a.x = bf2f(v[0]); a.y = bf2f(v[1]); a.z = bf2f(v[2]); a.w = bf2f(v[3]);
  b.x = bf2f(v[4]); b.y = bf2f(v[5]); b.z = bf2f(v[6]); b.w = bf2f(v[7]);
}

__device__ inline void gload_lds16(const unsigned short* src, unsigned short* dst) {
  __builtin_amdgcn_global_load_lds(
      (const __attribute__((address_space(1))) void*)src,
      (__attribute__((address_space(3))) void*)dst, 16, 0, 0);
}

// ---------------- fused per-token dots ----------------
__global__ __launch_bounds__(256)
void dot768x2_bf16(const unsigned short* __restrict__ x,
                   const float* __restrict__ w1, const float* __restrict__ b1,
                   const float* __restrict__ w2, const float* __restrict__ b2,
                   float* __restrict__ o1, float* __restrict__ o2, int ntok) {
  int tok = blockIdx.x * 4 + (threadIdx.x >> 6);
  int lane = threadIdx.x & 63;
  if (tok >= ntok) return;
  const unsigned short* xp = x + (size_t)tok * HD;
  float s1 = 0.f, s2 = 0.f;
#pragma unroll
  for (int i = 0; i < 3; ++i) {
    int c = (lane + (i << 6)) << 2;
    u16x4 xv = *(const u16x4*)(xp + c);
    float4 wa = *(const float4*)(w1 + c);
    float4 wb = *(const float4*)(w2 + c);
    float x0 = bf2f(xv[0]), x1 = bf2f(xv[1]), x2 = bf2f(xv[2]), x3 = bf2f(xv[3]);
    s1 = fmaf(x0, wa.x, s1); s1 = fmaf(x1, wa.y, s1);
    s1 = fmaf(x2, wa.z, s1); s1 = fmaf(x3, wa.w, s1);
    s2 = fmaf(x0, wb.x, s2); s2 = fmaf(x1, wb.y, s2);
    s2 = fmaf(x2, wb.z, s2); s2 = fmaf(x3, wb.w, s2);
  }
#pragma unroll
  for (int off = 32; off; off >>= 1) {
    s1 += __shfl_xor(s1, off);
    s2 += __shfl_xor(s2, off);
  }
  if (lane == 0) { o1[tok] = s1 + b1[0]; o2[tok] = s2 + b2[0]; }
}

__global__ __launch_bounds__(256)
void dot768x2_f32(const float* __restrict__ x,
                  const float* __restrict__ w1, const float* __restrict__ b1,
                  const float* __restrict__ w2, const float* __restrict__ b2,
                  float* __restrict__ o1, float* __restrict__ o2, int ntok) {
  int tok = blockIdx.x * 4 + (threadIdx.x >> 6);
  int lane = threadIdx.x & 63;
  if (tok >= ntok) return;
  const float* xp = x + (size_t)tok * HD;
  float s1 = 0.f, s2 = 0.f;
#pragma unroll
  for (int i = 0; i < 3; ++i) {
    int c = (lane + (i << 6)) << 2;
    float4 xv = *(const float4*)(xp + c);
    float4 wa = *(const float4*)(w1 + c);
    float4 wb = *(const float4*)(w2 + c);
    s1 = fmaf(xv.x, wa.x, s1); s1 = fmaf(xv.y, wa.y, s1);
    s1 = fmaf(xv.z, wa.z, s1); s1 = fmaf(xv.w, wa.w, s1);
    s2 = fmaf(xv.x, wb.x, s2); s2 = fmaf(xv.y, wb.y, s2);
    s2 = fmaf(xv.z, wb.z, s2); s2 = fmaf(xv.w, wb.w, s2);
  }
#pragma unroll
  for (int off = 32; off; off >>= 1) {
    s1 += __shfl_xor(s1, off);
    s2 += __shfl_xor(s2, off);
  }
  if (lane == 0) { o1[tok] = s1 + b1[0]; o2[tok] = s2 + b2[0]; }
}

__global__ __launch_bounds__(256)
void dot768_bf16(const unsigned short* __restrict__ x,
                 const float* __restrict__ w1, const float* __restrict__ b1,
                 float* __restrict__ o1, int ntok) {
  int tok = blockIdx.x * 4 + (threadIdx.x >> 6);
  int lane = threadIdx.x & 63;
  if (tok >= ntok) return;
  const unsigned short* xp = x + (size_t)tok * HD;
  float s1 = 0.f;
#pragma unroll
  for (int i = 0; i < 3; ++i) {
    int c = (lane + (i << 6)) << 2;
    u16x4 xv = *(const u16x4*)(xp + c);
    float4 wa = *(const float4*)(w1 + c);
    s1 = fmaf(bf2f(xv[0]), wa.x, s1); s1 = fmaf(bf2f(xv[1]), wa.y, s1);
    s1 = fmaf(bf2f(xv[2]), wa.z, s1); s1 = fmaf(bf2f(xv[3]), wa.w, s1);
  }
#pragma unroll
  for (int off = 32; off; off >>= 1) s1 += __shfl_xor(s1, off);
  if (lane == 0) o1[tok] = s1 + b1[0];
}

__global__ void bias_ock_kernel(const float* __restrict__ b1, const float* __restrict__ b2,
                                float* __restrict__ o) {
  int n = blockIdx.x * 256 + threadIdx.x;
  if (n < HD) o[n] = b1[n] + 3.f * b2[n];
}

// ---------------- bf16 prep: xbf = bf16(x), xw3 = bf16(x * w3[col]) ----------------
__global__ __launch_bounds__(256)
void bfprep_kernel(const float* __restrict__ x, const float* __restrict__ w3,
                   unsigned short* __restrict__ xbf, unsigned short* __restrict__ xw3) {
  size_t base = ((size_t)blockIdx.x * 256 + threadIdx.x) * 8;
  int col = (int)(base % HD);
  float4 a0 = *(const float4*)(x + base);
  float4 a1 = *(const float4*)(x + base + 4);
  float4 w0 = *(const float4*)(w3 + col);
  float4 w1 = *(const float4*)(w3 + col + 4);
  *(u16x8*)(xbf + base) = pack8(a0, a1);
  float4 s0, s1;
  s0.x = a0.x * w0.x; s0.y = a0.y * w0.y; s0.z = a0.z * w0.z; s0.w = a0.w * w0.w;
  s1.x = a1.x * w1.x; s1.y = a1.y * w1.y; s1.z = a1.z * w1.z; s1.w = a1.w * w1.w;
  *(u16x8*)(xw3 + base) = pack8(s0, s1);
}

// ---------------- w3-scale on bf16 input ----------------
__global__ __launch_bounds__(256)
void w3scale_bf16(const unsigned short* __restrict__ x, const float* __restrict__ w3,
                  unsigned short* __restrict__ xw3) {
  size_t base = ((size_t)blockIdx.x * 256 + threadIdx.x) * 8;
  int col = (int)(base % HD);
  u16x8 v = *(const u16x8*)(x + base);
  float4 a, b;
  cvt8f(v, a, b);
  float4 w0 = *(const float4*)(w3 + col);
  float4 w1 = *(const float4*)(w3 + col + 4);
  a.x *= w0.x; a.y *= w0.y; a.z *= w0.z; a.w *= w0.w;
  b.x *= w1.x; b.y *= w1.y; b.z *= w1.z; b.w *= w1.w;
  *(u16x8*)(xw3 + base) = pack8(a, b);
}

// ---------------- modeprep: y1 = (M1==1 ? 3a-b : a-b), y2 = a*b (bf16) ----------------
template<int M1>
__global__ __launch_bounds__(256)
void modeprep_kernel(const unsigned short* __restrict__ a, const unsigned short* __restrict__ b,
                     unsigned short* __restrict__ y1, unsigned short* __restrict__ y2) {
  size_t base = ((size_t)blockIdx.x * 256 + threadIdx.x) * 8;
  u16x8 av = *(const u16x8*)(a + base);
  u16x8 bv = *(const u16x8*)(b + base);
  float4 a0, a1, b0, b1;
  cvt8f(av, a0, a1);
  cvt8f(bv, b0, b1);
  float4 p0, p1, q0, q1;
  if (M1 == 1) {
    p0.x = fmaf(3.f, a0.x, -b0.x); p0.y = fmaf(3.f, a0.y, -b0.y);
    p0.z = fmaf(3.f, a0.z, -b0.z); p0.w = fmaf(3.f, a0.w, -b0.w);
    p1.x = fmaf(3.f, a1.x, -b1.x); p1.y = fmaf(3.f, a1.y, -b1.y);
    p1.z = fmaf(3.f, a1.z, -b1.z); p1.w = fmaf(3.f, a1.w, -b1.w);
  } else {
    p0.x = a0.x - b0.x; p0.y = a0.y - b0.y; p0.z = a0.z - b0.z; p0.w = a0.w - b0.w;
    p1.x = a1.x - b1.x; p1.y = a1.y - b1.y; p1.z = a1.z - b1.z; p1.w = a1.w - b1.w;
  }
  q0.x = a0.x * b0.x; q0.y = a0.y * b0.y; q0.z = a0.z * b0.z; q0.w = a0.w * b0.w;
  q1.x = a1.x * b1.x; q1.y = a1.y * b1.y; q1.z = a1.z * b1.z; q1.w = a1.w * b1.w;
  *(u16x8*)(y1 + base) = pack8(p0, p1);
  *(u16x8*)(y2 + base) = pack8(q0, q1);
}

// ---------------- P1: S = U . Vw3^T (MFMA), softmax over u, write Pt[v][u] bf16 ----------------
template<int NJ>
__global__ __launch_bounds__(256)
void p1_kernel(const unsigned short* __restrict__ Xbf, const unsigned short* __restrict__ Xw3,
               const float* __restrict__ s1g, const float* __restrict__ s2g,
               const int* __restrict__ maskg, unsigned short* __restrict__ PtG) {
  __shared__ __align__(16) unsigned short Ua[64 * 136];
  __shared__ __align__(16) unsigned short Vb[64 * 136];
  __shared__ float Sbuf[64][66];
  __shared__ float red[4][64];
  const int t = threadIdx.x;
  int ubc, vbc;
  if (NJ == 1) {
    ubc = vbc = blockIdx.x;
  } else {
    const int b = blockIdx.x / 12, pr = blockIdx.x % 12;
    const int i = pr / 3, jj = pr % 3;
    const int j = jj + (jj >= i ? 1 : 0);
    vbc = (b << 2) + i; ubc = (b << 2) + j;
  }
  const unsigned short* U = Xbf + (size_t)ubc * (64 * HD);
  const unsigned short* V = Xw3 + (size_t)vbc * (64 * HD);
  const int w = t >> 6, lane = t & 63, l15 = lane & 15, l4 = lane >> 4;
  const int srow = t >> 2, scol = (t & 3) << 5;
  f32x4 acc[4] = {};
  for (int k0 = 0; k0 < HD; k0 += 128) {
    const unsigned short* up = U + (size_t)srow * HD + k0 + scol;
    const unsigned short* vp = V + (size_t)srow * HD + k0 + scol;
    unsigned short* ua = &Ua[srow * 136 + scol];
    unsigned short* vb = &Vb[srow * 136 + scol];
#pragma unroll
    for (int z = 0; z < 4; ++z) {
      *(u16x8*)(ua + z * 8) = *(const u16x8*)(up + z * 8);
      *(u16x8*)(vb + z * 8) = *(const u16x8*)(vp + z * 8);
    }
    __syncthreads();
#pragma unroll
    for (int ks = 0; ks < 4; ++ks) {
      bf16x8 af = *(const bf16x8*)(&Ua[(w * 16 + l15) * 136 + ks * 32 + l4 * 8]);
#pragma unroll
      for (int n = 0; n < 4; ++n) {
        bf16x8 bf = *(const bf16x8*)(&Vb[(n * 16 + l15) * 136 + ks * 32 + l4 * 8]);
        acc[n] = __builtin_amdgcn_mfma_f32_16x16x32_bf16(af, bf, acc[n], 0, 0, 0);
      }
    }
    __syncthreads();
  }
  {
    float s1v[4];
#pragma unroll
    for (int r = 0; r < 4; ++r) {
      int u = w * 16 + l4 * 4 + r;
      s1v[r] = s1g[ubc * 64 + u] + (1.f - (float)maskg[ubc * 64 + u]) * NEGC;
    }
#pragma unroll
    for (int n = 0; n < 4; ++n) {
      int v = n * 16 + l15;
      float s2v = s2g[vbc * 64 + v] + (1.f - (float)maskg[vbc * 64 + v]) * NEGC;
#pragma unroll
      for (int r = 0; r < 4; ++r)
        Sbuf[w * 16 + l4 * 4 + r][v] = acc[n][r] + s1v[r] + s2v;
    }
  }
  __syncthreads();
  {
    const int v = t & 63, part = t >> 6;
    float m = -1e30f;
#pragma unroll
    for (int z = 0; z < 16; ++z) m = fmaxf(m, Sbuf[part * 16 + z][v]);
    red[part][v] = m;
    __syncthreads();
    float gm = fmaxf(fmaxf(red[0][v], red[1][v]), fmaxf(red[2][v], red[3][v]));
    float s = 0.f;
#pragma unroll
    for (int z = 0; z < 16; ++z) {
      float e = expf(Sbuf[part * 16 + z][v] - gm);
      Sbuf[part * 16 + z][v] = e;
      s += e;
    }
    __syncthreads();
    red[part][v] = s;
    __syncthreads();
    float cinv = 1.f / (red[0][v] + red[1][v] + red[2][v] + red[3][v]);
    unsigned short* pt = PtG + (size_t)blockIdx.x * 4096 + v * 64 + part * 16;
#pragma unroll
    for (int z = 0; z < 16; ++z) pt[z] = f2bf(Sbuf[part * 16 + z][v] * cinv);
  }
}

// ---------------- P2: ctx[v][d] = sum_j sum_u Pt_j[v][u] * U_j[u][d] -> bf16 ----------------
template<int NJ>
__global__ __launch_bounds__(256)
void p2_kernel(const unsigned short* __restrict__ Xbf, const unsigned short* __restrict__ PtG,
               unsigned short* __restrict__ outg) {
  __shared__ __align__(16) unsigned short Pts[NJ][64 * 72];
  __shared__ __align__(16) unsigned short U2[64 * 192];
  const int t = threadIdx.x;
  const int dq = blockIdx.x, bc = blockIdx.y;
  const int d0 = dq * 192;
  const int b = bc >> 2, i = bc & 3;
  const int w = t >> 6, lane = t & 63, l15 = lane & 15, l4 = lane >> 4;
  {
    const int v = t >> 2, cs = (t & 3) << 4;
#pragma unroll
    for (int jj = 0; jj < NJ; ++jj) {
      size_t src = (NJ == 1 ? (size_t)bc : (size_t)(b * 12 + i * 3 + jj)) * 4096 + v * 64 + cs;
      *(u16x8*)(&Pts[jj][v * 72 + cs]) = *(const u16x8*)(PtG + src);
      *(u16x8*)(&Pts[jj][v * 72 + cs + 8]) = *(const u16x8*)(PtG + src + 8);
    }
  }
  f32x4 acc[4][3] = {};
  const int su = t >> 2, sc0 = (t & 3) * 48;
  const int sswz = ((su >> 3) & 3) << 5;
  for (int jj = 0; jj < NJ; ++jj) {
    const int ubc = (NJ == 1) ? bc : ((b << 2) + (jj + (jj >= i ? 1 : 0)));
    __syncthreads();
    {
      const unsigned short* up = Xbf + (size_t)ubc * (64 * HD) + (size_t)su * HD + d0 + sc0;
#pragma unroll
      for (int it = 0; it < 6; ++it) {
        u16x8 vdat = *(const u16x8*)(up + it * 8);
        *(u16x8*)((char*)U2 + ((su * 384 + (sc0 + it * 8) * 2) ^ sswz)) = vdat;
      }
    }
    __syncthreads();
    const unsigned short* ptj = &Pts[jj][0];
#pragma unroll
    for (int ks = 0; ks < 2; ++ks) {
      bf16x8 bfr[3];
#pragma unroll
      for (int n = 0; n < 3; ++n) {
        const int col = (w * 3 + n) * 16 + l15;
#pragma unroll
        for (int e = 0; e < 8; ++e) {
          const int uk = ks * 32 + l4 * 8 + e;
          const int byte = (uk * 384 + col * 2) ^ (((uk >> 3) & 3) << 5);
          bfr[n][e] = *(const short*)((const char*)U2 + byte);
        }
      }
#pragma unroll
      for (int m = 0; m < 4; ++m) {
        bf16x8 af = *(const bf16x8*)(ptj + (m * 16 + l15) * 72 + ks * 32 + l4 * 8);
#pragma unroll
        for (int n = 0; n < 3; ++n)
          acc[m][n] = __builtin_amdgcn_mfma_f32_16x16x32_bf16(af, bfr[n], acc[m][n], 0, 0, 0);
      }
    }
  }
  unsigned short* op = outg + (size_t)bc * (64 * HD);
#pragma unroll
  for (int m = 0; m < 4; ++m)
#pragma unroll
    for (int n = 0; n < 3; ++n) {
      const int d = d0 + (w * 3 + n) * 16 + l15;
#pragma unroll
      for (int r = 0; r < 4; ++r) {
        const int v = m * 16 + l4 * 4 + r;
        op[(size_t)v * HD + d] = f2bf(acc[m][n][r]);
      }
    }
}

// ---------------- question pooling ----------------
__global__ __launch_bounds__(256)
void qpool_kernel(const float* __restrict__ q, const float* __restrict__ qa,
                  const int* __restrict__ qm, float* __restrict__ Q) {
  __shared__ float wgt[128];
  __shared__ float wred[4];
  int t = threadIdx.x, bc = blockIdx.x;
  const float* qap = qa + bc * 128;
  const int* qmp = qm + bc * 128;
  float v = -1e30f;
  if (t < 128) v = qap[t] + (1.f - (float)qmp[t]) * NEGC;
  float m = v;
#pragma unroll
  for (int off = 32; off; off >>= 1) m = fmaxf(m, __shfl_xor(m, off));
  if ((t & 63) == 0) wred[t >> 6] = m;
  __syncthreads();
  float gm = fmaxf(fmaxf(wred[0], wred[1]), fmaxf(wred[2], wred[3]));
  float e = (t < 128) ? expf(v - gm) : 0.f;
  float s = e;
#pragma unroll
  for (int off = 32; off; off >>= 1) s += __shfl_xor(s, off);
  __syncthreads();
  if ((t & 63) == 0) wred[t >> 6] = s;
  __syncthreads();
  float tot = wred[0] + wred[1] + wred[2] + wred[3];
  if (t < 128) wgt[t] = e / tot;
  __syncthreads();
  const float* qp = q + (size_t)bc * (128 * HD);
  float* Qp = Q + (size_t)bc * HD;
  for (int d = t; d < HD; d += 256) {
    float acc = 0.f;
    for (int l = 0; l < 128; ++l) acc = fmaf(wgt[l], qp[(size_t)l * HD + d], acc);
    Qp[d] = acc;
  }
}

// ---------------- A2 via MFMA: A2[q][v] = (q*w3).merged^T + rterm + cterm ----------------
__global__ __launch_bounds__(256)
void a2_mfma_kernel(const float* __restrict__ qin, const unsigned short* __restrict__ mergedb,
                    const float* __restrict__ qco1, const float* __restrict__ ms2,
                    const int* __restrict__ qm, const int* __restrict__ om,
                    const float* __restrict__ w3, float* __restrict__ A2) {
  __shared__ __align__(16) unsigned short Aq[128 * 72];
  __shared__ __align__(16) unsigned short Bm[64 * 72];
  const int t = threadIdx.x, bc = blockIdx.x;
  const float* qp = qin + (size_t)bc * (128 * HD);
  const unsigned short* mp = mergedb + (size_t)bc * (64 * HD);
  const int w = t >> 6, lane = t & 63, l15 = lane & 15, l4 = lane >> 4;
  const int arow = t >> 1, acs = (t & 1) << 5;
  const int brow = t >> 2, bcs = (t & 3) << 4;
  f32x4 acc[2][4] = {};
  for (int k0 = 0; k0 < HD; k0 += 64) {
    {
      const float* p = qp + (size_t)arow * HD + k0 + acs;
      const float* wp = w3 + k0 + acs;
      unsigned short* dst = &Aq[arow * 72 + acs];
#pragma unroll
      for (int z = 0; z < 4; ++z) {
        float4 a = *(const float4*)(p + z * 8);
        float4 b = *(const float4*)(p + z * 8 + 4);
        float4 wa = *(const float4*)(wp + z * 8);
        float4 wb = *(const float4*)(wp + z * 8 + 4);
        a.x *= wa.x; a.y *= wa.y; a.z *= wa.z; a.w *= wa.w;
        b.x *= wb.x; b.y *= wb.y; b.z *= wb.z; b.w *= wb.w;
        *(u16x8*)(dst + z * 8) = pack8(a, b);
      }
    }
    {
      const unsigned short* p = mp + (size_t)brow * HD + k0 + bcs;
      unsigned short* dst = &Bm[brow * 72 + bcs];
      *(u16x8*)(dst) = *(const u16x8*)(p);
      *(u16x8*)(dst + 8) = *(const u16x8*)(p + 8);
    }
    __syncthreads();
#pragma unroll
    for (int ks = 0; ks < 2; ++ks) {
      bf16x8 af[2], bf[4];
#pragma unroll
      for (int m = 0; m < 2; ++m)
        af[m] = *(const bf16x8*)(&Aq[(w * 32 + m * 16 + l15) * 72 + ks * 32 + l4 * 8]);
#pragma unroll
      for (int n = 0; n < 4; ++n)
        bf[n] = *(const bf16x8*)(&Bm[(n * 16 + l15) * 72 + ks * 32 + l4 * 8]);
#pragma unroll
      for (int m = 0; m < 2; ++m)
#pragma unroll
        for (int n = 0; n < 4; ++n)
          acc[m][n] = __builtin_amdgcn_mfma_f32_16x16x32_bf16(af[m], bf[n], acc[m][n], 0, 0, 0);
    }
    __syncthreads();
  }
  const float* qc = qco1 + bc * 128;
  const int* qmp = qm + bc * 128;
  const float* msp = ms2 + bc * 64;
  const int* omp = om + bc * 64;
  float* outp = A2 + (size_t)bc * (128 * 64);
#pragma unroll
  for (int n = 0; n < 4; ++n) {
    const int v = n * 16 + l15;
    const float ct = msp[v] + (1.f - (float)omp[v]) * NEGC;
#pragma unroll
    for (int m = 0; m < 2; ++m)
#pragma unroll
      for (int r = 0; r < 4; ++r) {
        const int qrow = w * 32 + m * 16 + l4 * 4 + r;
        const float rt = qc[qrow] + (1.f - (float)qmp[qrow]) * NEGC;
        outp[qrow * 64 + v] = acc[m][n][r] + rt + ct;
      }
  }
}

// ---------------- POAA via MFMA (outputs bf16) ----------------
__global__ __launch_bounds__(256)
void poaa_mfma_kernel(const float* __restrict__ A2, const float* __restrict__ qin,
                      const unsigned short* __restrict__ mergedb,
                      unsigned short* __restrict__ PLO, unsigned short* __restrict__ PHI) {
  __shared__ __align__(16) char smem[77312];
  __shared__ float red[4][64];
  __shared__ float rowm[128], rowfac[128];
  __shared__ float colfac[64];
  __shared__ float gmax_s;
  float* T = (float*)smem;                                   // [128][65] f32
  unsigned short* Tt = (unsigned short*)(smem + 33280);       // [64][136]
  unsigned short* Tft = (unsigned short*)(smem + 50688);      // [64][136]
  unsigned short* M2bf = (unsigned short*)(smem + 68096);     // [64][72]
  unsigned short* Qc = (unsigned short*)smem;                 // [128][72] (after phase2)
  unsigned short* Mc = (unsigned short*)(smem + 18432);       // [64][72]

  const int t = threadIdx.x, bc = blockIdx.x;
  const int w = t >> 6, lane = t & 63, l15 = lane & 15, l4 = lane >> 4;
  const float* a2 = A2 + (size_t)bc * (128 * 64);
  {
    int row = t >> 1, cs = (t & 1) << 5;
    const float* p = a2 + row * 64 + cs;
#pragma unroll
    for (int z = 0; z < 8; ++z) {
      float4 v = *(const float4*)(p + (z << 2));
      T[row * 65 + cs + (z << 2) + 0] = v.x;
      T[row * 65 + cs + (z << 2) + 1] = v.y;
      T[row * 65 + cs + (z << 2) + 2] = v.z;
      T[row * 65 + cs + (z << 2) + 3] = v.w;
    }
  }
  __syncthreads();
  {
    int qrow = t >> 1, h = t & 1;
    float m = -1e30f;
    for (int v = h * 32; v < h * 32 + 32; ++v) m = fmaxf(m, T[qrow * 65 + v]);
    m = fmaxf(m, __shfl_xor(m, 1));
    float s = 0.f;
    for (int v = h * 32; v < h * 32 + 32; ++v) s += expf(T[qrow * 65 + v] - m);
    s += __shfl_xor(s, 1);
    if (h == 0) { rowm[qrow] = m; rowfac[qrow] = s; }
  }
  float colm_loc = 0.f;
  {
    int v = t & 63, part = t >> 6;
    float m = -1e30f;
    for (int qq = part * 32; qq < part * 32 + 32; ++qq) m = fmaxf(m, T[qq * 65 + v]);
    red[part][v] = m;
    __syncthreads();
    float cm = fmaxf(fmaxf(red[0][v], red[1][v]), fmaxf(red[2][v], red[3][v]));
    float s = 0.f;
    for (int qq = part * 32; qq < part * 32 + 32; ++qq) s += expf(T[qq * 65 + v] - cm);
    __syncthreads();
    red[part][v] = s;
    __syncthreads();
    if (part == 0) { colm_loc = cm; colfac[v] = red[0][v] + red[1][v] + red[2][v] + red[3][v]; }
  }
  __syncthreads();
  if (t < 64) {
    float m = fmaxf(rowm[t], rowm[t + 64]);
#pragma unroll
    for (int off = 32; off; off >>= 1) m = fmaxf(m, __shfl_xor(m, off));
    if (t == 0) gmax_s = m;
  }
  __syncthreads();
  const float gmax = gmax_s;
  if (t < 128) rowfac[t] = expf(fminf(gmax - rowm[t], 60.f)) / rowfac[t];
  if (t < 64) colfac[t] = expf(fminf(gmax - colm_loc, 60.f)) / colfac[t];
  __syncthreads();
  {
    const int o = t >> 2, qs = (t & 3) << 5;
    for (int z = 0; z < 32; ++z) {
      const int qq = qs + z;
      float e = expf(T[qq * 65 + o] - gmax);
      Tt[o * 136 + qq] = f2bf(e);
      Tft[o * 136 + qq] = f2bf(e * rowfac[qq]);
    }
  }
  __syncthreads();
  {
    f32x4 m2acc[4] = {};
#pragma unroll
    for (int ks = 0; ks < 4; ++ks) {
      bf16x8 af = *(const bf16x8*)(&Tt[(w * 16 + l15) * 136 + ks * 32 + l4 * 8]);
#pragma unroll
      for (int n = 0; n < 4; ++n) {
        bf16x8 bf = *(const bf16x8*)(&Tft[(n * 16 + l15) * 136 + ks * 32 + l4 * 8]);
        m2acc[n] = __builtin_amdgcn_mfma_f32_16x16x32_bf16(af, bf, m2acc[n], 0, 0, 0);
      }
    }
#pragma unroll
    for (int n = 0; n < 4; ++n)
#pragma unroll
      for (int r = 0; r < 4; ++r) {
        const int o = w * 16 + l4 * 4 + r;
        M2bf[o * 72 + n * 16 + l15] = f2bf(colfac[o] * m2acc[n][r]);
      }
  }
  const int dql = t >> 1, dqs = (t & 1) << 5;
  const int dml = t >> 2, dms = (t & 3) << 4;
  const int swq = ((dql >> 3) & 3) << 5;
  const int swm = ((dml >> 3) & 3) << 5;
  unsigned short* plo = PLO + (size_t)bc * (64 * HD);
  unsigned short* phi = PHI + (size_t)bc * (64 * HD);
  const float* qp = qin + (size_t)bc * (128 * HD);
  const unsigned short* mp = mergedb + (size_t)bc * (64 * HD);
  for (int dc = 0; dc < 12; ++dc) {
    const int d0 = dc * 64;
    __syncthreads();
    {
      const float* p = qp + (size_t)dql * HD + d0 + dqs;
#pragma unroll
      for (int z = 0; z < 4; ++z) {
        float4 a = *(const float4*)(p + z * 8);
        float4 b = *(const float4*)(p + z * 8 + 4);
        *(u16x8*)((char*)Qc + ((dql * 144 + (dqs + z * 8) * 2) ^ swq)) = pack8(a, b);
      }
    }
    {
      const unsigned short* p = mp + (size_t)dml * HD + d0 + dms;
      *(u16x8*)((char*)Mc + ((dml * 144 + dms * 2) ^ swm)) = *(const u16x8*)p;
      *(u16x8*)((char*)Mc + ((dml * 144 + (dms + 8) * 2) ^ swm)) = *(const u16x8*)(p + 8);
    }
    __syncthreads();
    const int col = w * 16 + l15;
    f32x4 lacc[4] = {};
#pragma unroll
    for (int ks = 0; ks < 4; ++ks) {
      bf16x8 bf;
#pragma unroll
      for (int e = 0; e < 8; ++e) {
        const int qq = ks * 32 + l4 * 8 + e;
        bf[e] = *(const short*)((const char*)Qc + ((qq * 144 + col * 2) ^ (((qq >> 3) & 3) << 5)));
      }
#pragma unroll
      for (int m = 0; m < 4; ++m) {
        bf16x8 af = *(const bf16x8*)(&Tt[(m * 16 + l15) * 136 + ks * 32 + l4 * 8]);
        lacc[m] = __builtin_amdgcn_mfma_f32_16x16x32_bf16(af, bf, lacc[m], 0, 0, 0);
      }
    }
    f32x4 pacc[4] = {};
#pragma unroll
    for (int ks = 0; ks < 2; ++ks) {
      bf16x8 bf;
#pragma unroll
      for (int e = 0; e < 8; ++e) {
        const int vv = ks * 32 + l4 * 8 + e;
        bf[e] = *(const short*)((const char*)Mc + ((vv * 144 + col * 2) ^ (((vv >> 3) & 3) << 5)));
      }
#pragma unroll
      for (int m = 0; m < 4; ++m) {
        bf16x8 af = *(const bf16x8*)(&M2bf[(m * 16 + l15) * 72 + ks * 32 + l4 * 8]);
        pacc[m] = __builtin_amdgcn_mfma_f32_16x16x32_bf16(af, bf, pacc[m], 0, 0, 0);
      }
    }
#pragma unroll
    for (int m = 0; m < 4; ++m)
#pragma unroll
      for (int r = 0; r < 4; ++r) {
        const int o = m * 16 + l4 * 4 + r;
        const int d = d0 + w * 16 + l15;
        plo[(size_t)o * HD + d] = f2bf(colfac[o] * lacc[m][r]);
        phi[(size_t)o * HD + d] = f2bf(pacc[m][r]);
      }
  }
}

// ---------------- small f32 GEMM (Qg only) ----------------
struct GemmArgs {
  const float* a[4];
  const float* w[4];
  int nchunks;
  const float* bias;
  float* out;
};

__global__ __launch_bounds__(256)
void gemm_store_kernel(GemmArgs g) {
  __shared__ float As[64][33];
  __shared__ float Ws[32][65];
  const int t = threadIdx.x;
  const int m0 = blockIdx.y << 6, n0 = blockIdx.x << 6;
  const int tr = t >> 4, tc = t & 15;
  float acc[4][4];
#pragma unroll
  for (int x = 0; x < 4; ++x)
#pragma unroll
    for (int y = 0; y < 4; ++y) acc[x][y] = 0.f;
  const int arow = t >> 2, acs = (t & 3) << 3;
  const int wrow = t >> 3, wcs = (t & 7) << 3;
  for (int c = 0; c < g.nchunks; ++c) {
    const float* Ap = g.a[c] + (size_t)(m0 + arow) * HD + acs;
    const float* Wp = g.w[c] + (size_t)wrow * HD + n0 + wcs;
    for (int k0 = 0; k0 < HD; k0 += 32) {
      float4 a0 = *(const float4*)(Ap + k0);
      float4 a1 = *(const float4*)(Ap + k0 + 4);
      st8(&As[arow][acs], a0, a1);
      float4 w0 = *(const float4*)(Wp + (size_t)k0 * HD);
      float4 w1 = *(const float4*)(Wp + (size_t)k0 * HD + 4);
      st8(&Ws[wrow][wcs], w0, w1);
      __syncthreads();
#pragma unroll
      for (int kk = 0; kk < 32; ++kk) {
        float av[4], bv[4];
#pragma unroll
        for (int x = 0; x < 4; ++x) av[x] = As[(tr << 2) + x][kk];
#pragma unroll
        for (int y = 0; y < 4; ++y) bv[y] = Ws[kk][(tc << 2) + y];
#pragma unroll
        for (int x = 0; x < 4; ++x)
#pragma unroll
          for (int y = 0; y < 4; ++y) acc[x][y] = fmaf(av[x], bv[y], acc[x][y]);
      }
      __syncthreads();
    }
  }
#pragma unroll
  for (int x = 0; x < 4; ++x) {
    const int r = m0 + (tr << 2) + x;
#pragma unroll
    for (int y = 0; y < 4; ++y) {
      const int n = n0 + (tc << 2) + y;
      g.out[(size_t)r * HD + n] = acc[x][y] + g.bias[n];
    }
  }
}

// ---------------- weight convert+transpose ----------------
struct WcArgs {
  const float* src[4];
  unsigned short* dst;
  int Kw;
};

__global__ __launch_bounds__(256)
void wconv_kernel(WcArgs g) {
  __shared__ float tile[64][65];
  const int slice = blockIdx.y;
  const float* src = g.src[slice];
  const int kbase = slice * HD;
  const int bi = blockIdx.x % 12, bj = blockIdx.x / 12;
  const int t = threadIdx.x;
  const int r = t >> 2, cseg = (t & 3) << 4;
  const float* p = src + (size_t)(bi * 64 + r) * HD + bj * 64 + cseg;
#pragma unroll
  for (int j = 0; j < 16; j += 4) {
    float4 v = *(const float4*)(p + j);
    tile[r][cseg + j + 0] = v.x; tile[r][cseg + j + 1] = v.y;
    tile[r][cseg + j + 2] = v.z; tile[r][cseg + j + 3] = v.w;
  }
  __syncthreads();
  unsigned short* q = g.dst + (size_t)(bj * 64 + r) * g.Kw + kbase + bi * 64 + cseg;
  u16x8 lo, hi;
#pragma unroll
  for (int j = 0; j < 8; ++j) lo[j] = f2bf(tile[cseg + j][r]);
#pragma unroll
  for (int j = 0; j < 8; ++j) hi[j] = f2bf(tile[cseg + 8 + j][r]);
  *(u16x8*)q = lo;
  *(u16x8*)(q + 8) = hi;
}

// ---------------- bf16 MFMA GEMM (m97 structure: global_load_lds staging) ----------------
struct MMArgs {
  const unsigned short* a[4];   // per-768-chunk bf16 sources (all mode-0)
  int K;
  const unsigned short* wt;     // [768][K] bf16
  const float* bias;
  const unsigned short* aux0;   // o1 bf16  (EP_MERGE)
  const unsigned short* aux1;   // OCK bf16 (EP_MERGE)
  const float* aux2;            // Qg f32   (EP_MERGE)
  float* outf;                  // EP_RELU_MAX
  unsigned short* outb;         // others
};

template<int EP>
__global__ __launch_bounds__(256)
void mfma_gemm_kernel(MMArgs g) {
  __shared__ __align__(16) unsigned short As[128 * 32];   // linear, gload_lds dest
  __shared__ __align__(16) unsigned short Bs[128 * 32];
  const int t = threadIdx.x;
  const int lane = t & 63, w = t >> 6;
  const int wr = w >> 1, wc = w & 1;
  const int m0 = blockIdx.x << 7, n0 = blockIdx.y << 7;  // m-fast grid
  const int l15 = lane & 15, l4 = lane >> 4;
  f32x4 acc[4][4] = {};

  // staging: wave w covers rows w*32..w*32+31 of each tile, 2 issues of 1024B.
  // lane l in issue i -> row = w*32 + i*16 + (l>>2), col-seg = (l&3)*8 shorts.
  const int srow = w * 32 + (lane >> 2);
  const int scol = (lane & 3) * 8;
  unsigned short* adst0 = &As[w * 1024];
  unsigned short* bdst0 = &Bs[w * 1024];
  const int nkt = g.K >> 5;
  for (int kt = 0; kt < nkt; ++kt) {
    const int c = kt / 24;
    const int koff = (kt - c * 24) << 5;
    {
      const unsigned short* ap = g.a[c] + (size_t)(m0 + srow) * HD + koff + scol;
      const unsigned short* bp = g.wt + (size_t)(n0 + srow) * g.K + (kt << 5) + scol;
      gload_lds16(ap, adst0);
      gload_lds16(ap + (size_t)16 * HD, adst0 + 512);
      gload_lds16(bp, bdst0);
      gload_lds16(bp + (size_t)16 * g.K, bdst0 + 512);
    }
    __syncthreads();   // drains vmcnt(0): tiles ready
    bf16x8 af[4], bfr[4];
#pragma unroll
    for (int mi = 0; mi < 4; ++mi)
      af[mi] = *(const bf16x8*)(&As[(wr * 64 + mi * 16 + l15) * 32 + l4 * 8]);
#pragma unroll
    for (int ni = 0; ni < 4; ++ni)
      bfr[ni] = *(const bf16x8*)(&Bs[(wc * 64 + ni * 16 + l15) * 32 + l4 * 8]);
#pragma unroll
    for (int mi = 0; mi < 4; ++mi)
#pragma unroll
      for (int ni = 0; ni < 4; ++ni)
        acc[mi][ni] = __builtin_amdgcn_mfma_f32_16x16x32_bf16(af[mi], bfr[ni], acc[mi][ni], 0, 0, 0);
    __syncthreads();   // all reads done before next-tile DMA lands
  }

  if (EP == EP_RELU_MAX) {
#pragma unroll
    for (int ni = 0; ni < 4; ++ni) {
      const int n = n0 + wc * 64 + ni * 16 + l15;
      const float b = g.bias[n];
      float m = 0.f;
#pragma unroll
      for (int mi = 0; mi < 4; ++mi)
#pragma unroll
        for (int r = 0; r < 4; ++r)
          m = fmaxf(m, acc[mi][ni][r] + b);
      m = fmaxf(m, 0.f);
      m = fmaxf(m, __shfl_xor(m, 16));
      m = fmaxf(m, __shfl_xor(m, 32));
      if (l4 == 0) g.outf[(size_t)((m0 >> 6) + wr) * HD + n] = m;
    }
  } else {
#pragma unroll
    for (int mi = 0; mi < 4; ++mi)
#pragma unroll
      for (int r = 0; r < 4; ++r) {
        const int row = m0 + wr * 64 + mi * 16 + l4 * 4 + r;
#pragma unroll
        for (int ni = 0; ni < 4; ++ni) {
          const int n = n0 + wc * 64 + ni * 16 + l15;
          const size_t oi = (size_t)row * HD + n;
          float v = acc[mi][ni][r];
          if (EP == EP_TANH) {
            g.outb[oi] = f2bf(tanhf(v + g.bias[n]));
          } else if (EP == EP_MERGE) {
            float gg = v + g.aux2[(size_t)(row >> 6) * HD + n];
            float sg = 1.f / (1.f + expf(-gg));
            float o1v = bf2f(g.aux0[oi]);
            float ock = bf2f(g.aux1[oi]);
            g.outb[oi] = f2bf(fmaf(sg, o1v - ock, ock));
          } else {  // EP_RELU
            g.outb[oi] = f2bf(fmaxf(v + g.bias[n], 0.f));
          }
        }
      }
  }
}

extern "C" void kernel_launch(void* const* d_in, const int* in_sizes, int n_in,
                              void* d_out, int out_size, void* d_ws, size_t ws_size,
                              hipStream_t stream) {
  const float* enc_o = (const float*)d_in[0];
  const float* enc_q = (const float*)d_in[1];
  const int* om = (const int*)d_in[2];
  const int* qm = (const int*)d_in[3];
  const float* att_W1_w = (const float*)d_in[4];
  const float* att_W1_b = (const float*)d_in[5];
  const float* att_W2_w = (const float*)d_in[6];
  const float* att_W2_b = (const float*)d_in[7];
  const float* att_W3 = (const float*)d_in[8];
  const float* Wc_self_w = (const float*)d_in[9];
  const float* Wc_self_b = (const float*)d_in[10];
  const float* Wc_w = (const float*)d_in[11];
  const float* Wc_b = (const float*)d_in[12];
  const float* Va_w = (const float*)d_in[13];
  const float* Va_b = (const float*)d_in[14];
  const float* Wg_w = (const float*)d_in[15];
  const float* Wg_b = (const float*)d_in[16];
  const float* co_W1_w = (const float*)d_in[17];
  const float* co_W1_b = (const float*)d_in[18];
  const float* co_W2_w = (const float*)d_in[19];
  const float* co_W2_b = (const float*)d_in[20];
  const float* co_W3 = (const float*)d_in[21];
  const float* Wp_w = (const float*)d_in[22];
  const float* Wp_b = (const float*)d_in[23];
  const float* sa_W1_w = (const float*)d_in[24];
  const float* sa_W1_b = (const float*)d_in[25];
  const float* sa_W2_w = (const float*)d_in[26];
  const float* sa_W2_b = (const float*)d_in[27];
  const float* sa_W3 = (const float*)d_in[28];
  const float* Wf_w = (const float*)d_in[29];
  const float* Wf_b = (const float*)d_in[30];
  float* out = (float*)d_out;

  const int NTOK_O = 16384;
  const int NTOK_Q = 32768;
  const int HH = 768 * 768;

  float* ws = (float*)d_ws;
  size_t off = 0;
  auto carve = [&](size_t n) { float* p = ws + off; off += n; return p; };
  float* s1o   = carve(16384);
  float* s2o   = carve(16384);
  float* qa    = carve(32768);
  float* qco1  = carve(32768);
  float* ms2   = carve(16384);
  float* sa1   = carve(16384);
  float* sa2   = carve(16384);
  float* biasO = carve(1024);
  float* Qpool = carve(196608);
  float* Qg    = carve(196608);
  float* A2buf = carve(2097152);
  float* r1 = carve(12582912);   // [CSb|X1] -> [OPKb|X3]
  float* r2 = carve(12582912);   // [OCKb|X2] -> [PLOb|..] -> opkw3
  float* r3 = carve(12582912);   // [MRGb|..] -> [OSKb|X4]
  float* r4 = carve(12582912);   // [eobf|eow3] -> [PHIb|..]
  unsigned short* wtb = (unsigned short*)carve(1179648);
  if (ws_size < off * sizeof(float)) return;
  // bf16 aliases: each r-region = 25165824 shorts; "first half" = 12582912 shorts (25.2MB)
  unsigned short* CSb   = (unsigned short*)r1;
  unsigned short* OPKb  = (unsigned short*)r1;
  unsigned short* X1    = (unsigned short*)(r1 + 6291456);   // second half of r1
  unsigned short* X3    = (unsigned short*)(r1 + 6291456);
  unsigned short* OCKb  = (unsigned short*)r2;
  unsigned short* PLOb  = (unsigned short*)r2;
  unsigned short* opkw3 = (unsigned short*)r2;
  unsigned short* X2    = (unsigned short*)(r2 + 6291456);   // second half of r2
  unsigned short* MRGb  = (unsigned short*)r3;
  unsigned short* OSKb  = (unsigned short*)r3;
  unsigned short* X4    = (unsigned short*)(r3 + 6291456);   // second half of r3
  unsigned short* eobf  = (unsigned short*)r4;
  unsigned short* eow3  = (unsigned short*)(r4 + 6291456);
  unsigned short* PHIb  = (unsigned short*)r4;
  unsigned short* PtG   = (unsigned short*)A2buf;

  const dim3 GBIG(128, 6);  // m-fast
  const int PREP_GRID = NTOK_O * HD / (256 * 8);  // 6144

  // 1. bf16 prep of enc_o, then fused per-token scalars
  bfprep_kernel<<<PREP_GRID, 256, 0, stream>>>(enc_o, att_W3, eobf, eow3);
  dot768x2_bf16<<<NTOK_O / 4, 256, 0, stream>>>(eobf, att_W1_w, att_W1_b,
                                                att_W2_w, att_W2_b, s1o, s2o, NTOK_O);
  dot768x2_f32<<<NTOK_Q / 4, 256, 0, stream>>>(enc_q, Va_w, Va_b,
                                               co_W1_w, co_W1_b, qa, qco1, NTOK_Q);
  bias_ock_kernel<<<3, 256, 0, stream>>>(Wc_self_b, Wc_b, biasO);

  // 2. pairwise option-compare: p1 + p2 -> CS (bf16)
  p1_kernel<3><<<768, 256, 0, stream>>>(eobf, eow3, s1o, s2o, om, PtG);
  p2_kernel<3><<<dim3(4, 256), 256, 0, stream>>>(eobf, PtG, CSb);

  // 3. OCK = tanh([o1 | 3o1-CS | o1*CS] @ [Wc_self; Wc_hi; Wc_lo] + bias)
  {
    modeprep_kernel<1><<<PREP_GRID, 256, 0, stream>>>(eobf, CSb, X1, X2);
    WcArgs wa{};
    wa.src[0] = Wc_self_w; wa.src[1] = Wc_w; wa.src[2] = Wc_w + HH;
    wa.dst = wtb; wa.Kw = 2304;
    wconv_kernel<<<dim3(144, 3), 256, 0, stream>>>(wa);
    MMArgs g{};
    g.a[0] = eobf; g.a[1] = X1; g.a[2] = X2;
    g.K = 2304; g.wt = wtb; g.bias = biasO; g.outb = OCKb;
    mfma_gemm_kernel<EP_TANH><<<GBIG, 256, 0, stream>>>(g);
  }

  // 4. question pooling + Qg (f32)
  qpool_kernel<<<256, 256, 0, stream>>>(enc_q, qa, qm, Qpool);
  {
    GemmArgs g{};
    g.a[0] = Qpool; g.w[0] = Wg_w + 2 * HH;
    g.nchunks = 1; g.bias = Wg_b; g.out = Qg;
    gemm_store_kernel<<<dim3(12, 4), 256, 0, stream>>>(g);
  }

  // 5. merged = G*o1 + (1-G)*OCK  (bf16 out)
  {
    WcArgs wa{};
    wa.src[0] = Wg_w; wa.src[1] = Wg_w + HH;
    wa.dst = wtb; wa.Kw = 1536;
    wconv_kernel<<<dim3(144, 2), 256, 0, stream>>>(wa);
    MMArgs g{};
    g.a[0] = eobf; g.a[1] = OCKb;
    g.K = 1536; g.wt = wtb; g.bias = nullptr;
    g.aux0 = eobf; g.aux1 = OCKb; g.aux2 = Qg; g.outb = MRGb;
    mfma_gemm_kernel<EP_MERGE><<<GBIG, 256, 0, stream>>>(g);
  }

  // 6. co-attention: ms2 -> A2 (MFMA) -> poaa (MFMA, bf16 outs)
  dot768_bf16<<<NTOK_O / 4, 256, 0, stream>>>(MRGb, co_W2_w, co_W2_b, ms2, NTOK_O);
  a2_mfma_kernel<<<256, 256, 0, stream>>>(enc_q, MRGb, qco1, ms2, qm, om, co_W3, A2buf);
  poaa_mfma_kernel<<<256, 256, 0, stream>>>(A2buf, enc_q, MRGb, PLOb, PHIb);

  // 7. OPK = relu([merged | PLO | PHI] @ Wp + b)  (bf16 out)
  {
    WcArgs wa{};
    wa.src[0] = Wp_w; wa.src[1] = Wp_w + HH; wa.src[2] = Wp_w + 2 * HH;
    wa.dst = wtb; wa.Kw = 2304;
    wconv_kernel<<<dim3(144, 3), 256, 0, stream>>>(wa);
    MMArgs g{};
    g.a[0] = MRGb; g.a[1] = PLOb; g.a[2] = PHIb;
    g.K = 2304; g.wt = wtb; g.bias = Wp_b; g.outb = OPKb;
    mfma_gemm_kernel<EP_RELU><<<GBIG, 256, 0, stream>>>(g);
  }

  // 8. self-attention (p1/p2 on OPK bf16)
  dot768x2_bf16<<<NTOK_O / 4, 256, 0, stream>>>(OPKb, sa_W1_w, sa_W1_b,
                                                sa_W2_w, sa_W2_b, sa1, sa2, NTOK_O);
  w3scale_bf16<<<PREP_GRID, 256, 0, stream>>>(OPKb, sa_W3, opkw3);
  p1_kernel<1><<<256, 256, 0, stream>>>(OPKb, opkw3, sa1, sa2, om, PtG);
  p2_kernel<1><<<dim3(4, 256), 256, 0, stream>>>(OPKb, PtG, OSKb);

  // 9. out = max_lo relu([OPK | OSK | OPK-OSK | OPK*OSK] @ Wf + b)  (f32 out)
  {
    modeprep_kernel<3><<<PREP_GRID, 256, 0, stream>>>(OPKb, OSKb, X3, X4);
    WcArgs wa{};
    wa.src[0] = Wf_w; wa.src[1] = Wf_w + HH; wa.src[2] = Wf_w + 2 * HH; wa.src[3] = Wf_w + 3 * HH;
    wa.dst = wtb; wa.Kw = 3072;
    wconv_kernel<<<dim3(144, 4), 256, 0, stream>>>(wa);
    MMArgs g{};
    g.a[0] = OPKb; g.a[1] = OSKb; g.a[2] = X3; g.a[3] = X4;
    g.K = 3072; g.wt = wtb; g.bias = Wf_b; g.outf = out;
    mfma_gemm_kernel<EP_RELU_MAX><<<GBIG, 256, 0, stream>>>(g);
  }
}

// Round 7
// 703.713 us; speedup vs baseline: 7.7702x; 1.0693x over previous
//
#include <hip/hip_runtime.h>
#include <math.h>

// OptionCompareCell: B=64,C=4,LO=64,LQ=128,H=768
// Round 7: GEMM K-loop upgrades:
//  (a) LDS XOR swizzle via pre-swizzled GLOBAL source (linear gload_lds dest,
//      same involution on read) -> 8-way ds_read_b128 conflict becomes 2-way (free).
//  (b) double-buffered LDS with prefetch-issued-before-compute (2-phase T3 min
//      recipe): DMA latency hides under MFMA; 1 barrier per K-step.
// Everything else unchanged from round 6.

#define NEGC (-10000.0f)
constexpr int HD = 768;

constexpr int EP_TANH = 1;
constexpr int EP_MERGE = 2;
constexpr int EP_RELU = 3;
constexpr int EP_RELU_MAX = 4;

typedef __attribute__((ext_vector_type(8))) short bf16x8;
typedef __attribute__((ext_vector_type(8))) unsigned short u16x8;
typedef __attribute__((ext_vector_type(4))) unsigned short u16x4;
typedef __attribute__((ext_vector_type(4))) float f32x4;

__device__ inline void st8(float* dst, float4 a0, float4 a1) {
  dst[0] = a0.x; dst[1] = a0.y; dst[2] = a0.z; dst[3] = a0.w;
  dst[4] = a1.x; dst[5] = a1.y; dst[6] = a1.z; dst[7] = a1.w;
}

__device__ inline unsigned short f2bf(float x) {
  unsigned int u = __float_as_uint(x);
  u += 0x7fffu + ((u >> 16) & 1u);
  return (unsigned short)(u >> 16);
}

__device__ inline float bf2f(unsigned short u) {
  return __uint_as_float(((unsigned int)u) << 16);
}

__device__ inline u16x8 pack8(float4 a, float4 b) {
  u16x8 r;
  r[0] = f2bf(a.x); r[1] = f2bf(a.y); r[2] = f2bf(a.z); r[3] = f2bf(a.w);
  r[4] = f2bf(b.x); r[5] = f2bf(b.y); r[6] = f2bf(b.z); r[7] = f2bf(b.w);
  return r;
}

__device__ inline void cvt8f(u16x8 v, float4& a, float4& b) {
  a.x = bf2f(v[0]); a.y = bf2f(v[1]); a.z = bf2f(v[2]); a.w = bf2f(v[3]);
  b.x = bf2f(v[4]); b.y = bf2f(v[5]); b.z = bf2f(v[6]); b.w = bf2f(v[7]);
}

__device__ inline void gload_lds16(const unsigned short* src, unsigned short* dst) {
  __builtin_amdgcn_global_load_lds(
      (const __attribute__((address_space(1))) void*)src,
      (__attribute__((address_space(3))) void*)dst, 16, 0, 0);
}

// ---------------- fused per-token dots ----------------
__global__ __launch_bounds__(256)
void dot768x2_bf16(const unsigned short* __restrict__ x,
                   const float* __restrict__ w1, const float* __restrict__ b1,
                   const float* __restrict__ w2, const float* __restrict__ b2,
                   float* __restrict__ o1, float* __restrict__ o2, int ntok) {
  int tok = blockIdx.x * 4 + (threadIdx.x >> 6);
  int lane = threadIdx.x & 63;
  if (tok >= ntok) return;
  const unsigned short* xp = x + (size_t)tok * HD;
  float s1 = 0.f, s2 = 0.f;
#pragma unroll
  for (int i = 0; i < 3; ++i) {
    int c = (lane + (i << 6)) << 2;
    u16x4 xv = *(const u16x4*)(xp + c);
    float4 wa = *(const float4*)(w1 + c);
    float4 wb = *(const float4*)(w2 + c);
    float x0 = bf2f(xv[0]), x1 = bf2f(xv[1]), x2 = bf2f(xv[2]), x3 = bf2f(xv[3]);
    s1 = fmaf(x0, wa.x, s1); s1 = fmaf(x1, wa.y, s1);
    s1 = fmaf(x2, wa.z, s1); s1 = fmaf(x3, wa.w, s1);
    s2 = fmaf(x0, wb.x, s2); s2 = fmaf(x1, wb.y, s2);
    s2 = fmaf(x2, wb.z, s2); s2 = fmaf(x3, wb.w, s2);
  }
#pragma unroll
  for (int off = 32; off; off >>= 1) {
    s1 += __shfl_xor(s1, off);
    s2 += __shfl_xor(s2, off);
  }
  if (lane == 0) { o1[tok] = s1 + b1[0]; o2[tok] = s2 + b2[0]; }
}

__global__ __launch_bounds__(256)
void dot768x2_f32(const float* __restrict__ x,
                  const float* __restrict__ w1, const float* __restrict__ b1,
                  const float* __restrict__ w2, const float* __restrict__ b2,
                  float* __restrict__ o1, float* __restrict__ o2, int ntok) {
  int tok = blockIdx.x * 4 + (threadIdx.x >> 6);
  int lane = threadIdx.x & 63;
  if (tok >= ntok) return;
  const float* xp = x + (size_t)tok * HD;
  float s1 = 0.f, s2 = 0.f;
#pragma unroll
  for (int i = 0; i < 3; ++i) {
    int c = (lane + (i << 6)) << 2;
    float4 xv = *(const float4*)(xp + c);
    float4 wa = *(const float4*)(w1 + c);
    float4 wb = *(const float4*)(w2 + c);
    s1 = fmaf(xv.x, wa.x, s1); s1 = fmaf(xv.y, wa.y, s1);
    s1 = fmaf(xv.z, wa.z, s1); s1 = fmaf(xv.w, wa.w, s1);
    s2 = fmaf(xv.x, wb.x, s2); s2 = fmaf(xv.y, wb.y, s2);
    s2 = fmaf(xv.z, wb.z, s2); s2 = fmaf(xv.w, wb.w, s2);
  }
#pragma unroll
  for (int off = 32; off; off >>= 1) {
    s1 += __shfl_xor(s1, off);
    s2 += __shfl_xor(s2, off);
  }
  if (lane == 0) { o1[tok] = s1 + b1[0]; o2[tok] = s2 + b2[0]; }
}

__global__ __launch_bounds__(256)
void dot768_bf16(const unsigned short* __restrict__ x,
                 const float* __restrict__ w1, const float* __restrict__ b1,
                 float* __restrict__ o1, int ntok) {
  int tok = blockIdx.x * 4 + (threadIdx.x >> 6);
  int lane = threadIdx.x & 63;
  if (tok >= ntok) return;
  const unsigned short* xp = x + (size_t)tok * HD;
  float s1 = 0.f;
#pragma unroll
  for (int i = 0; i < 3; ++i) {
    int c = (lane + (i << 6)) << 2;
    u16x4 xv = *(const u16x4*)(xp + c);
    float4 wa = *(const float4*)(w1 + c);
    s1 = fmaf(bf2f(xv[0]), wa.x, s1); s1 = fmaf(bf2f(xv[1]), wa.y, s1);
    s1 = fmaf(bf2f(xv[2]), wa.z, s1); s1 = fmaf(bf2f(xv[3]), wa.w, s1);
  }
#pragma unroll
  for (int off = 32; off; off >>= 1) s1 += __shfl_xor(s1, off);
  if (lane == 0) o1[tok] = s1 + b1[0];
}

__global__ void bias_ock_kernel(const float* __restrict__ b1, const float* __restrict__ b2,
                                float* __restrict__ o) {
  int n = blockIdx.x * 256 + threadIdx.x;
  if (n < HD) o[n] = b1[n] + 3.f * b2[n];
}

// ---------------- bf16 prep: xbf = bf16(x), xw3 = bf16(x * w3[col]) ----------------
__global__ __launch_bounds__(256)
void bfprep_kernel(const float* __restrict__ x, const float* __restrict__ w3,
                   unsigned short* __restrict__ xbf, unsigned short* __restrict__ xw3) {
  size_t base = ((size_t)blockIdx.x * 256 + threadIdx.x) * 8;
  int col = (int)(base % HD);
  float4 a0 = *(const float4*)(x + base);
  float4 a1 = *(const float4*)(x + base + 4);
  float4 w0 = *(const float4*)(w3 + col);
  float4 w1 = *(const float4*)(w3 + col + 4);
  *(u16x8*)(xbf + base) = pack8(a0, a1);
  float4 s0, s1;
  s0.x = a0.x * w0.x; s0.y = a0.y * w0.y; s0.z = a0.z * w0.z; s0.w = a0.w * w0.w;
  s1.x = a1.x * w1.x; s1.y = a1.y * w1.y; s1.z = a1.z * w1.z; s1.w = a1.w * w1.w;
  *(u16x8*)(xw3 + base) = pack8(s0, s1);
}

// ---------------- w3-scale on bf16 input ----------------
__global__ __launch_bounds__(256)
void w3scale_bf16(const unsigned short* __restrict__ x, const float* __restrict__ w3,
                  unsigned short* __restrict__ xw3) {
  size_t base = ((size_t)blockIdx.x * 256 + threadIdx.x) * 8;
  int col = (int)(base % HD);
  u16x8 v = *(const u16x8*)(x + base);
  float4 a, b;
  cvt8f(v, a, b);
  float4 w0 = *(const float4*)(w3 + col);
  float4 w1 = *(const float4*)(w3 + col + 4);
  a.x *= w0.x; a.y *= w0.y; a.z *= w0.z; a.w *= w0.w;
  b.x *= w1.x; b.y *= w1.y; b.z *= w1.z; b.w *= w1.w;
  *(u16x8*)(xw3 + base) = pack8(a, b);
}

// ---------------- modeprep: y1 = (M1==1 ? 3a-b : a-b), y2 = a*b (bf16) ----------------
template<int M1>
__global__ __launch_bounds__(256)
void modeprep_kernel(const unsigned short* __restrict__ a, const unsigned short* __restrict__ b,
                     unsigned short* __restrict__ y1, unsigned short* __restrict__ y2) {
  size_t base = ((size_t)blockIdx.x * 256 + threadIdx.x) * 8;
  u16x8 av = *(const u16x8*)(a + base);
  u16x8 bv = *(const u16x8*)(b + base);
  float4 a0, a1, b0, b1;
  cvt8f(av, a0, a1);
  cvt8f(bv, b0, b1);
  float4 p0, p1, q0, q1;
  if (M1 == 1) {
    p0.x = fmaf(3.f, a0.x, -b0.x); p0.y = fmaf(3.f, a0.y, -b0.y);
    p0.z = fmaf(3.f, a0.z, -b0.z); p0.w = fmaf(3.f, a0.w, -b0.w);
    p1.x = fmaf(3.f, a1.x, -b1.x); p1.y = fmaf(3.f, a1.y, -b1.y);
    p1.z = fmaf(3.f, a1.z, -b1.z); p1.w = fmaf(3.f, a1.w, -b1.w);
  } else {
    p0.x = a0.x - b0.x; p0.y = a0.y - b0.y; p0.z = a0.z - b0.z; p0.w = a0.w - b0.w;
    p1.x = a1.x - b1.x; p1.y = a1.y - b1.y; p1.z = a1.z - b1.z; p1.w = a1.w - b1.w;
  }
  q0.x = a0.x * b0.x; q0.y = a0.y * b0.y; q0.z = a0.z * b0.z; q0.w = a0.w * b0.w;
  q1.x = a1.x * b1.x; q1.y = a1.y * b1.y; q1.z = a1.z * b1.z; q1.w = a1.w * b1.w;
  *(u16x8*)(y1 + base) = pack8(p0, p1);
  *(u16x8*)(y2 + base) = pack8(q0, q1);
}

// ---------------- P1: S = U . Vw3^T (MFMA), softmax over u, write Pt[v][u] bf16 ----------------
template<int NJ>
__global__ __launch_bounds__(256)
void p1_kernel(const unsigned short* __restrict__ Xbf, const unsigned short* __restrict__ Xw3,
               const float* __restrict__ s1g, const float* __restrict__ s2g,
               const int* __restrict__ maskg, unsigned short* __restrict__ PtG) {
  __shared__ __align__(16) unsigned short Ua[64 * 136];
  __shared__ __align__(16) unsigned short Vb[64 * 136];
  __shared__ float Sbuf[64][66];
  __shared__ float red[4][64];
  const int t = threadIdx.x;
  int ubc, vbc;
  if (NJ == 1) {
    ubc = vbc = blockIdx.x;
  } else {
    const int b = blockIdx.x / 12, pr = blockIdx.x % 12;
    const int i = pr / 3, jj = pr % 3;
    const int j = jj + (jj >= i ? 1 : 0);
    vbc = (b << 2) + i; ubc = (b << 2) + j;
  }
  const unsigned short* U = Xbf + (size_t)ubc * (64 * HD);
  const unsigned short* V = Xw3 + (size_t)vbc * (64 * HD);
  const int w = t >> 6, lane = t & 63, l15 = lane & 15, l4 = lane >> 4;
  const int srow = t >> 2, scol = (t & 3) << 5;
  f32x4 acc[4] = {};
  for (int k0 = 0; k0 < HD; k0 += 128) {
    const unsigned short* up = U + (size_t)srow * HD + k0 + scol;
    const unsigned short* vp = V + (size_t)srow * HD + k0 + scol;
    unsigned short* ua = &Ua[srow * 136 + scol];
    unsigned short* vb = &Vb[srow * 136 + scol];
#pragma unroll
    for (int z = 0; z < 4; ++z) {
      *(u16x8*)(ua + z * 8) = *(const u16x8*)(up + z * 8);
      *(u16x8*)(vb + z * 8) = *(const u16x8*)(vp + z * 8);
    }
    __syncthreads();
#pragma unroll
    for (int ks = 0; ks < 4; ++ks) {
      bf16x8 af = *(const bf16x8*)(&Ua[(w * 16 + l15) * 136 + ks * 32 + l4 * 8]);
#pragma unroll
      for (int n = 0; n < 4; ++n) {
        bf16x8 bf = *(const bf16x8*)(&Vb[(n * 16 + l15) * 136 + ks * 32 + l4 * 8]);
        acc[n] = __builtin_amdgcn_mfma_f32_16x16x32_bf16(af, bf, acc[n], 0, 0, 0);
      }
    }
    __syncthreads();
  }
  {
    float s1v[4];
#pragma unroll
    for (int r = 0; r < 4; ++r) {
      int u = w * 16 + l4 * 4 + r;
      s1v[r] = s1g[ubc * 64 + u] + (1.f - (float)maskg[ubc * 64 + u]) * NEGC;
    }
#pragma unroll
    for (int n = 0; n < 4; ++n) {
      int v = n * 16 + l15;
      float s2v = s2g[vbc * 64 + v] + (1.f - (float)maskg[vbc * 64 + v]) * NEGC;
#pragma unroll
      for (int r = 0; r < 4; ++r)
        Sbuf[w * 16 + l4 * 4 + r][v] = acc[n][r] + s1v[r] + s2v;
    }
  }
  __syncthreads();
  {
    const int v = t & 63, part = t >> 6;
    float m = -1e30f;
#pragma unroll
    for (int z = 0; z < 16; ++z) m = fmaxf(m, Sbuf[part * 16 + z][v]);
    red[part][v] = m;
    __syncthreads();
    float gm = fmaxf(fmaxf(red[0][v], red[1][v]), fmaxf(red[2][v], red[3][v]));
    float s = 0.f;
#pragma unroll
    for (int z = 0; z < 16; ++z) {
      float e = expf(Sbuf[part * 16 + z][v] - gm);
      Sbuf[part * 16 + z][v] = e;
      s += e;
    }
    __syncthreads();
    red[part][v] = s;
    __syncthreads();
    float cinv = 1.f / (red[0][v] + red[1][v] + red[2][v] + red[3][v]);
    unsigned short* pt = PtG + (size_t)blockIdx.x * 4096 + v * 64 + part * 16;
#pragma unroll
    for (int z = 0; z < 16; ++z) pt[z] = f2bf(Sbuf[part * 16 + z][v] * cinv);
  }
}

// ---------------- P2: ctx[v][d] = sum_j sum_u Pt_j[v][u] * U_j[u][d] -> bf16 ----------------
template<int NJ>
__global__ __launch_bounds__(256)
void p2_kernel(const unsigned short* __restrict__ Xbf, const unsigned short* __restrict__ PtG,
               unsigned short* __restrict__ outg) {
  __shared__ __align__(16) unsigned short Pts[NJ][64 * 72];
  __shared__ __align__(16) unsigned short U2[64 * 192];
  const int t = threadIdx.x;
  const int dq = blockIdx.x, bc = blockIdx.y;
  const int d0 = dq * 192;
  const int b = bc >> 2, i = bc & 3;
  const int w = t >> 6, lane = t & 63, l15 = lane & 15, l4 = lane >> 4;
  {
    const int v = t >> 2, cs = (t & 3) << 4;
#pragma unroll
    for (int jj = 0; jj < NJ; ++jj) {
      size_t src = (NJ == 1 ? (size_t)bc : (size_t)(b * 12 + i * 3 + jj)) * 4096 + v * 64 + cs;
      *(u16x8*)(&Pts[jj][v * 72 + cs]) = *(const u16x8*)(PtG + src);
      *(u16x8*)(&Pts[jj][v * 72 + cs + 8]) = *(const u16x8*)(PtG + src + 8);
    }
  }
  f32x4 acc[4][3] = {};
  const int su = t >> 2, sc0 = (t & 3) * 48;
  const int sswz = ((su >> 3) & 3) << 5;
  for (int jj = 0; jj < NJ; ++jj) {
    const int ubc = (NJ == 1) ? bc : ((b << 2) + (jj + (jj >= i ? 1 : 0)));
    __syncthreads();
    {
      const unsigned short* up = Xbf + (size_t)ubc * (64 * HD) + (size_t)su * HD + d0 + sc0;
#pragma unroll
      for (int it = 0; it < 6; ++it) {
        u16x8 vdat = *(const u16x8*)(up + it * 8);
        *(u16x8*)((char*)U2 + ((su * 384 + (sc0 + it * 8) * 2) ^ sswz)) = vdat;
      }
    }
    __syncthreads();
    const unsigned short* ptj = &Pts[jj][0];
#pragma unroll
    for (int ks = 0; ks < 2; ++ks) {
      bf16x8 bfr[3];
#pragma unroll
      for (int n = 0; n < 3; ++n) {
        const int col = (w * 3 + n) * 16 + l15;
#pragma unroll
        for (int e = 0; e < 8; ++e) {
          const int uk = ks * 32 + l4 * 8 + e;
          const int byte = (uk * 384 + col * 2) ^ (((uk >> 3) & 3) << 5);
          bfr[n][e] = *(const short*)((const char*)U2 + byte);
        }
      }
#pragma unroll
      for (int m = 0; m < 4; ++m) {
        bf16x8 af = *(const bf16x8*)(ptj + (m * 16 + l15) * 72 + ks * 32 + l4 * 8);
#pragma unroll
        for (int n = 0; n < 3; ++n)
          acc[m][n] = __builtin_amdgcn_mfma_f32_16x16x32_bf16(af, bfr[n], acc[m][n], 0, 0, 0);
      }
    }
  }
  unsigned short* op = outg + (size_t)bc * (64 * HD);
#pragma unroll
  for (int m = 0; m < 4; ++m)
#pragma unroll
    for (int n = 0; n < 3; ++n) {
      const int d = d0 + (w * 3 + n) * 16 + l15;
#pragma unroll
      for (int r = 0; r < 4; ++r) {
        const int v = m * 16 + l4 * 4 + r;
        op[(size_t)v * HD + d] = f2bf(acc[m][n][r]);
      }
    }
}

// ---------------- question pooling ----------------
__global__ __launch_bounds__(256)
void qpool_kernel(const float* __restrict__ q, const float* __restrict__ qa,
                  const int* __restrict__ qm, float* __restrict__ Q) {
  __shared__ float wgt[128];
  __shared__ float wred[4];
  int t = threadIdx.x, bc = blockIdx.x;
  const float* qap = qa + bc * 128;
  const int* qmp = qm + bc * 128;
  float v = -1e30f;
  if (t < 128) v = qap[t] + (1.f - (float)qmp[t]) * NEGC;
  float m = v;
#pragma unroll
  for (int off = 32; off; off >>= 1) m = fmaxf(m, __shfl_xor(m, off));
  if ((t & 63) == 0) wred[t >> 6] = m;
  __syncthreads();
  float gm = fmaxf(fmaxf(wred[0], wred[1]), fmaxf(wred[2], wred[3]));
  float e = (t < 128) ? expf(v - gm) : 0.f;
  float s = e;
#pragma unroll
  for (int off = 32; off; off >>= 1) s += __shfl_xor(s, off);
  __syncthreads();
  if ((t & 63) == 0) wred[t >> 6] = s;
  __syncthreads();
  float tot = wred[0] + wred[1] + wred[2] + wred[3];
  if (t < 128) wgt[t] = e / tot;
  __syncthreads();
  const float* qp = q + (size_t)bc * (128 * HD);
  float* Qp = Q + (size_t)bc * HD;
  for (int d = t; d < HD; d += 256) {
    float acc = 0.f;
    for (int l = 0; l < 128; ++l) acc = fmaf(wgt[l], qp[(size_t)l * HD + d], acc);
    Qp[d] = acc;
  }
}

// ---------------- A2 via MFMA: A2[q][v] = (q*w3).merged^T + rterm + cterm ----------------
__global__ __launch_bounds__(256)
void a2_mfma_kernel(const float* __restrict__ qin, const unsigned short* __restrict__ mergedb,
                    const float* __restrict__ qco1, const float* __restrict__ ms2,
                    const int* __restrict__ qm, const int* __restrict__ om,
                    const float* __restrict__ w3, float* __restrict__ A2) {
  __shared__ __align__(16) unsigned short Aq[128 * 72];
  __shared__ __align__(16) unsigned short Bm[64 * 72];
  const int t = threadIdx.x, bc = blockIdx.x;
  const float* qp = qin + (size_t)bc * (128 * HD);
  const unsigned short* mp = mergedb + (size_t)bc * (64 * HD);
  const int w = t >> 6, lane = t & 63, l15 = lane & 15, l4 = lane >> 4;
  const int arow = t >> 1, acs = (t & 1) << 5;
  const int brow = t >> 2, bcs = (t & 3) << 4;
  f32x4 acc[2][4] = {};
  for (int k0 = 0; k0 < HD; k0 += 64) {
    {
      const float* p = qp + (size_t)arow * HD + k0 + acs;
      const float* wp = w3 + k0 + acs;
      unsigned short* dst = &Aq[arow * 72 + acs];
#pragma unroll
      for (int z = 0; z < 4; ++z) {
        float4 a = *(const float4*)(p + z * 8);
        float4 b = *(const float4*)(p + z * 8 + 4);
        float4 wa = *(const float4*)(wp + z * 8);
        float4 wb = *(const float4*)(wp + z * 8 + 4);
        a.x *= wa.x; a.y *= wa.y; a.z *= wa.z; a.w *= wa.w;
        b.x *= wb.x; b.y *= wb.y; b.z *= wb.z; b.w *= wb.w;
        *(u16x8*)(dst + z * 8) = pack8(a, b);
      }
    }
    {
      const unsigned short* p = mp + (size_t)brow * HD + k0 + bcs;
      unsigned short* dst = &Bm[brow * 72 + bcs];
      *(u16x8*)(dst) = *(const u16x8*)(p);
      *(u16x8*)(dst + 8) = *(const u16x8*)(p + 8);
    }
    __syncthreads();
#pragma unroll
    for (int ks = 0; ks < 2; ++ks) {
      bf16x8 af[2], bf[4];
#pragma unroll
      for (int m = 0; m < 2; ++m)
        af[m] = *(const bf16x8*)(&Aq[(w * 32 + m * 16 + l15) * 72 + ks * 32 + l4 * 8]);
#pragma unroll
      for (int n = 0; n < 4; ++n)
        bf[n] = *(const bf16x8*)(&Bm[(n * 16 + l15) * 72 + ks * 32 + l4 * 8]);
#pragma unroll
      for (int m = 0; m < 2; ++m)
#pragma unroll
        for (int n = 0; n < 4; ++n)
          acc[m][n] = __builtin_amdgcn_mfma_f32_16x16x32_bf16(af[m], bf[n], acc[m][n], 0, 0, 0);
    }
    __syncthreads();
  }
  const float* qc = qco1 + bc * 128;
  const int* qmp = qm + bc * 128;
  const float* msp = ms2 + bc * 64;
  const int* omp = om + bc * 64;
  float* outp = A2 + (size_t)bc * (128 * 64);
#pragma unroll
  for (int n = 0; n < 4; ++n) {
    const int v = n * 16 + l15;
    const float ct = msp[v] + (1.f - (float)omp[v]) * NEGC;
#pragma unroll
    for (int m = 0; m < 2; ++m)
#pragma unroll
      for (int r = 0; r < 4; ++r) {
        const int qrow = w * 32 + m * 16 + l4 * 4 + r;
        const float rt = qc[qrow] + (1.f - (float)qmp[qrow]) * NEGC;
        outp[qrow * 64 + v] = acc[m][n][r] + rt + ct;
      }
  }
}

// ---------------- POAA via MFMA (outputs bf16) ----------------
__global__ __launch_bounds__(256)
void poaa_mfma_kernel(const float* __restrict__ A2, const float* __restrict__ qin,
                      const unsigned short* __restrict__ mergedb,
                      unsigned short* __restrict__ PLO, unsigned short* __restrict__ PHI) {
  __shared__ __align__(16) char smem[77312];
  __shared__ float red[4][64];
  __shared__ float rowm[128], rowfac[128];
  __shared__ float colfac[64];
  __shared__ float gmax_s;
  float* T = (float*)smem;                                   // [128][65] f32
  unsigned short* Tt = (unsigned short*)(smem + 33280);       // [64][136]
  unsigned short* Tft = (unsigned short*)(smem + 50688);      // [64][136]
  unsigned short* M2bf = (unsigned short*)(smem + 68096);     // [64][72]
  unsigned short* Qc = (unsigned short*)smem;                 // [128][72] (after phase2)
  unsigned short* Mc = (unsigned short*)(smem + 18432);       // [64][72]

  const int t = threadIdx.x, bc = blockIdx.x;
  const int w = t >> 6, lane = t & 63, l15 = lane & 15, l4 = lane >> 4;
  const float* a2 = A2 + (size_t)bc * (128 * 64);
  {
    int row = t >> 1, cs = (t & 1) << 5;
    const float* p = a2 + row * 64 + cs;
#pragma unroll
    for (int z = 0; z < 8; ++z) {
      float4 v = *(const float4*)(p + (z << 2));
      T[row * 65 + cs + (z << 2) + 0] = v.x;
      T[row * 65 + cs + (z << 2) + 1] = v.y;
      T[row * 65 + cs + (z << 2) + 2] = v.z;
      T[row * 65 + cs + (z << 2) + 3] = v.w;
    }
  }
  __syncthreads();
  {
    int qrow = t >> 1, h = t & 1;
    float m = -1e30f;
    for (int v = h * 32; v < h * 32 + 32; ++v) m = fmaxf(m, T[qrow * 65 + v]);
    m = fmaxf(m, __shfl_xor(m, 1));
    float s = 0.f;
    for (int v = h * 32; v < h * 32 + 32; ++v) s += expf(T[qrow * 65 + v] - m);
    s += __shfl_xor(s, 1);
    if (h == 0) { rowm[qrow] = m; rowfac[qrow] = s; }
  }
  float colm_loc = 0.f;
  {
    int v = t & 63, part = t >> 6;
    float m = -1e30f;
    for (int qq = part * 32; qq < part * 32 + 32; ++qq) m = fmaxf(m, T[qq * 65 + v]);
    red[part][v] = m;
    __syncthreads();
    float cm = fmaxf(fmaxf(red[0][v], red[1][v]), fmaxf(red[2][v], red[3][v]));
    float s = 0.f;
    for (int qq = part * 32; qq < part * 32 + 32; ++qq) s += expf(T[qq * 65 + v] - cm);
    __syncthreads();
    red[part][v] = s;
    __syncthreads();
    if (part == 0) { colm_loc = cm; colfac[v] = red[0][v] + red[1][v] + red[2][v] + red[3][v]; }
  }
  __syncthreads();
  if (t < 64) {
    float m = fmaxf(rowm[t], rowm[t + 64]);
#pragma unroll
    for (int off = 32; off; off >>= 1) m = fmaxf(m, __shfl_xor(m, off));
    if (t == 0) gmax_s = m;
  }
  __syncthreads();
  const float gmax = gmax_s;
  if (t < 128) rowfac[t] = expf(fminf(gmax - rowm[t], 60.f)) / rowfac[t];
  if (t < 64) colfac[t] = expf(fminf(gmax - colm_loc, 60.f)) / colfac[t];
  __syncthreads();
  {
    const int o = t >> 2, qs = (t & 3) << 5;
    for (int z = 0; z < 32; ++z) {
      const int qq = qs + z;
      float e = expf(T[qq * 65 + o] - gmax);
      Tt[o * 136 + qq] = f2bf(e);
      Tft[o * 136 + qq] = f2bf(e * rowfac[qq]);
    }
  }
  __syncthreads();
  {
    f32x4 m2acc[4] = {};
#pragma unroll
    for (int ks = 0; ks < 4; ++ks) {
      bf16x8 af = *(const bf16x8*)(&Tt[(w * 16 + l15) * 136 + ks * 32 + l4 * 8]);
#pragma unroll
      for (int n = 0; n < 4; ++n) {
        bf16x8 bf = *(const bf16x8*)(&Tft[(n * 16 + l15) * 136 + ks * 32 + l4 * 8]);
        m2acc[n] = __builtin_amdgcn_mfma_f32_16x16x32_bf16(af, bf, m2acc[n], 0, 0, 0);
      }
    }
#pragma unroll
    for (int n = 0; n < 4; ++n)
#pragma unroll
      for (int r = 0; r < 4; ++r) {
        const int o = w * 16 + l4 * 4 + r;
        M2bf[o * 72 + n * 16 + l15] = f2bf(colfac[o] * m2acc[n][r]);
      }
  }
  const int dql = t >> 1, dqs = (t & 1) << 5;
  const int dml = t >> 2, dms = (t & 3) << 4;
  const int swq = ((dql >> 3) & 3) << 5;
  const int swm = ((dml >> 3) & 3) << 5;
  unsigned short* plo = PLO + (size_t)bc * (64 * HD);
  unsigned short* phi = PHI + (size_t)bc * (64 * HD);
  const float* qp = qin + (size_t)bc * (128 * HD);
  const unsigned short* mp = mergedb + (size_t)bc * (64 * HD);
  for (int dc = 0; dc < 12; ++dc) {
    const int d0 = dc * 64;
    __syncthreads();
    {
      const float* p = qp + (size_t)dql * HD + d0 + dqs;
#pragma unroll
      for (int z = 0; z < 4; ++z) {
        float4 a = *(const float4*)(p + z * 8);
        float4 b = *(const float4*)(p + z * 8 + 4);
        *(u16x8*)((char*)Qc + ((dql * 144 + (dqs + z * 8) * 2) ^ swq)) = pack8(a, b);
      }
    }
    {
      const unsigned short* p = mp + (size_t)dml * HD + d0 + dms;
      *(u16x8*)((char*)Mc + ((dml * 144 + dms * 2) ^ swm)) = *(const u16x8*)p;
      *(u16x8*)((char*)Mc + ((dml * 144 + (dms + 8) * 2) ^ swm)) = *(const u16x8*)(p + 8);
    }
    __syncthreads();
    const int col = w * 16 + l15;
    f32x4 lacc[4] = {};
#pragma unroll
    for (int ks = 0; ks < 4; ++ks) {
      bf16x8 bf;
#pragma unroll
      for (int e = 0; e < 8; ++e) {
        const int qq = ks * 32 + l4 * 8 + e;
        bf[e] = *(const short*)((const char*)Qc + ((qq * 144 + col * 2) ^ (((qq >> 3) & 3) << 5)));
      }
#pragma unroll
      for (int m = 0; m < 4; ++m) {
        bf16x8 af = *(const bf16x8*)(&Tt[(m * 16 + l15) * 136 + ks * 32 + l4 * 8]);
        lacc[m] = __builtin_amdgcn_mfma_f32_16x16x32_bf16(af, bf, lacc[m], 0, 0, 0);
      }
    }
    f32x4 pacc[4] = {};
#pragma unroll
    for (int ks = 0; ks < 2; ++ks) {
      bf16x8 bf;
#pragma unroll
      for (int e = 0; e < 8; ++e) {
        const int vv = ks * 32 + l4 * 8 + e;
        bf[e] = *(const short*)((const char*)Mc + ((vv * 144 + col * 2) ^ (((vv >> 3) & 3) << 5)));
      }
#pragma unroll
      for (int m = 0; m < 4; ++m) {
        bf16x8 af = *(const bf16x8*)(&M2bf[(m * 16 + l15) * 72 + ks * 32 + l4 * 8]);
        pacc[m] = __builtin_amdgcn_mfma_f32_16x16x32_bf16(af, bf, pacc[m], 0, 0, 0);
      }
    }
#pragma unroll
    for (int m = 0; m < 4; ++m)
#pragma unroll
      for (int r = 0; r < 4; ++r) {
        const int o = m * 16 + l4 * 4 + r;
        const int d = d0 + w * 16 + l15;
        plo[(size_t)o * HD + d] = f2bf(colfac[o] * lacc[m][r]);
        phi[(size_t)o * HD + d] = f2bf(pacc[m][r]);
      }
  }
}

// ---------------- small f32 GEMM (Qg only) ----------------
struct GemmArgs {
  const float* a[4];
  const float* w[4];
  int nchunks;
  const float* bias;
  float* out;
};

__global__ __launch_bounds__(256)
void gemm_store_kernel(GemmArgs g) {
  __shared__ float As[64][33];
  __shared__ float Ws[32][65];
  const int t = threadIdx.x;
  const int m0 = blockIdx.y << 6, n0 = blockIdx.x << 6;
  const int tr = t >> 4, tc = t & 15;
  float acc[4][4];
#pragma unroll
  for (int x = 0; x < 4; ++x)
#pragma unroll
    for (int y = 0; y < 4; ++y) acc[x][y] = 0.f;
  const int arow = t >> 2, acs = (t & 3) << 3;
  const int wrow = t >> 3, wcs = (t & 7) << 3;
  for (int c = 0; c < g.nchunks; ++c) {
    const float* Ap = g.a[c] + (size_t)(m0 + arow) * HD + acs;
    const float* Wp = g.w[c] + (size_t)wrow * HD + n0 + wcs;
    for (int k0 = 0; k0 < HD; k0 += 32) {
      float4 a0 = *(const float4*)(Ap + k0);
      float4 a1 = *(const float4*)(Ap + k0 + 4);
      st8(&As[arow][acs], a0, a1);
      float4 w0 = *(const float4*)(Wp + (size_t)k0 * HD);
      float4 w1 = *(const float4*)(Wp + (size_t)k0 * HD + 4);
      st8(&Ws[wrow][wcs], w0, w1);
      __syncthreads();
#pragma unroll
      for (int kk = 0; kk < 32; ++kk) {
        float av[4], bv[4];
#pragma unroll
        for (int x = 0; x < 4; ++x) av[x] = As[(tr << 2) + x][kk];
#pragma unroll
        for (int y = 0; y < 4; ++y) bv[y] = Ws[kk][(tc << 2) + y];
#pragma unroll
        for (int x = 0; x < 4; ++x)
#pragma unroll
          for (int y = 0; y < 4; ++y) acc[x][y] = fmaf(av[x], bv[y], acc[x][y]);
      }
      __syncthreads();
    }
  }
#pragma unroll
  for (int x = 0; x < 4; ++x) {
    const int r = m0 + (tr << 2) + x;
#pragma unroll
    for (int y = 0; y < 4; ++y) {
      const int n = n0 + (tc << 2) + y;
      g.out[(size_t)r * HD + n] = acc[x][y] + g.bias[n];
    }
  }
}

// ---------------- weight convert+transpose ----------------
struct WcArgs {
  const float* src[4];
  unsigned short* dst;
  int Kw;
};

__global__ __launch_bounds__(256)
void wconv_kernel(WcArgs g) {
  __shared__ float tile[64][65];
  const int slice = blockIdx.y;
  const float* src = g.src[slice];
  const int kbase = slice * HD;
  const int bi = blockIdx.x % 12, bj = blockIdx.x / 12;
  const int t = threadIdx.x;
  const int r = t >> 2, cseg = (t & 3) << 4;
  const float* p = src + (size_t)(bi * 64 + r) * HD + bj * 64 + cseg;
#pragma unroll
  for (int j = 0; j < 16; j += 4) {
    float4 v = *(const float4*)(p + j);
    tile[r][cseg + j + 0] = v.x; tile[r][cseg + j + 1] = v.y;
    tile[r][cseg + j + 2] = v.z; tile[r][cseg + j + 3] = v.w;
  }
  __syncthreads();
  unsigned short* q = g.dst + (size_t)(bj * 64 + r) * g.Kw + kbase + bi * 64 + cseg;
  u16x8 lo, hi;
#pragma unroll
  for (int j = 0; j < 8; ++j) lo[j] = f2bf(tile[cseg + j][r]);
#pragma unroll
  for (int j = 0; j < 8; ++j) hi[j] = f2bf(tile[cseg + 8 + j][r]);
  *(u16x8*)q = lo;
  *(u16x8*)(q + 8) = hi;
}

// ---------------- bf16 MFMA GEMM: gload_lds + XOR-swizzle + double buffer ----------------
struct MMArgs {
  const unsigned short* a[4];   // per-768-chunk bf16 sources (all mode-0)
  int K;
  const unsigned short* wt;     // [768][K] bf16
  const float* bias;
  const unsigned short* aux0;   // o1 bf16  (EP_MERGE)
  const unsigned short* aux1;   // OCK bf16 (EP_MERGE)
  const float* aux2;            // Qg f32   (EP_MERGE)
  float* outf;                  // EP_RELU_MAX
  unsigned short* outb;         // others
};

template<int EP>
__global__ __launch_bounds__(256)
void mfma_gemm_kernel(MMArgs g) {
  __shared__ __align__(16) unsigned short As[2][128 * 32];
  __shared__ __align__(16) unsigned short Bs[2][128 * 32];
  const int t = threadIdx.x;
  const int lane = t & 63, w = t >> 6;
  const int wr = w >> 1, wc = w & 1;
  const int m0 = blockIdx.x << 7, n0 = blockIdx.y << 7;  // m-fast grid
  const int l15 = lane & 15, l4 = lane >> 4;
  f32x4 acc[4][4] = {};

  // staging: lane l writes LDS bytes (w*32 + i*16 + (l>>2))*64 + (l&3)*16 (linear).
  // pre-swizzled GLOBAL col so swizzled reads see linear data:
  //   LDS[row][seg] must hold data[row][seg ^ ((row>>1)&3)]; (row>>1)&3 == (l>>3)&3.
  const int srow = w * 32 + (lane >> 2);
  const int gcol = (((lane & 3) ^ ((lane >> 3) & 3))) * 8;   // shorts
  // read-side swizzle: (row>>1)&3 == (l15>>1)&3 (static per lane)
  const int rsw = (l15 >> 1) & 3;
  const int rcol = ((l4 ^ rsw)) * 8;                          // shorts

  const int nkt = g.K >> 5;
  {
    const unsigned short* ap = g.a[0] + (size_t)(m0 + srow) * HD + gcol;
    const unsigned short* bp = g.wt + (size_t)(n0 + srow) * g.K + gcol;
    gload_lds16(ap, &As[0][w * 1024]);
    gload_lds16(ap + (size_t)16 * HD, &As[0][w * 1024 + 512]);
    gload_lds16(bp, &Bs[0][w * 1024]);
    gload_lds16(bp + (size_t)16 * g.K, &Bs[0][w * 1024 + 512]);
  }
  __syncthreads();
  int cur = 0;
  for (int kt = 0; kt < nkt; ++kt) {
    if (kt + 1 < nkt) {
      const int c1 = (kt + 1) / 24;
      const int koff1 = ((kt + 1) - c1 * 24) << 5;
      const int nb = cur ^ 1;
      const unsigned short* ap = g.a[c1] + (size_t)(m0 + srow) * HD + koff1 + gcol;
      const unsigned short* bp = g.wt + (size_t)(n0 + srow) * g.K + ((kt + 1) << 5) + gcol;
      gload_lds16(ap, &As[nb][w * 1024]);
      gload_lds16(ap + (size_t)16 * HD, &As[nb][w * 1024 + 512]);
      gload_lds16(bp, &Bs[nb][w * 1024]);
      gload_lds16(bp + (size_t)16 * g.K, &Bs[nb][w * 1024 + 512]);
    }
    bf16x8 af[4], bfr[4];
#pragma unroll
    for (int mi = 0; mi < 4; ++mi)
      af[mi] = *(const bf16x8*)(&As[cur][(wr * 64 + mi * 16 + l15) * 32 + rcol]);
#pragma unroll
    for (int ni = 0; ni < 4; ++ni)
      bfr[ni] = *(const bf16x8*)(&Bs[cur][(wc * 64 + ni * 16 + l15) * 32 + rcol]);
#pragma unroll
    for (int mi = 0; mi < 4; ++mi)
#pragma unroll
      for (int ni = 0; ni < 4; ++ni)
        acc[mi][ni] = __builtin_amdgcn_mfma_f32_16x16x32_bf16(af[mi], bfr[ni], acc[mi][ni], 0, 0, 0);
    __syncthreads();   // drains DMA into buf^1 AND guards re-stage of buf cur
    cur ^= 1;
  }

  if (EP == EP_RELU_MAX) {
#pragma unroll
    for (int ni = 0; ni < 4; ++ni) {
      const int n = n0 + wc * 64 + ni * 16 + l15;
      const float b = g.bias[n];
      float m = 0.f;
#pragma unroll
      for (int mi = 0; mi < 4; ++mi)
#pragma unroll
        for (int r = 0; r < 4; ++r)
          m = fmaxf(m, acc[mi][ni][r] + b);
      m = fmaxf(m, 0.f);
      m = fmaxf(m, __shfl_xor(m, 16));
      m = fmaxf(m, __shfl_xor(m, 32));
      if (l4 == 0) g.outf[(size_t)((m0 >> 6) + wr) * HD + n] = m;
    }
  } else {
#pragma unroll
    for (int mi = 0; mi < 4; ++mi)
#pragma unroll
      for (int r = 0; r < 4; ++r) {
        const int row = m0 + wr * 64 + mi * 16 + l4 * 4 + r;
#pragma unroll
        for (int ni = 0; ni < 4; ++ni) {
          const int n = n0 + wc * 64 + ni * 16 + l15;
          const size_t oi = (size_t)row * HD + n;
          float v = acc[mi][ni][r];
          if (EP == EP_TANH) {
            g.outb[oi] = f2bf(tanhf(v + g.bias[n]));
          } else if (EP == EP_MERGE) {
            float gg = v + g.aux2[(size_t)(row >> 6) * HD + n];
            float sg = 1.f / (1.f + expf(-gg));
            float o1v = bf2f(g.aux0[oi]);
            float ock = bf2f(g.aux1[oi]);
            g.outb[oi] = f2bf(fmaf(sg, o1v - ock, ock));
          } else {  // EP_RELU
            g.outb[oi] = f2bf(fmaxf(v + g.bias[n], 0.f));
          }
        }
      }
  }
}

extern "C" void kernel_launch(void* const* d_in, const int* in_sizes, int n_in,
                              void* d_out, int out_size, void* d_ws, size_t ws_size,
                              hipStream_t stream) {
  const float* enc_o = (const float*)d_in[0];
  const float* enc_q = (const float*)d_in[1];
  const int* om = (const int*)d_in[2];
  const int* qm = (const int*)d_in[3];
  const float* att_W1_w = (const float*)d_in[4];
  const float* att_W1_b = (const float*)d_in[5];
  const float* att_W2_w = (const float*)d_in[6];
  const float* att_W2_b = (const float*)d_in[7];
  const float* att_W3 = (const float*)d_in[8];
  const float* Wc_self_w = (const float*)d_in[9];
  const float* Wc_self_b = (const float*)d_in[10];
  const float* Wc_w = (const float*)d_in[11];
  const float* Wc_b = (const float*)d_in[12];
  const float* Va_w = (const float*)d_in[13];
  const float* Va_b = (const float*)d_in[14];
  const float* Wg_w = (const float*)d_in[15];
  const float* Wg_b = (const float*)d_in[16];
  const float* co_W1_w = (const float*)d_in[17];
  const float* co_W1_b = (const float*)d_in[18];
  const float* co_W2_w = (const float*)d_in[19];
  const float* co_W2_b = (const float*)d_in[20];
  const float* co_W3 = (const float*)d_in[21];
  const float* Wp_w = (const float*)d_in[22];
  const float* Wp_b = (const float*)d_in[23];
  const float* sa_W1_w = (const float*)d_in[24];
  const float* sa_W1_b = (const float*)d_in[25];
  const float* sa_W2_w = (const float*)d_in[26];
  const float* sa_W2_b = (const float*)d_in[27];
  const float* sa_W3 = (const float*)d_in[28];
  const float* Wf_w = (const float*)d_in[29];
  const float* Wf_b = (const float*)d_in[30];
  float* out = (float*)d_out;

  const int NTOK_O = 16384;
  const int NTOK_Q = 32768;
  const int HH = 768 * 768;

  float* ws = (float*)d_ws;
  size_t off = 0;
  auto carve = [&](size_t n) { float* p = ws + off; off += n; return p; };
  float* s1o   = carve(16384);
  float* s2o   = carve(16384);
  float* qa    = carve(32768);
  float* qco1  = carve(32768);
  float* ms2   = carve(16384);
  float* sa1   = carve(16384);
  float* sa2   = carve(16384);
  float* biasO = carve(1024);
  float* Qpool = carve(196608);
  float* Qg    = carve(196608);
  float* A2buf = carve(2097152);
  float* r1 = carve(12582912);   // [CSb|X1] -> [OPKb|X3]
  float* r2 = carve(12582912);   // [OCKb|X2] -> [PLOb|..] -> opkw3
  float* r3 = carve(12582912);   // [MRGb|..] -> [OSKb|X4]
  float* r4 = carve(12582912);   // [eobf|eow3] -> [PHIb|..]
  unsigned short* wtb = (unsigned short*)carve(1179648);
  if (ws_size < off * sizeof(float)) return;
  unsigned short* CSb   = (unsigned short*)r1;
  unsigned short* OPKb  = (unsigned short*)r1;
  unsigned short* X1    = (unsigned short*)(r1 + 6291456);
  unsigned short* X3    = (unsigned short*)(r1 + 6291456);
  unsigned short* OCKb  = (unsigned short*)r2;
  unsigned short* PLOb  = (unsigned short*)r2;
  unsigned short* opkw3 = (unsigned short*)r2;
  unsigned short* X2    = (unsigned short*)(r2 + 6291456);
  unsigned short* MRGb  = (unsigned short*)r3;
  unsigned short* OSKb  = (unsigned short*)r3;
  unsigned short* X4    = (unsigned short*)(r3 + 6291456);
  unsigned short* eobf  = (unsigned short*)r4;
  unsigned short* eow3  = (unsigned short*)(r4 + 6291456);
  unsigned short* PHIb  = (unsigned short*)r4;
  unsigned short* PtG   = (unsigned short*)A2buf;

  const dim3 GBIG(128, 6);  // m-fast: contemporaneous blocks share the weight n-slice
  const int PREP_GRID = NTOK_O * HD / (256 * 8);  // 6144

  // 1. bf16 prep of enc_o, then fused per-token scalars
  bfprep_kernel<<<PREP_GRID, 256, 0, stream>>>(enc_o, att_W3, eobf, eow3);
  dot768x2_bf16<<<NTOK_O / 4, 256, 0, stream>>>(eobf, att_W1_w, att_W1_b,
                                                att_W2_w, att_W2_b, s1o, s2o, NTOK_O);
  dot768x2_f32<<<NTOK_Q / 4, 256, 0, stream>>>(enc_q, Va_w, Va_b,
                                               co_W1_w, co_W1_b, qa, qco1, NTOK_Q);
  bias_ock_kernel<<<3, 256, 0, stream>>>(Wc_self_b, Wc_b, biasO);

  // 2. pairwise option-compare: p1 + p2 -> CS (bf16)
  p1_kernel<3><<<768, 256, 0, stream>>>(eobf, eow3, s1o, s2o, om, PtG);
  p2_kernel<3><<<dim3(4, 256), 256, 0, stream>>>(eobf, PtG, CSb);

  // 3. OCK = tanh([o1 | 3o1-CS | o1*CS] @ [Wc_self; Wc_hi; Wc_lo] + bias)
  {
    modeprep_kernel<1><<<PREP_GRID, 256, 0, stream>>>(eobf, CSb, X1, X2);
    WcArgs wa{};
    wa.src[0] = Wc_self_w; wa.src[1] = Wc_w; wa.src[2] = Wc_w + HH;
    wa.dst = wtb; wa.Kw = 2304;
    wconv_kernel<<<dim3(144, 3), 256, 0, stream>>>(wa);
    MMArgs g{};
    g.a[0] = eobf; g.a[1] = X1; g.a[2] = X2;
    g.K = 2304; g.wt = wtb; g.bias = biasO; g.outb = OCKb;
    mfma_gemm_kernel<EP_TANH><<<GBIG, 256, 0, stream>>>(g);
  }

  // 4. question pooling + Qg (f32)
  qpool_kernel<<<256, 256, 0, stream>>>(enc_q, qa, qm, Qpool);
  {
    GemmArgs g{};
    g.a[0] = Qpool; g.w[0] = Wg_w + 2 * HH;
    g.nchunks = 1; g.bias = Wg_b; g.out = Qg;
    gemm_store_kernel<<<dim3(12, 4), 256, 0, stream>>>(g);
  }

  // 5. merged = G*o1 + (1-G)*OCK  (bf16 out)
  {
    WcArgs wa{};
    wa.src[0] = Wg_w; wa.src[1] = Wg_w + HH;
    wa.dst = wtb; wa.Kw = 1536;
    wconv_kernel<<<dim3(144, 2), 256, 0, stream>>>(wa);
    MMArgs g{};
    g.a[0] = eobf; g.a[1] = OCKb;
    g.K = 1536; g.wt = wtb; g.bias = nullptr;
    g.aux0 = eobf; g.aux1 = OCKb; g.aux2 = Qg; g.outb = MRGb;
    mfma_gemm_kernel<EP_MERGE><<<GBIG, 256, 0, stream>>>(g);
  }

  // 6. co-attention: ms2 -> A2 (MFMA) -> poaa (MFMA, bf16 outs)
  dot768_bf16<<<NTOK_O / 4, 256, 0, stream>>>(MRGb, co_W2_w, co_W2_b, ms2, NTOK_O);
  a2_mfma_kernel<<<256, 256, 0, stream>>>(enc_q, MRGb, qco1, ms2, qm, om, co_W3, A2buf);
  poaa_mfma_kernel<<<256, 256, 0, stream>>>(A2buf, enc_q, MRGb, PLOb, PHIb);

  // 7. OPK = relu([merged | PLO | PHI] @ Wp + b)  (bf16 out)
  {
    WcArgs wa{};
    wa.src[0] = Wp_w; wa.src[1] = Wp_w + HH; wa.src[2] = Wp_w + 2 * HH;
    wa.dst = wtb; wa.Kw = 2304;
    wconv_kernel<<<dim3(144, 3), 256, 0, stream>>>(wa);
    MMArgs g{};
    g.a[0] = MRGb; g.a[1] = PLOb; g.a[2] = PHIb;
    g.K = 2304; g.wt = wtb; g.bias = Wp_b; g.outb = OPKb;
    mfma_gemm_kernel<EP_RELU><<<GBIG, 256, 0, stream>>>(g);
  }

  // 8. self-attention (p1/p2 on OPK bf16)
  dot768x2_bf16<<<NTOK_O / 4, 256, 0, stream>>>(OPKb, sa_W1_w, sa_W1_b,
                                                sa_W2_w, sa_W2_b, sa1, sa2, NTOK_O);
  w3scale_bf16<<<PREP_GRID, 256, 0, stream>>>(OPKb, sa_W3, opkw3);
  p1_kernel<1><<<256, 256, 0, stream>>>(OPKb, opkw3, sa1, sa2, om, PtG);
  p2_kernel<1><<<dim3(4, 256), 256, 0, stream>>>(OPKb, PtG, OSKb);

  // 9. out = max_lo relu([OPK | OSK | OPK-OSK | OPK*OSK] @ Wf + b)  (f32 out)
  {
    modeprep_kernel<3><<<PREP_GRID, 256, 0, stream>>>(OPKb, OSKb, X3, X4);
    WcArgs wa{};
    wa.src[0] = Wf_w; wa.src[1] = Wf_w + HH; wa.src[2] = Wf_w + 2 * HH; wa.src[3] = Wf_w + 3 * HH;
    wa.dst = wtb; wa.Kw = 3072;
    wconv_kernel<<<dim3(144, 4), 256, 0, stream>>>(wa);
    MMArgs g{};
    g.a[0] = OPKb; g.a[1] = OSKb; g.a[2] = X3; g.a[3] = X4;
    g.K = 3072; g.wt = wtb; g.bias = Wf_b; g.outf = out;
    mfma_gemm_kernel<EP_RELU_MAX><<<GBIG, 256, 0, stream>>>(g);
  }
}

// Round 8
// 659.707 us; speedup vs baseline: 8.2885x; 1.0667x over previous
//
#include <hip/hip_runtime.h>
#include <math.h>

// OptionCompareCell: B=64,C=4,LO=64,LQ=128,H=768
// Round 8: GEMM K-loop -> 3-deep software pipeline with COUNTED vmcnt + raw
//          s_barrier (T3+T4): loads stay in flight across 2 K-steps instead of
//          being drained by __syncthreads' vmcnt(0) every step.
//          Keeps round-7 XOR swizzle (0 bank conflicts, verified).
// Everything else unchanged from round 7.

#define NEGC (-10000.0f)
constexpr int HD = 768;

constexpr int EP_TANH = 1;
constexpr int EP_MERGE = 2;
constexpr int EP_RELU = 3;
constexpr int EP_RELU_MAX = 4;

typedef __attribute__((ext_vector_type(8))) short bf16x8;
typedef __attribute__((ext_vector_type(8))) unsigned short u16x8;
typedef __attribute__((ext_vector_type(4))) unsigned short u16x4;
typedef __attribute__((ext_vector_type(4))) float f32x4;

__device__ inline void st8(float* dst, float4 a0, float4 a1) {
  dst[0] = a0.x; dst[1] = a0.y; dst[2] = a0.z; dst[3] = a0.w;
  dst[4] = a1.x; dst[5] = a1.y; dst[6] = a1.z; dst[7] = a1.w;
}

__device__ inline unsigned short f2bf(float x) {
  unsigned int u = __float_as_uint(x);
  u += 0x7fffu + ((u >> 16) & 1u);
  return (unsigned short)(u >> 16);
}

__device__ inline float bf2f(unsigned short u) {
  return __uint_as_float(((unsigned int)u) << 16);
}

__device__ inline u16x8 pack8(float4 a, float4 b) {
  u16x8 r;
  r[0] = f2bf(a.x); r[1] = f2bf(a.y); r[2] = f2bf(a.z); r[3] = f2bf(a.w);
  r[4] = f2bf(b.x); r[5] = f2bf(b.y); r[6] = f2bf(b.z); r[7] = f2bf(b.w);
  return r;
}

__device__ inline void cvt8f(u16x8 v, float4& a, float4& b) {
  a.x = bf2f(v[0]); a.y = bf2f(v[1]); a.z = bf2f(v[2]); a.w = bf2f(v[3]);
  b.x = bf2f(v[4]); b.y = bf2f(v[5]); b.z = bf2f(v[6]); b.w = bf2f(v[7]);
}

__device__ inline void gload_lds16(const unsigned short* src, unsigned short* dst) {
  __builtin_amdgcn_global_load_lds(
      (const __attribute__((address_space(1))) void*)src,
      (__attribute__((address_space(3))) void*)dst, 16, 0, 0);
}

// ---------------- fused per-token dots ----------------
__global__ __launch_bounds__(256)
void dot768x2_bf16(const unsigned short* __restrict__ x,
                   const float* __restrict__ w1, const float* __restrict__ b1,
                   const float* __restrict__ w2, const float* __restrict__ b2,
                   float* __restrict__ o1, float* __restrict__ o2, int ntok) {
  int tok = blockIdx.x * 4 + (threadIdx.x >> 6);
  int lane = threadIdx.x & 63;
  if (tok >= ntok) return;
  const unsigned short* xp = x + (size_t)tok * HD;
  float s1 = 0.f, s2 = 0.f;
#pragma unroll
  for (int i = 0; i < 3; ++i) {
    int c = (lane + (i << 6)) << 2;
    u16x4 xv = *(const u16x4*)(xp + c);
    float4 wa = *(const float4*)(w1 + c);
    float4 wb = *(const float4*)(w2 + c);
    float x0 = bf2f(xv[0]), x1 = bf2f(xv[1]), x2 = bf2f(xv[2]), x3 = bf2f(xv[3]);
    s1 = fmaf(x0, wa.x, s1); s1 = fmaf(x1, wa.y, s1);
    s1 = fmaf(x2, wa.z, s1); s1 = fmaf(x3, wa.w, s1);
    s2 = fmaf(x0, wb.x, s2); s2 = fmaf(x1, wb.y, s2);
    s2 = fmaf(x2, wb.z, s2); s2 = fmaf(x3, wb.w, s2);
  }
#pragma unroll
  for (int off = 32; off; off >>= 1) {
    s1 += __shfl_xor(s1, off);
    s2 += __shfl_xor(s2, off);
  }
  if (lane == 0) { o1[tok] = s1 + b1[0]; o2[tok] = s2 + b2[0]; }
}

__global__ __launch_bounds__(256)
void dot768x2_f32(const float* __restrict__ x,
                  const float* __restrict__ w1, const float* __restrict__ b1,
                  const float* __restrict__ w2, const float* __restrict__ b2,
                  float* __restrict__ o1, float* __restrict__ o2, int ntok) {
  int tok = blockIdx.x * 4 + (threadIdx.x >> 6);
  int lane = threadIdx.x & 63;
  if (tok >= ntok) return;
  const float* xp = x + (size_t)tok * HD;
  float s1 = 0.f, s2 = 0.f;
#pragma unroll
  for (int i = 0; i < 3; ++i) {
    int c = (lane + (i << 6)) << 2;
    float4 xv = *(const float4*)(xp + c);
    float4 wa = *(const float4*)(w1 + c);
    float4 wb = *(const float4*)(w2 + c);
    s1 = fmaf(xv.x, wa.x, s1); s1 = fmaf(xv.y, wa.y, s1);
    s1 = fmaf(xv.z, wa.z, s1); s1 = fmaf(xv.w, wa.w, s1);
    s2 = fmaf(xv.x, wb.x, s2); s2 = fmaf(xv.y, wb.y, s2);
    s2 = fmaf(xv.z, wb.z, s2); s2 = fmaf(xv.w, wb.w, s2);
  }
#pragma unroll
  for (int off = 32; off; off >>= 1) {
    s1 += __shfl_xor(s1, off);
    s2 += __shfl_xor(s2, off);
  }
  if (lane == 0) { o1[tok] = s1 + b1[0]; o2[tok] = s2 + b2[0]; }
}

__global__ __launch_bounds__(256)
void dot768_bf16(const unsigned short* __restrict__ x,
                 const float* __restrict__ w1, const float* __restrict__ b1,
                 float* __restrict__ o1, int ntok) {
  int tok = blockIdx.x * 4 + (threadIdx.x >> 6);
  int lane = threadIdx.x & 63;
  if (tok >= ntok) return;
  const unsigned short* xp = x + (size_t)tok * HD;
  float s1 = 0.f;
#pragma unroll
  for (int i = 0; i < 3; ++i) {
    int c = (lane + (i << 6)) << 2;
    u16x4 xv = *(const u16x4*)(xp + c);
    float4 wa = *(const float4*)(w1 + c);
    s1 = fmaf(bf2f(xv[0]), wa.x, s1); s1 = fmaf(bf2f(xv[1]), wa.y, s1);
    s1 = fmaf(bf2f(xv[2]), wa.z, s1); s1 = fmaf(bf2f(xv[3]), wa.w, s1);
  }
#pragma unroll
  for (int off = 32; off; off >>= 1) s1 += __shfl_xor(s1, off);
  if (lane == 0) o1[tok] = s1 + b1[0];
}

__global__ void bias_ock_kernel(const float* __restrict__ b1, const float* __restrict__ b2,
                                float* __restrict__ o) {
  int n = blockIdx.x * 256 + threadIdx.x;
  if (n < HD) o[n] = b1[n] + 3.f * b2[n];
}

// ---------------- bf16 prep: xbf = bf16(x), xw3 = bf16(x * w3[col]) ----------------
__global__ __launch_bounds__(256)
void bfprep_kernel(const float* __restrict__ x, const float* __restrict__ w3,
                   unsigned short* __restrict__ xbf, unsigned short* __restrict__ xw3) {
  size_t base = ((size_t)blockIdx.x * 256 + threadIdx.x) * 8;
  int col = (int)(base % HD);
  float4 a0 = *(const float4*)(x + base);
  float4 a1 = *(const float4*)(x + base + 4);
  float4 w0 = *(const float4*)(w3 + col);
  float4 w1 = *(const float4*)(w3 + col + 4);
  *(u16x8*)(xbf + base) = pack8(a0, a1);
  float4 s0, s1;
  s0.x = a0.x * w0.x; s0.y = a0.y * w0.y; s0.z = a0.z * w0.z; s0.w = a0.w * w0.w;
  s1.x = a1.x * w1.x; s1.y = a1.y * w1.y; s1.z = a1.z * w1.z; s1.w = a1.w * w1.w;
  *(u16x8*)(xw3 + base) = pack8(s0, s1);
}

// ---------------- w3-scale on bf16 input ----------------
__global__ __launch_bounds__(256)
void w3scale_bf16(const unsigned short* __restrict__ x, const float* __restrict__ w3,
                  unsigned short* __restrict__ xw3) {
  size_t base = ((size_t)blockIdx.x * 256 + threadIdx.x) * 8;
  int col = (int)(base % HD);
  u16x8 v = *(const u16x8*)(x + base);
  float4 a, b;
  cvt8f(v, a, b);
  float4 w0 = *(const float4*)(w3 + col);
  float4 w1 = *(const float4*)(w3 + col + 4);
  a.x *= w0.x; a.y *= w0.y; a.z *= w0.z; a.w *= w0.w;
  b.x *= w1.x; b.y *= w1.y; b.z *= w1.z; b.w *= w1.w;
  *(u16x8*)(xw3 + base) = pack8(a, b);
}

// ---------------- modeprep: y1 = (M1==1 ? 3a-b : a-b), y2 = a*b (bf16) ----------------
template<int M1>
__global__ __launch_bounds__(256)
void modeprep_kernel(const unsigned short* __restrict__ a, const unsigned short* __restrict__ b,
                     unsigned short* __restrict__ y1, unsigned short* __restrict__ y2) {
  size_t base = ((size_t)blockIdx.x * 256 + threadIdx.x) * 8;
  u16x8 av = *(const u16x8*)(a + base);
  u16x8 bv = *(const u16x8*)(b + base);
  float4 a0, a1, b0, b1;
  cvt8f(av, a0, a1);
  cvt8f(bv, b0, b1);
  float4 p0, p1, q0, q1;
  if (M1 == 1) {
    p0.x = fmaf(3.f, a0.x, -b0.x); p0.y = fmaf(3.f, a0.y, -b0.y);
    p0.z = fmaf(3.f, a0.z, -b0.z); p0.w = fmaf(3.f, a0.w, -b0.w);
    p1.x = fmaf(3.f, a1.x, -b1.x); p1.y = fmaf(3.f, a1.y, -b1.y);
    p1.z = fmaf(3.f, a1.z, -b1.z); p1.w = fmaf(3.f, a1.w, -b1.w);
  } else {
    p0.x = a0.x - b0.x; p0.y = a0.y - b0.y; p0.z = a0.z - b0.z; p0.w = a0.w - b0.w;
    p1.x = a1.x - b1.x; p1.y = a1.y - b1.y; p1.z = a1.z - b1.z; p1.w = a1.w - b1.w;
  }
  q0.x = a0.x * b0.x; q0.y = a0.y * b0.y; q0.z = a0.z * b0.z; q0.w = a0.w * b0.w;
  q1.x = a1.x * b1.x; q1.y = a1.y * b1.y; q1.z = a1.z * b1.z; q1.w = a1.w * b1.w;
  *(u16x8*)(y1 + base) = pack8(p0, p1);
  *(u16x8*)(y2 + base) = pack8(q0, q1);
}

// ---------------- P1: S = U . Vw3^T (MFMA), softmax over u, write Pt[v][u] bf16 ----------------
template<int NJ>
__global__ __launch_bounds__(256)
void p1_kernel(const unsigned short* __restrict__ Xbf, const unsigned short* __restrict__ Xw3,
               const float* __restrict__ s1g, const float* __restrict__ s2g,
               const int* __restrict__ maskg, unsigned short* __restrict__ PtG) {
  __shared__ __align__(16) unsigned short Ua[64 * 136];
  __shared__ __align__(16) unsigned short Vb[64 * 136];
  __shared__ float Sbuf[64][66];
  __shared__ float red[4][64];
  const int t = threadIdx.x;
  int ubc, vbc;
  if (NJ == 1) {
    ubc = vbc = blockIdx.x;
  } else {
    const int b = blockIdx.x / 12, pr = blockIdx.x % 12;
    const int i = pr / 3, jj = pr % 3;
    const int j = jj + (jj >= i ? 1 : 0);
    vbc = (b << 2) + i; ubc = (b << 2) + j;
  }
  const unsigned short* U = Xbf + (size_t)ubc * (64 * HD);
  const unsigned short* V = Xw3 + (size_t)vbc * (64 * HD);
  const int w = t >> 6, lane = t & 63, l15 = lane & 15, l4 = lane >> 4;
  const int srow = t >> 2, scol = (t & 3) << 5;
  f32x4 acc[4] = {};
  for (int k0 = 0; k0 < HD; k0 += 128) {
    const unsigned short* up = U + (size_t)srow * HD + k0 + scol;
    const unsigned short* vp = V + (size_t)srow * HD + k0 + scol;
    unsigned short* ua = &Ua[srow * 136 + scol];
    unsigned short* vb = &Vb[srow * 136 + scol];
#pragma unroll
    for (int z = 0; z < 4; ++z) {
      *(u16x8*)(ua + z * 8) = *(const u16x8*)(up + z * 8);
      *(u16x8*)(vb + z * 8) = *(const u16x8*)(vp + z * 8);
    }
    __syncthreads();
#pragma unroll
    for (int ks = 0; ks < 4; ++ks) {
      bf16x8 af = *(const bf16x8*)(&Ua[(w * 16 + l15) * 136 + ks * 32 + l4 * 8]);
#pragma unroll
      for (int n = 0; n < 4; ++n) {
        bf16x8 bf = *(const bf16x8*)(&Vb[(n * 16 + l15) * 136 + ks * 32 + l4 * 8]);
        acc[n] = __builtin_amdgcn_mfma_f32_16x16x32_bf16(af, bf, acc[n], 0, 0, 0);
      }
    }
    __syncthreads();
  }
  {
    float s1v[4];
#pragma unroll
    for (int r = 0; r < 4; ++r) {
      int u = w * 16 + l4 * 4 + r;
      s1v[r] = s1g[ubc * 64 + u] + (1.f - (float)maskg[ubc * 64 + u]) * NEGC;
    }
#pragma unroll
    for (int n = 0; n < 4; ++n) {
      int v = n * 16 + l15;
      float s2v = s2g[vbc * 64 + v] + (1.f - (float)maskg[vbc * 64 + v]) * NEGC;
#pragma unroll
      for (int r = 0; r < 4; ++r)
        Sbuf[w * 16 + l4 * 4 + r][v] = acc[n][r] + s1v[r] + s2v;
    }
  }
  __syncthreads();
  {
    const int v = t & 63, part = t >> 6;
    float m = -1e30f;
#pragma unroll
    for (int z = 0; z < 16; ++z) m = fmaxf(m, Sbuf[part * 16 + z][v]);
    red[part][v] = m;
    __syncthreads();
    float gm = fmaxf(fmaxf(red[0][v], red[1][v]), fmaxf(red[2][v], red[3][v]));
    float s = 0.f;
#pragma unroll
    for (int z = 0; z < 16; ++z) {
      float e = expf(Sbuf[part * 16 + z][v] - gm);
      Sbuf[part * 16 + z][v] = e;
      s += e;
    }
    __syncthreads();
    red[part][v] = s;
    __syncthreads();
    float cinv = 1.f / (red[0][v] + red[1][v] + red[2][v] + red[3][v]);
    unsigned short* pt = PtG + (size_t)blockIdx.x * 4096 + v * 64 + part * 16;
#pragma unroll
    for (int z = 0; z < 16; ++z) pt[z] = f2bf(Sbuf[part * 16 + z][v] * cinv);
  }
}

// ---------------- P2: ctx[v][d] = sum_j sum_u Pt_j[v][u] * U_j[u][d] -> bf16 ----------------
template<int NJ>
__global__ __launch_bounds__(256)
void p2_kernel(const unsigned short* __restrict__ Xbf, const unsigned short* __restrict__ PtG,
               unsigned short* __restrict__ outg) {
  __shared__ __align__(16) unsigned short Pts[NJ][64 * 72];
  __shared__ __align__(16) unsigned short U2[64 * 192];
  const int t = threadIdx.x;
  const int dq = blockIdx.x, bc = blockIdx.y;
  const int d0 = dq * 192;
  const int b = bc >> 2, i = bc & 3;
  const int w = t >> 6, lane = t & 63, l15 = lane & 15, l4 = lane >> 4;
  {
    const int v = t >> 2, cs = (t & 3) << 4;
#pragma unroll
    for (int jj = 0; jj < NJ; ++jj) {
      size_t src = (NJ == 1 ? (size_t)bc : (size_t)(b * 12 + i * 3 + jj)) * 4096 + v * 64 + cs;
      *(u16x8*)(&Pts[jj][v * 72 + cs]) = *(const u16x8*)(PtG + src);
      *(u16x8*)(&Pts[jj][v * 72 + cs + 8]) = *(const u16x8*)(PtG + src + 8);
    }
  }
  f32x4 acc[4][3] = {};
  const int su = t >> 2, sc0 = (t & 3) * 48;
  const int sswz = ((su >> 3) & 3) << 5;
  for (int jj = 0; jj < NJ; ++jj) {
    const int ubc = (NJ == 1) ? bc : ((b << 2) + (jj + (jj >= i ? 1 : 0)));
    __syncthreads();
    {
      const unsigned short* up = Xbf + (size_t)ubc * (64 * HD) + (size_t)su * HD + d0 + sc0;
#pragma unroll
      for (int it = 0; it < 6; ++it) {
        u16x8 vdat = *(const u16x8*)(up + it * 8);
        *(u16x8*)((char*)U2 + ((su * 384 + (sc0 + it * 8) * 2) ^ sswz)) = vdat;
      }
    }
    __syncthreads();
    const unsigned short* ptj = &Pts[jj][0];
#pragma unroll
    for (int ks = 0; ks < 2; ++ks) {
      bf16x8 bfr[3];
#pragma unroll
      for (int n = 0; n < 3; ++n) {
        const int col = (w * 3 + n) * 16 + l15;
#pragma unroll
        for (int e = 0; e < 8; ++e) {
          const int uk = ks * 32 + l4 * 8 + e;
          const int byte = (uk * 384 + col * 2) ^ (((uk >> 3) & 3) << 5);
          bfr[n][e] = *(const short*)((const char*)U2 + byte);
        }
      }
#pragma unroll
      for (int m = 0; m < 4; ++m) {
        bf16x8 af = *(const bf16x8*)(ptj + (m * 16 + l15) * 72 + ks * 32 + l4 * 8);
#pragma unroll
        for (int n = 0; n < 3; ++n)
          acc[m][n] = __builtin_amdgcn_mfma_f32_16x16x32_bf16(af, bfr[n], acc[m][n], 0, 0, 0);
      }
    }
  }
  unsigned short* op = outg + (size_t)bc * (64 * HD);
#pragma unroll
  for (int m = 0; m < 4; ++m)
#pragma unroll
    for (int n = 0; n < 3; ++n) {
      const int d = d0 + (w * 3 + n) * 16 + l15;
#pragma unroll
      for (int r = 0; r < 4; ++r) {
        const int v = m * 16 + l4 * 4 + r;
        op[(size_t)v * HD + d] = f2bf(acc[m][n][r]);
      }
    }
}

// ---------------- question pooling ----------------
__global__ __launch_bounds__(256)
void qpool_kernel(const float* __restrict__ q, const float* __restrict__ qa,
                  const int* __restrict__ qm, float* __restrict__ Q) {
  __shared__ float wgt[128];
  __shared__ float wred[4];
  int t = threadIdx.x, bc = blockIdx.x;
  const float* qap = qa + bc * 128;
  const int* qmp = qm + bc * 128;
  float v = -1e30f;
  if (t < 128) v = qap[t] + (1.f - (float)qmp[t]) * NEGC;
  float m = v;
#pragma unroll
  for (int off = 32; off; off >>= 1) m = fmaxf(m, __shfl_xor(m, off));
  if ((t & 63) == 0) wred[t >> 6] = m;
  __syncthreads();
  float gm = fmaxf(fmaxf(wred[0], wred[1]), fmaxf(wred[2], wred[3]));
  float e = (t < 128) ? expf(v - gm) : 0.f;
  float s = e;
#pragma unroll
  for (int off = 32; off; off >>= 1) s += __shfl_xor(s, off);
  __syncthreads();
  if ((t & 63) == 0) wred[t >> 6] = s;
  __syncthreads();
  float tot = wred[0] + wred[1] + wred[2] + wred[3];
  if (t < 128) wgt[t] = e / tot;
  __syncthreads();
  const float* qp = q + (size_t)bc * (128 * HD);
  float* Qp = Q + (size_t)bc * HD;
  for (int d = t; d < HD; d += 256) {
    float acc = 0.f;
    for (int l = 0; l < 128; ++l) acc = fmaf(wgt[l], qp[(size_t)l * HD + d], acc);
    Qp[d] = acc;
  }
}

// ---------------- A2 via MFMA: A2[q][v] = (q*w3).merged^T + rterm + cterm ----------------
__global__ __launch_bounds__(256)
void a2_mfma_kernel(const float* __restrict__ qin, const unsigned short* __restrict__ mergedb,
                    const float* __restrict__ qco1, const float* __restrict__ ms2,
                    const int* __restrict__ qm, const int* __restrict__ om,
                    const float* __restrict__ w3, float* __restrict__ A2) {
  __shared__ __align__(16) unsigned short Aq[128 * 72];
  __shared__ __align__(16) unsigned short Bm[64 * 72];
  const int t = threadIdx.x, bc = blockIdx.x;
  const float* qp = qin + (size_t)bc * (128 * HD);
  const unsigned short* mp = mergedb + (size_t)bc * (64 * HD);
  const int w = t >> 6, lane = t & 63, l15 = lane & 15, l4 = lane >> 4;
  const int arow = t >> 1, acs = (t & 1) << 5;
  const int brow = t >> 2, bcs = (t & 3) << 4;
  f32x4 acc[2][4] = {};
  for (int k0 = 0; k0 < HD; k0 += 64) {
    {
      const float* p = qp + (size_t)arow * HD + k0 + acs;
      const float* wp = w3 + k0 + acs;
      unsigned short* dst = &Aq[arow * 72 + acs];
#pragma unroll
      for (int z = 0; z < 4; ++z) {
        float4 a = *(const float4*)(p + z * 8);
        float4 b = *(const float4*)(p + z * 8 + 4);
        float4 wa = *(const float4*)(wp + z * 8);
        float4 wb = *(const float4*)(wp + z * 8 + 4);
        a.x *= wa.x; a.y *= wa.y; a.z *= wa.z; a.w *= wa.w;
        b.x *= wb.x; b.y *= wb.y; b.z *= wb.z; b.w *= wb.w;
        *(u16x8*)(dst + z * 8) = pack8(a, b);
      }
    }
    {
      const unsigned short* p = mp + (size_t)brow * HD + k0 + bcs;
      unsigned short* dst = &Bm[brow * 72 + bcs];
      *(u16x8*)(dst) = *(const u16x8*)(p);
      *(u16x8*)(dst + 8) = *(const u16x8*)(p + 8);
    }
    __syncthreads();
#pragma unroll
    for (int ks = 0; ks < 2; ++ks) {
      bf16x8 af[2], bf[4];
#pragma unroll
      for (int m = 0; m < 2; ++m)
        af[m] = *(const bf16x8*)(&Aq[(w * 32 + m * 16 + l15) * 72 + ks * 32 + l4 * 8]);
#pragma unroll
      for (int n = 0; n < 4; ++n)
        bf[n] = *(const bf16x8*)(&Bm[(n * 16 + l15) * 72 + ks * 32 + l4 * 8]);
#pragma unroll
      for (int m = 0; m < 2; ++m)
#pragma unroll
        for (int n = 0; n < 4; ++n)
          acc[m][n] = __builtin_amdgcn_mfma_f32_16x16x32_bf16(af[m], bf[n], acc[m][n], 0, 0, 0);
    }
    __syncthreads();
  }
  const float* qc = qco1 + bc * 128;
  const int* qmp = qm + bc * 128;
  const float* msp = ms2 + bc * 64;
  const int* omp = om + bc * 64;
  float* outp = A2 + (size_t)bc * (128 * 64);
#pragma unroll
  for (int n = 0; n < 4; ++n) {
    const int v = n * 16 + l15;
    const float ct = msp[v] + (1.f - (float)omp[v]) * NEGC;
#pragma unroll
    for (int m = 0; m < 2; ++m)
#pragma unroll
      for (int r = 0; r < 4; ++r) {
        const int qrow = w * 32 + m * 16 + l4 * 4 + r;
        const float rt = qc[qrow] + (1.f - (float)qmp[qrow]) * NEGC;
        outp[qrow * 64 + v] = acc[m][n][r] + rt + ct;
      }
  }
}

// ---------------- POAA via MFMA (outputs bf16) ----------------
__global__ __launch_bounds__(256)
void poaa_mfma_kernel(const float* __restrict__ A2, const float* __restrict__ qin,
                      const unsigned short* __restrict__ mergedb,
                      unsigned short* __restrict__ PLO, unsigned short* __restrict__ PHI) {
  __shared__ __align__(16) char smem[77312];
  __shared__ float red[4][64];
  __shared__ float rowm[128], rowfac[128];
  __shared__ float colfac[64];
  __shared__ float gmax_s;
  float* T = (float*)smem;                                   // [128][65] f32
  unsigned short* Tt = (unsigned short*)(smem + 33280);       // [64][136]
  unsigned short* Tft = (unsigned short*)(smem + 50688);      // [64][136]
  unsigned short* M2bf = (unsigned short*)(smem + 68096);     // [64][72]
  unsigned short* Qc = (unsigned short*)smem;                 // [128][72] (after phase2)
  unsigned short* Mc = (unsigned short*)(smem + 18432);       // [64][72]

  const int t = threadIdx.x, bc = blockIdx.x;
  const int w = t >> 6, lane = t & 63, l15 = lane & 15, l4 = lane >> 4;
  const float* a2 = A2 + (size_t)bc * (128 * 64);
  {
    int row = t >> 1, cs = (t & 1) << 5;
    const float* p = a2 + row * 64 + cs;
#pragma unroll
    for (int z = 0; z < 8; ++z) {
      float4 v = *(const float4*)(p + (z << 2));
      T[row * 65 + cs + (z << 2) + 0] = v.x;
      T[row * 65 + cs + (z << 2) + 1] = v.y;
      T[row * 65 + cs + (z << 2) + 2] = v.z;
      T[row * 65 + cs + (z << 2) + 3] = v.w;
    }
  }
  __syncthreads();
  {
    int qrow = t >> 1, h = t & 1;
    float m = -1e30f;
    for (int v = h * 32; v < h * 32 + 32; ++v) m = fmaxf(m, T[qrow * 65 + v]);
    m = fmaxf(m, __shfl_xor(m, 1));
    float s = 0.f;
    for (int v = h * 32; v < h * 32 + 32; ++v) s += expf(T[qrow * 65 + v] - m);
    s += __shfl_xor(s, 1);
    if (h == 0) { rowm[qrow] = m; rowfac[qrow] = s; }
  }
  float colm_loc = 0.f;
  {
    int v = t & 63, part = t >> 6;
    float m = -1e30f;
    for (int qq = part * 32; qq < part * 32 + 32; ++qq) m = fmaxf(m, T[qq * 65 + v]);
    red[part][v] = m;
    __syncthreads();
    float cm = fmaxf(fmaxf(red[0][v], red[1][v]), fmaxf(red[2][v], red[3][v]));
    float s = 0.f;
    for (int qq = part * 32; qq < part * 32 + 32; ++qq) s += expf(T[qq * 65 + v] - cm);
    __syncthreads();
    red[part][v] = s;
    __syncthreads();
    if (part == 0) { colm_loc = cm; colfac[v] = red[0][v] + red[1][v] + red[2][v] + red[3][v]; }
  }
  __syncthreads();
  if (t < 64) {
    float m = fmaxf(rowm[t], rowm[t + 64]);
#pragma unroll
    for (int off = 32; off; off >>= 1) m = fmaxf(m, __shfl_xor(m, off));
    if (t == 0) gmax_s = m;
  }
  __syncthreads();
  const float gmax = gmax_s;
  if (t < 128) rowfac[t] = expf(fminf(gmax - rowm[t], 60.f)) / rowfac[t];
  if (t < 64) colfac[t] = expf(fminf(gmax - colm_loc, 60.f)) / colfac[t];
  __syncthreads();
  {
    const int o = t >> 2, qs = (t & 3) << 5;
    for (int z = 0; z < 32; ++z) {
      const int qq = qs + z;
      float e = expf(T[qq * 65 + o] - gmax);
      Tt[o * 136 + qq] = f2bf(e);
      Tft[o * 136 + qq] = f2bf(e * rowfac[qq]);
    }
  }
  __syncthreads();
  {
    f32x4 m2acc[4] = {};
#pragma unroll
    for (int ks = 0; ks < 4; ++ks) {
      bf16x8 af = *(const bf16x8*)(&Tt[(w * 16 + l15) * 136 + ks * 32 + l4 * 8]);
#pragma unroll
      for (int n = 0; n < 4; ++n) {
        bf16x8 bf = *(const bf16x8*)(&Tft[(n * 16 + l15) * 136 + ks * 32 + l4 * 8]);
        m2acc[n] = __builtin_amdgcn_mfma_f32_16x16x32_bf16(af, bf, m2acc[n], 0, 0, 0);
      }
    }
#pragma unroll
    for (int n = 0; n < 4; ++n)
#pragma unroll
      for (int r = 0; r < 4; ++r) {
        const int o = w * 16 + l4 * 4 + r;
        M2bf[o * 72 + n * 16 + l15] = f2bf(colfac[o] * m2acc[n][r]);
      }
  }
  const int dql = t >> 1, dqs = (t & 1) << 5;
  const int dml = t >> 2, dms = (t & 3) << 4;
  const int swq = ((dql >> 3) & 3) << 5;
  const int swm = ((dml >> 3) & 3) << 5;
  unsigned short* plo = PLO + (size_t)bc * (64 * HD);
  unsigned short* phi = PHI + (size_t)bc * (64 * HD);
  const float* qp = qin + (size_t)bc * (128 * HD);
  const unsigned short* mp = mergedb + (size_t)bc * (64 * HD);
  for (int dc = 0; dc < 12; ++dc) {
    const int d0 = dc * 64;
    __syncthreads();
    {
      const float* p = qp + (size_t)dql * HD + d0 + dqs;
#pragma unroll
      for (int z = 0; z < 4; ++z) {
        float4 a = *(const float4*)(p + z * 8);
        float4 b = *(const float4*)(p + z * 8 + 4);
        *(u16x8*)((char*)Qc + ((dql * 144 + (dqs + z * 8) * 2) ^ swq)) = pack8(a, b);
      }
    }
    {
      const unsigned short* p = mp + (size_t)dml * HD + d0 + dms;
      *(u16x8*)((char*)Mc + ((dml * 144 + dms * 2) ^ swm)) = *(const u16x8*)p;
      *(u16x8*)((char*)Mc + ((dml * 144 + (dms + 8) * 2) ^ swm)) = *(const u16x8*)(p + 8);
    }
    __syncthreads();
    const int col = w * 16 + l15;
    f32x4 lacc[4] = {};
#pragma unroll
    for (int ks = 0; ks < 4; ++ks) {
      bf16x8 bf;
#pragma unroll
      for (int e = 0; e < 8; ++e) {
        const int qq = ks * 32 + l4 * 8 + e;
        bf[e] = *(const short*)((const char*)Qc + ((qq * 144 + col * 2) ^ (((qq >> 3) & 3) << 5)));
      }
#pragma unroll
      for (int m = 0; m < 4; ++m) {
        bf16x8 af = *(const bf16x8*)(&Tt[(m * 16 + l15) * 136 + ks * 32 + l4 * 8]);
        lacc[m] = __builtin_amdgcn_mfma_f32_16x16x32_bf16(af, bf, lacc[m], 0, 0, 0);
      }
    }
    f32x4 pacc[4] = {};
#pragma unroll
    for (int ks = 0; ks < 2; ++ks) {
      bf16x8 bf;
#pragma unroll
      for (int e = 0; e < 8; ++e) {
        const int vv = ks * 32 + l4 * 8 + e;
        bf[e] = *(const short*)((const char*)Mc + ((vv * 144 + col * 2) ^ (((vv >> 3) & 3) << 5)));
      }
#pragma unroll
      for (int m = 0; m < 4; ++m) {
        bf16x8 af = *(const bf16x8*)(&M2bf[(m * 16 + l15) * 72 + ks * 32 + l4 * 8]);
        pacc[m] = __builtin_amdgcn_mfma_f32_16x16x32_bf16(af, bf, pacc[m], 0, 0, 0);
      }
    }
#pragma unroll
    for (int m = 0; m < 4; ++m)
#pragma unroll
      for (int r = 0; r < 4; ++r) {
        const int o = m * 16 + l4 * 4 + r;
        const int d = d0 + w * 16 + l15;
        plo[(size_t)o * HD + d] = f2bf(colfac[o] * lacc[m][r]);
        phi[(size_t)o * HD + d] = f2bf(pacc[m][r]);
      }
  }
}

// ---------------- small f32 GEMM (Qg only) ----------------
struct GemmArgs {
  const float* a[4];
  const float* w[4];
  int nchunks;
  const float* bias;
  float* out;
};

__global__ __launch_bounds__(256)
void gemm_store_kernel(GemmArgs g) {
  __shared__ float As[64][33];
  __shared__ float Ws[32][65];
  const int t = threadIdx.x;
  const int m0 = blockIdx.y << 6, n0 = blockIdx.x << 6;
  const int tr = t >> 4, tc = t & 15;
  float acc[4][4];
#pragma unroll
  for (int x = 0; x < 4; ++x)
#pragma unroll
    for (int y = 0; y < 4; ++y) acc[x][y] = 0.f;
  const int arow = t >> 2, acs = (t & 3) << 3;
  const int wrow = t >> 3, wcs = (t & 7) << 3;
  for (int c = 0; c < g.nchunks; ++c) {
    const float* Ap = g.a[c] + (size_t)(m0 + arow) * HD + acs;
    const float* Wp = g.w[c] + (size_t)wrow * HD + n0 + wcs;
    for (int k0 = 0; k0 < HD; k0 += 32) {
      float4 a0 = *(const float4*)(Ap + k0);
      float4 a1 = *(const float4*)(Ap + k0 + 4);
      st8(&As[arow][acs], a0, a1);
      float4 w0 = *(const float4*)(Wp + (size_t)k0 * HD);
      float4 w1 = *(const float4*)(Wp + (size_t)k0 * HD + 4);
      st8(&Ws[wrow][wcs], w0, w1);
      __syncthreads();
#pragma unroll
      for (int kk = 0; kk < 32; ++kk) {
        float av[4], bv[4];
#pragma unroll
        for (int x = 0; x < 4; ++x) av[x] = As[(tr << 2) + x][kk];
#pragma unroll
        for (int y = 0; y < 4; ++y) bv[y] = Ws[kk][(tc << 2) + y];
#pragma unroll
        for (int x = 0; x < 4; ++x)
#pragma unroll
          for (int y = 0; y < 4; ++y) acc[x][y] = fmaf(av[x], bv[y], acc[x][y]);
      }
      __syncthreads();
    }
  }
#pragma unroll
  for (int x = 0; x < 4; ++x) {
    const int r = m0 + (tr << 2) + x;
#pragma unroll
    for (int y = 0; y < 4; ++y) {
      const int n = n0 + (tc << 2) + y;
      g.out[(size_t)r * HD + n] = acc[x][y] + g.bias[n];
    }
  }
}

// ---------------- weight convert+transpose ----------------
struct WcArgs {
  const float* src[4];
  unsigned short* dst;
  int Kw;
};

__global__ __launch_bounds__(256)
void wconv_kernel(WcArgs g) {
  __shared__ float tile[64][65];
  const int slice = blockIdx.y;
  const float* src = g.src[slice];
  const int kbase = slice * HD;
  const int bi = blockIdx.x % 12, bj = blockIdx.x / 12;
  const int t = threadIdx.x;
  const int r = t >> 2, cseg = (t & 3) << 4;
  const float* p = src + (size_t)(bi * 64 + r) * HD + bj * 64 + cseg;
#pragma unroll
  for (int j = 0; j < 16; j += 4) {
    float4 v = *(const float4*)(p + j);
    tile[r][cseg + j + 0] = v.x; tile[r][cseg + j + 1] = v.y;
    tile[r][cseg + j + 2] = v.z; tile[r][cseg + j + 3] = v.w;
  }
  __syncthreads();
  unsigned short* q = g.dst + (size_t)(bj * 64 + r) * g.Kw + kbase + bi * 64 + cseg;
  u16x8 lo, hi;
#pragma unroll
  for (int j = 0; j < 8; ++j) lo[j] = f2bf(tile[cseg + j][r]);
#pragma unroll
  for (int j = 0; j < 8; ++j) hi[j] = f2bf(tile[cseg + 8 + j][r]);
  *(u16x8*)q = lo;
  *(u16x8*)(q + 8) = hi;
}

// ---- bf16 MFMA GEMM: gload_lds + swizzle + 3-deep counted-vmcnt pipeline ----
struct MMArgs {
  const unsigned short* a[4];   // per-768-chunk bf16 sources (all mode-0)
  int K;
  const unsigned short* wt;     // [768][K] bf16
  const float* bias;
  const unsigned short* aux0;   // o1 bf16  (EP_MERGE)
  const unsigned short* aux1;   // OCK bf16 (EP_MERGE)
  const float* aux2;            // Qg f32   (EP_MERGE)
  float* outf;                  // EP_RELU_MAX
  unsigned short* outb;         // others
};

template<int EP>
__global__ __launch_bounds__(256)
void mfma_gemm_kernel(MMArgs g) {
  __shared__ __align__(16) unsigned short As[3][128 * 32];
  __shared__ __align__(16) unsigned short Bs[3][128 * 32];
  const int t = threadIdx.x;
  const int lane = t & 63, w = t >> 6;
  const int wr = w >> 1, wc = w & 1;
  const int m0 = blockIdx.x << 7, n0 = blockIdx.y << 7;  // m-fast grid
  const int l15 = lane & 15, l4 = lane >> 4;
  f32x4 acc[4][4] = {};

  // round-7 verified swizzle: pre-swizzled GLOBAL source, linear LDS dest,
  // same involution on the read side. (0 bank conflicts measured.)
  const int srow = w * 32 + (lane >> 2);
  const int gcol = (((lane & 3) ^ ((lane >> 3) & 3))) * 8;   // shorts
  const int rsw = (l15 >> 1) & 3;
  const int rcol = ((l4 ^ rsw)) * 8;                          // shorts

  const int nkt = g.K >> 5;

  auto issue = [&](int kt, int buf) {
    const int c = kt / 24;
    const int koff = (kt - c * 24) << 5;
    const unsigned short* ap = g.a[c] + (size_t)(m0 + srow) * HD + koff + gcol;
    const unsigned short* bp = g.wt + (size_t)(n0 + srow) * g.K + (kt << 5) + gcol;
    gload_lds16(ap, &As[buf][w * 1024]);
    gload_lds16(ap + (size_t)16 * HD, &As[buf][w * 1024 + 512]);
    gload_lds16(bp, &Bs[buf][w * 1024]);
    gload_lds16(bp + (size_t)16 * g.K, &Bs[buf][w * 1024 + 512]);
  };

  auto compute = [&](int kt, int buf, bool prefetch) {
    bf16x8 af[4], bfr[4];
#pragma unroll
    for (int mi = 0; mi < 4; ++mi)
      af[mi] = *(const bf16x8*)(&As[buf][(wr * 64 + mi * 16 + l15) * 32 + rcol]);
#pragma unroll
    for (int ni = 0; ni < 4; ++ni)
      bfr[ni] = *(const bf16x8*)(&Bs[buf][(wc * 64 + ni * 16 + l15) * 32 + rcol]);
    asm volatile("s_waitcnt lgkmcnt(0)" ::: "memory");  // my frags in regs
    __builtin_amdgcn_s_barrier();                        // everyone done reading buf
    if (prefetch) issue(kt + 3, buf);                    // safe to overwrite now
#pragma unroll
    for (int mi = 0; mi < 4; ++mi)
#pragma unroll
      for (int ni = 0; ni < 4; ++ni)
        acc[mi][ni] = __builtin_amdgcn_mfma_f32_16x16x32_bf16(af[mi], bfr[ni], acc[mi][ni], 0, 0, 0);
  };

  // prologue: 3 tiles in flight (12 loads/wave)
  issue(0, 0); issue(1, 1); issue(2, 2);
  int buf = 0;
  int kt = 0;
  for (; kt < nkt - 2; ++kt) {
    // tile kt's 4 loads (oldest) done; tiles kt+1,kt+2 (8 loads) stay in flight
    asm volatile("s_waitcnt vmcnt(8)" ::: "memory");
    __builtin_amdgcn_s_barrier();
    compute(kt, buf, kt + 3 < nkt);
    buf = (buf == 2) ? 0 : buf + 1;
  }
  // epilogue: drain 4 -> 0
  asm volatile("s_waitcnt vmcnt(4)" ::: "memory");
  __builtin_amdgcn_s_barrier();
  compute(kt, buf, false);
  buf = (buf == 2) ? 0 : buf + 1;
  ++kt;
  asm volatile("s_waitcnt vmcnt(0)" ::: "memory");
  __builtin_amdgcn_s_barrier();
  compute(kt, buf, false);

  if (EP == EP_RELU_MAX) {
#pragma unroll
    for (int ni = 0; ni < 4; ++ni) {
      const int n = n0 + wc * 64 + ni * 16 + l15;
      const float b = g.bias[n];
      float m = 0.f;
#pragma unroll
      for (int mi = 0; mi < 4; ++mi)
#pragma unroll
        for (int r = 0; r < 4; ++r)
          m = fmaxf(m, acc[mi][ni][r] + b);
      m = fmaxf(m, 0.f);
      m = fmaxf(m, __shfl_xor(m, 16));
      m = fmaxf(m, __shfl_xor(m, 32));
      if (l4 == 0) g.outf[(size_t)((m0 >> 6) + wr) * HD + n] = m;
    }
  } else {
#pragma unroll
    for (int mi = 0; mi < 4; ++mi)
#pragma unroll
      for (int r = 0; r < 4; ++r) {
        const int row = m0 + wr * 64 + mi * 16 + l4 * 4 + r;
#pragma unroll
        for (int ni = 0; ni < 4; ++ni) {
          const int n = n0 + wc * 64 + ni * 16 + l15;
          const size_t oi = (size_t)row * HD + n;
          float v = acc[mi][ni][r];
          if (EP == EP_TANH) {
            g.outb[oi] = f2bf(tanhf(v + g.bias[n]));
          } else if (EP == EP_MERGE) {
            float gg = v + g.aux2[(size_t)(row >> 6) * HD + n];
            float sg = 1.f / (1.f + expf(-gg));
            float o1v = bf2f(g.aux0[oi]);
            float ock = bf2f(g.aux1[oi]);
            g.outb[oi] = f2bf(fmaf(sg, o1v - ock, ock));
          } else {  // EP_RELU
            g.outb[oi] = f2bf(fmaxf(v + g.bias[n], 0.f));
          }
        }
      }
  }
}

extern "C" void kernel_launch(void* const* d_in, const int* in_sizes, int n_in,
                              void* d_out, int out_size, void* d_ws, size_t ws_size,
                              hipStream_t stream) {
  const float* enc_o = (const float*)d_in[0];
  const float* enc_q = (const float*)d_in[1];
  const int* om = (const int*)d_in[2];
  const int* qm = (const int*)d_in[3];
  const float* att_W1_w = (const float*)d_in[4];
  const float* att_W1_b = (const float*)d_in[5];
  const float* att_W2_w = (const float*)d_in[6];
  const float* att_W2_b = (const float*)d_in[7];
  const float* att_W3 = (const float*)d_in[8];
  const float* Wc_self_w = (const float*)d_in[9];
  const float* Wc_self_b = (const float*)d_in[10];
  const float* Wc_w = (const float*)d_in[11];
  const float* Wc_b = (const float*)d_in[12];
  const float* Va_w = (const float*)d_in[13];
  const float* Va_b = (const float*)d_in[14];
  const float* Wg_w = (const float*)d_in[15];
  const float* Wg_b = (const float*)d_in[16];
  const float* co_W1_w = (const float*)d_in[17];
  const float* co_W1_b = (const float*)d_in[18];
  const float* co_W2_w = (const float*)d_in[19];
  const float* co_W2_b = (const float*)d_in[20];
  const float* co_W3 = (const float*)d_in[21];
  const float* Wp_w = (const float*)d_in[22];
  const float* Wp_b = (const float*)d_in[23];
  const float* sa_W1_w = (const float*)d_in[24];
  const float* sa_W1_b = (const float*)d_in[25];
  const float* sa_W2_w = (const float*)d_in[26];
  const float* sa_W2_b = (const float*)d_in[27];
  const float* sa_W3 = (const float*)d_in[28];
  const float* Wf_w = (const float*)d_in[29];
  const float* Wf_b = (const float*)d_in[30];
  float* out = (float*)d_out;

  const int NTOK_O = 16384;
  const int NTOK_Q = 32768;
  const int HH = 768 * 768;

  float* ws = (float*)d_ws;
  size_t off = 0;
  auto carve = [&](size_t n) { float* p = ws + off; off += n; return p; };
  float* s1o   = carve(16384);
  float* s2o   = carve(16384);
  float* qa    = carve(32768);
  float* qco1  = carve(32768);
  float* ms2   = carve(16384);
  float* sa1   = carve(16384);
  float* sa2   = carve(16384);
  float* biasO = carve(1024);
  float* Qpool = carve(196608);
  float* Qg    = carve(196608);
  float* A2buf = carve(2097152);
  float* r1 = carve(12582912);   // [CSb|X1] -> [OPKb|X3]
  float* r2 = carve(12582912);   // [OCKb|X2] -> [PLOb|..] -> opkw3
  float* r3 = carve(12582912);   // [MRGb|..] -> [OSKb|X4]
  float* r4 = carve(12582912);   // [eobf|eow3] -> [PHIb|..]
  unsigned short* wtb = (unsigned short*)carve(1179648);
  if (ws_size < off * sizeof(float)) return;
  unsigned short* CSb   = (unsigned short*)r1;
  unsigned short* OPKb  = (unsigned short*)r1;
  unsigned short* X1    = (unsigned short*)(r1 + 6291456);
  unsigned short* X3    = (unsigned short*)(r1 + 6291456);
  unsigned short* OCKb  = (unsigned short*)r2;
  unsigned short* PLOb  = (unsigned short*)r2;
  unsigned short* opkw3 = (unsigned short*)r2;
  unsigned short* X2    = (unsigned short*)(r2 + 6291456);
  unsigned short* MRGb  = (unsigned short*)r3;
  unsigned short* OSKb  = (unsigned short*)r3;
  unsigned short* X4    = (unsigned short*)(r3 + 6291456);
  unsigned short* eobf  = (unsigned short*)r4;
  unsigned short* eow3  = (unsigned short*)(r4 + 6291456);
  unsigned short* PHIb  = (unsigned short*)r4;
  unsigned short* PtG   = (unsigned short*)A2buf;

  const dim3 GBIG(128, 6);  // m-fast: contemporaneous blocks share the weight n-slice
  const int PREP_GRID = NTOK_O * HD / (256 * 8);  // 6144

  // 1. bf16 prep of enc_o, then fused per-token scalars
  bfprep_kernel<<<PREP_GRID, 256, 0, stream>>>(enc_o, att_W3, eobf, eow3);
  dot768x2_bf16<<<NTOK_O / 4, 256, 0, stream>>>(eobf, att_W1_w, att_W1_b,
                                                att_W2_w, att_W2_b, s1o, s2o, NTOK_O);
  dot768x2_f32<<<NTOK_Q / 4, 256, 0, stream>>>(enc_q, Va_w, Va_b,
                                               co_W1_w, co_W1_b, qa, qco1, NTOK_Q);
  bias_ock_kernel<<<3, 256, 0, stream>>>(Wc_self_b, Wc_b, biasO);

  // 2. pairwise option-compare: p1 + p2 -> CS (bf16)
  p1_kernel<3><<<768, 256, 0, stream>>>(eobf, eow3, s1o, s2o, om, PtG);
  p2_kernel<3><<<dim3(4, 256), 256, 0, stream>>>(eobf, PtG, CSb);

  // 3. OCK = tanh([o1 | 3o1-CS | o1*CS] @ [Wc_self; Wc_hi; Wc_lo] + bias)
  {
    modeprep_kernel<1><<<PREP_GRID, 256, 0, stream>>>(eobf, CSb, X1, X2);
    WcArgs wa{};
    wa.src[0] = Wc_self_w; wa.src[1] = Wc_w; wa.src[2] = Wc_w + HH;
    wa.dst = wtb; wa.Kw = 2304;
    wconv_kernel<<<dim3(144, 3), 256, 0, stream>>>(wa);
    MMArgs g{};
    g.a[0] = eobf; g.a[1] = X1; g.a[2] = X2;
    g.K = 2304; g.wt = wtb; g.bias = biasO; g.outb = OCKb;
    mfma_gemm_kernel<EP_TANH><<<GBIG, 256, 0, stream>>>(g);
  }

  // 4. question pooling + Qg (f32)
  qpool_kernel<<<256, 256, 0, stream>>>(enc_q, qa, qm, Qpool);
  {
    GemmArgs g{};
    g.a[0] = Qpool; g.w[0] = Wg_w + 2 * HH;
    g.nchunks = 1; g.bias = Wg_b; g.out = Qg;
    gemm_store_kernel<<<dim3(12, 4), 256, 0, stream>>>(g);
  }

  // 5. merged = G*o1 + (1-G)*OCK  (bf16 out)
  {
    WcArgs wa{};
    wa.src[0] = Wg_w; wa.src[1] = Wg_w + HH;
    wa.dst = wtb; wa.Kw = 1536;
    wconv_kernel<<<dim3(144, 2), 256, 0, stream>>>(wa);
    MMArgs g{};
    g.a[0] = eobf; g.a[1] = OCKb;
    g.K = 1536; g.wt = wtb; g.bias = nullptr;
    g.aux0 = eobf; g.aux1 = OCKb; g.aux2 = Qg; g.outb = MRGb;
    mfma_gemm_kernel<EP_MERGE><<<GBIG, 256, 0, stream>>>(g);
  }

  // 6. co-attention: ms2 -> A2 (MFMA) -> poaa (MFMA, bf16 outs)
  dot768_bf16<<<NTOK_O / 4, 256, 0, stream>>>(MRGb, co_W2_w, co_W2_b, ms2, NTOK_O);
  a2_mfma_kernel<<<256, 256, 0, stream>>>(enc_q, MRGb, qco1, ms2, qm, om, co_W3, A2buf);
  poaa_mfma_kernel<<<256, 256, 0, stream>>>(A2buf, enc_q, MRGb, PLOb, PHIb);

  // 7. OPK = relu([merged | PLO | PHI] @ Wp + b)  (bf16 out)
  {
    WcArgs wa{};
    wa.src[0] = Wp_w; wa.src[1] = Wp_w + HH; wa.src[2] = Wp_w + 2 * HH;
    wa.dst = wtb; wa.Kw = 2304;
    wconv_kernel<<<dim3(144, 3), 256, 0, stream>>>(wa);
    MMArgs g{};
    g.a[0] = MRGb; g.a[1] = PLOb; g.a[2] = PHIb;
    g.K = 2304; g.wt = wtb; g.bias = Wp_b; g.outb = OPKb;
    mfma_gemm_kernel<EP_RELU><<<GBIG, 256, 0, stream>>>(g);
  }

  // 8. self-attention (p1/p2 on OPK bf16)
  dot768x2_bf16<<<NTOK_O / 4, 256, 0, stream>>>(OPKb, sa_W1_w, sa_W1_b,
                                                sa_W2_w, sa_W2_b, sa1, sa2, NTOK_O);
  w3scale_bf16<<<PREP_GRID, 256, 0, stream>>>(OPKb, sa_W3, opkw3);
  p1_kernel<1><<<256, 256, 0, stream>>>(OPKb, opkw3, sa1, sa2, om, PtG);
  p2_kernel<1><<<dim3(4, 256), 256, 0, stream>>>(OPKb, PtG, OSKb);

  // 9. out = max_lo relu([OPK | OSK | OPK-OSK | OPK*OSK] @ Wf + b)  (f32 out)
  {
    modeprep_kernel<3><<<PREP_GRID, 256, 0, stream>>>(OPKb, OSKb, X3, X4);
    WcArgs wa{};
    wa.src[0] = Wf_w; wa.src[1] = Wf_w + HH; wa.src[2] = Wf_w + 2 * HH; wa.src[3] = Wf_w + 3 * HH;
    wa.dst = wtb; wa.Kw = 3072;
    wconv_kernel<<<dim3(144, 4), 256, 0, stream>>>(wa);
    MMArgs g{};
    g.a[0] = OPKb; g.a[1] = OSKb; g.a[2] = X3; g.a[3] = X4;
    g.K = 3072; g.wt = wtb; g.bias = Wf_b; g.outf = out;
    mfma_gemm_kernel<EP_RELU_MAX><<<GBIG, 256, 0, stream>>>(g);
  }
}

// Round 9
// 619.729 us; speedup vs baseline: 8.8232x; 1.0645x over previous
//
#include <hip/hip_runtime.h>
#include <math.h>

// OptionCompareCell: B=64,C=4,LO=64,LQ=128,H=768
// Round 9: non-GEMM batch:
//  (1) modeprep fused into p2 epilogues (p2<3> -> X1,X2 ; p2<1> -> OSK,X3,X4)
//  (2) bfprep_dot: enc_o read once -> eobf,eow3,s1o,s2o
//  (3) opkprep: OPKb read once -> opkw3,sa1,sa2
//  (4) a2 split over 2 q-halves (512 blocks)
//  (5) poaa split over 2 d-halves (512 blocks, stats duplicated)
// GEMM (3-deep counted-vmcnt pipeline + swizzle, 0 conflicts) unchanged from r8.

#define NEGC (-10000.0f)
constexpr int HD = 768;

constexpr int EP_TANH = 1;
constexpr int EP_MERGE = 2;
constexpr int EP_RELU = 3;
constexpr int EP_RELU_MAX = 4;

typedef __attribute__((ext_vector_type(8))) short bf16x8;
typedef __attribute__((ext_vector_type(8))) unsigned short u16x8;
typedef __attribute__((ext_vector_type(4))) unsigned short u16x4;
typedef __attribute__((ext_vector_type(4))) float f32x4;

__device__ inline void st8(float* dst, float4 a0, float4 a1) {
  dst[0] = a0.x; dst[1] = a0.y; dst[2] = a0.z; dst[3] = a0.w;
  dst[4] = a1.x; dst[5] = a1.y; dst[6] = a1.z; dst[7] = a1.w;
}

__device__ inline unsigned short f2bf(float x) {
  unsigned int u = __float_as_uint(x);
  u += 0x7fffu + ((u >> 16) & 1u);
  return (unsigned short)(u >> 16);
}

__device__ inline float bf2f(unsigned short u) {
  return __uint_as_float(((unsigned int)u) << 16);
}

__device__ inline u16x8 pack8(float4 a, float4 b) {
  u16x8 r;
  r[0] = f2bf(a.x); r[1] = f2bf(a.y); r[2] = f2bf(a.z); r[3] = f2bf(a.w);
  r[4] = f2bf(b.x); r[5] = f2bf(b.y); r[6] = f2bf(b.z); r[7] = f2bf(b.w);
  return r;
}

__device__ inline u16x4 pack4(float4 a) {
  u16x4 r;
  r[0] = f2bf(a.x); r[1] = f2bf(a.y); r[2] = f2bf(a.z); r[3] = f2bf(a.w);
  return r;
}

__device__ inline void gload_lds16(const unsigned short* src, unsigned short* dst) {
  __builtin_amdgcn_global_load_lds(
      (const __attribute__((address_space(1))) void*)src,
      (__attribute__((address_space(3))) void*)dst, 16, 0, 0);
}

// ---------------- fused enc_o prep: eobf, eow3, s1o, s2o in one pass ----------------
__global__ __launch_bounds__(256)
void bfprep_dot_kernel(const float* __restrict__ x, const float* __restrict__ w3,
                       const float* __restrict__ w1, const float* __restrict__ b1,
                       const float* __restrict__ w2, const float* __restrict__ b2,
                       unsigned short* __restrict__ xbf, unsigned short* __restrict__ xw3,
                       float* __restrict__ o1, float* __restrict__ o2, int ntok) {
  int tok = blockIdx.x * 4 + (threadIdx.x >> 6);
  int lane = threadIdx.x & 63;
  if (tok >= ntok) return;
  const float* xp = x + (size_t)tok * HD;
  unsigned short* xb = xbf + (size_t)tok * HD;
  unsigned short* xw = xw3 + (size_t)tok * HD;
  float s1 = 0.f, s2 = 0.f;
#pragma unroll
  for (int i = 0; i < 3; ++i) {
    int c = (lane + (i << 6)) << 2;
    float4 xv = *(const float4*)(xp + c);
    float4 w3v = *(const float4*)(w3 + c);
    float4 wa = *(const float4*)(w1 + c);
    float4 wb = *(const float4*)(w2 + c);
    s1 = fmaf(xv.x, wa.x, s1); s1 = fmaf(xv.y, wa.y, s1);
    s1 = fmaf(xv.z, wa.z, s1); s1 = fmaf(xv.w, wa.w, s1);
    s2 = fmaf(xv.x, wb.x, s2); s2 = fmaf(xv.y, wb.y, s2);
    s2 = fmaf(xv.z, wb.z, s2); s2 = fmaf(xv.w, wb.w, s2);
    *(u16x4*)(xb + c) = pack4(xv);
    float4 sv;
    sv.x = xv.x * w3v.x; sv.y = xv.y * w3v.y; sv.z = xv.z * w3v.z; sv.w = xv.w * w3v.w;
    *(u16x4*)(xw + c) = pack4(sv);
  }
#pragma unroll
  for (int off = 32; off; off >>= 1) {
    s1 += __shfl_xor(s1, off);
    s2 += __shfl_xor(s2, off);
  }
  if (lane == 0) { o1[tok] = s1 + b1[0]; o2[tok] = s2 + b2[0]; }
}

// ---------------- fused OPK prep: opkw3, sa1, sa2 in one pass ----------------
__global__ __launch_bounds__(256)
void opkprep_kernel(const unsigned short* __restrict__ x, const float* __restrict__ w3,
                    const float* __restrict__ w1, const float* __restrict__ b1,
                    const float* __restrict__ w2, const float* __restrict__ b2,
                    unsigned short* __restrict__ xw3,
                    float* __restrict__ o1, float* __restrict__ o2, int ntok) {
  int tok = blockIdx.x * 4 + (threadIdx.x >> 6);
  int lane = threadIdx.x & 63;
  if (tok >= ntok) return;
  const unsigned short* xp = x + (size_t)tok * HD;
  unsigned short* xw = xw3 + (size_t)tok * HD;
  float s1 = 0.f, s2 = 0.f;
#pragma unroll
  for (int i = 0; i < 3; ++i) {
    int c = (lane + (i << 6)) << 2;
    u16x4 xv = *(const u16x4*)(xp + c);
    float x0 = bf2f(xv[0]), x1 = bf2f(xv[1]), x2 = bf2f(xv[2]), x3 = bf2f(xv[3]);
    float4 w3v = *(const float4*)(w3 + c);
    float4 wa = *(const float4*)(w1 + c);
    float4 wb = *(const float4*)(w2 + c);
    s1 = fmaf(x0, wa.x, s1); s1 = fmaf(x1, wa.y, s1);
    s1 = fmaf(x2, wa.z, s1); s1 = fmaf(x3, wa.w, s1);
    s2 = fmaf(x0, wb.x, s2); s2 = fmaf(x1, wb.y, s2);
    s2 = fmaf(x2, wb.z, s2); s2 = fmaf(x3, wb.w, s2);
    u16x4 sv;
    sv[0] = f2bf(x0 * w3v.x); sv[1] = f2bf(x1 * w3v.y);
    sv[2] = f2bf(x2 * w3v.z); sv[3] = f2bf(x3 * w3v.w);
    *(u16x4*)(xw + c) = sv;
  }
#pragma unroll
  for (int off = 32; off; off >>= 1) {
    s1 += __shfl_xor(s1, off);
    s2 += __shfl_xor(s2, off);
  }
  if (lane == 0) { o1[tok] = s1 + b1[0]; o2[tok] = s2 + b2[0]; }
}

__global__ __launch_bounds__(256)
void dot768x2_f32(const float* __restrict__ x,
                  const float* __restrict__ w1, const float* __restrict__ b1,
                  const float* __restrict__ w2, const float* __restrict__ b2,
                  float* __restrict__ o1, float* __restrict__ o2, int ntok) {
  int tok = blockIdx.x * 4 + (threadIdx.x >> 6);
  int lane = threadIdx.x & 63;
  if (tok >= ntok) return;
  const float* xp = x + (size_t)tok * HD;
  float s1 = 0.f, s2 = 0.f;
#pragma unroll
  for (int i = 0; i < 3; ++i) {
    int c = (lane + (i << 6)) << 2;
    float4 xv = *(const float4*)(xp + c);
    float4 wa = *(const float4*)(w1 + c);
    float4 wb = *(const float4*)(w2 + c);
    s1 = fmaf(xv.x, wa.x, s1); s1 = fmaf(xv.y, wa.y, s1);
    s1 = fmaf(xv.z, wa.z, s1); s1 = fmaf(xv.w, wa.w, s1);
    s2 = fmaf(xv.x, wb.x, s2); s2 = fmaf(xv.y, wb.y, s2);
    s2 = fmaf(xv.z, wb.z, s2); s2 = fmaf(xv.w, wb.w, s2);
  }
#pragma unroll
  for (int off = 32; off; off >>= 1) {
    s1 += __shfl_xor(s1, off);
    s2 += __shfl_xor(s2, off);
  }
  if (lane == 0) { o1[tok] = s1 + b1[0]; o2[tok] = s2 + b2[0]; }
}

__global__ __launch_bounds__(256)
void dot768_bf16(const unsigned short* __restrict__ x,
                 const float* __restrict__ w1, const float* __restrict__ b1,
                 float* __restrict__ o1, int ntok) {
  int tok = blockIdx.x * 4 + (threadIdx.x >> 6);
  int lane = threadIdx.x & 63;
  if (tok >= ntok) return;
  const unsigned short* xp = x + (size_t)tok * HD;
  float s1 = 0.f;
#pragma unroll
  for (int i = 0; i < 3; ++i) {
    int c = (lane + (i << 6)) << 2;
    u16x4 xv = *(const u16x4*)(xp + c);
    float4 wa = *(const float4*)(w1 + c);
    s1 = fmaf(bf2f(xv[0]), wa.x, s1); s1 = fmaf(bf2f(xv[1]), wa.y, s1);
    s1 = fmaf(bf2f(xv[2]), wa.z, s1); s1 = fmaf(bf2f(xv[3]), wa.w, s1);
  }
#pragma unroll
  for (int off = 32; off; off >>= 1) s1 += __shfl_xor(s1, off);
  if (lane == 0) o1[tok] = s1 + b1[0];
}

__global__ void bias_ock_kernel(const float* __restrict__ b1, const float* __restrict__ b2,
                                float* __restrict__ o) {
  int n = blockIdx.x * 256 + threadIdx.x;
  if (n < HD) o[n] = b1[n] + 3.f * b2[n];
}

// ---------------- P1: S = U . Vw3^T (MFMA), softmax over u, write Pt[v][u] bf16 ----------------
template<int NJ>
__global__ __launch_bounds__(256)
void p1_kernel(const unsigned short* __restrict__ Xbf, const unsigned short* __restrict__ Xw3,
               const float* __restrict__ s1g, const float* __restrict__ s2g,
               const int* __restrict__ maskg, unsigned short* __restrict__ PtG) {
  __shared__ __align__(16) unsigned short Ua[64 * 136];
  __shared__ __align__(16) unsigned short Vb[64 * 136];
  __shared__ float Sbuf[64][66];
  __shared__ float red[4][64];
  const int t = threadIdx.x;
  int ubc, vbc;
  if (NJ == 1) {
    ubc = vbc = blockIdx.x;
  } else {
    const int b = blockIdx.x / 12, pr = blockIdx.x % 12;
    const int i = pr / 3, jj = pr % 3;
    const int j = jj + (jj >= i ? 1 : 0);
    vbc = (b << 2) + i; ubc = (b << 2) + j;
  }
  const unsigned short* U = Xbf + (size_t)ubc * (64 * HD);
  const unsigned short* V = Xw3 + (size_t)vbc * (64 * HD);
  const int w = t >> 6, lane = t & 63, l15 = lane & 15, l4 = lane >> 4;
  const int srow = t >> 2, scol = (t & 3) << 5;
  f32x4 acc[4] = {};
  for (int k0 = 0; k0 < HD; k0 += 128) {
    const unsigned short* up = U + (size_t)srow * HD + k0 + scol;
    const unsigned short* vp = V + (size_t)srow * HD + k0 + scol;
    unsigned short* ua = &Ua[srow * 136 + scol];
    unsigned short* vb = &Vb[srow * 136 + scol];
#pragma unroll
    for (int z = 0; z < 4; ++z) {
      *(u16x8*)(ua + z * 8) = *(const u16x8*)(up + z * 8);
      *(u16x8*)(vb + z * 8) = *(const u16x8*)(vp + z * 8);
    }
    __syncthreads();
#pragma unroll
    for (int ks = 0; ks < 4; ++ks) {
      bf16x8 af = *(const bf16x8*)(&Ua[(w * 16 + l15) * 136 + ks * 32 + l4 * 8]);
#pragma unroll
      for (int n = 0; n < 4; ++n) {
        bf16x8 bf = *(const bf16x8*)(&Vb[(n * 16 + l15) * 136 + ks * 32 + l4 * 8]);
        acc[n] = __builtin_amdgcn_mfma_f32_16x16x32_bf16(af, bf, acc[n], 0, 0, 0);
      }
    }
    __syncthreads();
  }
  {
    float s1v[4];
#pragma unroll
    for (int r = 0; r < 4; ++r) {
      int u = w * 16 + l4 * 4 + r;
      s1v[r] = s1g[ubc * 64 + u] + (1.f - (float)maskg[ubc * 64 + u]) * NEGC;
    }
#pragma unroll
    for (int n = 0; n < 4; ++n) {
      int v = n * 16 + l15;
      float s2v = s2g[vbc * 64 + v] + (1.f - (float)maskg[vbc * 64 + v]) * NEGC;
#pragma unroll
      for (int r = 0; r < 4; ++r)
        Sbuf[w * 16 + l4 * 4 + r][v] = acc[n][r] + s1v[r] + s2v;
    }
  }
  __syncthreads();
  {
    const int v = t & 63, part = t >> 6;
    float m = -1e30f;
#pragma unroll
    for (int z = 0; z < 16; ++z) m = fmaxf(m, Sbuf[part * 16 + z][v]);
    red[part][v] = m;
    __syncthreads();
    float gm = fmaxf(fmaxf(red[0][v], red[1][v]), fmaxf(red[2][v], red[3][v]));
    float s = 0.f;
#pragma unroll
    for (int z = 0; z < 16; ++z) {
      float e = expf(Sbuf[part * 16 + z][v] - gm);
      Sbuf[part * 16 + z][v] = e;
      s += e;
    }
    __syncthreads();
    red[part][v] = s;
    __syncthreads();
    float cinv = 1.f / (red[0][v] + red[1][v] + red[2][v] + red[3][v]);
    unsigned short* pt = PtG + (size_t)blockIdx.x * 4096 + v * 64 + part * 16;
#pragma unroll
    for (int z = 0; z < 16; ++z) pt[z] = f2bf(Sbuf[part * 16 + z][v] * cinv);
  }
}

// ---- P2: ctx = sum_j Pt_j . U_j ; fused epilogue: NJ=3 -> X1,X2 ; NJ=1 -> OSK,X3,X4 ----
template<int NJ>
__global__ __launch_bounds__(256)
void p2_kernel(const unsigned short* __restrict__ Xbf, const unsigned short* __restrict__ PtG,
               const unsigned short* __restrict__ Oi,
               unsigned short* __restrict__ osk,
               unsigned short* __restrict__ y1, unsigned short* __restrict__ y2) {
  __shared__ __align__(16) unsigned short Pts[NJ][64 * 72];
  __shared__ __align__(16) unsigned short U2[64 * 192];
  const int t = threadIdx.x;
  const int dq = blockIdx.x, bc = blockIdx.y;
  const int d0 = dq * 192;
  const int b = bc >> 2, i = bc & 3;
  const int w = t >> 6, lane = t & 63, l15 = lane & 15, l4 = lane >> 4;
  {
    const int v = t >> 2, cs = (t & 3) << 4;
#pragma unroll
    for (int jj = 0; jj < NJ; ++jj) {
      size_t src = (NJ == 1 ? (size_t)bc : (size_t)(b * 12 + i * 3 + jj)) * 4096 + v * 64 + cs;
      *(u16x8*)(&Pts[jj][v * 72 + cs]) = *(const u16x8*)(PtG + src);
      *(u16x8*)(&Pts[jj][v * 72 + cs + 8]) = *(const u16x8*)(PtG + src + 8);
    }
  }
  f32x4 acc[4][3] = {};
  const int su = t >> 2, sc0 = (t & 3) * 48;
  const int sswz = ((su >> 3) & 3) << 5;
  for (int jj = 0; jj < NJ; ++jj) {
    const int ubc = (NJ == 1) ? bc : ((b << 2) + (jj + (jj >= i ? 1 : 0)));
    __syncthreads();
    {
      const unsigned short* up = Xbf + (size_t)ubc * (64 * HD) + (size_t)su * HD + d0 + sc0;
#pragma unroll
      for (int it = 0; it < 6; ++it) {
        u16x8 vdat = *(const u16x8*)(up + it * 8);
        *(u16x8*)((char*)U2 + ((su * 384 + (sc0 + it * 8) * 2) ^ sswz)) = vdat;
      }
    }
    __syncthreads();
    const unsigned short* ptj = &Pts[jj][0];
#pragma unroll
    for (int ks = 0; ks < 2; ++ks) {
      bf16x8 bfr[3];
#pragma unroll
      for (int n = 0; n < 3; ++n) {
        const int col = (w * 3 + n) * 16 + l15;
#pragma unroll
        for (int e = 0; e < 8; ++e) {
          const int uk = ks * 32 + l4 * 8 + e;
          const int byte = (uk * 384 + col * 2) ^ (((uk >> 3) & 3) << 5);
          bfr[n][e] = *(const short*)((const char*)U2 + byte);
        }
      }
#pragma unroll
      for (int m = 0; m < 4; ++m) {
        bf16x8 af = *(const bf16x8*)(ptj + (m * 16 + l15) * 72 + ks * 32 + l4 * 8);
#pragma unroll
        for (int n = 0; n < 3; ++n)
          acc[m][n] = __builtin_amdgcn_mfma_f32_16x16x32_bf16(af, bfr[n], acc[m][n], 0, 0, 0);
      }
    }
  }
  const unsigned short* oip = Oi + (size_t)bc * (64 * HD);
  const size_t obase = (size_t)bc * (64 * HD);
#pragma unroll
  for (int m = 0; m < 4; ++m)
#pragma unroll
    for (int n = 0; n < 3; ++n) {
      const int d = d0 + (w * 3 + n) * 16 + l15;
#pragma unroll
      for (int r = 0; r < 4; ++r) {
        const int v = m * 16 + l4 * 4 + r;
        const size_t idx = obase + (size_t)v * HD + d;
        const float cs = acc[m][n][r];
        const float oi = bf2f(oip[(size_t)v * HD + d]);
        if (NJ == 3) {
          y1[idx] = f2bf(fmaf(3.f, oi, -cs));
          y2[idx] = f2bf(oi * cs);
        } else {
          osk[idx] = f2bf(cs);
          y1[idx] = f2bf(oi - cs);
          y2[idx] = f2bf(oi * cs);
        }
      }
    }
}

// ---------------- question pooling ----------------
__global__ __launch_bounds__(256)
void qpool_kernel(const float* __restrict__ q, const float* __restrict__ qa,
                  const int* __restrict__ qm, float* __restrict__ Q) {
  __shared__ float wgt[128];
  __shared__ float wred[4];
  int t = threadIdx.x, bc = blockIdx.x;
  const float* qap = qa + bc * 128;
  const int* qmp = qm + bc * 128;
  float v = -1e30f;
  if (t < 128) v = qap[t] + (1.f - (float)qmp[t]) * NEGC;
  float m = v;
#pragma unroll
  for (int off = 32; off; off >>= 1) m = fmaxf(m, __shfl_xor(m, off));
  if ((t & 63) == 0) wred[t >> 6] = m;
  __syncthreads();
  float gm = fmaxf(fmaxf(wred[0], wred[1]), fmaxf(wred[2], wred[3]));
  float e = (t < 128) ? expf(v - gm) : 0.f;
  float s = e;
#pragma unroll
  for (int off = 32; off; off >>= 1) s += __shfl_xor(s, off);
  __syncthreads();
  if ((t & 63) == 0) wred[t >> 6] = s;
  __syncthreads();
  float tot = wred[0] + wred[1] + wred[2] + wred[3];
  if (t < 128) wgt[t] = e / tot;
  __syncthreads();
  const float* qp = q + (size_t)bc * (128 * HD);
  float* Qp = Q + (size_t)bc * HD;
  for (int d = t; d < HD; d += 256) {
    float acc = 0.f;
    for (int l = 0; l < 128; ++l) acc = fmaf(wgt[l], qp[(size_t)l * HD + d], acc);
    Qp[d] = acc;
  }
}

// ---------------- A2 via MFMA, split over 2 q-halves: grid (2, 256) ----------------
__global__ __launch_bounds__(256)
void a2_mfma_kernel(const float* __restrict__ qin, const unsigned short* __restrict__ mergedb,
                    const float* __restrict__ qco1, const float* __restrict__ ms2,
                    const int* __restrict__ qm, const int* __restrict__ om,
                    const float* __restrict__ w3, float* __restrict__ A2) {
  __shared__ __align__(16) unsigned short Aq[64 * 72];
  __shared__ __align__(16) unsigned short Bm[64 * 72];
  const int t = threadIdx.x, qh = blockIdx.x, bc = blockIdx.y;
  const float* qp = qin + (size_t)bc * (128 * HD) + (size_t)(qh * 64) * HD;
  const unsigned short* mp = mergedb + (size_t)bc * (64 * HD);
  const int w = t >> 6, lane = t & 63, l15 = lane & 15, l4 = lane >> 4;
  const int srow = t >> 2, scs = (t & 3) << 4;
  f32x4 acc[4] = {};
  for (int k0 = 0; k0 < HD; k0 += 64) {
    {
      const float* p = qp + (size_t)srow * HD + k0 + scs;
      const float* wp = w3 + k0 + scs;
      unsigned short* dst = &Aq[srow * 72 + scs];
#pragma unroll
      for (int z = 0; z < 2; ++z) {
        float4 a = *(const float4*)(p + z * 8);
        float4 b = *(const float4*)(p + z * 8 + 4);
        float4 wa = *(const float4*)(wp + z * 8);
        float4 wb = *(const float4*)(wp + z * 8 + 4);
        a.x *= wa.x; a.y *= wa.y; a.z *= wa.z; a.w *= wa.w;
        b.x *= wb.x; b.y *= wb.y; b.z *= wb.z; b.w *= wb.w;
        *(u16x8*)(dst + z * 8) = pack8(a, b);
      }
    }
    {
      const unsigned short* p = mp + (size_t)srow * HD + k0 + scs;
      unsigned short* dst = &Bm[srow * 72 + scs];
      *(u16x8*)(dst) = *(const u16x8*)(p);
      *(u16x8*)(dst + 8) = *(const u16x8*)(p + 8);
    }
    __syncthreads();
#pragma unroll
    for (int ks = 0; ks < 2; ++ks) {
      bf16x8 af = *(const bf16x8*)(&Aq[(w * 16 + l15) * 72 + ks * 32 + l4 * 8]);
#pragma unroll
      for (int n = 0; n < 4; ++n) {
        bf16x8 bf = *(const bf16x8*)(&Bm[(n * 16 + l15) * 72 + ks * 32 + l4 * 8]);
        acc[n] = __builtin_amdgcn_mfma_f32_16x16x32_bf16(af, bf, acc[n], 0, 0, 0);
      }
    }
    __syncthreads();
  }
  const float* qc = qco1 + bc * 128;
  const int* qmp = qm + bc * 128;
  const float* msp = ms2 + bc * 64;
  const int* omp = om + bc * 64;
  float* outp = A2 + (size_t)bc * (128 * 64) + (size_t)(qh * 64) * 64;
#pragma unroll
  for (int n = 0; n < 4; ++n) {
    const int v = n * 16 + l15;
    const float ct = msp[v] + (1.f - (float)omp[v]) * NEGC;
#pragma unroll
    for (int r = 0; r < 4; ++r) {
      const int ql = w * 16 + l4 * 4 + r;
      const int qrow = qh * 64 + ql;
      const float rt = qc[qrow] + (1.f - (float)qmp[qrow]) * NEGC;
      outp[ql * 64 + v] = acc[n][r] + rt + ct;
    }
  }
}

// ---------------- POAA via MFMA, split over 2 d-halves: grid (2, 256) ----------------
__global__ __launch_bounds__(256)
void poaa_mfma_kernel(const float* __restrict__ A2, const float* __restrict__ qin,
                      const unsigned short* __restrict__ mergedb,
                      unsigned short* __restrict__ PLO, unsigned short* __restrict__ PHI) {
  __shared__ __align__(16) char smem[77312];
  __shared__ float red[4][64];
  __shared__ float rowm[128], rowfac[128];
  __shared__ float colfac[64];
  __shared__ float gmax_s;
  float* T = (float*)smem;                                   // [128][65] f32
  unsigned short* Tt = (unsigned short*)(smem + 33280);       // [64][136]
  unsigned short* Tft = (unsigned short*)(smem + 50688);      // [64][136]
  unsigned short* M2bf = (unsigned short*)(smem + 68096);     // [64][72]
  unsigned short* Qc = (unsigned short*)smem;                 // [128][72] (after phase2)
  unsigned short* Mc = (unsigned short*)(smem + 18432);       // [64][72]

  const int t = threadIdx.x, dqh = blockIdx.x, bc = blockIdx.y;
  const int w = t >> 6, lane = t & 63, l15 = lane & 15, l4 = lane >> 4;
  const float* a2 = A2 + (size_t)bc * (128 * 64);
  {
    int row = t >> 1, cs = (t & 1) << 5;
    const float* p = a2 + row * 64 + cs;
#pragma unroll
    for (int z = 0; z < 8; ++z) {
      float4 v = *(const float4*)(p + (z << 2));
      T[row * 65 + cs + (z << 2) + 0] = v.x;
      T[row * 65 + cs + (z << 2) + 1] = v.y;
      T[row * 65 + cs + (z << 2) + 2] = v.z;
      T[row * 65 + cs + (z << 2) + 3] = v.w;
    }
  }
  __syncthreads();
  {
    int qrow = t >> 1, h = t & 1;
    float m = -1e30f;
    for (int v = h * 32; v < h * 32 + 32; ++v) m = fmaxf(m, T[qrow * 65 + v]);
    m = fmaxf(m, __shfl_xor(m, 1));
    float s = 0.f;
    for (int v = h * 32; v < h * 32 + 32; ++v) s += expf(T[qrow * 65 + v] - m);
    s += __shfl_xor(s, 1);
    if (h == 0) { rowm[qrow] = m; rowfac[qrow] = s; }
  }
  float colm_loc = 0.f;
  {
    int v = t & 63, part = t >> 6;
    float m = -1e30f;
    for (int qq = part * 32; qq < part * 32 + 32; ++qq) m = fmaxf(m, T[qq * 65 + v]);
    red[part][v] = m;
    __syncthreads();
    float cm = fmaxf(fmaxf(red[0][v], red[1][v]), fmaxf(red[2][v], red[3][v]));
    float s = 0.f;
    for (int qq = part * 32; qq < part * 32 + 32; ++qq) s += expf(T[qq * 65 + v] - cm);
    __syncthreads();
    red[part][v] = s;
    __syncthreads();
    if (part == 0) { colm_loc = cm; colfac[v] = red[0][v] + red[1][v] + red[2][v] + red[3][v]; }
  }
  __syncthreads();
  if (t < 64) {
    float m = fmaxf(rowm[t], rowm[t + 64]);
#pragma unroll
    for (int off = 32; off; off >>= 1) m = fmaxf(m, __shfl_xor(m, off));
    if (t == 0) gmax_s = m;
  }
  __syncthreads();
  const float gmax = gmax_s;
  if (t < 128) rowfac[t] = expf(fminf(gmax - rowm[t], 60.f)) / rowfac[t];
  if (t < 64) colfac[t] = expf(fminf(gmax - colm_loc, 60.f)) / colfac[t];
  __syncthreads();
  {
    const int o = t >> 2, qs = (t & 3) << 5;
    for (int z = 0; z < 32; ++z) {
      const int qq = qs + z;
      float e = expf(T[qq * 65 + o] - gmax);
      Tt[o * 136 + qq] = f2bf(e);
      Tft[o * 136 + qq] = f2bf(e * rowfac[qq]);
    }
  }
  __syncthreads();
  {
    f32x4 m2acc[4] = {};
#pragma unroll
    for (int ks = 0; ks < 4; ++ks) {
      bf16x8 af = *(const bf16x8*)(&Tt[(w * 16 + l15) * 136 + ks * 32 + l4 * 8]);
#pragma unroll
      for (int n = 0; n < 4; ++n) {
        bf16x8 bf = *(const bf16x8*)(&Tft[(n * 16 + l15) * 136 + ks * 32 + l4 * 8]);
        m2acc[n] = __builtin_amdgcn_mfma_f32_16x16x32_bf16(af, bf, m2acc[n], 0, 0, 0);
      }
    }
#pragma unroll
    for (int n = 0; n < 4; ++n)
#pragma unroll
      for (int r = 0; r < 4; ++r) {
        const int o = w * 16 + l4 * 4 + r;
        M2bf[o * 72 + n * 16 + l15] = f2bf(colfac[o] * m2acc[n][r]);
      }
  }
  const int dql = t >> 1, dqs = (t & 1) << 5;
  const int dml = t >> 2, dms = (t & 3) << 4;
  const int swq = ((dql >> 3) & 3) << 5;
  const int swm = ((dml >> 3) & 3) << 5;
  unsigned short* plo = PLO + (size_t)bc * (64 * HD);
  unsigned short* phi = PHI + (size_t)bc * (64 * HD);
  const float* qp = qin + (size_t)bc * (128 * HD);
  const unsigned short* mp = mergedb + (size_t)bc * (64 * HD);
  for (int dc = dqh * 6; dc < dqh * 6 + 6; ++dc) {
    const int d0 = dc * 64;
    __syncthreads();
    {
      const float* p = qp + (size_t)dql * HD + d0 + dqs;
#pragma unroll
      for (int z = 0; z < 4; ++z) {
        float4 a = *(const float4*)(p + z * 8);
        float4 b = *(const float4*)(p + z * 8 + 4);
        *(u16x8*)((char*)Qc + ((dql * 144 + (dqs + z * 8) * 2) ^ swq)) = pack8(a, b);
      }
    }
    {
      const unsigned short* p = mp + (size_t)dml * HD + d0 + dms;
      *(u16x8*)((char*)Mc + ((dml * 144 + dms * 2) ^ swm)) = *(const u16x8*)p;
      *(u16x8*)((char*)Mc + ((dml * 144 + (dms + 8) * 2) ^ swm)) = *(const u16x8*)(p + 8);
    }
    __syncthreads();
    const int col = w * 16 + l15;
    f32x4 lacc[4] = {};
#pragma unroll
    for (int ks = 0; ks < 4; ++ks) {
      bf16x8 bf;
#pragma unroll
      for (int e = 0; e < 8; ++e) {
        const int qq = ks * 32 + l4 * 8 + e;
        bf[e] = *(const short*)((const char*)Qc + ((qq * 144 + col * 2) ^ (((qq >> 3) & 3) << 5)));
      }
#pragma unroll
      for (int m = 0; m < 4; ++m) {
        bf16x8 af = *(const bf16x8*)(&Tt[(m * 16 + l15) * 136 + ks * 32 + l4 * 8]);
        lacc[m] = __builtin_amdgcn_mfma_f32_16x16x32_bf16(af, bf, lacc[m], 0, 0, 0);
      }
    }
    f32x4 pacc[4] = {};
#pragma unroll
    for (int ks = 0; ks < 2; ++ks) {
      bf16x8 bf;
#pragma unroll
      for (int e = 0; e < 8; ++e) {
        const int vv = ks * 32 + l4 * 8 + e;
        bf[e] = *(const short*)((const char*)Mc + ((vv * 144 + col * 2) ^ (((vv >> 3) & 3) << 5)));
      }
#pragma unroll
      for (int m = 0; m < 4; ++m) {
        bf16x8 af = *(const bf16x8*)(&M2bf[(m * 16 + l15) * 72 + ks * 32 + l4 * 8]);
        pacc[m] = __builtin_amdgcn_mfma_f32_16x16x32_bf16(af, bf, pacc[m], 0, 0, 0);
      }
    }
#pragma unroll
    for (int m = 0; m < 4; ++m)
#pragma unroll
      for (int r = 0; r < 4; ++r) {
        const int o = m * 16 + l4 * 4 + r;
        const int d = d0 + w * 16 + l15;
        plo[(size_t)o * HD + d] = f2bf(colfac[o] * lacc[m][r]);
        phi[(size_t)o * HD + d] = f2bf(pacc[m][r]);
      }
  }
}

// ---------------- small f32 GEMM (Qg only) ----------------
struct GemmArgs {
  const float* a[4];
  const float* w[4];
  int nchunks;
  const float* bias;
  float* out;
};

__global__ __launch_bounds__(256)
void gemm_store_kernel(GemmArgs g) {
  __shared__ float As[64][33];
  __shared__ float Ws[32][65];
  const int t = threadIdx.x;
  const int m0 = blockIdx.y << 6, n0 = blockIdx.x << 6;
  const int tr = t >> 4, tc = t & 15;
  float acc[4][4];
#pragma unroll
  for (int x = 0; x < 4; ++x)
#pragma unroll
    for (int y = 0; y < 4; ++y) acc[x][y] = 0.f;
  const int arow = t >> 2, acs = (t & 3) << 3;
  const int wrow = t >> 3, wcs = (t & 7) << 3;
  for (int c = 0; c < g.nchunks; ++c) {
    const float* Ap = g.a[c] + (size_t)(m0 + arow) * HD + acs;
    const float* Wp = g.w[c] + (size_t)wrow * HD + n0 + wcs;
    for (int k0 = 0; k0 < HD; k0 += 32) {
      float4 a0 = *(const float4*)(Ap + k0);
      float4 a1 = *(const float4*)(Ap + k0 + 4);
      st8(&As[arow][acs], a0, a1);
      float4 w0 = *(const float4*)(Wp + (size_t)k0 * HD);
      float4 w1 = *(const float4*)(Wp + (size_t)k0 * HD + 4);
      st8(&Ws[wrow][wcs], w0, w1);
      __syncthreads();
#pragma unroll
      for (int kk = 0; kk < 32; ++kk) {
        float av[4], bv[4];
#pragma unroll
        for (int x = 0; x < 4; ++x) av[x] = As[(tr << 2) + x][kk];
#pragma unroll
        for (int y = 0; y < 4; ++y) bv[y] = Ws[kk][(tc << 2) + y];
#pragma unroll
        for (int x = 0; x < 4; ++x)
#pragma unroll
          for (int y = 0; y < 4; ++y) acc[x][y] = fmaf(av[x], bv[y], acc[x][y]);
      }
      __syncthreads();
    }
  }
#pragma unroll
  for (int x = 0; x < 4; ++x) {
    const int r = m0 + (tr << 2) + x;
#pragma unroll
    for (int y = 0; y < 4; ++y) {
      const int n = n0 + (tc << 2) + y;
      g.out[(size_t)r * HD + n] = acc[x][y] + g.bias[n];
    }
  }
}

// ---------------- weight convert+transpose ----------------
struct WcArgs {
  const float* src[4];
  unsigned short* dst;
  int Kw;
};

__global__ __launch_bounds__(256)
void wconv_kernel(WcArgs g) {
  __shared__ float tile[64][65];
  const int slice = blockIdx.y;
  const float* src = g.src[slice];
  const int kbase = slice * HD;
  const int bi = blockIdx.x % 12, bj = blockIdx.x / 12;
  const int t = threadIdx.x;
  const int r = t >> 2, cseg = (t & 3) << 4;
  const float* p = src + (size_t)(bi * 64 + r) * HD + bj * 64 + cseg;
#pragma unroll
  for (int j = 0; j < 16; j += 4) {
    float4 v = *(const float4*)(p + j);
    tile[r][cseg + j + 0] = v.x; tile[r][cseg + j + 1] = v.y;
    tile[r][cseg + j + 2] = v.z; tile[r][cseg + j + 3] = v.w;
  }
  __syncthreads();
  unsigned short* q = g.dst + (size_t)(bj * 64 + r) * g.Kw + kbase + bi * 64 + cseg;
  u16x8 lo, hi;
#pragma unroll
  for (int j = 0; j < 8; ++j) lo[j] = f2bf(tile[cseg + j][r]);
#pragma unroll
  for (int j = 0; j < 8; ++j) hi[j] = f2bf(tile[cseg + 8 + j][r]);
  *(u16x8*)q = lo;
  *(u16x8*)(q + 8) = hi;
}

// ---- bf16 MFMA GEMM: gload_lds + swizzle + 3-deep counted-vmcnt pipeline ----
struct MMArgs {
  const unsigned short* a[4];   // per-768-chunk bf16 sources (all mode-0)
  int K;
  const unsigned short* wt;     // [768][K] bf16
  const float* bias;
  const unsigned short* aux0;   // o1 bf16  (EP_MERGE)
  const unsigned short* aux1;   // OCK bf16 (EP_MERGE)
  const float* aux2;            // Qg f32   (EP_MERGE)
  float* outf;                  // EP_RELU_MAX
  unsigned short* outb;         // others
};

template<int EP>
__global__ __launch_bounds__(256)
void mfma_gemm_kernel(MMArgs g) {
  __shared__ __align__(16) unsigned short As[3][128 * 32];
  __shared__ __align__(16) unsigned short Bs[3][128 * 32];
  const int t = threadIdx.x;
  const int lane = t & 63, w = t >> 6;
  const int wr = w >> 1, wc = w & 1;
  const int m0 = blockIdx.x << 7, n0 = blockIdx.y << 7;  // m-fast grid
  const int l15 = lane & 15, l4 = lane >> 4;
  f32x4 acc[4][4] = {};

  const int srow = w * 32 + (lane >> 2);
  const int gcol = (((lane & 3) ^ ((lane >> 3) & 3))) * 8;   // shorts
  const int rsw = (l15 >> 1) & 3;
  const int rcol = ((l4 ^ rsw)) * 8;                          // shorts

  const int nkt = g.K >> 5;

  auto issue = [&](int kt, int buf) {
    const int c = kt / 24;
    const int koff = (kt - c * 24) << 5;
    const unsigned short* ap = g.a[c] + (size_t)(m0 + srow) * HD + koff + gcol;
    const unsigned short* bp = g.wt + (size_t)(n0 + srow) * g.K + (kt << 5) + gcol;
    gload_lds16(ap, &As[buf][w * 1024]);
    gload_lds16(ap + (size_t)16 * HD, &As[buf][w * 1024 + 512]);
    gload_lds16(bp, &Bs[buf][w * 1024]);
    gload_lds16(bp + (size_t)16 * g.K, &Bs[buf][w * 1024 + 512]);
  };

  auto compute = [&](int kt, int buf, bool prefetch) {
    bf16x8 af[4], bfr[4];
#pragma unroll
    for (int mi = 0; mi < 4; ++mi)
      af[mi] = *(const bf16x8*)(&As[buf][(wr * 64 + mi * 16 + l15) * 32 + rcol]);
#pragma unroll
    for (int ni = 0; ni < 4; ++ni)
      bfr[ni] = *(const bf16x8*)(&Bs[buf][(wc * 64 + ni * 16 + l15) * 32 + rcol]);
    asm volatile("s_waitcnt lgkmcnt(0)" ::: "memory");  // my frags in regs
    __builtin_amdgcn_s_barrier();                        // everyone done reading buf
    if (prefetch) issue(kt + 3, buf);                    // safe to overwrite now
#pragma unroll
    for (int mi = 0; mi < 4; ++mi)
#pragma unroll
      for (int ni = 0; ni < 4; ++ni)
        acc[mi][ni] = __builtin_amdgcn_mfma_f32_16x16x32_bf16(af[mi], bfr[ni], acc[mi][ni], 0, 0, 0);
  };

  issue(0, 0); issue(1, 1); issue(2, 2);
  int buf = 0;
  int kt = 0;
  for (; kt < nkt - 2; ++kt) {
    asm volatile("s_waitcnt vmcnt(8)" ::: "memory");
    __builtin_amdgcn_s_barrier();
    compute(kt, buf, kt + 3 < nkt);
    buf = (buf == 2) ? 0 : buf + 1;
  }
  asm volatile("s_waitcnt vmcnt(4)" ::: "memory");
  __builtin_amdgcn_s_barrier();
  compute(kt, buf, false);
  buf = (buf == 2) ? 0 : buf + 1;
  ++kt;
  asm volatile("s_waitcnt vmcnt(0)" ::: "memory");
  __builtin_amdgcn_s_barrier();
  compute(kt, buf, false);

  if (EP == EP_RELU_MAX) {
#pragma unroll
    for (int ni = 0; ni < 4; ++ni) {
      const int n = n0 + wc * 64 + ni * 16 + l15;
      const float b = g.bias[n];
      float m = 0.f;
#pragma unroll
      for (int mi = 0; mi < 4; ++mi)
#pragma unroll
        for (int r = 0; r < 4; ++r)
          m = fmaxf(m, acc[mi][ni][r] + b);
      m = fmaxf(m, 0.f);
      m = fmaxf(m, __shfl_xor(m, 16));
      m = fmaxf(m, __shfl_xor(m, 32));
      if (l4 == 0) g.outf[(size_t)((m0 >> 6) + wr) * HD + n] = m;
    }
  } else {
#pragma unroll
    for (int mi = 0; mi < 4; ++mi)
#pragma unroll
      for (int r = 0; r < 4; ++r) {
        const int row = m0 + wr * 64 + mi * 16 + l4 * 4 + r;
#pragma unroll
        for (int ni = 0; ni < 4; ++ni) {
          const int n = n0 + wc * 64 + ni * 16 + l15;
          const size_t oi = (size_t)row * HD + n;
          float v = acc[mi][ni][r];
          if (EP == EP_TANH) {
            g.outb[oi] = f2bf(tanhf(v + g.bias[n]));
          } else if (EP == EP_MERGE) {
            float gg = v + g.aux2[(size_t)(row >> 6) * HD + n];
            float sg = 1.f / (1.f + expf(-gg));
            float o1v = bf2f(g.aux0[oi]);
            float ock = bf2f(g.aux1[oi]);
            g.outb[oi] = f2bf(fmaf(sg, o1v - ock, ock));
          } else {  // EP_RELU
            g.outb[oi] = f2bf(fmaxf(v + g.bias[n], 0.f));
          }
        }
      }
  }
}

extern "C" void kernel_launch(void* const* d_in, const int* in_sizes, int n_in,
                              void* d_out, int out_size, void* d_ws, size_t ws_size,
                              hipStream_t stream) {
  const float* enc_o = (const float*)d_in[0];
  const float* enc_q = (const float*)d_in[1];
  const int* om = (const int*)d_in[2];
  const int* qm = (const int*)d_in[3];
  const float* att_W1_w = (const float*)d_in[4];
  const float* att_W1_b = (const float*)d_in[5];
  const float* att_W2_w = (const float*)d_in[6];
  const float* att_W2_b = (const float*)d_in[7];
  const float* att_W3 = (const float*)d_in[8];
  const float* Wc_self_w = (const float*)d_in[9];
  const float* Wc_self_b = (const float*)d_in[10];
  const float* Wc_w = (const float*)d_in[11];
  const float* Wc_b = (const float*)d_in[12];
  const float* Va_w = (const float*)d_in[13];
  const float* Va_b = (const float*)d_in[14];
  const float* Wg_w = (const float*)d_in[15];
  const float* Wg_b = (const float*)d_in[16];
  const float* co_W1_w = (const float*)d_in[17];
  const float* co_W1_b = (const float*)d_in[18];
  const float* co_W2_w = (const float*)d_in[19];
  const float* co_W2_b = (const float*)d_in[20];
  const float* co_W3 = (const float*)d_in[21];
  const float* Wp_w = (const float*)d_in[22];
  const float* Wp_b = (const float*)d_in[23];
  const float* sa_W1_w = (const float*)d_in[24];
  const float* sa_W1_b = (const float*)d_in[25];
  const float* sa_W2_w = (const float*)d_in[26];
  const float* sa_W2_b = (const float*)d_in[27];
  const float* sa_W3 = (const float*)d_in[28];
  const float* Wf_w = (const float*)d_in[29];
  const float* Wf_b = (const float*)d_in[30];
  float* out = (float*)d_out;

  const int NTOK_O = 16384;
  const int NTOK_Q = 32768;
  const int HH = 768 * 768;

  float* ws = (float*)d_ws;
  size_t off = 0;
  auto carve = [&](size_t n) { float* p = ws + off; off += n; return p; };
  float* s1o   = carve(16384);
  float* s2o   = carve(16384);
  float* qa    = carve(32768);
  float* qco1  = carve(32768);
  float* ms2   = carve(16384);
  float* sa1   = carve(16384);
  float* sa2   = carve(16384);
  float* biasO = carve(1024);
  float* Qpool = carve(196608);
  float* Qg    = carve(196608);
  float* A2buf = carve(2097152);
  float* r1 = carve(12582912);   // [-- | X1] -> [OPKb | X3]
  float* r2 = carve(12582912);   // [OCKb | X2] -> [PLOb | ..] -> opkw3
  float* r3 = carve(12582912);   // [MRGb | ..] -> [OSKb | X4]
  float* r4 = carve(12582912);   // [eobf | eow3] -> [PHIb | ..]
  unsigned short* wtb = (unsigned short*)carve(1179648);
  if (ws_size < off * sizeof(float)) return;
  unsigned short* OPKb  = (unsigned short*)r1;
  unsigned short* X1    = (unsigned short*)(r1 + 6291456);
  unsigned short* X3    = (unsigned short*)(r1 + 6291456);
  unsigned short* OCKb  = (unsigned short*)r2;
  unsigned short* PLOb  = (unsigned short*)r2;
  unsigned short* opkw3 = (unsigned short*)r2;
  unsigned short* X2    = (unsigned short*)(r2 + 6291456);
  unsigned short* MRGb  = (unsigned short*)r3;
  unsigned short* OSKb  = (unsigned short*)r3;
  unsigned short* X4    = (unsigned short*)(r3 + 6291456);
  unsigned short* eobf  = (unsigned short*)r4;
  unsigned short* eow3  = (unsigned short*)(r4 + 6291456);
  unsigned short* PHIb  = (unsigned short*)r4;
  unsigned short* PtG   = (unsigned short*)A2buf;

  const dim3 GBIG(128, 6);  // m-fast: contemporaneous blocks share the weight n-slice

  // 1. fused enc_o prep (eobf, eow3, s1o, s2o) + enc_q dots
  bfprep_dot_kernel<<<NTOK_O / 4, 256, 0, stream>>>(enc_o, att_W3, att_W1_w, att_W1_b,
                                                    att_W2_w, att_W2_b, eobf, eow3,
                                                    s1o, s2o, NTOK_O);
  dot768x2_f32<<<NTOK_Q / 4, 256, 0, stream>>>(enc_q, Va_w, Va_b,
                                               co_W1_w, co_W1_b, qa, qco1, NTOK_Q);
  bias_ock_kernel<<<3, 256, 0, stream>>>(Wc_self_b, Wc_b, biasO);

  // 2. pairwise option-compare: p1 + p2 (fused modeprep -> X1, X2)
  p1_kernel<3><<<768, 256, 0, stream>>>(eobf, eow3, s1o, s2o, om, PtG);
  p2_kernel<3><<<dim3(4, 256), 256, 0, stream>>>(eobf, PtG, eobf, nullptr, X1, X2);

  // 3. OCK = tanh([o1 | 3o1-CS | o1*CS] @ [Wc_self; Wc_hi; Wc_lo] + bias)
  {
    WcArgs wa{};
    wa.src[0] = Wc_self_w; wa.src[1] = Wc_w; wa.src[2] = Wc_w + HH;
    wa.dst = wtb; wa.Kw = 2304;
    wconv_kernel<<<dim3(144, 3), 256, 0, stream>>>(wa);
    MMArgs g{};
    g.a[0] = eobf; g.a[1] = X1; g.a[2] = X2;
    g.K = 2304; g.wt = wtb; g.bias = biasO; g.outb = OCKb;
    mfma_gemm_kernel<EP_TANH><<<GBIG, 256, 0, stream>>>(g);
  }

  // 4. question pooling + Qg (f32)
  qpool_kernel<<<256, 256, 0, stream>>>(enc_q, qa, qm, Qpool);
  {
    GemmArgs g{};
    g.a[0] = Qpool; g.w[0] = Wg_w + 2 * HH;
    g.nchunks = 1; g.bias = Wg_b; g.out = Qg;
    gemm_store_kernel<<<dim3(12, 4), 256, 0, stream>>>(g);
  }

  // 5. merged = G*o1 + (1-G)*OCK  (bf16 out)
  {
    WcArgs wa{};
    wa.src[0] = Wg_w; wa.src[1] = Wg_w + HH;
    wa.dst = wtb; wa.Kw = 1536;
    wconv_kernel<<<dim3(144, 2), 256, 0, stream>>>(wa);
    MMArgs g{};
    g.a[0] = eobf; g.a[1] = OCKb;
    g.K = 1536; g.wt = wtb; g.bias = nullptr;
    g.aux0 = eobf; g.aux1 = OCKb; g.aux2 = Qg; g.outb = MRGb;
    mfma_gemm_kernel<EP_MERGE><<<GBIG, 256, 0, stream>>>(g);
  }

  // 6. co-attention: ms2 -> A2 (split) -> poaa (split)
  dot768_bf16<<<NTOK_O / 4, 256, 0, stream>>>(MRGb, co_W2_w, co_W2_b, ms2, NTOK_O);
  a2_mfma_kernel<<<dim3(2, 256), 256, 0, stream>>>(enc_q, MRGb, qco1, ms2, qm, om, co_W3, A2buf);
  poaa_mfma_kernel<<<dim3(2, 256), 256, 0, stream>>>(A2buf, enc_q, MRGb, PLOb, PHIb);

  // 7. OPK = relu([merged | PLO | PHI] @ Wp + b)  (bf16 out)
  {
    WcArgs wa{};
    wa.src[0] = Wp_w; wa.src[1] = Wp_w + HH; wa.src[2] = Wp_w + 2 * HH;
    wa.dst = wtb; wa.Kw = 2304;
    wconv_kernel<<<dim3(144, 3), 256, 0, stream>>>(wa);
    MMArgs g{};
    g.a[0] = MRGb; g.a[1] = PLOb; g.a[2] = PHIb;
    g.K = 2304; g.wt = wtb; g.bias = Wp_b; g.outb = OPKb;
    mfma_gemm_kernel<EP_RELU><<<GBIG, 256, 0, stream>>>(g);
  }

  // 8. self-attention: fused OPK prep -> p1 -> p2 (fused -> OSK, X3, X4)
  opkprep_kernel<<<NTOK_O / 4, 256, 0, stream>>>(OPKb, sa_W3, sa_W1_w, sa_W1_b,
                                                 sa_W2_w, sa_W2_b, opkw3, sa1, sa2, NTOK_O);
  p1_kernel<1><<<256, 256, 0, stream>>>(OPKb, opkw3, sa1, sa2, om, PtG);
  p2_kernel<1><<<dim3(4, 256), 256, 0, stream>>>(OPKb, PtG, OPKb, OSKb, X3, X4);

  // 9. out = max_lo relu([OPK | OSK | OPK-OSK | OPK*OSK] @ Wf + b)  (f32 out)
  {
    WcArgs wa{};
    wa.src[0] = Wf_w; wa.src[1] = Wf_w + HH; wa.src[2] = Wf_w + 2 * HH; wa.src[3] = Wf_w + 3 * HH;
    wa.dst = wtb; wa.Kw = 3072;
    wconv_kernel<<<dim3(144, 4), 256, 0, stream>>>(wa);
    MMArgs g{};
    g.a[0] = OPKb; g.a[1] = OSKb; g.a[2] = X3; g.a[3] = X4;
    g.K = 3072; g.wt = wtb; g.bias = Wf_b; g.outf = out;
    mfma_gemm_kernel<EP_RELU_MAX><<<GBIG, 256, 0, stream>>>(g);
  }
}

// Round 10
// 609.409 us; speedup vs baseline: 8.9726x; 1.0169x over previous
//
#include <hip/hip_runtime.h>
#include <math.h>

// OptionCompareCell: B=64,C=4,LO=64,LQ=128,H=768
// Round 10:
//  (1) a2 fused into poaa phase-0 (A2 never materialized; Aq/Bm staged in T's
//      LDS region, T written after barrier)
//  (2) qpool2: Va/co_W1 dots fused into qpool (one enc_q pass saved)
//  (3) wconv_all: all 12 weight slices converted once into [768][9216] bf16
//      living in r4's second half (GEMMs use kstride=9216)
//  (4) s_setprio(1/0) around GEMM MFMA cluster (T5 probe)
// GEMM core (3-deep counted-vmcnt pipeline + swizzle, 0 conflicts) unchanged.

#define NEGC (-10000.0f)
constexpr int HD = 768;
constexpr int KSTR = 9216;   // combined weight K-stride

constexpr int EP_TANH = 1;
constexpr int EP_MERGE = 2;
constexpr int EP_RELU = 3;
constexpr int EP_RELU_MAX = 4;

typedef __attribute__((ext_vector_type(8))) short bf16x8;
typedef __attribute__((ext_vector_type(8))) unsigned short u16x8;
typedef __attribute__((ext_vector_type(4))) unsigned short u16x4;
typedef __attribute__((ext_vector_type(4))) float f32x4;

__device__ inline void st8(float* dst, float4 a0, float4 a1) {
  dst[0] = a0.x; dst[1] = a0.y; dst[2] = a0.z; dst[3] = a0.w;
  dst[4] = a1.x; dst[5] = a1.y; dst[6] = a1.z; dst[7] = a1.w;
}

__device__ inline unsigned short f2bf(float x) {
  unsigned int u = __float_as_uint(x);
  u += 0x7fffu + ((u >> 16) & 1u);
  return (unsigned short)(u >> 16);
}

__device__ inline float bf2f(unsigned short u) {
  return __uint_as_float(((unsigned int)u) << 16);
}

__device__ inline u16x8 pack8(float4 a, float4 b) {
  u16x8 r;
  r[0] = f2bf(a.x); r[1] = f2bf(a.y); r[2] = f2bf(a.z); r[3] = f2bf(a.w);
  r[4] = f2bf(b.x); r[5] = f2bf(b.y); r[6] = f2bf(b.z); r[7] = f2bf(b.w);
  return r;
}

__device__ inline u16x4 pack4(float4 a) {
  u16x4 r;
  r[0] = f2bf(a.x); r[1] = f2bf(a.y); r[2] = f2bf(a.z); r[3] = f2bf(a.w);
  return r;
}

__device__ inline void gload_lds16(const unsigned short* src, unsigned short* dst) {
  __builtin_amdgcn_global_load_lds(
      (const __attribute__((address_space(1))) void*)src,
      (__attribute__((address_space(3))) void*)dst, 16, 0, 0);
}

// ---------------- fused enc_o prep: eobf, eow3, s1o, s2o in one pass ----------------
__global__ __launch_bounds__(256)
void bfprep_dot_kernel(const float* __restrict__ x, const float* __restrict__ w3,
                       const float* __restrict__ w1, const float* __restrict__ b1,
                       const float* __restrict__ w2, const float* __restrict__ b2,
                       unsigned short* __restrict__ xbf, unsigned short* __restrict__ xw3,
                       float* __restrict__ o1, float* __restrict__ o2, int ntok) {
  int tok = blockIdx.x * 4 + (threadIdx.x >> 6);
  int lane = threadIdx.x & 63;
  if (tok >= ntok) return;
  const float* xp = x + (size_t)tok * HD;
  unsigned short* xb = xbf + (size_t)tok * HD;
  unsigned short* xw = xw3 + (size_t)tok * HD;
  float s1 = 0.f, s2 = 0.f;
#pragma unroll
  for (int i = 0; i < 3; ++i) {
    int c = (lane + (i << 6)) << 2;
    float4 xv = *(const float4*)(xp + c);
    float4 w3v = *(const float4*)(w3 + c);
    float4 wa = *(const float4*)(w1 + c);
    float4 wb = *(const float4*)(w2 + c);
    s1 = fmaf(xv.x, wa.x, s1); s1 = fmaf(xv.y, wa.y, s1);
    s1 = fmaf(xv.z, wa.z, s1); s1 = fmaf(xv.w, wa.w, s1);
    s2 = fmaf(xv.x, wb.x, s2); s2 = fmaf(xv.y, wb.y, s2);
    s2 = fmaf(xv.z, wb.z, s2); s2 = fmaf(xv.w, wb.w, s2);
    *(u16x4*)(xb + c) = pack4(xv);
    float4 sv;
    sv.x = xv.x * w3v.x; sv.y = xv.y * w3v.y; sv.z = xv.z * w3v.z; sv.w = xv.w * w3v.w;
    *(u16x4*)(xw + c) = pack4(sv);
  }
#pragma unroll
  for (int off = 32; off; off >>= 1) {
    s1 += __shfl_xor(s1, off);
    s2 += __shfl_xor(s2, off);
  }
  if (lane == 0) { o1[tok] = s1 + b1[0]; o2[tok] = s2 + b2[0]; }
}

// ---------------- fused OPK prep: opkw3, sa1, sa2 in one pass ----------------
__global__ __launch_bounds__(256)
void opkprep_kernel(const unsigned short* __restrict__ x, const float* __restrict__ w3,
                    const float* __restrict__ w1, const float* __restrict__ b1,
                    const float* __restrict__ w2, const float* __restrict__ b2,
                    unsigned short* __restrict__ xw3,
                    float* __restrict__ o1, float* __restrict__ o2, int ntok) {
  int tok = blockIdx.x * 4 + (threadIdx.x >> 6);
  int lane = threadIdx.x & 63;
  if (tok >= ntok) return;
  const unsigned short* xp = x + (size_t)tok * HD;
  unsigned short* xw = xw3 + (size_t)tok * HD;
  float s1 = 0.f, s2 = 0.f;
#pragma unroll
  for (int i = 0; i < 3; ++i) {
    int c = (lane + (i << 6)) << 2;
    u16x4 xv = *(const u16x4*)(xp + c);
    float x0 = bf2f(xv[0]), x1 = bf2f(xv[1]), x2 = bf2f(xv[2]), x3 = bf2f(xv[3]);
    float4 w3v = *(const float4*)(w3 + c);
    float4 wa = *(const float4*)(w1 + c);
    float4 wb = *(const float4*)(w2 + c);
    s1 = fmaf(x0, wa.x, s1); s1 = fmaf(x1, wa.y, s1);
    s1 = fmaf(x2, wa.z, s1); s1 = fmaf(x3, wa.w, s1);
    s2 = fmaf(x0, wb.x, s2); s2 = fmaf(x1, wb.y, s2);
    s2 = fmaf(x2, wb.z, s2); s2 = fmaf(x3, wb.w, s2);
    u16x4 sv;
    sv[0] = f2bf(x0 * w3v.x); sv[1] = f2bf(x1 * w3v.y);
    sv[2] = f2bf(x2 * w3v.z); sv[3] = f2bf(x3 * w3v.w);
    *(u16x4*)(xw + c) = sv;
  }
#pragma unroll
  for (int off = 32; off; off >>= 1) {
    s1 += __shfl_xor(s1, off);
    s2 += __shfl_xor(s2, off);
  }
  if (lane == 0) { o1[tok] = s1 + b1[0]; o2[tok] = s2 + b2[0]; }
}

__global__ __launch_bounds__(256)
void dot768_bf16(const unsigned short* __restrict__ x,
                 const float* __restrict__ w1, const float* __restrict__ b1,
                 float* __restrict__ o1, int ntok) {
  int tok = blockIdx.x * 4 + (threadIdx.x >> 6);
  int lane = threadIdx.x & 63;
  if (tok >= ntok) return;
  const unsigned short* xp = x + (size_t)tok * HD;
  float s1 = 0.f;
#pragma unroll
  for (int i = 0; i < 3; ++i) {
    int c = (lane + (i << 6)) << 2;
    u16x4 xv = *(const u16x4*)(xp + c);
    float4 wa = *(const float4*)(w1 + c);
    s1 = fmaf(bf2f(xv[0]), wa.x, s1); s1 = fmaf(bf2f(xv[1]), wa.y, s1);
    s1 = fmaf(bf2f(xv[2]), wa.z, s1); s1 = fmaf(bf2f(xv[3]), wa.w, s1);
  }
#pragma unroll
  for (int off = 32; off; off >>= 1) s1 += __shfl_xor(s1, off);
  if (lane == 0) o1[tok] = s1 + b1[0];
}

__global__ void bias_ock_kernel(const float* __restrict__ b1, const float* __restrict__ b2,
                                float* __restrict__ o) {
  int n = blockIdx.x * 256 + threadIdx.x;
  if (n < HD) o[n] = b1[n] + 3.f * b2[n];
}

// ---- qpool2: per bc, fused Va/co_W1 dots + masked softmax + pooled Q ----
__global__ __launch_bounds__(256)
void qpool2_kernel(const float* __restrict__ q,
                   const float* __restrict__ Va_w, const float* __restrict__ Va_b,
                   const float* __restrict__ coW1_w, const float* __restrict__ coW1_b,
                   const int* __restrict__ qm,
                   float* __restrict__ qco1, float* __restrict__ Q) {
  __shared__ float qa_s[128];
  __shared__ float wgt[128];
  __shared__ float wred[4];
  const int t = threadIdx.x, bc = blockIdx.x;
  const int lane = t & 63, wv = t >> 6;
  const float* qb = q + (size_t)bc * (128 * HD);
  for (int it = 0; it < 32; ++it) {
    const int tl = it * 4 + wv;
    const float* xp = qb + (size_t)tl * HD;
    float s1 = 0.f, s2 = 0.f;
#pragma unroll
    for (int i = 0; i < 3; ++i) {
      int c = (lane + (i << 6)) << 2;
      float4 xv = *(const float4*)(xp + c);
      float4 wa = *(const float4*)(Va_w + c);
      float4 wb = *(const float4*)(coW1_w + c);
      s1 = fmaf(xv.x, wa.x, s1); s1 = fmaf(xv.y, wa.y, s1);
      s1 = fmaf(xv.z, wa.z, s1); s1 = fmaf(xv.w, wa.w, s1);
      s2 = fmaf(xv.x, wb.x, s2); s2 = fmaf(xv.y, wb.y, s2);
      s2 = fmaf(xv.z, wb.z, s2); s2 = fmaf(xv.w, wb.w, s2);
    }
#pragma unroll
    for (int off = 32; off; off >>= 1) {
      s1 += __shfl_xor(s1, off);
      s2 += __shfl_xor(s2, off);
    }
    if (lane == 0) {
      qa_s[tl] = s1 + Va_b[0];
      qco1[bc * 128 + tl] = s2 + coW1_b[0];
    }
  }
  __syncthreads();
  const int* qmp = qm + bc * 128;
  float v = -1e30f;
  if (t < 128) v = qa_s[t] + (1.f - (float)qmp[t]) * NEGC;
  float m = v;
#pragma unroll
  for (int off = 32; off; off >>= 1) m = fmaxf(m, __shfl_xor(m, off));
  if ((t & 63) == 0) wred[t >> 6] = m;
  __syncthreads();
  float gm = fmaxf(fmaxf(wred[0], wred[1]), fmaxf(wred[2], wred[3]));
  float e = (t < 128) ? expf(v - gm) : 0.f;
  float s = e;
#pragma unroll
  for (int off = 32; off; off >>= 1) s += __shfl_xor(s, off);
  __syncthreads();
  if ((t & 63) == 0) wred[t >> 6] = s;
  __syncthreads();
  float tot = wred[0] + wred[1] + wred[2] + wred[3];
  if (t < 128) wgt[t] = e / tot;
  __syncthreads();
  float* Qp = Q + (size_t)bc * HD;
  for (int d = t; d < HD; d += 256) {
    float acc = 0.f;
    for (int l = 0; l < 128; ++l) acc = fmaf(wgt[l], qb[(size_t)l * HD + d], acc);
    Qp[d] = acc;
  }
}

// ---------------- P1: S = U . Vw3^T (MFMA), softmax over u, write Pt[v][u] bf16 ----------------
template<int NJ>
__global__ __launch_bounds__(256)
void p1_kernel(const unsigned short* __restrict__ Xbf, const unsigned short* __restrict__ Xw3,
               const float* __restrict__ s1g, const float* __restrict__ s2g,
               const int* __restrict__ maskg, unsigned short* __restrict__ PtG) {
  __shared__ __align__(16) unsigned short Ua[64 * 136];
  __shared__ __align__(16) unsigned short Vb[64 * 136];
  __shared__ float Sbuf[64][66];
  __shared__ float red[4][64];
  const int t = threadIdx.x;
  int ubc, vbc;
  if (NJ == 1) {
    ubc = vbc = blockIdx.x;
  } else {
    const int b = blockIdx.x / 12, pr = blockIdx.x % 12;
    const int i = pr / 3, jj = pr % 3;
    const int j = jj + (jj >= i ? 1 : 0);
    vbc = (b << 2) + i; ubc = (b << 2) + j;
  }
  const unsigned short* U = Xbf + (size_t)ubc * (64 * HD);
  const unsigned short* V = Xw3 + (size_t)vbc * (64 * HD);
  const int w = t >> 6, lane = t & 63, l15 = lane & 15, l4 = lane >> 4;
  const int srow = t >> 2, scol = (t & 3) << 5;
  f32x4 acc[4] = {};
  for (int k0 = 0; k0 < HD; k0 += 128) {
    const unsigned short* up = U + (size_t)srow * HD + k0 + scol;
    const unsigned short* vp = V + (size_t)srow * HD + k0 + scol;
    unsigned short* ua = &Ua[srow * 136 + scol];
    unsigned short* vb = &Vb[srow * 136 + scol];
#pragma unroll
    for (int z = 0; z < 4; ++z) {
      *(u16x8*)(ua + z * 8) = *(const u16x8*)(up + z * 8);
      *(u16x8*)(vb + z * 8) = *(const u16x8*)(vp + z * 8);
    }
    __syncthreads();
#pragma unroll
    for (int ks = 0; ks < 4; ++ks) {
      bf16x8 af = *(const bf16x8*)(&Ua[(w * 16 + l15) * 136 + ks * 32 + l4 * 8]);
#pragma unroll
      for (int n = 0; n < 4; ++n) {
        bf16x8 bf = *(const bf16x8*)(&Vb[(n * 16 + l15) * 136 + ks * 32 + l4 * 8]);
        acc[n] = __builtin_amdgcn_mfma_f32_16x16x32_bf16(af, bf, acc[n], 0, 0, 0);
      }
    }
    __syncthreads();
  }
  {
    float s1v[4];
#pragma unroll
    for (int r = 0; r < 4; ++r) {
      int u = w * 16 + l4 * 4 + r;
      s1v[r] = s1g[ubc * 64 + u] + (1.f - (float)maskg[ubc * 64 + u]) * NEGC;
    }
#pragma unroll
    for (int n = 0; n < 4; ++n) {
      int v = n * 16 + l15;
      float s2v = s2g[vbc * 64 + v] + (1.f - (float)maskg[vbc * 64 + v]) * NEGC;
#pragma unroll
      for (int r = 0; r < 4; ++r)
        Sbuf[w * 16 + l4 * 4 + r][v] = acc[n][r] + s1v[r] + s2v;
    }
  }
  __syncthreads();
  {
    const int v = t & 63, part = t >> 6;
    float m = -1e30f;
#pragma unroll
    for (int z = 0; z < 16; ++z) m = fmaxf(m, Sbuf[part * 16 + z][v]);
    red[part][v] = m;
    __syncthreads();
    float gm = fmaxf(fmaxf(red[0][v], red[1][v]), fmaxf(red[2][v], red[3][v]));
    float s = 0.f;
#pragma unroll
    for (int z = 0; z < 16; ++z) {
      float e = expf(Sbuf[part * 16 + z][v] - gm);
      Sbuf[part * 16 + z][v] = e;
      s += e;
    }
    __syncthreads();
    red[part][v] = s;
    __syncthreads();
    float cinv = 1.f / (red[0][v] + red[1][v] + red[2][v] + red[3][v]);
    unsigned short* pt = PtG + (size_t)blockIdx.x * 4096 + v * 64 + part * 16;
#pragma unroll
    for (int z = 0; z < 16; ++z) pt[z] = f2bf(Sbuf[part * 16 + z][v] * cinv);
  }
}

// ---- P2: ctx = sum_j Pt_j . U_j ; fused epilogue: NJ=3 -> X1,X2 ; NJ=1 -> OSK,X3,X4 ----
template<int NJ>
__global__ __launch_bounds__(256)
void p2_kernel(const unsigned short* __restrict__ Xbf, const unsigned short* __restrict__ PtG,
               const unsigned short* __restrict__ Oi,
               unsigned short* __restrict__ osk,
               unsigned short* __restrict__ y1, unsigned short* __restrict__ y2) {
  __shared__ __align__(16) unsigned short Pts[NJ][64 * 72];
  __shared__ __align__(16) unsigned short U2[64 * 192];
  const int t = threadIdx.x;
  const int dq = blockIdx.x, bc = blockIdx.y;
  const int d0 = dq * 192;
  const int b = bc >> 2, i = bc & 3;
  const int w = t >> 6, lane = t & 63, l15 = lane & 15, l4 = lane >> 4;
  {
    const int v = t >> 2, cs = (t & 3) << 4;
#pragma unroll
    for (int jj = 0; jj < NJ; ++jj) {
      size_t src = (NJ == 1 ? (size_t)bc : (size_t)(b * 12 + i * 3 + jj)) * 4096 + v * 64 + cs;
      *(u16x8*)(&Pts[jj][v * 72 + cs]) = *(const u16x8*)(PtG + src);
      *(u16x8*)(&Pts[jj][v * 72 + cs + 8]) = *(const u16x8*)(PtG + src + 8);
    }
  }
  f32x4 acc[4][3] = {};
  const int su = t >> 2, sc0 = (t & 3) * 48;
  const int sswz = ((su >> 3) & 3) << 5;
  for (int jj = 0; jj < NJ; ++jj) {
    const int ubc = (NJ == 1) ? bc : ((b << 2) + (jj + (jj >= i ? 1 : 0)));
    __syncthreads();
    {
      const unsigned short* up = Xbf + (size_t)ubc * (64 * HD) + (size_t)su * HD + d0 + sc0;
#pragma unroll
      for (int it = 0; it < 6; ++it) {
        u16x8 vdat = *(const u16x8*)(up + it * 8);
        *(u16x8*)((char*)U2 + ((su * 384 + (sc0 + it * 8) * 2) ^ sswz)) = vdat;
      }
    }
    __syncthreads();
    const unsigned short* ptj = &Pts[jj][0];
#pragma unroll
    for (int ks = 0; ks < 2; ++ks) {
      bf16x8 bfr[3];
#pragma unroll
      for (int n = 0; n < 3; ++n) {
        const int col = (w * 3 + n) * 16 + l15;
#pragma unroll
        for (int e = 0; e < 8; ++e) {
          const int uk = ks * 32 + l4 * 8 + e;
          const int byte = (uk * 384 + col * 2) ^ (((uk >> 3) & 3) << 5);
          bfr[n][e] = *(const short*)((const char*)U2 + byte);
        }
      }
#pragma unroll
      for (int m = 0; m < 4; ++m) {
        bf16x8 af = *(const bf16x8*)(ptj + (m * 16 + l15) * 72 + ks * 32 + l4 * 8);
#pragma unroll
        for (int n = 0; n < 3; ++n)
          acc[m][n] = __builtin_amdgcn_mfma_f32_16x16x32_bf16(af, bfr[n], acc[m][n], 0, 0, 0);
      }
    }
  }
  const unsigned short* oip = Oi + (size_t)bc * (64 * HD);
  const size_t obase = (size_t)bc * (64 * HD);
#pragma unroll
  for (int m = 0; m < 4; ++m)
#pragma unroll
    for (int n = 0; n < 3; ++n) {
      const int d = d0 + (w * 3 + n) * 16 + l15;
#pragma unroll
      for (int r = 0; r < 4; ++r) {
        const int v = m * 16 + l4 * 4 + r;
        const size_t idx = obase + (size_t)v * HD + d;
        const float cs = acc[m][n][r];
        const float oi = bf2f(oip[(size_t)v * HD + d]);
        if (NJ == 3) {
          y1[idx] = f2bf(fmaf(3.f, oi, -cs));
          y2[idx] = f2bf(oi * cs);
        } else {
          osk[idx] = f2bf(cs);
          y1[idx] = f2bf(oi - cs);
          y2[idx] = f2bf(oi * cs);
        }
      }
    }
}

// ---- POAA fused with A2: phase0 computes A2 via MFMA into T, then stats + chunks ----
__global__ __launch_bounds__(256)
void poaa2_kernel(const float* __restrict__ qin, const unsigned short* __restrict__ mergedb,
                  const float* __restrict__ qco1, const float* __restrict__ ms2,
                  const int* __restrict__ qm, const int* __restrict__ om,
                  const float* __restrict__ w3,
                  unsigned short* __restrict__ PLO, unsigned short* __restrict__ PHI) {
  __shared__ __align__(16) char smem[77312];
  __shared__ float red[4][64];
  __shared__ float rowm[128], rowfac[128];
  __shared__ float colfac[64];
  __shared__ float gmax_s;
  float* T = (float*)smem;                                   // [128][65] f32
  unsigned short* Aq = (unsigned short*)smem;                 // [128][72] (phase0)
  unsigned short* Bm = (unsigned short*)(smem + 18432);       // [64][72]  (phase0)
  unsigned short* Tt = (unsigned short*)(smem + 33280);       // [64][136]
  unsigned short* Tft = (unsigned short*)(smem + 50688);      // [64][136]
  unsigned short* M2bf = (unsigned short*)(smem + 68096);     // [64][72]
  unsigned short* Qc = (unsigned short*)smem;                 // [128][72] (chunk phase)
  unsigned short* Mc = (unsigned short*)(smem + 18432);       // [64][72]

  const int t = threadIdx.x, dqh = blockIdx.x, bc = blockIdx.y;
  const int w = t >> 6, lane = t & 63, l15 = lane & 15, l4 = lane >> 4;
  const float* qp = qin + (size_t)bc * (128 * HD);
  const unsigned short* mp = mergedb + (size_t)bc * (64 * HD);
  const float* qc = qco1 + bc * 128;
  const int* qmp = qm + bc * 128;
  const float* msp = ms2 + bc * 64;
  const int* omp = om + bc * 64;

  // ---- phase 0: A2 = (q*w3).merged^T via MFMA (round-5-verified tile) ----
  {
    const int arow = t >> 1, acs = (t & 1) << 5;
    const int brow = t >> 2, bcs = (t & 3) << 4;
    f32x4 acc[2][4] = {};
    for (int k0 = 0; k0 < HD; k0 += 64) {
      {
        const float* p = qp + (size_t)arow * HD + k0 + acs;
        const float* wp = w3 + k0 + acs;
        unsigned short* dst = &Aq[arow * 72 + acs];
#pragma unroll
        for (int z = 0; z < 4; ++z) {
          float4 a = *(const float4*)(p + z * 8);
          float4 b = *(const float4*)(p + z * 8 + 4);
          float4 wa = *(const float4*)(wp + z * 8);
          float4 wb = *(const float4*)(wp + z * 8 + 4);
          a.x *= wa.x; a.y *= wa.y; a.z *= wa.z; a.w *= wa.w;
          b.x *= wb.x; b.y *= wb.y; b.z *= wb.z; b.w *= wb.w;
          *(u16x8*)(dst + z * 8) = pack8(a, b);
        }
      }
      {
        const unsigned short* p = mp + (size_t)brow * HD + k0 + bcs;
        unsigned short* dst = &Bm[brow * 72 + bcs];
        *(u16x8*)(dst) = *(const u16x8*)(p);
        *(u16x8*)(dst + 8) = *(const u16x8*)(p + 8);
      }
      __syncthreads();
#pragma unroll
      for (int ks = 0; ks < 2; ++ks) {
        bf16x8 af[2], bf[4];
#pragma unroll
        for (int m = 0; m < 2; ++m)
          af[m] = *(const bf16x8*)(&Aq[(w * 32 + m * 16 + l15) * 72 + ks * 32 + l4 * 8]);
#pragma unroll
        for (int n = 0; n < 4; ++n)
          bf[n] = *(const bf16x8*)(&Bm[(n * 16 + l15) * 72 + ks * 32 + l4 * 8]);
#pragma unroll
        for (int m = 0; m < 2; ++m)
#pragma unroll
          for (int n = 0; n < 4; ++n)
            acc[m][n] = __builtin_amdgcn_mfma_f32_16x16x32_bf16(af[m], bf[n], acc[m][n], 0, 0, 0);
      }
      __syncthreads();
    }
    // write T (overwrites Aq/Bm region; all reads completed at loop-end barrier)
#pragma unroll
    for (int n = 0; n < 4; ++n) {
      const int v = n * 16 + l15;
      const float ct = msp[v] + (1.f - (float)omp[v]) * NEGC;
#pragma unroll
      for (int m = 0; m < 2; ++m)
#pragma unroll
        for (int r = 0; r < 4; ++r) {
          const int qrow = w * 32 + m * 16 + l4 * 4 + r;
          const float rt = qc[qrow] + (1.f - (float)qmp[qrow]) * NEGC;
          T[qrow * 65 + v] = acc[m][n][r] + rt + ct;
        }
    }
  }
  __syncthreads();
  // ---- stats (unchanged) ----
  {
    int qrow = t >> 1, h = t & 1;
    float m = -1e30f;
    for (int v = h * 32; v < h * 32 + 32; ++v) m = fmaxf(m, T[qrow * 65 + v]);
    m = fmaxf(m, __shfl_xor(m, 1));
    float s = 0.f;
    for (int v = h * 32; v < h * 32 + 32; ++v) s += expf(T[qrow * 65 + v] - m);
    s += __shfl_xor(s, 1);
    if (h == 0) { rowm[qrow] = m; rowfac[qrow] = s; }
  }
  float colm_loc = 0.f;
  {
    int v = t & 63, part = t >> 6;
    float m = -1e30f;
    for (int qq = part * 32; qq < part * 32 + 32; ++qq) m = fmaxf(m, T[qq * 65 + v]);
    red[part][v] = m;
    __syncthreads();
    float cm = fmaxf(fmaxf(red[0][v], red[1][v]), fmaxf(red[2][v], red[3][v]));
    float s = 0.f;
    for (int qq = part * 32; qq < part * 32 + 32; ++qq) s += expf(T[qq * 65 + v] - cm);
    __syncthreads();
    red[part][v] = s;
    __syncthreads();
    if (part == 0) { colm_loc = cm; colfac[v] = red[0][v] + red[1][v] + red[2][v] + red[3][v]; }
  }
  __syncthreads();
  if (t < 64) {
    float m = fmaxf(rowm[t], rowm[t + 64]);
#pragma unroll
    for (int off = 32; off; off >>= 1) m = fmaxf(m, __shfl_xor(m, off));
    if (t == 0) gmax_s = m;
  }
  __syncthreads();
  const float gmax = gmax_s;
  if (t < 128) rowfac[t] = expf(fminf(gmax - rowm[t], 60.f)) / rowfac[t];
  if (t < 64) colfac[t] = expf(fminf(gmax - colm_loc, 60.f)) / colfac[t];
  __syncthreads();
  {
    const int o = t >> 2, qs = (t & 3) << 5;
    for (int z = 0; z < 32; ++z) {
      const int qq = qs + z;
      float e = expf(T[qq * 65 + o] - gmax);
      Tt[o * 136 + qq] = f2bf(e);
      Tft[o * 136 + qq] = f2bf(e * rowfac[qq]);
    }
  }
  __syncthreads();
  {
    f32x4 m2acc[4] = {};
#pragma unroll
    for (int ks = 0; ks < 4; ++ks) {
      bf16x8 af = *(const bf16x8*)(&Tt[(w * 16 + l15) * 136 + ks * 32 + l4 * 8]);
#pragma unroll
      for (int n = 0; n < 4; ++n) {
        bf16x8 bf = *(const bf16x8*)(&Tft[(n * 16 + l15) * 136 + ks * 32 + l4 * 8]);
        m2acc[n] = __builtin_amdgcn_mfma_f32_16x16x32_bf16(af, bf, m2acc[n], 0, 0, 0);
      }
    }
#pragma unroll
    for (int n = 0; n < 4; ++n)
#pragma unroll
      for (int r = 0; r < 4; ++r) {
        const int o = w * 16 + l4 * 4 + r;
        M2bf[o * 72 + n * 16 + l15] = f2bf(colfac[o] * m2acc[n][r]);
      }
  }
  // ---- chunk phase (d-half dqh) ----
  const int dql = t >> 1, dqs = (t & 1) << 5;
  const int dml = t >> 2, dms = (t & 3) << 4;
  const int swq = ((dql >> 3) & 3) << 5;
  const int swm = ((dml >> 3) & 3) << 5;
  unsigned short* plo = PLO + (size_t)bc * (64 * HD);
  unsigned short* phi = PHI + (size_t)bc * (64 * HD);
  for (int dc = dqh * 6; dc < dqh * 6 + 6; ++dc) {
    const int d0 = dc * 64;
    __syncthreads();
    {
      const float* p = qp + (size_t)dql * HD + d0 + dqs;
#pragma unroll
      for (int z = 0; z < 4; ++z) {
        float4 a = *(const float4*)(p + z * 8);
        float4 b = *(const float4*)(p + z * 8 + 4);
        *(u16x8*)((char*)Qc + ((dql * 144 + (dqs + z * 8) * 2) ^ swq)) = pack8(a, b);
      }
    }
    {
      const unsigned short* p = mp + (size_t)dml * HD + d0 + dms;
      *(u16x8*)((char*)Mc + ((dml * 144 + dms * 2) ^ swm)) = *(const u16x8*)p;
      *(u16x8*)((char*)Mc + ((dml * 144 + (dms + 8) * 2) ^ swm)) = *(const u16x8*)(p + 8);
    }
    __syncthreads();
    const int col = w * 16 + l15;
    f32x4 lacc[4] = {};
#pragma unroll
    for (int ks = 0; ks < 4; ++ks) {
      bf16x8 bf;
#pragma unroll
      for (int e = 0; e < 8; ++e) {
        const int qq = ks * 32 + l4 * 8 + e;
        bf[e] = *(const short*)((const char*)Qc + ((qq * 144 + col * 2) ^ (((qq >> 3) & 3) << 5)));
      }
#pragma unroll
      for (int m = 0; m < 4; ++m) {
        bf16x8 af = *(const bf16x8*)(&Tt[(m * 16 + l15) * 136 + ks * 32 + l4 * 8]);
        lacc[m] = __builtin_amdgcn_mfma_f32_16x16x32_bf16(af, bf, lacc[m], 0, 0, 0);
      }
    }
    f32x4 pacc[4] = {};
#pragma unroll
    for (int ks = 0; ks < 2; ++ks) {
      bf16x8 bf;
#pragma unroll
      for (int e = 0; e < 8; ++e) {
        const int vv = ks * 32 + l4 * 8 + e;
        bf[e] = *(const short*)((const char*)Mc + ((vv * 144 + col * 2) ^ (((vv >> 3) & 3) << 5)));
      }
#pragma unroll
      for (int m = 0; m < 4; ++m) {
        bf16x8 af = *(const bf16x8*)(&M2bf[(m * 16 + l15) * 72 + ks * 32 + l4 * 8]);
        pacc[m] = __builtin_amdgcn_mfma_f32_16x16x32_bf16(af, bf, pacc[m], 0, 0, 0);
      }
    }
#pragma unroll
    for (int m = 0; m < 4; ++m)
#pragma unroll
      for (int r = 0; r < 4; ++r) {
        const int o = m * 16 + l4 * 4 + r;
        const int d = d0 + w * 16 + l15;
        plo[(size_t)o * HD + d] = f2bf(colfac[o] * lacc[m][r]);
        phi[(size_t)o * HD + d] = f2bf(pacc[m][r]);
      }
  }
}

// ---------------- small f32 GEMM (Qg only) ----------------
struct GemmArgs {
  const float* a[4];
  const float* w[4];
  int nchunks;
  const float* bias;
  float* out;
};

__global__ __launch_bounds__(256)
void gemm_store_kernel(GemmArgs g) {
  __shared__ float As[64][33];
  __shared__ float Ws[32][65];
  const int t = threadIdx.x;
  const int m0 = blockIdx.y << 6, n0 = blockIdx.x << 6;
  const int tr = t >> 4, tc = t & 15;
  float acc[4][4];
#pragma unroll
  for (int x = 0; x < 4; ++x)
#pragma unroll
    for (int y = 0; y < 4; ++y) acc[x][y] = 0.f;
  const int arow = t >> 2, acs = (t & 3) << 3;
  const int wrow = t >> 3, wcs = (t & 7) << 3;
  for (int c = 0; c < g.nchunks; ++c) {
    const float* Ap = g.a[c] + (size_t)(m0 + arow) * HD + acs;
    const float* Wp = g.w[c] + (size_t)wrow * HD + n0 + wcs;
    for (int k0 = 0; k0 < HD; k0 += 32) {
      float4 a0 = *(const float4*)(Ap + k0);
      float4 a1 = *(const float4*)(Ap + k0 + 4);
      st8(&As[arow][acs], a0, a1);
      float4 w0 = *(const float4*)(Wp + (size_t)k0 * HD);
      float4 w1 = *(const float4*)(Wp + (size_t)k0 * HD + 4);
      st8(&Ws[wrow][wcs], w0, w1);
      __syncthreads();
#pragma unroll
      for (int kk = 0; kk < 32; ++kk) {
        float av[4], bv[4];
#pragma unroll
        for (int x = 0; x < 4; ++x) av[x] = As[(tr << 2) + x][kk];
#pragma unroll
        for (int y = 0; y < 4; ++y) bv[y] = Ws[kk][(tc << 2) + y];
#pragma unroll
        for (int x = 0; x < 4; ++x)
#pragma unroll
          for (int y = 0; y < 4; ++y) acc[x][y] = fmaf(av[x], bv[y], acc[x][y]);
      }
      __syncthreads();
    }
  }
#pragma unroll
  for (int x = 0; x < 4; ++x) {
    const int r = m0 + (tr << 2) + x;
#pragma unroll
    for (int y = 0; y < 4; ++y) {
      const int n = n0 + (tc << 2) + y;
      g.out[(size_t)r * HD + n] = acc[x][y] + g.bias[n];
    }
  }
}

// ---------------- wconv_all: 12 weight slices -> wall[768][9216] bf16 ----------------
struct WcAllArgs {
  const float* src[12];
  int basecol[12];
  unsigned short* dst;
};

__global__ __launch_bounds__(256)
void wconv_all_kernel(WcAllArgs g) {
  __shared__ float tile[64][65];
  const int slice = blockIdx.y;
  const float* src = g.src[slice];
  const int bi = blockIdx.x % 12, bj = blockIdx.x / 12;
  const int t = threadIdx.x;
  const int r = t >> 2, cseg = (t & 3) << 4;
  const float* p = src + (size_t)(bi * 64 + r) * HD + bj * 64 + cseg;
#pragma unroll
  for (int j = 0; j < 16; j += 4) {
    float4 v = *(const float4*)(p + j);
    tile[r][cseg + j + 0] = v.x; tile[r][cseg + j + 1] = v.y;
    tile[r][cseg + j + 2] = v.z; tile[r][cseg + j + 3] = v.w;
  }
  __syncthreads();
  unsigned short* q = g.dst + (size_t)(bj * 64 + r) * KSTR + g.basecol[slice] + bi * 64 + cseg;
  u16x8 lo, hi;
#pragma unroll
  for (int j = 0; j < 8; ++j) lo[j] = f2bf(tile[cseg + j][r]);
#pragma unroll
  for (int j = 0; j < 8; ++j) hi[j] = f2bf(tile[cseg + 8 + j][r]);
  *(u16x8*)q = lo;
  *(u16x8*)(q + 8) = hi;
}

// ---- bf16 MFMA GEMM: gload_lds + swizzle + 3-deep counted-vmcnt pipeline ----
struct MMArgs {
  const unsigned short* a[4];   // per-768-chunk bf16 sources (all mode-0)
  int K;
  const unsigned short* wt;     // wall + basecol, row stride KSTR
  const float* bias;
  const unsigned short* aux0;   // o1 bf16  (EP_MERGE)
  const unsigned short* aux1;   // OCK bf16 (EP_MERGE)
  const float* aux2;            // Qg f32   (EP_MERGE)
  float* outf;                  // EP_RELU_MAX
  unsigned short* outb;         // others
};

template<int EP>
__global__ __launch_bounds__(256)
void mfma_gemm_kernel(MMArgs g) {
  __shared__ __align__(16) unsigned short As[3][128 * 32];
  __shared__ __align__(16) unsigned short Bs[3][128 * 32];
  const int t = threadIdx.x;
  const int lane = t & 63, w = t >> 6;
  const int wr = w >> 1, wc = w & 1;
  const int m0 = blockIdx.x << 7, n0 = blockIdx.y << 7;  // m-fast grid
  const int l15 = lane & 15, l4 = lane >> 4;
  f32x4 acc[4][4] = {};

  const int srow = w * 32 + (lane >> 2);
  const int gcol = (((lane & 3) ^ ((lane >> 3) & 3))) * 8;   // shorts
  const int rsw = (l15 >> 1) & 3;
  const int rcol = ((l4 ^ rsw)) * 8;                          // shorts

  const int nkt = g.K >> 5;

  auto issue = [&](int kt, int buf) {
    const int c = kt / 24;
    const int koff = (kt - c * 24) << 5;
    const unsigned short* ap = g.a[c] + (size_t)(m0 + srow) * HD + koff + gcol;
    const unsigned short* bp = g.wt + (size_t)(n0 + srow) * KSTR + (kt << 5) + gcol;
    gload_lds16(ap, &As[buf][w * 1024]);
    gload_lds16(ap + (size_t)16 * HD, &As[buf][w * 1024 + 512]);
    gload_lds16(bp, &Bs[buf][w * 1024]);
    gload_lds16(bp + (size_t)16 * KSTR, &Bs[buf][w * 1024 + 512]);
  };

  auto compute = [&](int kt, int buf, bool prefetch) {
    bf16x8 af[4], bfr[4];
#pragma unroll
    for (int mi = 0; mi < 4; ++mi)
      af[mi] = *(const bf16x8*)(&As[buf][(wr * 64 + mi * 16 + l15) * 32 + rcol]);
#pragma unroll
    for (int ni = 0; ni < 4; ++ni)
      bfr[ni] = *(const bf16x8*)(&Bs[buf][(wc * 64 + ni * 16 + l15) * 32 + rcol]);
    asm volatile("s_waitcnt lgkmcnt(0)" ::: "memory");  // my frags in regs
    __builtin_amdgcn_s_barrier();                        // everyone done reading buf
    if (prefetch) issue(kt + 3, buf);                    // safe to overwrite now
    __builtin_amdgcn_s_setprio(1);
#pragma unroll
    for (int mi = 0; mi < 4; ++mi)
#pragma unroll
      for (int ni = 0; ni < 4; ++ni)
        acc[mi][ni] = __builtin_amdgcn_mfma_f32_16x16x32_bf16(af[mi], bfr[ni], acc[mi][ni], 0, 0, 0);
    __builtin_amdgcn_s_setprio(0);
  };

  issue(0, 0); issue(1, 1); issue(2, 2);
  int buf = 0;
  int kt = 0;
  for (; kt < nkt - 2; ++kt) {
    asm volatile("s_waitcnt vmcnt(8)" ::: "memory");
    __builtin_amdgcn_s_barrier();
    compute(kt, buf, kt + 3 < nkt);
    buf = (buf == 2) ? 0 : buf + 1;
  }
  asm volatile("s_waitcnt vmcnt(4)" ::: "memory");
  __builtin_amdgcn_s_barrier();
  compute(kt, buf, false);
  buf = (buf == 2) ? 0 : buf + 1;
  ++kt;
  asm volatile("s_waitcnt vmcnt(0)" ::: "memory");
  __builtin_amdgcn_s_barrier();
  compute(kt, buf, false);

  if (EP == EP_RELU_MAX) {
#pragma unroll
    for (int ni = 0; ni < 4; ++ni) {
      const int n = n0 + wc * 64 + ni * 16 + l15;
      const float b = g.bias[n];
      float m = 0.f;
#pragma unroll
      for (int mi = 0; mi < 4; ++mi)
#pragma unroll
        for (int r = 0; r < 4; ++r)
          m = fmaxf(m, acc[mi][ni][r] + b);
      m = fmaxf(m, 0.f);
      m = fmaxf(m, __shfl_xor(m, 16));
      m = fmaxf(m, __shfl_xor(m, 32));
      if (l4 == 0) g.outf[(size_t)((m0 >> 6) + wr) * HD + n] = m;
    }
  } else {
#pragma unroll
    for (int mi = 0; mi < 4; ++mi)
#pragma unroll
      for (int r = 0; r < 4; ++r) {
        const int row = m0 + wr * 64 + mi * 16 + l4 * 4 + r;
#pragma unroll
        for (int ni = 0; ni < 4; ++ni) {
          const int n = n0 + wc * 64 + ni * 16 + l15;
          const size_t oi = (size_t)row * HD + n;
          float v = acc[mi][ni][r];
          if (EP == EP_TANH) {
            g.outb[oi] = f2bf(tanhf(v + g.bias[n]));
          } else if (EP == EP_MERGE) {
            float gg = v + g.aux2[(size_t)(row >> 6) * HD + n];
            float sg = 1.f / (1.f + expf(-gg));
            float o1v = bf2f(g.aux0[oi]);
            float ock = bf2f(g.aux1[oi]);
            g.outb[oi] = f2bf(fmaf(sg, o1v - ock, ock));
          } else {  // EP_RELU
            g.outb[oi] = f2bf(fmaxf(v + g.bias[n], 0.f));
          }
        }
      }
  }
}

extern "C" void kernel_launch(void* const* d_in, const int* in_sizes, int n_in,
                              void* d_out, int out_size, void* d_ws, size_t ws_size,
                              hipStream_t stream) {
  const float* enc_o = (const float*)d_in[0];
  const float* enc_q = (const float*)d_in[1];
  const int* om = (const int*)d_in[2];
  const int* qm = (const int*)d_in[3];
  const float* att_W1_w = (const float*)d_in[4];
  const float* att_W1_b = (const float*)d_in[5];
  const float* att_W2_w = (const float*)d_in[6];
  const float* att_W2_b = (const float*)d_in[7];
  const float* att_W3 = (const float*)d_in[8];
  const float* Wc_self_w = (const float*)d_in[9];
  const float* Wc_self_b = (const float*)d_in[10];
  const float* Wc_w = (const float*)d_in[11];
  const float* Wc_b = (const float*)d_in[12];
  const float* Va_w = (const float*)d_in[13];
  const float* Va_b = (const float*)d_in[14];
  const float* Wg_w = (const float*)d_in[15];
  const float* Wg_b = (const float*)d_in[16];
  const float* co_W1_w = (const float*)d_in[17];
  const float* co_W1_b = (const float*)d_in[18];
  const float* co_W2_w = (const float*)d_in[19];
  const float* co_W2_b = (const float*)d_in[20];
  const float* co_W3 = (const float*)d_in[21];
  const float* Wp_w = (const float*)d_in[22];
  const float* Wp_b = (const float*)d_in[23];
  const float* sa_W1_w = (const float*)d_in[24];
  const float* sa_W1_b = (const float*)d_in[25];
  const float* sa_W2_w = (const float*)d_in[26];
  const float* sa_W2_b = (const float*)d_in[27];
  const float* sa_W3 = (const float*)d_in[28];
  const float* Wf_w = (const float*)d_in[29];
  const float* Wf_b = (const float*)d_in[30];
  float* out = (float*)d_out;

  const int NTOK_O = 16384;
  const int HH = 768 * 768;

  float* ws = (float*)d_ws;
  size_t off = 0;
  auto carve = [&](size_t n) { float* p = ws + off; off += n; return p; };
  float* s1o   = carve(16384);
  float* s2o   = carve(16384);
  float* qco1  = carve(32768);
  float* ms2   = carve(16384);
  float* sa1   = carve(16384);
  float* sa2   = carve(16384);
  float* biasO = carve(1024);
  float* Qpool = carve(196608);
  float* Qg    = carve(196608);
  float* A2buf = carve(2097152);   // PtG only
  float* r1 = carve(12582912);   // [-- | X1] -> [OPKb | X3]
  float* r2 = carve(12582912);   // [OCKb | X2] -> [PLOb | ..] -> opkw3
  float* r3 = carve(12582912);   // [MRGb | ..] -> [OSKb | X4]
  float* r4 = carve(12582912);   // [eobf | eow3] -> [PHIb | wall]
  if (ws_size < off * sizeof(float)) return;
  unsigned short* OPKb  = (unsigned short*)r1;
  unsigned short* X1    = (unsigned short*)(r1 + 6291456);
  unsigned short* X3    = (unsigned short*)(r1 + 6291456);
  unsigned short* OCKb  = (unsigned short*)r2;
  unsigned short* PLOb  = (unsigned short*)r2;
  unsigned short* opkw3 = (unsigned short*)r2;
  unsigned short* X2    = (unsigned short*)(r2 + 6291456);
  unsigned short* MRGb  = (unsigned short*)r3;
  unsigned short* OSKb  = (unsigned short*)r3;
  unsigned short* X4    = (unsigned short*)(r3 + 6291456);
  unsigned short* eobf  = (unsigned short*)r4;
  unsigned short* eow3  = (unsigned short*)(r4 + 6291456);   // dead after p1<3>
  unsigned short* PHIb  = (unsigned short*)r4;
  unsigned short* wall  = (unsigned short*)(r4 + 6291456);   // 768*9216 bf16 = 14.2 MB
  unsigned short* PtG   = (unsigned short*)A2buf;

  const dim3 GBIG(128, 6);  // m-fast

  // 1. fused enc_o prep + fused qpool (qa/qco1 dots inside)
  bfprep_dot_kernel<<<NTOK_O / 4, 256, 0, stream>>>(enc_o, att_W3, att_W1_w, att_W1_b,
                                                    att_W2_w, att_W2_b, eobf, eow3,
                                                    s1o, s2o, NTOK_O);
  qpool2_kernel<<<256, 256, 0, stream>>>(enc_q, Va_w, Va_b, co_W1_w, co_W1_b,
                                         qm, qco1, Qpool);
  bias_ock_kernel<<<3, 256, 0, stream>>>(Wc_self_b, Wc_b, biasO);

  // 2. p1<3> (uses eow3), then wconv_all (overwrites eow3 region), then p2<3>
  p1_kernel<3><<<768, 256, 0, stream>>>(eobf, eow3, s1o, s2o, om, PtG);
  {
    WcAllArgs wa{};
    wa.src[0] = Wc_self_w; wa.src[1] = Wc_w;        wa.src[2] = Wc_w + HH;
    wa.src[3] = Wg_w;      wa.src[4] = Wg_w + HH;
    wa.src[5] = Wp_w;      wa.src[6] = Wp_w + HH;   wa.src[7] = Wp_w + 2 * HH;
    wa.src[8] = Wf_w;      wa.src[9] = Wf_w + HH;   wa.src[10] = Wf_w + 2 * HH;
    wa.src[11] = Wf_w + 3 * HH;
    int bases[12] = {0, 768, 1536, 2304, 3072, 3840, 4608, 5376, 6144, 6912, 7680, 8448};
    for (int i = 0; i < 12; ++i) wa.basecol[i] = bases[i];
    wa.dst = wall;
    wconv_all_kernel<<<dim3(144, 12), 256, 0, stream>>>(wa);
  }
  p2_kernel<3><<<dim3(4, 256), 256, 0, stream>>>(eobf, PtG, eobf, nullptr, X1, X2);

  // 3. OCK = tanh([o1 | 3o1-CS | o1*CS] @ Wc + bias)
  {
    MMArgs g{};
    g.a[0] = eobf; g.a[1] = X1; g.a[2] = X2;
    g.K = 2304; g.wt = wall + 0; g.bias = biasO; g.outb = OCKb;
    mfma_gemm_kernel<EP_TANH><<<GBIG, 256, 0, stream>>>(g);
  }

  // 4. Qg (f32)
  {
    GemmArgs g{};
    g.a[0] = Qpool; g.w[0] = Wg_w + 2 * HH;
    g.nchunks = 1; g.bias = Wg_b; g.out = Qg;
    gemm_store_kernel<<<dim3(12, 4), 256, 0, stream>>>(g);
  }

  // 5. merged = G*o1 + (1-G)*OCK
  {
    MMArgs g{};
    g.a[0] = eobf; g.a[1] = OCKb;
    g.K = 1536; g.wt = wall + 2304; g.bias = nullptr;
    g.aux0 = eobf; g.aux1 = OCKb; g.aux2 = Qg; g.outb = MRGb;
    mfma_gemm_kernel<EP_MERGE><<<GBIG, 256, 0, stream>>>(g);
  }

  // 6. co-attention: ms2 -> poaa2 (A2 fused)
  dot768_bf16<<<NTOK_O / 4, 256, 0, stream>>>(MRGb, co_W2_w, co_W2_b, ms2, NTOK_O);
  poaa2_kernel<<<dim3(2, 256), 256, 0, stream>>>(enc_q, MRGb, qco1, ms2, qm, om,
                                                 co_W3, PLOb, PHIb);

  // 7. OPK = relu([merged | PLO | PHI] @ Wp + b)
  {
    MMArgs g{};
    g.a[0] = MRGb; g.a[1] = PLOb; g.a[2] = PHIb;
    g.K = 2304; g.wt = wall + 3840; g.bias = Wp_b; g.outb = OPKb;
    mfma_gemm_kernel<EP_RELU><<<GBIG, 256, 0, stream>>>(g);
  }

  // 8. self-attention
  opkprep_kernel<<<NTOK_O / 4, 256, 0, stream>>>(OPKb, sa_W3, sa_W1_w, sa_W1_b,
                                                 sa_W2_w, sa_W2_b, opkw3, sa1, sa2, NTOK_O);
  p1_kernel<1><<<256, 256, 0, stream>>>(OPKb, opkw3, sa1, sa2, om, PtG);
  p2_kernel<1><<<dim3(4, 256), 256, 0, stream>>>(OPKb, PtG, OPKb, OSKb, X3, X4);

  // 9. out = max_lo relu([OPK | OSK | OPK-OSK | OPK*OSK] @ Wf + b)
  {
    MMArgs g{};
    g.a[0] = OPKb; g.a[1] = OSKb; g.a[2] = X3; g.a[3] = X4;
    g.K = 3072; g.wt = wall + 6144; g.bias = Wf_b; g.outf = out;
    mfma_gemm_kernel<EP_RELU_MAX><<<GBIG, 256, 0, stream>>>(g);
  }
}